// Round 1
// baseline (2877.104 us; speedup 1.0000x reference)
//
#include <hip/hip_runtime.h>

#define EPS_BN 1e-5f

// ---------------- elementwise / setup kernels ----------------

__global__ void k_fill(float* __restrict__ p, float v, int n) {
  int i = blockIdx.x * blockDim.x + threadIdx.x;
  if (i < n) p[i] = v;
}

__global__ void k_edge_deg(const int* __restrict__ dst, float* __restrict__ deg, int E) {
  int e = blockIdx.x * blockDim.x + threadIdx.x;
  if (e < E) atomicAdd(&deg[dst[e]], 1.0f);
}

__global__ void k_dinv(float* __restrict__ d, int n) {
  int i = blockIdx.x * blockDim.x + threadIdx.x;
  if (i < n) {
    float v = d[i];
    d[i] = v > 0.f ? rsqrtf(fmaxf(v, 1e-12f)) : 0.f;
  }
}

// out[n,c] = dinv[n]^2 * H[n,c]   (GCN self-loop term, initializes agg buffer)
__global__ void k_self_init(const float* __restrict__ dinv, const float* __restrict__ H,
                            float* __restrict__ out, int n, int cshift) {
  int i = blockIdx.x * blockDim.x + threadIdx.x;
  int tot = n << cshift;
  if (i < tot) {
    float dv = dinv[i >> cshift];
    out[i] = dv * dv * H[i];
  }
}

// out[dst,c] += dinv[src]*dinv[dst] * H[src,c]   (ew == 1 at level 1)
__global__ void k_edge_agg(const int* __restrict__ src, const int* __restrict__ dst,
                           const float* __restrict__ dinv, const float* __restrict__ H,
                           float* __restrict__ out, int E, int cshift) {
  int i = blockIdx.x * blockDim.x + threadIdx.x;
  int e = i >> cshift;
  if (e >= E) return;
  int c = i & ((1 << cshift) - 1);
  int s = src[e], d = dst[e];
  float coef = dinv[s] * dinv[d];
  atomicAdd(&out[((size_t)d << cshift) + c], coef * H[((size_t)s << cshift) + c]);
}

// T[src,c] += S[dst,c]   (t = A S with ew == 1)
__global__ void k_scatter_as(const int* __restrict__ src, const int* __restrict__ dst,
                             const float* __restrict__ S, float* __restrict__ T,
                             int E, int cshift) {
  int i = blockIdx.x * blockDim.x + threadIdx.x;
  int e = i >> cshift;
  if (e >= E) return;
  int c = i & ((1 << cshift) - 1);
  int s = src[e], d = dst[e];
  atomicAdd(&T[((size_t)s << cshift) + c], S[((size_t)d << cshift) + c]);
}

// ---------------- GEMM kernels (fp32, simple 64x64 tiles) ----------------
// C[M,N] = A[M,K] @ B[K,N].  Requires N%64==0, K%16==0.  M guarded.
__global__ __launch_bounds__(256) void k_sgemm_nn(
    const float* __restrict__ A, const float* __restrict__ B, float* __restrict__ C,
    int M, int N, int K) {
  __shared__ float As[16][64];
  __shared__ float Bs[16][68];
  int t = threadIdx.x;
  int tx = t & 15, ty = t >> 4;
  int row0 = blockIdx.y * 64, col0 = blockIdx.x * 64;
  float acc[4][4] = {};
  for (int k0 = 0; k0 < K; k0 += 16) {
    int ar = t >> 2;             // 0..63
    int ak = (t & 3) * 4;        // 0,4,8,12
    float4 av = make_float4(0.f, 0.f, 0.f, 0.f);
    if (row0 + ar < M) av = *(const float4*)(A + (size_t)(row0 + ar) * K + k0 + ak);
    As[ak + 0][ar] = av.x; As[ak + 1][ar] = av.y;
    As[ak + 2][ar] = av.z; As[ak + 3][ar] = av.w;
    int bk = t >> 4;             // 0..15
    int bc = (t & 15) * 4;
    float4 bv = *(const float4*)(B + (size_t)(k0 + bk) * N + col0 + bc);
    *(float4*)&Bs[bk][bc] = bv;
    __syncthreads();
#pragma unroll
    for (int k = 0; k < 16; ++k) {
      float a[4], b[4];
#pragma unroll
      for (int u = 0; u < 4; ++u) a[u] = As[k][ty * 4 + u];
#pragma unroll
      for (int v = 0; v < 4; ++v) b[v] = Bs[k][tx * 4 + v];
#pragma unroll
      for (int u = 0; u < 4; ++u)
#pragma unroll
        for (int v = 0; v < 4; ++v) acc[u][v] += a[u] * b[v];
    }
    __syncthreads();
  }
#pragma unroll
  for (int u = 0; u < 4; ++u) {
    int r = row0 + ty * 4 + u;
    if (r < M) {
#pragma unroll
      for (int v = 0; v < 4; ++v) C[(size_t)r * N + col0 + tx * 4 + v] = acc[u][v];
    }
  }
}

// C[I,J] += A[M,I]^T @ B[M,J] over rows [z*chunk, z*chunk+chunk).  I%64==0, J%64==0.
// C must be zeroed first (atomic accumulation across z-chunks).
__global__ __launch_bounds__(256) void k_sgemm_tn(
    const float* __restrict__ A, const float* __restrict__ B, float* __restrict__ C,
    int M, int I, int J, int mChunk) {
  __shared__ float As[16][68];
  __shared__ float Bs[16][68];
  int t = threadIdx.x;
  int tx = t & 15, ty = t >> 4;
  int i0 = blockIdx.y * 64, j0 = blockIdx.x * 64;
  int m0 = blockIdx.z * mChunk;
  int m1 = min(m0 + mChunk, M);
  float acc[4][4] = {};
  for (int mb = m0; mb < m1; mb += 16) {
    int mr = t >> 4;            // 0..15
    int cc = (t & 15) * 4;      // 0..60
    int m = mb + mr;
    float4 av = make_float4(0.f, 0.f, 0.f, 0.f);
    float4 bv = make_float4(0.f, 0.f, 0.f, 0.f);
    if (m < m1) {
      av = *(const float4*)(A + (size_t)m * I + i0 + cc);
      bv = *(const float4*)(B + (size_t)m * J + j0 + cc);
    }
    *(float4*)&As[mr][cc] = av;
    *(float4*)&Bs[mr][cc] = bv;
    __syncthreads();
#pragma unroll
    for (int k = 0; k < 16; ++k) {
      float a[4], b[4];
#pragma unroll
      for (int u = 0; u < 4; ++u) a[u] = As[k][ty * 4 + u];
#pragma unroll
      for (int v = 0; v < 4; ++v) b[v] = Bs[k][tx * 4 + v];
#pragma unroll
      for (int u = 0; u < 4; ++u)
#pragma unroll
        for (int v = 0; v < 4; ++v) acc[u][v] += a[u] * b[v];
    }
    __syncthreads();
  }
#pragma unroll
  for (int u = 0; u < 4; ++u)
#pragma unroll
    for (int v = 0; v < 4; ++v)
      atomicAdd(&C[(size_t)(i0 + ty * 4 + u) * J + j0 + tx * 4 + v], acc[u][v]);
}

// ---------------- BN / softmax / reductions ----------------

__global__ void k_col_stats(const float* __restrict__ X, const float* __restrict__ bias,
                            float* __restrict__ cs, float* __restrict__ csq,
                            int M, int C, int rpb) {
  int c = threadIdx.x;
  if (c >= C) return;
  int r0 = blockIdx.x * rpb, r1 = min(r0 + rpb, M);
  float b = bias[c];
  float s = 0.f, sq = 0.f;
  for (int r = r0; r < r1; ++r) {
    float v = X[(size_t)r * C + c] + b;
    s += v; sq += v * v;
  }
  atomicAdd(&cs[c], s);
  atomicAdd(&csq[c], sq);
}

__global__ void k_bn_silu(const float* __restrict__ X, const float* __restrict__ bias,
                          const float* __restrict__ cs, const float* __restrict__ csq,
                          const float* __restrict__ g, const float* __restrict__ be,
                          const float* __restrict__ resid, float* __restrict__ out,
                          int tot, int cmask, float invM) {
  int i = blockIdx.x * blockDim.x + threadIdx.x;
  if (i >= tot) return;
  int c = i & cmask;
  float m = cs[c] * invM;
  float var = csq[c] * invM - m * m;
  float v = (X[i] + bias[c] - m) * rsqrtf(var + EPS_BN) * g[c] + be[c];
  float y = v / (1.f + expf(-v));      // SiLU
  if (resid) y += resid[i];
  out[i] = y;
}

template <int C>
__global__ void k_softmax_ent(float* __restrict__ X, float* __restrict__ entAcc) {
  __shared__ float sh[C];
  int r = blockIdx.x, c = threadIdx.x;
  size_t base = (size_t)r * C;
  float v = X[base + c];
  sh[c] = v; __syncthreads();
  for (int o = C / 2; o > 0; o >>= 1) { if (c < o) sh[c] = fmaxf(sh[c], sh[c + o]); __syncthreads(); }
  float mx = sh[0]; __syncthreads();
  float e = expf(v - mx);
  sh[c] = e; __syncthreads();
  for (int o = C / 2; o > 0; o >>= 1) { if (c < o) sh[c] += sh[c + o]; __syncthreads(); }
  float p = e / sh[0];
  X[base + c] = p;
  __syncthreads();
  sh[c] = -p * logf(p + 1e-15f);
  __syncthreads();
  for (int o = C / 2; o > 0; o >>= 1) { if (c < o) sh[c] += sh[c + o]; __syncthreads(); }
  if (c == 0) atomicAdd(entAcc, sh[0]);
}

__global__ void k_trace(const float* __restrict__ A, int K, float* __restrict__ out) {
  __shared__ float sh[256];
  int t = threadIdx.x;
  float s = 0.f;
  for (int i = t; i < K; i += 256) s += A[(size_t)i * K + i];
  sh[t] = s; __syncthreads();
  for (int o = 128; o > 0; o >>= 1) { if (t < o) sh[t] += sh[t + o]; __syncthreads(); }
  if (t == 0) *out = sh[0];
}

__global__ void k_sumsq(const float* __restrict__ A, int n, float* __restrict__ out) {
  __shared__ float sh[256];
  int t = threadIdx.x;
  float s = 0.f;
  for (int i = blockIdx.x * 256 + t; i < n; i += gridDim.x * 256) { float v = A[i]; s += v * v; }
  sh[t] = s; __syncthreads();
  for (int o = 128; o > 0; o >>= 1) { if (t < o) sh[t] += sh[t + o]; __syncthreads(); }
  if (t == 0) atomicAdd(out, sh[0]);
}

// ---------------- level-2 dense graph ----------------

// dinv2[q] = rsqrt(1 + sum_p Ap[p,q])
__global__ void k_deg2(const float* __restrict__ Ap, float* __restrict__ dinv2, int Np) {
  int q = blockIdx.x * blockDim.x + threadIdx.x;
  if (q >= Np) return;
  float d = 1.0f;
  for (int p = 0; p < Np; ++p) d += Ap[(size_t)p * Np + q];
  dinv2[q] = d > 0.f ? rsqrtf(fmaxf(d, 1e-12f)) : 0.f;
}

// out[q,c] = dq * sum_p dinv2[p]*Ap[p,q]*H[p,c]  +  dq^2 * H[q,c]
__global__ void k_dense_agg(const float* __restrict__ Ap, const float* __restrict__ dinv2,
                            const float* __restrict__ H, float* __restrict__ out,
                            int Np, int C) {
  int q = blockIdx.x, c = threadIdx.x;
  float acc = 0.f;
  for (int p = 0; p < Np; ++p)
    acc += dinv2[p] * Ap[(size_t)p * Np + q] * H[(size_t)p * C + c];
  float dq = dinv2[q];
  out[(size_t)q * C + c] = dq * acc + dq * dq * H[(size_t)q * C + c];
}

// ---------------- final head ----------------
// scal: [0]=ent1_sum [1]=ent2_sum [2]=cross1 [3]=||sts1||^2 [4]=||apool||^2 [5]=cross2 [6]=||sts2||^2
__global__ void k_final(const float* __restrict__ xp2, const float* __restrict__ Wlin,
                        const float* __restrict__ blin, const float* __restrict__ scal,
                        float* __restrict__ out, int N1, int E1, int K1, int K2, int OUT) {
  __shared__ float pooled[128];
  __shared__ float logits[32];
  int t = threadIdx.x;   // 128 threads
  float s = 0.f;
  for (int r = 0; r < K2; ++r) s += xp2[(size_t)r * 128 + t];
  pooled[t] = s / (float)K2;
  __syncthreads();
  if (t < OUT) {
    float acc = blin[t];
    for (int k = 0; k < 128; ++k) acc += pooled[k] * Wlin[(size_t)k * OUT + t];
    logits[t] = acc;
  }
  __syncthreads();
  if (t == 0) {
    float mx = logits[0];
    for (int j = 1; j < OUT; ++j) mx = fmaxf(mx, logits[j]);
    float se = 0.f;
    for (int j = 0; j < OUT; ++j) se += expf(logits[j] - mx);
    float lse = mx + logf(se);
    for (int j = 0; j < OUT; ++j) out[j] = logits[j] - lse;
    float n1 = (float)N1;
    float ent1 = scal[0] / n1;
    float ent2 = scal[1] / (float)K1;
    float link1 = sqrtf(fmaxf((float)E1 - 2.f * scal[2] + scal[3], 0.f)) / (n1 * n1);
    float link2 = sqrtf(fmaxf(scal[4] - 2.f * scal[5] + scal[6], 0.f)) / ((float)K1 * (float)K1);
    out[OUT] = ent1 + ent2 + link1 + link2;
  }
}

// ---------------- host ----------------

extern "C" void kernel_launch(void* const* d_in, const int* in_sizes, int n_in,
                              void* d_out, int out_size, void* d_ws, size_t ws_size,
                              hipStream_t stream) {
  (void)n_in; (void)out_size; (void)ws_size;
  const float* x = (const float*)d_in[0];
  const int* ei  = (const int*)d_in[1];
  const int N = in_sizes[0] / 128;   // 20000
  const int E = in_sizes[1] / 2;     // 640000
  const int* src = ei;
  const int* dst = ei + E;
  const float *W1a=(const float*)d_in[4],  *b1a=(const float*)d_in[5],
              *g1a=(const float*)d_in[6],  *be1a=(const float*)d_in[7];
  const float *W1b=(const float*)d_in[8],  *b1b=(const float*)d_in[9],
              *g1b=(const float*)d_in[10], *be1b=(const float*)d_in[11];
  const float *Wp1=(const float*)d_in[12], *bp1=(const float*)d_in[13],
              *gp1=(const float*)d_in[14], *bep1=(const float*)d_in[15];
  const float *W2a=(const float*)d_in[16], *b2a=(const float*)d_in[17],
              *g2a=(const float*)d_in[18], *be2a=(const float*)d_in[19];
  const float *W2b=(const float*)d_in[20], *b2b=(const float*)d_in[21],
              *g2b=(const float*)d_in[22], *be2b=(const float*)d_in[23];
  const float *Wp2=(const float*)d_in[24], *bp2=(const float*)d_in[25],
              *gp2=(const float*)d_in[26], *bep2=(const float*)d_in[27];
  const float *Wlin=(const float*)d_in[28], *blin=(const float*)d_in[29];
  const int K1 = in_sizes[12] / 128;   // 256
  const int K2 = in_sizes[24] / 128;   // 64
  const int OUT = in_sizes[29];        // 10

  // bump allocator over d_ws
  char* base = (char*)d_ws;
  size_t off = 0;
  auto alloc = [&](size_t nf) -> float* {
    float* p = (float*)(base + off);
    off += ((nf * sizeof(float) + 255) & ~(size_t)255);
    return p;
  };
  float* scal  = alloc(16);
  float* cs    = alloc(256);
  float* csq   = alloc(256);
  float* dinv  = alloc(N);
  float* dinv2 = alloc(K1);
  float* apool = alloc((size_t)K1 * K1);
  float* sts   = alloc((size_t)K1 * K1);
  float* xp    = alloc((size_t)K1 * 128);
  float* h2    = alloc((size_t)K1 * 128);
  float* y2    = alloc((size_t)K1 * 128);
  float* xa2   = alloc((size_t)K1 * 128);
  float* x2f   = alloc((size_t)K1 * 128);
  float* s2b   = alloc((size_t)K1 * K2);
  float* t2    = alloc((size_t)K1 * K2);
  float* a2    = alloc((size_t)K2 * K2);
  float* sts2  = alloc((size_t)K2 * K2);
  float* xp2   = alloc((size_t)K2 * 128);
  float* R1 = alloc((size_t)N * 128);   // block-A output
  float* R2 = alloc((size_t)N * 128);   // residual output (level-1 x)
  float* R3 = alloc((size_t)N * K1);    // GEMM output H / later t = A S
  float* R4 = alloc((size_t)N * K1);    // aggregation / S

  auto cdiv = [](long long a, long long b) { return (int)((a + b - 1) / b); };

  hipMemsetAsync(scal, 0, 16 * sizeof(float), stream);

  // degree -> dinv (level 1, ew = 1, self loop +1)
  k_fill<<<cdiv(N, 256), 256, 0, stream>>>(dinv, 1.f, N);
  k_edge_deg<<<cdiv(E, 256), 256, 0, stream>>>(dst, dinv, E);
  k_dinv<<<cdiv(N, 256), 256, 0, stream>>>(dinv, N);

  auto gemm_nn = [&](const float* A, const float* B, float* C, int M, int Nn, int K) {
    dim3 g(Nn / 64, cdiv(M, 64));
    k_sgemm_nn<<<g, 256, 0, stream>>>(A, B, C, M, Nn, K);
  };
  auto gemm_tn = [&](const float* A, const float* B, float* C, int M, int I, int J, int nz) {
    hipMemsetAsync(C, 0, (size_t)I * J * sizeof(float), stream);
    int chunk = cdiv(M, nz);
    chunk = (chunk + 15) & ~15;
    int zz = cdiv(M, chunk);
    dim3 g(J / 64, I / 64, zz);
    k_sgemm_tn<<<g, 256, 0, stream>>>(A, B, C, M, I, J, chunk);
  };

  // level-1 ResidualBlock: GCN(W) -> BN -> SiLU (+resid)
  auto block1 = [&](const float* xin, const float* W, const float* b, const float* gg,
                    const float* be, const float* resid, float* outp, int C, int cshift) {
    gemm_nn(xin, W, R3, N, C, 128);
    int tot = N << cshift;
    k_self_init<<<cdiv(tot, 256), 256, 0, stream>>>(dinv, R3, R4, N, cshift);
    long long te = (long long)E << cshift;
    k_edge_agg<<<cdiv(te, 256), 256, 0, stream>>>(src, dst, dinv, R3, R4, E, cshift);
    hipMemsetAsync(cs, 0, C * sizeof(float), stream);
    hipMemsetAsync(csq, 0, C * sizeof(float), stream);
    k_col_stats<<<cdiv(N, 128), C, 0, stream>>>(R4, b, cs, csq, N, C, 128);
    k_bn_silu<<<cdiv(tot, 256), 256, 0, stream>>>(R4, b, cs, csq, gg, be, resid, outp,
                                                  tot, C - 1, 1.f / N);
  };

  block1(x,  W1a, b1a, g1a, be1a, nullptr, R1, 128, 7);
  block1(R1, W1b, b1b, g1b, be1b, R1,      R2, 128, 7);   // level-1 x = R2
  block1(R2, Wp1, bp1, gp1, bep1, nullptr, R4, K1, 8);    // pooling features (in-place in R4)
  k_softmax_ent<256><<<N, 256, 0, stream>>>(R4, &scal[0]);  // S = R4, ent1 sum

  // t = A S  (scatter by src), then pooled products
  hipMemsetAsync(R3, 0, (size_t)N * K1 * sizeof(float), stream);
  k_scatter_as<<<cdiv((long long)E * K1, 256), 256, 0, stream>>>(src, dst, R4, R3, E, 8);

  gemm_tn(R4, R3, apool, N, K1, K1, 64);   // a_pool = S^T (A S)
  gemm_tn(R4, R4, sts,   N, K1, K1, 64);   // sts = S^T S
  gemm_tn(R4, R2, xp,    N, K1, 128, 64);  // xp = S^T x
  k_trace<<<1, 256, 0, stream>>>(apool, K1, &scal[2]);
  k_sumsq<<<64, 256, 0, stream>>>(sts, K1 * K1, &scal[3]);
  k_sumsq<<<64, 256, 0, stream>>>(apool, K1 * K1, &scal[4]);  // sum(ew2^2) for level 2

  // ---------------- level 2 (dense 256-node graph, ew = apool) ----------------
  k_deg2<<<1, 256, 0, stream>>>(apool, dinv2, K1);

  auto block2 = [&](const float* xin, const float* W, const float* b, const float* gg,
                    const float* be, const float* resid, float* outp, int C) {
    gemm_nn(xin, W, h2, K1, C, 128);
    k_dense_agg<<<K1, C, 0, stream>>>(apool, dinv2, h2, y2, K1, C);
    hipMemsetAsync(cs, 0, C * sizeof(float), stream);
    hipMemsetAsync(csq, 0, C * sizeof(float), stream);
    k_col_stats<<<cdiv(K1, 128), C, 0, stream>>>(y2, b, cs, csq, K1, C, 128);
    k_bn_silu<<<cdiv(K1 * C, 256), 256, 0, stream>>>(y2, b, cs, csq, gg, be, resid, outp,
                                                     K1 * C, C - 1, 1.f / K1);
  };

  block2(xp,  W2a, b2a, g2a, be2a, nullptr, xa2, 128);
  block2(xa2, W2b, b2b, g2b, be2b, xa2,     x2f, 128);   // level-2 x = x2f
  block2(x2f, Wp2, bp2, gp2, bep2, nullptr, s2b, K2);
  k_softmax_ent<64><<<K1, 64, 0, stream>>>(s2b, &scal[1]);  // s2 = s2b, ent2 sum

  gemm_nn(apool, s2b, t2, K1, K2, K1);      // t2 = Apool @ s2
  gemm_tn(s2b, t2,  a2,   K1, K2, K2, 1);   // a2 = s2^T t2
  gemm_tn(s2b, s2b, sts2, K1, K2, K2, 1);   // sts2 = s2^T s2
  gemm_tn(s2b, x2f, xp2,  K1, K2, 128, 1);  // xp2 = s2^T x2f
  k_trace<<<1, 256, 0, stream>>>(a2, K2, &scal[5]);
  k_sumsq<<<16, 256, 0, stream>>>(sts2, K2 * K2, &scal[6]);

  k_final<<<1, 128, 0, stream>>>(xp2, Wlin, blin, scal, (float*)d_out, N, E, K1, K2, OUT);
}

// Round 2
// 1776.363 us; speedup vs baseline: 1.6197x; 1.6197x over previous
//
#include <hip/hip_runtime.h>

#define EPS_BN 1e-5f

// ---------------- CSR build ----------------

__global__ void k_hist(const int* __restrict__ idx, int* __restrict__ cnt, int E) {
  int e = blockIdx.x * blockDim.x + threadIdx.x;
  if (e < E) atomicAdd(&cnt[idx[e]], 1);
}

__global__ __launch_bounds__(1024) void k_scan(
    const int* __restrict__ cnt, int* __restrict__ rowptr, int* __restrict__ cursor,
    int N, int E) {
  __shared__ int sh[1024];
  int t = threadIdx.x;
  int chunk = (N + 1023) / 1024;
  int i0 = t * chunk, i1 = min(i0 + chunk, N);
  int s = 0;
  for (int i = i0; i < i1; ++i) s += cnt[i];
  sh[t] = s; __syncthreads();
  for (int o = 1; o < 1024; o <<= 1) {
    int v = (t >= o) ? sh[t - o] : 0;
    __syncthreads();
    sh[t] += v;
    __syncthreads();
  }
  int run = (t == 0) ? 0 : sh[t - 1];
  for (int i = i0; i < i1; ++i) { rowptr[i] = run; cursor[i] = run; run += cnt[i]; }
  if (t == 1023) rowptr[N] = E;
}

__global__ void k_fill_csr(const int* __restrict__ key, const int* __restrict__ val,
                           int* __restrict__ cursor, int* __restrict__ col, int E) {
  int e = blockIdx.x * blockDim.x + threadIdx.x;
  if (e < E) {
    int pos = atomicAdd(&cursor[key[e]], 1);
    col[pos] = val[e];
  }
}

// dinv[i] = rsqrt(1 + indegree)   (level-1 ew==1, self-loop +1)
__global__ void k_dinv_cnt(const int* __restrict__ cnt, float* __restrict__ dinv, int n) {
  int i = blockIdx.x * blockDim.x + threadIdx.x;
  if (i < n) dinv[i] = rsqrtf(1.0f + (float)cnt[i]);
}

// ---------------- gather aggregation (no atomics) ----------------

// out[d,c] = dinv[d] * sum_{e: dst=d} dinv[src_e] * H[src_e,c] + dinv[d]^2 * H[d,c]
__global__ void k_gather_agg(const int* __restrict__ rowptr, const int* __restrict__ col,
                             const float* __restrict__ dinv, const float* __restrict__ H,
                             float* __restrict__ out, int C) {
  int d = blockIdx.x;
  int c = threadIdx.x;
  int b = rowptr[d], e = rowptr[d + 1];
  float acc = 0.f;
  for (int i = b; i < e; ++i) {
    int s = col[i];
    acc += dinv[s] * H[(size_t)s * C + c];
  }
  float dd = dinv[d];
  out[(size_t)d * C + c] = dd * acc + dd * dd * H[(size_t)d * C + c];
}

// T[s,j] = sum_{e: src=s} S[dst_e, j]     (t = A S, ew == 1)
__global__ void k_gather_T(const int* __restrict__ rowptr, const int* __restrict__ col,
                           const float* __restrict__ S, float* __restrict__ T, int C) {
  int s = blockIdx.x;
  int j = threadIdx.x;
  int b = rowptr[s], e = rowptr[s + 1];
  float acc = 0.f;
  for (int i = b; i < e; ++i) {
    int d = col[i];
    acc += S[(size_t)d * C + j];
  }
  T[(size_t)s * C + j] = acc;
}

// ---------------- GEMM kernels (fp32, simple 64x64 tiles) ----------------
// C[M,N] = A[M,K] @ B[K,N].  Requires N%64==0, K%16==0.  M guarded.
__global__ __launch_bounds__(256) void k_sgemm_nn(
    const float* __restrict__ A, const float* __restrict__ B, float* __restrict__ C,
    int M, int N, int K) {
  __shared__ float As[16][64];
  __shared__ float Bs[16][68];
  int t = threadIdx.x;
  int tx = t & 15, ty = t >> 4;
  int row0 = blockIdx.y * 64, col0 = blockIdx.x * 64;
  float acc[4][4] = {};
  for (int k0 = 0; k0 < K; k0 += 16) {
    int ar = t >> 2;
    int ak = (t & 3) * 4;
    float4 av = make_float4(0.f, 0.f, 0.f, 0.f);
    if (row0 + ar < M) av = *(const float4*)(A + (size_t)(row0 + ar) * K + k0 + ak);
    As[ak + 0][ar] = av.x; As[ak + 1][ar] = av.y;
    As[ak + 2][ar] = av.z; As[ak + 3][ar] = av.w;
    int bk = t >> 4;
    int bc = (t & 15) * 4;
    float4 bv = *(const float4*)(B + (size_t)(k0 + bk) * N + col0 + bc);
    *(float4*)&Bs[bk][bc] = bv;
    __syncthreads();
#pragma unroll
    for (int k = 0; k < 16; ++k) {
      float a[4], b[4];
#pragma unroll
      for (int u = 0; u < 4; ++u) a[u] = As[k][ty * 4 + u];
#pragma unroll
      for (int v = 0; v < 4; ++v) b[v] = Bs[k][tx * 4 + v];
#pragma unroll
      for (int u = 0; u < 4; ++u)
#pragma unroll
        for (int v = 0; v < 4; ++v) acc[u][v] += a[u] * b[v];
    }
    __syncthreads();
  }
#pragma unroll
  for (int u = 0; u < 4; ++u) {
    int r = row0 + ty * 4 + u;
    if (r < M) {
#pragma unroll
      for (int v = 0; v < 4; ++v) C[(size_t)r * N + col0 + tx * 4 + v] = acc[u][v];
    }
  }
}

// C[I,J] += A[M,I]^T @ B[M,J] over rows [z*chunk, z*chunk+chunk).  I%64==0, J%64==0.
// C must be zeroed first (atomic accumulation across z-chunks).
__global__ __launch_bounds__(256) void k_sgemm_tn(
    const float* __restrict__ A, const float* __restrict__ B, float* __restrict__ C,
    int M, int I, int J, int mChunk) {
  __shared__ float As[16][68];
  __shared__ float Bs[16][68];
  int t = threadIdx.x;
  int tx = t & 15, ty = t >> 4;
  int i0 = blockIdx.y * 64, j0 = blockIdx.x * 64;
  int m0 = blockIdx.z * mChunk;
  int m1 = min(m0 + mChunk, M);
  float acc[4][4] = {};
  for (int mb = m0; mb < m1; mb += 16) {
    int mr = t >> 4;
    int cc = (t & 15) * 4;
    int m = mb + mr;
    float4 av = make_float4(0.f, 0.f, 0.f, 0.f);
    float4 bv = make_float4(0.f, 0.f, 0.f, 0.f);
    if (m < m1) {
      av = *(const float4*)(A + (size_t)m * I + i0 + cc);
      bv = *(const float4*)(B + (size_t)m * J + j0 + cc);
    }
    *(float4*)&As[mr][cc] = av;
    *(float4*)&Bs[mr][cc] = bv;
    __syncthreads();
#pragma unroll
    for (int k = 0; k < 16; ++k) {
      float a[4], b[4];
#pragma unroll
      for (int u = 0; u < 4; ++u) a[u] = As[k][ty * 4 + u];
#pragma unroll
      for (int v = 0; v < 4; ++v) b[v] = Bs[k][tx * 4 + v];
#pragma unroll
      for (int u = 0; u < 4; ++u)
#pragma unroll
        for (int v = 0; v < 4; ++v) acc[u][v] += a[u] * b[v];
    }
    __syncthreads();
  }
#pragma unroll
  for (int u = 0; u < 4; ++u)
#pragma unroll
    for (int v = 0; v < 4; ++v)
      atomicAdd(&C[(size_t)(i0 + ty * 4 + u) * J + j0 + tx * 4 + v], acc[u][v]);
}

// ---------------- BN / softmax / reductions ----------------

__global__ void k_col_stats(const float* __restrict__ X, const float* __restrict__ bias,
                            float* __restrict__ cs, float* __restrict__ csq,
                            int M, int C, int rpb) {
  int c = threadIdx.x;
  if (c >= C) return;
  int r0 = blockIdx.x * rpb, r1 = min(r0 + rpb, M);
  float b = bias[c];
  float s = 0.f, sq = 0.f;
  for (int r = r0; r < r1; ++r) {
    float v = X[(size_t)r * C + c] + b;
    s += v; sq += v * v;
  }
  atomicAdd(&cs[c], s);
  atomicAdd(&csq[c], sq);
}

__global__ void k_bn_silu(const float* __restrict__ X, const float* __restrict__ bias,
                          const float* __restrict__ cs, const float* __restrict__ csq,
                          const float* __restrict__ g, const float* __restrict__ be,
                          const float* __restrict__ resid, float* __restrict__ out,
                          int tot, int cmask, float invM) {
  int i = blockIdx.x * blockDim.x + threadIdx.x;
  if (i >= tot) return;
  int c = i & cmask;
  float m = cs[c] * invM;
  float var = csq[c] * invM - m * m;
  float v = (X[i] + bias[c] - m) * rsqrtf(var + EPS_BN) * g[c] + be[c];
  float y = v / (1.f + expf(-v));
  if (resid) y += resid[i];
  out[i] = y;
}

template <int C>
__global__ void k_softmax_ent(float* __restrict__ X, float* __restrict__ entAcc) {
  __shared__ float sh[C];
  int r = blockIdx.x, c = threadIdx.x;
  size_t base = (size_t)r * C;
  float v = X[base + c];
  sh[c] = v; __syncthreads();
  for (int o = C / 2; o > 0; o >>= 1) { if (c < o) sh[c] = fmaxf(sh[c], sh[c + o]); __syncthreads(); }
  float mx = sh[0]; __syncthreads();
  float e = expf(v - mx);
  sh[c] = e; __syncthreads();
  for (int o = C / 2; o > 0; o >>= 1) { if (c < o) sh[c] += sh[c + o]; __syncthreads(); }
  float p = e / sh[0];
  X[base + c] = p;
  __syncthreads();
  sh[c] = -p * logf(p + 1e-15f);
  __syncthreads();
  for (int o = C / 2; o > 0; o >>= 1) { if (c < o) sh[c] += sh[c + o]; __syncthreads(); }
  if (c == 0) atomicAdd(entAcc, sh[0]);
}

__global__ void k_trace(const float* __restrict__ A, int K, float* __restrict__ out) {
  __shared__ float sh[256];
  int t = threadIdx.x;
  float s = 0.f;
  for (int i = t; i < K; i += 256) s += A[(size_t)i * K + i];
  sh[t] = s; __syncthreads();
  for (int o = 128; o > 0; o >>= 1) { if (t < o) sh[t] += sh[t + o]; __syncthreads(); }
  if (t == 0) *out = sh[0];
}

__global__ void k_sumsq(const float* __restrict__ A, int n, float* __restrict__ out) {
  __shared__ float sh[256];
  int t = threadIdx.x;
  float s = 0.f;
  for (int i = blockIdx.x * 256 + t; i < n; i += gridDim.x * 256) { float v = A[i]; s += v * v; }
  sh[t] = s; __syncthreads();
  for (int o = 128; o > 0; o >>= 1) { if (t < o) sh[t] += sh[t + o]; __syncthreads(); }
  if (t == 0) atomicAdd(out, sh[0]);
}

// ---------------- level-2 dense graph ----------------

__global__ void k_deg2(const float* __restrict__ Ap, float* __restrict__ dinv2, int Np) {
  int q = blockIdx.x * blockDim.x + threadIdx.x;
  if (q >= Np) return;
  float d = 1.0f;
  for (int p = 0; p < Np; ++p) d += Ap[(size_t)p * Np + q];
  dinv2[q] = d > 0.f ? rsqrtf(fmaxf(d, 1e-12f)) : 0.f;
}

__global__ void k_dense_agg(const float* __restrict__ Ap, const float* __restrict__ dinv2,
                            const float* __restrict__ H, float* __restrict__ out,
                            int Np, int C) {
  int q = blockIdx.x, c = threadIdx.x;
  float acc = 0.f;
  for (int p = 0; p < Np; ++p)
    acc += dinv2[p] * Ap[(size_t)p * Np + q] * H[(size_t)p * C + c];
  float dq = dinv2[q];
  out[(size_t)q * C + c] = dq * acc + dq * dq * H[(size_t)q * C + c];
}

// ---------------- final head ----------------
// scal: [0]=ent1_sum [1]=ent2_sum [2]=cross1 [3]=||sts1||^2 [4]=||apool||^2 [5]=cross2 [6]=||sts2||^2
__global__ void k_final(const float* __restrict__ xp2, const float* __restrict__ Wlin,
                        const float* __restrict__ blin, const float* __restrict__ scal,
                        float* __restrict__ out, int N1, int E1, int K1, int K2, int OUT) {
  __shared__ float pooled[128];
  __shared__ float logits[32];
  int t = threadIdx.x;
  float s = 0.f;
  for (int r = 0; r < K2; ++r) s += xp2[(size_t)r * 128 + t];
  pooled[t] = s / (float)K2;
  __syncthreads();
  if (t < OUT) {
    float acc = blin[t];
    for (int k = 0; k < 128; ++k) acc += pooled[k] * Wlin[(size_t)k * OUT + t];
    logits[t] = acc;
  }
  __syncthreads();
  if (t == 0) {
    float mx = logits[0];
    for (int j = 1; j < OUT; ++j) mx = fmaxf(mx, logits[j]);
    float se = 0.f;
    for (int j = 0; j < OUT; ++j) se += expf(logits[j] - mx);
    float lse = mx + logf(se);
    for (int j = 0; j < OUT; ++j) out[j] = logits[j] - lse;
    float n1 = (float)N1;
    float ent1 = scal[0] / n1;
    float ent2 = scal[1] / (float)K1;
    float link1 = sqrtf(fmaxf((float)E1 - 2.f * scal[2] + scal[3], 0.f)) / (n1 * n1);
    float link2 = sqrtf(fmaxf(scal[4] - 2.f * scal[5] + scal[6], 0.f)) / ((float)K1 * (float)K1);
    out[OUT] = ent1 + ent2 + link1 + link2;
  }
}

// ---------------- host ----------------

extern "C" void kernel_launch(void* const* d_in, const int* in_sizes, int n_in,
                              void* d_out, int out_size, void* d_ws, size_t ws_size,
                              hipStream_t stream) {
  (void)n_in; (void)out_size; (void)ws_size;
  const float* x = (const float*)d_in[0];
  const int* ei  = (const int*)d_in[1];
  const int N = in_sizes[0] / 128;   // 20000
  const int E = in_sizes[1] / 2;     // 640000
  const int* src = ei;
  const int* dst = ei + E;
  const float *W1a=(const float*)d_in[4],  *b1a=(const float*)d_in[5],
              *g1a=(const float*)d_in[6],  *be1a=(const float*)d_in[7];
  const float *W1b=(const float*)d_in[8],  *b1b=(const float*)d_in[9],
              *g1b=(const float*)d_in[10], *be1b=(const float*)d_in[11];
  const float *Wp1=(const float*)d_in[12], *bp1=(const float*)d_in[13],
              *gp1=(const float*)d_in[14], *bep1=(const float*)d_in[15];
  const float *W2a=(const float*)d_in[16], *b2a=(const float*)d_in[17],
              *g2a=(const float*)d_in[18], *be2a=(const float*)d_in[19];
  const float *W2b=(const float*)d_in[20], *b2b=(const float*)d_in[21],
              *g2b=(const float*)d_in[22], *be2b=(const float*)d_in[23];
  const float *Wp2=(const float*)d_in[24], *bp2=(const float*)d_in[25],
              *gp2=(const float*)d_in[26], *bep2=(const float*)d_in[27];
  const float *Wlin=(const float*)d_in[28], *blin=(const float*)d_in[29];
  const int K1 = in_sizes[12] / 128;   // 256
  const int K2 = in_sizes[24] / 128;   // 64
  const int OUT = in_sizes[29];        // 10

  // bump allocator over d_ws
  char* base = (char*)d_ws;
  size_t off = 0;
  auto allocb = [&](size_t bytes) -> void* {
    void* p = (void*)(base + off);
    off += ((bytes + 255) & ~(size_t)255);
    return p;
  };
  auto alloc = [&](size_t nf) -> float* { return (float*)allocb(nf * 4); };
  auto alloci = [&](size_t ni) -> int* { return (int*)allocb(ni * 4); };

  float* scal  = alloc(16);
  float* cs    = alloc(256);
  float* csq   = alloc(256);
  float* dinv  = alloc(N);
  float* dinv2 = alloc(K1);
  float* apool = alloc((size_t)K1 * K1);
  float* sts   = alloc((size_t)K1 * K1);
  float* xp    = alloc((size_t)K1 * 128);
  float* h2    = alloc((size_t)K1 * 128);
  float* y2    = alloc((size_t)K1 * 128);
  float* xa2   = alloc((size_t)K1 * 128);
  float* x2f   = alloc((size_t)K1 * 128);
  float* s2b   = alloc((size_t)K1 * K2);
  float* t2    = alloc((size_t)K1 * K2);
  float* a2    = alloc((size_t)K2 * K2);
  float* sts2  = alloc((size_t)K2 * K2);
  float* xp2   = alloc((size_t)K2 * 128);
  float* R1 = alloc((size_t)N * 128);
  float* R2 = alloc((size_t)N * 128);
  float* R3 = alloc((size_t)N * K1);
  float* R4 = alloc((size_t)N * K1);
  // CSR structures
  int* cnt_d = alloci(N);
  int* rp_d  = alloci(N + 1);
  int* cur_d = alloci(N);
  int* col_s = alloci(E);   // CSR by dst: source ids
  int* cnt_s = alloci(N);
  int* rp_s  = alloci(N + 1);
  int* cur_s = alloci(N);
  int* col_d = alloci(E);   // CSR by src: dest ids

  auto cdiv = [](long long a, long long b) { return (int)((a + b - 1) / b); };

  hipMemsetAsync(scal, 0, 16 * sizeof(float), stream);

  // ---- CSR by dst (+ dinv from indegree) ----
  hipMemsetAsync(cnt_d, 0, N * sizeof(int), stream);
  k_hist<<<cdiv(E, 256), 256, 0, stream>>>(dst, cnt_d, E);
  k_scan<<<1, 1024, 0, stream>>>(cnt_d, rp_d, cur_d, N, E);
  k_fill_csr<<<cdiv(E, 256), 256, 0, stream>>>(dst, src, cur_d, col_s, E);
  k_dinv_cnt<<<cdiv(N, 256), 256, 0, stream>>>(cnt_d, dinv, N);
  // ---- CSR by src ----
  hipMemsetAsync(cnt_s, 0, N * sizeof(int), stream);
  k_hist<<<cdiv(E, 256), 256, 0, stream>>>(src, cnt_s, E);
  k_scan<<<1, 1024, 0, stream>>>(cnt_s, rp_s, cur_s, N, E);
  k_fill_csr<<<cdiv(E, 256), 256, 0, stream>>>(src, dst, cur_s, col_d, E);

  auto gemm_nn = [&](const float* A, const float* B, float* C, int M, int Nn, int K) {
    dim3 g(Nn / 64, cdiv(M, 64));
    k_sgemm_nn<<<g, 256, 0, stream>>>(A, B, C, M, Nn, K);
  };
  auto gemm_tn = [&](const float* A, const float* B, float* C, int M, int I, int J, int nz) {
    hipMemsetAsync(C, 0, (size_t)I * J * sizeof(float), stream);
    int chunk = cdiv(M, nz);
    chunk = (chunk + 15) & ~15;
    int zz = cdiv(M, chunk);
    dim3 g(J / 64, I / 64, zz);
    k_sgemm_tn<<<g, 256, 0, stream>>>(A, B, C, M, I, J, chunk);
  };

  // level-1 ResidualBlock: GCN(W) -> BN -> SiLU (+resid)
  auto block1 = [&](const float* xin, const float* W, const float* b, const float* gg,
                    const float* be, const float* resid, float* outp, int C) {
    gemm_nn(xin, W, R3, N, C, 128);
    k_gather_agg<<<N, C, 0, stream>>>(rp_d, col_s, dinv, R3, R4, C);
    hipMemsetAsync(cs, 0, C * sizeof(float), stream);
    hipMemsetAsync(csq, 0, C * sizeof(float), stream);
    k_col_stats<<<cdiv(N, 128), C, 0, stream>>>(R4, b, cs, csq, N, C, 128);
    int tot = N * C;
    k_bn_silu<<<cdiv(tot, 256), 256, 0, stream>>>(R4, b, cs, csq, gg, be, resid, outp,
                                                  tot, C - 1, 1.f / N);
  };

  block1(x,  W1a, b1a, g1a, be1a, nullptr, R1, 128);
  block1(R1, W1b, b1b, g1b, be1b, R1,      R2, 128);    // level-1 x = R2
  block1(R2, Wp1, bp1, gp1, bep1, nullptr, R4, K1);     // pooling features (in R4)
  k_softmax_ent<256><<<N, 256, 0, stream>>>(R4, &scal[0]);  // S = R4, ent1 sum

  // t = A S  (gather by src), then pooled products
  k_gather_T<<<N, K1, 0, stream>>>(rp_s, col_d, R4, R3, K1);

  gemm_tn(R4, R3, apool, N, K1, K1, 64);   // a_pool = S^T (A S)
  gemm_tn(R4, R4, sts,   N, K1, K1, 64);   // sts = S^T S
  gemm_tn(R4, R2, xp,    N, K1, 128, 64);  // xp = S^T x
  k_trace<<<1, 256, 0, stream>>>(apool, K1, &scal[2]);
  k_sumsq<<<64, 256, 0, stream>>>(sts, K1 * K1, &scal[3]);
  k_sumsq<<<64, 256, 0, stream>>>(apool, K1 * K1, &scal[4]);  // sum(ew2^2) for level 2

  // ---------------- level 2 (dense 256-node graph, ew = apool) ----------------
  k_deg2<<<1, 256, 0, stream>>>(apool, dinv2, K1);

  auto block2 = [&](const float* xin, const float* W, const float* b, const float* gg,
                    const float* be, const float* resid, float* outp, int C) {
    gemm_nn(xin, W, h2, K1, C, 128);
    k_dense_agg<<<K1, C, 0, stream>>>(apool, dinv2, h2, y2, K1, C);
    hipMemsetAsync(cs, 0, C * sizeof(float), stream);
    hipMemsetAsync(csq, 0, C * sizeof(float), stream);
    k_col_stats<<<cdiv(K1, 128), C, 0, stream>>>(y2, b, cs, csq, K1, C, 128);
    k_bn_silu<<<cdiv(K1 * C, 256), 256, 0, stream>>>(y2, b, cs, csq, gg, be, resid, outp,
                                                     K1 * C, C - 1, 1.f / K1);
  };

  block2(xp,  W2a, b2a, g2a, be2a, nullptr, xa2, 128);
  block2(xa2, W2b, b2b, g2b, be2b, xa2,     x2f, 128);   // level-2 x = x2f
  block2(x2f, Wp2, bp2, gp2, bep2, nullptr, s2b, K2);
  k_softmax_ent<64><<<K1, 64, 0, stream>>>(s2b, &scal[1]);  // s2 = s2b, ent2 sum

  gemm_nn(apool, s2b, t2, K1, K2, K1);      // t2 = Apool @ s2
  gemm_tn(s2b, t2,  a2,   K1, K2, K2, 1);   // a2 = s2^T t2
  gemm_tn(s2b, s2b, sts2, K1, K2, K2, 1);   // sts2 = s2^T s2
  gemm_tn(s2b, x2f, xp2,  K1, K2, 128, 1);  // xp2 = s2^T x2f
  k_trace<<<1, 256, 0, stream>>>(a2, K2, &scal[5]);
  k_sumsq<<<16, 256, 0, stream>>>(sts2, K2 * K2, &scal[6]);

  k_final<<<1, 128, 0, stream>>>(xp2, Wlin, blin, scal, (float*)d_out, N, E, K1, K2, OUT);
}

// Round 3
// 1567.763 us; speedup vs baseline: 1.8352x; 1.1331x over previous
//
#include <hip/hip_runtime.h>

#define EPS_BN 1e-5f
typedef unsigned int uint;
typedef unsigned short ushort;
typedef __attribute__((ext_vector_type(8))) short bf16x8;
typedef __attribute__((ext_vector_type(4))) float f32x4;

__device__ inline ushort f2bf(float f) {
  uint u = __float_as_uint(f);
  uint r = (u + 0x7FFFu + ((u >> 16) & 1u)) >> 16;
  return (ushort)r;
}

// ---------------- CSR build ----------------

__global__ void k_hist(const int* __restrict__ idx, int* __restrict__ cnt, int E) {
  int e = blockIdx.x * blockDim.x + threadIdx.x;
  if (e < E) atomicAdd(&cnt[idx[e]], 1);
}

__global__ __launch_bounds__(1024) void k_scan(
    const int* __restrict__ cnt, int* __restrict__ rowptr, int* __restrict__ cursor,
    int N, int E) {
  __shared__ int sh[1024];
  int t = threadIdx.x;
  int chunk = (N + 1023) / 1024;
  int i0 = t * chunk, i1 = min(i0 + chunk, N);
  int s = 0;
  for (int i = i0; i < i1; ++i) s += cnt[i];
  sh[t] = s; __syncthreads();
  for (int o = 1; o < 1024; o <<= 1) {
    int v = (t >= o) ? sh[t - o] : 0;
    __syncthreads();
    sh[t] += v;
    __syncthreads();
  }
  int run = (t == 0) ? 0 : sh[t - 1];
  for (int i = i0; i < i1; ++i) { rowptr[i] = run; cursor[i] = run; run += cnt[i]; }
  if (t == 1023) rowptr[N] = E;
}

__global__ void k_fill_csr(const int* __restrict__ key, const int* __restrict__ val,
                           int* __restrict__ cursor, int* __restrict__ col, int E) {
  int e = blockIdx.x * blockDim.x + threadIdx.x;
  if (e < E) {
    int pos = atomicAdd(&cursor[key[e]], 1);
    col[pos] = val[e];
  }
}

__global__ void k_dinv_cnt(const int* __restrict__ cnt, float* __restrict__ dinv, int n) {
  int i = blockIdx.x * blockDim.x + threadIdx.x;
  if (i < n) dinv[i] = rsqrtf(1.0f + (float)cnt[i]);
}

// ---------------- gather aggregation (no atomics) ----------------

__global__ void k_gather_agg(const int* __restrict__ rowptr, const int* __restrict__ col,
                             const float* __restrict__ dinv, const float* __restrict__ H,
                             float* __restrict__ out, int C) {
  int d = blockIdx.x;
  int c = threadIdx.x;
  int b = rowptr[d], e = rowptr[d + 1];
  float acc = 0.f;
  for (int i = b; i < e; ++i) {
    int s = col[i];
    acc += dinv[s] * H[(size_t)s * C + c];
  }
  float dd = dinv[d];
  out[(size_t)d * C + c] = dd * acc + dd * dd * H[(size_t)d * C + c];
}

__global__ void k_gather_T(const int* __restrict__ rowptr, const int* __restrict__ col,
                           const float* __restrict__ S, float* __restrict__ T, int C) {
  int s = blockIdx.x;
  int j = threadIdx.x;
  int b = rowptr[s], e = rowptr[s + 1];
  float acc = 0.f;
  for (int i = b; i < e; ++i) {
    int d = col[i];
    acc += S[(size_t)d * C + j];
  }
  T[(size_t)s * C + j] = acc;
}

// ---------------- conversion / transpose ----------------

__global__ void k_conv(const float* __restrict__ in, ushort* __restrict__ out, int n4) {
  int i = blockIdx.x * blockDim.x + threadIdx.x;
  if (i < n4) {
    float4 v = ((const float4*)in)[i];
    ushort4 o;
    o.x = f2bf(v.x); o.y = f2bf(v.y); o.z = f2bf(v.z); o.w = f2bf(v.w);
    ((ushort4*)out)[i] = o;
  }
}

// out[c, r] = bf16(in[r, c])
__global__ void k_tconv(const float* __restrict__ in, ushort* __restrict__ out,
                        int R, int Cc) {
  __shared__ float tile[32][33];
  int c0 = blockIdx.x * 32, r0 = blockIdx.y * 32;
  int tx = threadIdx.x, ty = threadIdx.y;
  for (int i = 0; i < 32; i += 8) {
    int r = r0 + ty + i, c = c0 + tx;
    if (r < R && c < Cc) tile[ty + i][tx] = in[(size_t)r * Cc + c];
  }
  __syncthreads();
  for (int i = 0; i < 32; i += 8) {
    int oc = c0 + ty + i;
    int orr = r0 + tx;
    if (oc < Cc && orr < R) out[(size_t)oc * R + orr] = f2bf(tile[tx][ty + i]);
  }
}

// ---------------- bf16 MFMA NT GEMM ----------------
// C[i,j] (+)= sum_k A[i*K+k] * B[j*K+k];  A:[I,K] bf16, B:[J,K] bf16, C fp32.
// J%64==0, K%32==0, kChunk%32==0. I guarded. atom!=0 -> atomicAdd (C pre-zeroed).
__global__ __launch_bounds__(256) void k_mfma_nt(
    const ushort* __restrict__ A, const ushort* __restrict__ B, float* __restrict__ C,
    int I, int J, int K, int kChunk, int atom) {
  __shared__ ushort As[64][40];
  __shared__ ushort Bs[64][40];
  int t = threadIdx.x;
  int w = t >> 6, l = t & 63;
  int i0 = blockIdx.y * 64, j0 = blockIdx.x * 64;
  int k0 = blockIdx.z * kChunk;
  int k1 = min(k0 + kChunk, K);
  f32x4 acc[4] = {};
  int lrow = t >> 2;
  int lk = (t & 3) * 8;
  for (int kk = k0; kk < k1; kk += 32) {
    uint4 av = make_uint4(0u, 0u, 0u, 0u);
    int ar = i0 + lrow;
    if (ar < I) av = *(const uint4*)(A + (size_t)ar * K + kk + lk);
    uint4 bv = *(const uint4*)(B + (size_t)(j0 + lrow) * K + kk + lk);
    *(uint4*)&As[lrow][lk] = av;
    *(uint4*)&Bs[lrow][lk] = bv;
    __syncthreads();
    bf16x8 af = *(const bf16x8*)&As[16 * w + (l & 15)][(l >> 4) * 8];
#pragma unroll
    for (int jt = 0; jt < 4; ++jt) {
      bf16x8 bf = *(const bf16x8*)&Bs[16 * jt + (l & 15)][(l >> 4) * 8];
      acc[jt] = __builtin_amdgcn_mfma_f32_16x16x32_bf16(af, bf, acc[jt], 0, 0, 0);
    }
    __syncthreads();
  }
  int rbase = i0 + 16 * w + ((l >> 4) * 4);
  int cbase = j0 + (l & 15);
#pragma unroll
  for (int jt = 0; jt < 4; ++jt) {
#pragma unroll
    for (int rr = 0; rr < 4; ++rr) {
      int r = rbase + rr;
      if (r < I) {
        float* p = &C[(size_t)r * J + jt * 16 + cbase];
        if (atom) atomicAdd(p, acc[jt][rr]); else *p = acc[jt][rr];
      }
    }
  }
}

// ---------------- fp32 GEMM (small, level-2) ----------------
__global__ __launch_bounds__(256) void k_sgemm_nn(
    const float* __restrict__ A, const float* __restrict__ B, float* __restrict__ C,
    int M, int N, int K) {
  __shared__ float As[16][64];
  __shared__ float Bs[16][68];
  int t = threadIdx.x;
  int tx = t & 15, ty = t >> 4;
  int row0 = blockIdx.y * 64, col0 = blockIdx.x * 64;
  float acc[4][4] = {};
  for (int k0 = 0; k0 < K; k0 += 16) {
    int ar = t >> 2;
    int ak = (t & 3) * 4;
    float4 av = make_float4(0.f, 0.f, 0.f, 0.f);
    if (row0 + ar < M) av = *(const float4*)(A + (size_t)(row0 + ar) * K + k0 + ak);
    As[ak + 0][ar] = av.x; As[ak + 1][ar] = av.y;
    As[ak + 2][ar] = av.z; As[ak + 3][ar] = av.w;
    int bk = t >> 4;
    int bc = (t & 15) * 4;
    float4 bv = *(const float4*)(B + (size_t)(k0 + bk) * N + col0 + bc);
    *(float4*)&Bs[bk][bc] = bv;
    __syncthreads();
#pragma unroll
    for (int k = 0; k < 16; ++k) {
      float a[4], b[4];
#pragma unroll
      for (int u = 0; u < 4; ++u) a[u] = As[k][ty * 4 + u];
#pragma unroll
      for (int v = 0; v < 4; ++v) b[v] = Bs[k][tx * 4 + v];
#pragma unroll
      for (int u = 0; u < 4; ++u)
#pragma unroll
        for (int v = 0; v < 4; ++v) acc[u][v] += a[u] * b[v];
    }
    __syncthreads();
  }
#pragma unroll
  for (int u = 0; u < 4; ++u) {
    int r = row0 + ty * 4 + u;
    if (r < M) {
#pragma unroll
      for (int v = 0; v < 4; ++v) C[(size_t)r * N + col0 + tx * 4 + v] = acc[u][v];
    }
  }
}

__global__ __launch_bounds__(256) void k_sgemm_tn(
    const float* __restrict__ A, const float* __restrict__ B, float* __restrict__ C,
    int M, int I, int J, int mChunk) {
  __shared__ float As[16][68];
  __shared__ float Bs[16][68];
  int t = threadIdx.x;
  int tx = t & 15, ty = t >> 4;
  int i0 = blockIdx.y * 64, j0 = blockIdx.x * 64;
  int m0 = blockIdx.z * mChunk;
  int m1 = min(m0 + mChunk, M);
  float acc[4][4] = {};
  for (int mb = m0; mb < m1; mb += 16) {
    int mr = t >> 4;
    int cc = (t & 15) * 4;
    int m = mb + mr;
    float4 av = make_float4(0.f, 0.f, 0.f, 0.f);
    float4 bv = make_float4(0.f, 0.f, 0.f, 0.f);
    if (m < m1) {
      av = *(const float4*)(A + (size_t)m * I + i0 + cc);
      bv = *(const float4*)(B + (size_t)m * J + j0 + cc);
    }
    *(float4*)&As[mr][cc] = av;
    *(float4*)&Bs[mr][cc] = bv;
    __syncthreads();
#pragma unroll
    for (int k = 0; k < 16; ++k) {
      float a[4], b[4];
#pragma unroll
      for (int u = 0; u < 4; ++u) a[u] = As[k][ty * 4 + u];
#pragma unroll
      for (int v = 0; v < 4; ++v) b[v] = Bs[k][tx * 4 + v];
#pragma unroll
      for (int u = 0; u < 4; ++u)
#pragma unroll
        for (int v = 0; v < 4; ++v) acc[u][v] += a[u] * b[v];
    }
    __syncthreads();
  }
#pragma unroll
  for (int u = 0; u < 4; ++u)
#pragma unroll
    for (int v = 0; v < 4; ++v)
      atomicAdd(&C[(size_t)(i0 + ty * 4 + u) * J + j0 + tx * 4 + v], acc[u][v]);
}

// ---------------- BN / softmax / reductions ----------------

__global__ void k_col_stats(const float* __restrict__ X, const float* __restrict__ bias,
                            float* __restrict__ cs, float* __restrict__ csq,
                            int M, int C, int rpb) {
  int c = threadIdx.x;
  if (c >= C) return;
  int r0 = blockIdx.x * rpb, r1 = min(r0 + rpb, M);
  float b = bias[c];
  float s = 0.f, sq = 0.f;
  for (int r = r0; r < r1; ++r) {
    float v = X[(size_t)r * C + c] + b;
    s += v; sq += v * v;
  }
  atomicAdd(&cs[c], s);
  atomicAdd(&csq[c], sq);
}

__global__ void k_bn_silu(const float* __restrict__ X, const float* __restrict__ bias,
                          const float* __restrict__ cs, const float* __restrict__ csq,
                          const float* __restrict__ g, const float* __restrict__ be,
                          const float* __restrict__ resid, float* __restrict__ out,
                          ushort* __restrict__ outb,
                          int tot, int cmask, float invM) {
  int i = blockIdx.x * blockDim.x + threadIdx.x;
  if (i >= tot) return;
  int c = i & cmask;
  float m = cs[c] * invM;
  float var = csq[c] * invM - m * m;
  float v = (X[i] + bias[c] - m) * rsqrtf(var + EPS_BN) * g[c] + be[c];
  float y = v / (1.f + expf(-v));
  if (resid) y += resid[i];
  out[i] = y;
  if (outb) outb[i] = f2bf(y);
}

// one wave per row; C in {64, 256}
template <int C>
__global__ void k_softmax_ent2(float* __restrict__ X, float* __restrict__ entAcc, int nrows) {
  constexpr int VPT = C / 64;
  int gt = blockIdx.x * blockDim.x + threadIdx.x;
  int row = gt >> 6;
  int l = gt & 63;
  if (row >= nrows) return;
  float d[VPT];
  size_t base = (size_t)row * C;
  if (VPT == 4) {
    float4 v = *(const float4*)(X + base + l * 4);
    d[0] = v.x; d[1] = v.y; d[2] = v.z; d[3] = v.w;
  } else {
    d[0] = X[base + l];
  }
  float mx = d[0];
#pragma unroll
  for (int i = 1; i < VPT; ++i) mx = fmaxf(mx, d[i]);
  for (int o = 32; o > 0; o >>= 1) mx = fmaxf(mx, __shfl_xor(mx, o));
  float se = 0.f;
  float e[VPT];
#pragma unroll
  for (int i = 0; i < VPT; ++i) { d[i] -= mx; e[i] = expf(d[i]); se += e[i]; }
  for (int o = 32; o > 0; o >>= 1) se += __shfl_xor(se, o);
  float inv = 1.f / se;
  float pd = 0.f;
#pragma unroll
  for (int i = 0; i < VPT; ++i) { e[i] *= inv; pd += e[i] * d[i]; }
  if (VPT == 4) {
    float4 v; v.x = e[0]; v.y = e[1]; v.z = e[2]; v.w = e[3];
    *(float4*)(X + base + l * 4) = v;
  } else {
    X[base + l] = e[0];
  }
  for (int o = 32; o > 0; o >>= 1) pd += __shfl_xor(pd, o);
  if (l == 0) atomicAdd(entAcc, logf(se) - pd);
}

__global__ void k_trace(const float* __restrict__ A, int K, float* __restrict__ out) {
  __shared__ float sh[256];
  int t = threadIdx.x;
  float s = 0.f;
  for (int i = t; i < K; i += 256) s += A[(size_t)i * K + i];
  sh[t] = s; __syncthreads();
  for (int o = 128; o > 0; o >>= 1) { if (t < o) sh[t] += sh[t + o]; __syncthreads(); }
  if (t == 0) *out = sh[0];
}

__global__ void k_sumsq(const float* __restrict__ A, int n, float* __restrict__ out) {
  __shared__ float sh[256];
  int t = threadIdx.x;
  float s = 0.f;
  for (int i = blockIdx.x * 256 + t; i < n; i += gridDim.x * 256) { float v = A[i]; s += v * v; }
  sh[t] = s; __syncthreads();
  for (int o = 128; o > 0; o >>= 1) { if (t < o) sh[t] += sh[t + o]; __syncthreads(); }
  if (t == 0) atomicAdd(out, sh[0]);
}

// ---------------- level-2 dense graph ----------------

__global__ void k_deg2(const float* __restrict__ Ap, float* __restrict__ dinv2, int Np) {
  int q = blockIdx.x * blockDim.x + threadIdx.x;
  if (q >= Np) return;
  float d = 1.0f;
  for (int p = 0; p < Np; ++p) d += Ap[(size_t)p * Np + q];
  dinv2[q] = d > 0.f ? rsqrtf(fmaxf(d, 1e-12f)) : 0.f;
}

__global__ void k_dense_agg(const float* __restrict__ Ap, const float* __restrict__ dinv2,
                            const float* __restrict__ H, float* __restrict__ out,
                            int Np, int C) {
  int q = blockIdx.x, c = threadIdx.x;
  float acc = 0.f;
  for (int p = 0; p < Np; ++p)
    acc += dinv2[p] * Ap[(size_t)p * Np + q] * H[(size_t)p * C + c];
  float dq = dinv2[q];
  out[(size_t)q * C + c] = dq * acc + dq * dq * H[(size_t)q * C + c];
}

// ---------------- final head ----------------
__global__ void k_final(const float* __restrict__ xp2, const float* __restrict__ Wlin,
                        const float* __restrict__ blin, const float* __restrict__ scal,
                        float* __restrict__ out, int N1, int E1, int K1, int K2, int OUT) {
  __shared__ float pooled[128];
  __shared__ float logits[32];
  int t = threadIdx.x;
  float s = 0.f;
  for (int r = 0; r < K2; ++r) s += xp2[(size_t)r * 128 + t];
  pooled[t] = s / (float)K2;
  __syncthreads();
  if (t < OUT) {
    float acc = blin[t];
    for (int k = 0; k < 128; ++k) acc += pooled[k] * Wlin[(size_t)k * OUT + t];
    logits[t] = acc;
  }
  __syncthreads();
  if (t == 0) {
    float mx = logits[0];
    for (int j = 1; j < OUT; ++j) mx = fmaxf(mx, logits[j]);
    float se = 0.f;
    for (int j = 0; j < OUT; ++j) se += expf(logits[j] - mx);
    float lse = mx + logf(se);
    for (int j = 0; j < OUT; ++j) out[j] = logits[j] - lse;
    float n1 = (float)N1;
    float ent1 = scal[0] / n1;
    float ent2 = scal[1] / (float)K1;
    float link1 = sqrtf(fmaxf((float)E1 - 2.f * scal[2] + scal[3], 0.f)) / (n1 * n1);
    float link2 = sqrtf(fmaxf(scal[4] - 2.f * scal[5] + scal[6], 0.f)) / ((float)K1 * (float)K1);
    out[OUT] = ent1 + ent2 + link1 + link2;
  }
}

// ---------------- host ----------------

extern "C" void kernel_launch(void* const* d_in, const int* in_sizes, int n_in,
                              void* d_out, int out_size, void* d_ws, size_t ws_size,
                              hipStream_t stream) {
  (void)n_in; (void)out_size; (void)ws_size;
  const float* x = (const float*)d_in[0];
  const int* ei  = (const int*)d_in[1];
  const int N = in_sizes[0] / 128;   // 20000
  const int E = in_sizes[1] / 2;     // 640000
  const int* src = ei;
  const int* dst = ei + E;
  const float *W1a=(const float*)d_in[4],  *b1a=(const float*)d_in[5],
              *g1a=(const float*)d_in[6],  *be1a=(const float*)d_in[7];
  const float *W1b=(const float*)d_in[8],  *b1b=(const float*)d_in[9],
              *g1b=(const float*)d_in[10], *be1b=(const float*)d_in[11];
  const float *Wp1=(const float*)d_in[12], *bp1=(const float*)d_in[13],
              *gp1=(const float*)d_in[14], *bep1=(const float*)d_in[15];
  const float *W2a=(const float*)d_in[16], *b2a=(const float*)d_in[17],
              *g2a=(const float*)d_in[18], *be2a=(const float*)d_in[19];
  const float *W2b=(const float*)d_in[20], *b2b=(const float*)d_in[21],
              *g2b=(const float*)d_in[22], *be2b=(const float*)d_in[23];
  const float *Wp2=(const float*)d_in[24], *bp2=(const float*)d_in[25],
              *gp2=(const float*)d_in[26], *bep2=(const float*)d_in[27];
  const float *Wlin=(const float*)d_in[28], *blin=(const float*)d_in[29];
  const int K1 = in_sizes[12] / 128;   // 256
  const int K2 = in_sizes[24] / 128;   // 64
  const int OUT = in_sizes[29];        // 10

  char* base = (char*)d_ws;
  size_t off = 0;
  auto allocb = [&](size_t bytes) -> void* {
    void* p = (void*)(base + off);
    off += ((bytes + 255) & ~(size_t)255);
    return p;
  };
  auto alloc = [&](size_t nf) -> float* { return (float*)allocb(nf * 4); };
  auto alloci = [&](size_t ni) -> int* { return (int*)allocb(ni * 4); };
  auto allocu = [&](size_t nu) -> ushort* { return (ushort*)allocb(nu * 2); };

  float* scal  = alloc(16);
  float* cs    = alloc(256);
  float* csq   = alloc(256);
  float* dinv  = alloc(N);
  float* dinv2 = alloc(K1);
  float* apool = alloc((size_t)K1 * K1);
  float* sts   = alloc((size_t)K1 * K1);
  float* xp    = alloc((size_t)K1 * 128);
  float* h2    = alloc((size_t)K1 * 128);
  float* y2    = alloc((size_t)K1 * 128);
  float* xa2   = alloc((size_t)K1 * 128);
  float* x2f   = alloc((size_t)K1 * 128);
  float* s2b   = alloc((size_t)K1 * K2);
  float* t2    = alloc((size_t)K1 * K2);
  float* a2    = alloc((size_t)K2 * K2);
  float* sts2  = alloc((size_t)K2 * K2);
  float* xp2   = alloc((size_t)K2 * 128);
  float* R1 = alloc((size_t)N * 128);   // also aliased by St (bf16 [K1,N]) later
  float* R2 = alloc((size_t)N * 128);
  float* R3 = alloc((size_t)N * K1);
  float* R4 = alloc((size_t)N * K1);    // first half aliased by ASt later
  ushort* B16A = allocu((size_t)N * 128);  // xb -> R1b -> R2b -> R2t
  ushort* W1at = allocu(128 * 128);
  ushort* W1bt = allocu(128 * 128);
  ushort* Wp1t = allocu((size_t)K1 * 128);
  // CSR structures
  int* cnt_d = alloci(N);
  int* rp_d  = alloci(N + 1);
  int* cur_d = alloci(N);
  int* col_s = alloci(E);
  int* cnt_s = alloci(N);
  int* rp_s  = alloci(N + 1);
  int* cur_s = alloci(N);
  int* col_d = alloci(E);

  ushort* St  = (ushort*)R1;   // [K1, N] bf16 = 10.24 MB == sizeof(R1)
  ushort* ASt = (ushort*)R4;   // [K1, N] bf16 fits in R4 (N*K1*4 B)
  ushort* R2t = B16A;          // [128, N] bf16

  auto cdiv = [](long long a, long long b) { return (int)((a + b - 1) / b); };

  hipMemsetAsync(scal, 0, 16 * sizeof(float), stream);

  // ---- CSR by dst (+ dinv) ----
  hipMemsetAsync(cnt_d, 0, N * sizeof(int), stream);
  k_hist<<<cdiv(E, 256), 256, 0, stream>>>(dst, cnt_d, E);
  k_scan<<<1, 1024, 0, stream>>>(cnt_d, rp_d, cur_d, N, E);
  k_fill_csr<<<cdiv(E, 256), 256, 0, stream>>>(dst, src, cur_d, col_s, E);
  k_dinv_cnt<<<cdiv(N, 256), 256, 0, stream>>>(cnt_d, dinv, N);
  // ---- CSR by src ----
  hipMemsetAsync(cnt_s, 0, N * sizeof(int), stream);
  k_hist<<<cdiv(E, 256), 256, 0, stream>>>(src, cnt_s, E);
  k_scan<<<1, 1024, 0, stream>>>(cnt_s, rp_s, cur_s, N, E);
  k_fill_csr<<<cdiv(E, 256), 256, 0, stream>>>(src, dst, cur_s, col_d, E);

  // ---- weight transposes + x conversion ----
  {
    dim3 b32(32, 8);
    k_tconv<<<dim3(4, 4), b32, 0, stream>>>(W1a, W1at, 128, 128);
    k_tconv<<<dim3(4, 4), b32, 0, stream>>>(W1b, W1bt, 128, 128);
    k_tconv<<<dim3(8, 4), b32, 0, stream>>>(Wp1, Wp1t, 128, K1);
  }
  k_conv<<<cdiv((size_t)N * 128 / 4, 256), 256, 0, stream>>>(x, B16A, N * 128 / 4);

  auto mfma_nt = [&](const ushort* A, const ushort* B, float* C,
                     int I, int J, int K, int nz) {
    int chunk = K, z = 1;
    if (nz > 1) {
      chunk = ((cdiv(K, nz) + 31) & ~31);
      z = cdiv(K, chunk);
      hipMemsetAsync(C, 0, (size_t)I * J * sizeof(float), stream);
    }
    dim3 g(J / 64, cdiv(I, 64), z);
    k_mfma_nt<<<g, 256, 0, stream>>>(A, B, C, I, J, K, chunk, z > 1 ? 1 : 0);
  };
  auto gemm_nn = [&](const float* A, const float* B, float* C, int M, int Nn, int K) {
    dim3 g(Nn / 64, cdiv(M, 64));
    k_sgemm_nn<<<g, 256, 0, stream>>>(A, B, C, M, Nn, K);
  };
  auto gemm_tn = [&](const float* A, const float* B, float* C, int M, int I, int J, int nz) {
    hipMemsetAsync(C, 0, (size_t)I * J * sizeof(float), stream);
    int chunk = cdiv(M, nz);
    chunk = (chunk + 15) & ~15;
    int zz = cdiv(M, chunk);
    dim3 g(J / 64, I / 64, zz);
    k_sgemm_tn<<<g, 256, 0, stream>>>(A, B, C, M, I, J, chunk);
  };

  // level-1 ResidualBlock: GCN(W) -> BN -> SiLU (+resid); bf16 in, fp32(+bf16) out
  auto block1 = [&](const ushort* xin_b, const ushort* Wt, const float* b, const float* gg,
                    const float* be, const float* resid, float* outp, ushort* outb, int C) {
    mfma_nt(xin_b, Wt, R3, N, C, 128, 1);
    k_gather_agg<<<N, C, 0, stream>>>(rp_d, col_s, dinv, R3, R4, C);
    hipMemsetAsync(cs, 0, C * sizeof(float), stream);
    hipMemsetAsync(csq, 0, C * sizeof(float), stream);
    k_col_stats<<<cdiv(N, 16), C, 0, stream>>>(R4, b, cs, csq, N, C, 16);
    int tot = N * C;
    k_bn_silu<<<cdiv(tot, 256), 256, 0, stream>>>(R4, b, cs, csq, gg, be, resid, outp,
                                                  outb, tot, C - 1, 1.f / N);
  };

  block1(B16A, W1at, b1a, g1a, be1a, nullptr, R1, B16A, 128);  // R1 + R1b (B16A)
  block1(B16A, W1bt, b1b, g1b, be1b, R1,      R2, B16A, 128);  // R2 + R2b (B16A)
  block1(B16A, Wp1t, bp1, gp1, bep1, nullptr, R4, nullptr, K1); // pooling feats in R4
  k_softmax_ent2<256><<<cdiv(N, 4), 256, 0, stream>>>(R4, &scal[0], N);  // S in R4

  // AS (fp32) then bf16 transposes
  k_gather_T<<<N, K1, 0, stream>>>(rp_s, col_d, R4, R3, K1);   // R3 = A S
  {
    dim3 b32(32, 8);
    dim3 gS(K1 / 32, cdiv(N, 32));
    k_tconv<<<gS, b32, 0, stream>>>(R4, St, N, K1);            // St = S^T bf16
    k_tconv<<<gS, b32, 0, stream>>>(R3, ASt, N, K1);           // ASt = (AS)^T bf16
    dim3 gX(128 / 32, cdiv(N, 32));
    k_tconv<<<gX, b32, 0, stream>>>(R2, R2t, N, 128);          // R2t = x^T bf16
  }

  mfma_nt(St, ASt, apool, K1, K1, N, 16);   // a_pool = S^T (A S)
  mfma_nt(St, St,  sts,   K1, K1, N, 16);   // sts = S^T S
  mfma_nt(St, R2t, xp,    K1, 128, N, 16);  // xp = S^T x
  k_trace<<<1, 256, 0, stream>>>(apool, K1, &scal[2]);
  k_sumsq<<<64, 256, 0, stream>>>(sts, K1 * K1, &scal[3]);
  k_sumsq<<<64, 256, 0, stream>>>(apool, K1 * K1, &scal[4]);

  // ---------------- level 2 (dense 256-node graph) ----------------
  k_deg2<<<1, 256, 0, stream>>>(apool, dinv2, K1);

  auto block2 = [&](const float* xin, const float* W, const float* b, const float* gg,
                    const float* be, const float* resid, float* outp, int C) {
    gemm_nn(xin, W, h2, K1, C, 128);
    k_dense_agg<<<K1, C, 0, stream>>>(apool, dinv2, h2, y2, K1, C);
    hipMemsetAsync(cs, 0, C * sizeof(float), stream);
    hipMemsetAsync(csq, 0, C * sizeof(float), stream);
    k_col_stats<<<cdiv(K1, 16), C, 0, stream>>>(y2, b, cs, csq, K1, C, 16);
    k_bn_silu<<<cdiv(K1 * C, 256), 256, 0, stream>>>(y2, b, cs, csq, gg, be, resid, outp,
                                                     nullptr, K1 * C, C - 1, 1.f / K1);
  };

  block2(xp,  W2a, b2a, g2a, be2a, nullptr, xa2, 128);
  block2(xa2, W2b, b2b, g2b, be2b, xa2,     x2f, 128);
  block2(x2f, Wp2, bp2, gp2, bep2, nullptr, s2b, K2);
  k_softmax_ent2<64><<<cdiv(K1, 4), 256, 0, stream>>>(s2b, &scal[1], K1);

  gemm_nn(apool, s2b, t2, K1, K2, K1);
  gemm_tn(s2b, t2,  a2,   K1, K2, K2, 1);
  gemm_tn(s2b, s2b, sts2, K1, K2, K2, 1);
  gemm_tn(s2b, x2f, xp2,  K1, K2, 128, 1);
  k_trace<<<1, 256, 0, stream>>>(a2, K2, &scal[5]);
  k_sumsq<<<16, 256, 0, stream>>>(sts2, K2 * K2, &scal[6]);

  k_final<<<1, 128, 0, stream>>>(xp2, Wlin, blin, scal, (float*)d_out, N, E, K1, K2, OUT);
}

// Round 5
// 1369.991 us; speedup vs baseline: 2.1001x; 1.1444x over previous
//
#include <hip/hip_runtime.h>

#define EPS_BN 1e-5f
typedef unsigned int uint;
typedef unsigned short ushort;
typedef __attribute__((ext_vector_type(8))) short bf16x8;
typedef __attribute__((ext_vector_type(4))) float f32x4;

__device__ inline ushort f2bf(float f) {
  uint u = __float_as_uint(f);
  uint r = (u + 0x7FFFu + ((u >> 16) & 1u)) >> 16;
  return (ushort)r;
}
__device__ inline float bflo(uint h) { return __uint_as_float(h << 16); }
__device__ inline float bfhi(uint h) { return __uint_as_float(h & 0xFFFF0000u); }

// ---------------- CSR build ----------------

__global__ void k_hist(const int* __restrict__ idx, int* __restrict__ cnt, int E) {
  int e = blockIdx.x * blockDim.x + threadIdx.x;
  if (e < E) atomicAdd(&cnt[idx[e]], 1);
}

__global__ __launch_bounds__(1024) void k_scan(
    const int* __restrict__ cnt, int* __restrict__ rowptr, int* __restrict__ cursor,
    int N, int E) {
  __shared__ int sh[1024];
  int t = threadIdx.x;
  int chunk = (N + 1023) / 1024;
  int i0 = t * chunk, i1 = min(i0 + chunk, N);
  int s = 0;
  for (int i = i0; i < i1; ++i) s += cnt[i];
  sh[t] = s; __syncthreads();
  for (int o = 1; o < 1024; o <<= 1) {
    int v = (t >= o) ? sh[t - o] : 0;
    __syncthreads();
    sh[t] += v;
    __syncthreads();
  }
  int run = (t == 0) ? 0 : sh[t - 1];
  for (int i = i0; i < i1; ++i) { rowptr[i] = run; cursor[i] = run; run += cnt[i]; }
  if (t == 1023) rowptr[N] = E;
}

__global__ void k_fill_csr(const int* __restrict__ key, const int* __restrict__ val,
                           int* __restrict__ cursor, int* __restrict__ col, int E) {
  int e = blockIdx.x * blockDim.x + threadIdx.x;
  if (e < E) {
    int pos = atomicAdd(&cursor[key[e]], 1);
    col[pos] = val[e];
  }
}

__global__ void k_dinv_cnt(const int* __restrict__ cnt, float* __restrict__ dinv, int n) {
  int i = blockIdx.x * blockDim.x + threadIdx.x;
  if (i < n) dinv[i] = rsqrtf(1.0f + (float)cnt[i]);
}

// ---------------- gather aggregation, bf16 input, 2 ch/thread ----------------

__global__ void k_gather_agg_b2(const int* __restrict__ rowptr, const int* __restrict__ col,
                                const float* __restrict__ dinv, const ushort* __restrict__ H,
                                float* __restrict__ out, int C2) {
  int d = blockIdx.x;
  int c2 = threadIdx.x;
  const uint* H2 = (const uint*)H;
  int b = rowptr[d], e = rowptr[d + 1];
  float a0 = 0.f, a1 = 0.f;
  for (int i = b; i < e; ++i) {
    int s = col[i];
    float dv = dinv[s];
    uint h = H2[(size_t)s * C2 + c2];
    a0 += dv * bflo(h);
    a1 += dv * bfhi(h);
  }
  float dd = dinv[d];
  uint hd = H2[(size_t)d * C2 + c2];
  float2 o;
  o.x = dd * a0 + dd * dd * bflo(hd);
  o.y = dd * a1 + dd * dd * bfhi(hd);
  *(float2*)(out + (size_t)d * (C2 * 2) + c2 * 2) = o;
}

__global__ void k_gather_T_b2(const int* __restrict__ rowptr, const int* __restrict__ col,
                              const ushort* __restrict__ S, float* __restrict__ T, int C2) {
  int s = blockIdx.x;
  int c2 = threadIdx.x;
  const uint* S2 = (const uint*)S;
  int b = rowptr[s], e = rowptr[s + 1];
  float a0 = 0.f, a1 = 0.f;
  for (int i = b; i < e; ++i) {
    int d = col[i];
    uint h = S2[(size_t)d * C2 + c2];
    a0 += bflo(h);
    a1 += bfhi(h);
  }
  float2 o; o.x = a0; o.y = a1;
  *(float2*)(T + (size_t)s * (C2 * 2) + c2 * 2) = o;
}

// ---------------- conversion / transpose ----------------

__global__ void k_conv(const float* __restrict__ in, ushort* __restrict__ out, int n4) {
  int i = blockIdx.x * blockDim.x + threadIdx.x;
  if (i < n4) {
    float4 v = ((const float4*)in)[i];
    ushort4 o;
    o.x = f2bf(v.x); o.y = f2bf(v.y); o.z = f2bf(v.z); o.w = f2bf(v.w);
    ((ushort4*)out)[i] = o;
  }
}

// out[c, r] = bf16(in[r, c])
__global__ void k_tconv(const float* __restrict__ in, ushort* __restrict__ out,
                        int R, int Cc) {
  __shared__ float tile[32][33];
  int c0 = blockIdx.x * 32, r0 = blockIdx.y * 32;
  int tx = threadIdx.x, ty = threadIdx.y;
  for (int i = 0; i < 32; i += 8) {
    int r = r0 + ty + i, c = c0 + tx;
    if (r < R && c < Cc) tile[ty + i][tx] = in[(size_t)r * Cc + c];
  }
  __syncthreads();
  for (int i = 0; i < 32; i += 8) {
    int oc = c0 + ty + i;
    int orr = r0 + tx;
    if (oc < Cc && orr < R) out[(size_t)oc * R + orr] = f2bf(tile[tx][ty + i]);
  }
}

// ---------------- bf16 MFMA NT GEMM ----------------
__global__ __launch_bounds__(256) void k_mfma_nt(
    const ushort* __restrict__ A, const ushort* __restrict__ B, float* __restrict__ C,
    ushort* __restrict__ Cb, int I, int J, int K, int kChunk, int atom) {
  __shared__ ushort As[64][40];
  __shared__ ushort Bs[64][40];
  int t = threadIdx.x;
  int w = t >> 6, l = t & 63;
  int i0 = blockIdx.y * 64, j0 = blockIdx.x * 64;
  int k0 = blockIdx.z * kChunk;
  int k1 = min(k0 + kChunk, K);
  f32x4 acc[4] = {};
  int lrow = t >> 2;
  int lk = (t & 3) * 8;
  for (int kk = k0; kk < k1; kk += 32) {
    uint4 av = make_uint4(0u, 0u, 0u, 0u);
    int ar = i0 + lrow;
    if (ar < I) av = *(const uint4*)(A + (size_t)ar * K + kk + lk);
    uint4 bv = *(const uint4*)(B + (size_t)(j0 + lrow) * K + kk + lk);
    *(uint4*)&As[lrow][lk] = av;
    *(uint4*)&Bs[lrow][lk] = bv;
    __syncthreads();
    bf16x8 af = *(const bf16x8*)&As[16 * w + (l & 15)][(l >> 4) * 8];
#pragma unroll
    for (int jt = 0; jt < 4; ++jt) {
      bf16x8 bf = *(const bf16x8*)&Bs[16 * jt + (l & 15)][(l >> 4) * 8];
      acc[jt] = __builtin_amdgcn_mfma_f32_16x16x32_bf16(af, bf, acc[jt], 0, 0, 0);
    }
    __syncthreads();
  }
  int rbase = i0 + 16 * w + ((l >> 4) * 4);
  int cbase = j0 + (l & 15);
#pragma unroll
  for (int jt = 0; jt < 4; ++jt) {
#pragma unroll
    for (int rr = 0; rr < 4; ++rr) {
      int r = rbase + rr;
      if (r < I) {
        size_t idx = (size_t)r * J + jt * 16 + cbase;
        if (Cb) Cb[idx] = f2bf(acc[jt][rr]);
        else if (atom) atomicAdd(&C[idx], acc[jt][rr]);
        else C[idx] = acc[jt][rr];
      }
    }
  }
}

// ---------------- fp32 GEMM (small, level-2) ----------------
__global__ __launch_bounds__(256) void k_sgemm_nn(
    const float* __restrict__ A, const float* __restrict__ B, float* __restrict__ C,
    int M, int N, int K) {
  __shared__ float As[16][64];
  __shared__ float Bs[16][68];
  int t = threadIdx.x;
  int tx = t & 15, ty = t >> 4;
  int row0 = blockIdx.y * 64, col0 = blockIdx.x * 64;
  float acc[4][4] = {};
  for (int k0 = 0; k0 < K; k0 += 16) {
    int ar = t >> 2;
    int ak = (t & 3) * 4;
    float4 av = make_float4(0.f, 0.f, 0.f, 0.f);
    if (row0 + ar < M) av = *(const float4*)(A + (size_t)(row0 + ar) * K + k0 + ak);
    As[ak + 0][ar] = av.x; As[ak + 1][ar] = av.y;
    As[ak + 2][ar] = av.z; As[ak + 3][ar] = av.w;
    int bk = t >> 4;
    int bc = (t & 15) * 4;
    float4 bv = *(const float4*)(B + (size_t)(k0 + bk) * N + col0 + bc);
    *(float4*)&Bs[bk][bc] = bv;
    __syncthreads();
#pragma unroll
    for (int k = 0; k < 16; ++k) {
      float a[4], b[4];
#pragma unroll
      for (int u = 0; u < 4; ++u) a[u] = As[k][ty * 4 + u];
#pragma unroll
      for (int v = 0; v < 4; ++v) b[v] = Bs[k][tx * 4 + v];
#pragma unroll
      for (int u = 0; u < 4; ++u)
#pragma unroll
        for (int v = 0; v < 4; ++v) acc[u][v] += a[u] * b[v];
    }
    __syncthreads();
  }
#pragma unroll
  for (int u = 0; u < 4; ++u) {
    int r = row0 + ty * 4 + u;
    if (r < M) {
#pragma unroll
      for (int v = 0; v < 4; ++v) C[(size_t)r * N + col0 + tx * 4 + v] = acc[u][v];
    }
  }
}

__global__ __launch_bounds__(256) void k_sgemm_tn(
    const float* __restrict__ A, const float* __restrict__ B, float* __restrict__ C,
    int M, int I, int J, int mChunk) {
  __shared__ float As[16][68];
  __shared__ float Bs[16][68];
  int t = threadIdx.x;
  int tx = t & 15, ty = t >> 4;
  int i0 = blockIdx.y * 64, j0 = blockIdx.x * 64;
  int m0 = blockIdx.z * mChunk;
  int m1 = min(m0 + mChunk, M);
  float acc[4][4] = {};
  for (int mb = m0; mb < m1; mb += 16) {
    int mr = t >> 4;
    int cc = (t & 15) * 4;
    int m = mb + mr;
    float4 av = make_float4(0.f, 0.f, 0.f, 0.f);
    float4 bv = make_float4(0.f, 0.f, 0.f, 0.f);
    if (m < m1) {
      av = *(const float4*)(A + (size_t)m * I + i0 + cc);
      bv = *(const float4*)(B + (size_t)m * J + j0 + cc);
    }
    *(float4*)&As[mr][cc] = av;
    *(float4*)&Bs[mr][cc] = bv;
    __syncthreads();
#pragma unroll
    for (int k = 0; k < 16; ++k) {
      float a[4], b[4];
#pragma unroll
      for (int u = 0; u < 4; ++u) a[u] = As[k][ty * 4 + u];
#pragma unroll
      for (int v = 0; v < 4; ++v) b[v] = Bs[k][tx * 4 + v];
#pragma unroll
      for (int u = 0; u < 4; ++u)
#pragma unroll
        for (int v = 0; v < 4; ++v) acc[u][v] += a[u] * b[v];
    }
    __syncthreads();
  }
#pragma unroll
  for (int u = 0; u < 4; ++u)
#pragma unroll
    for (int v = 0; v < 4; ++v)
      atomicAdd(&C[(size_t)(i0 + ty * 4 + u) * J + j0 + tx * 4 + v], acc[u][v]);
}

// ---------------- BN stats (no atomics) ----------------

__global__ void k_col_stats2(const float* __restrict__ X, const float* __restrict__ bias,
                             float* __restrict__ part, int M, int C, int rpb) {
  int c = threadIdx.x;
  int b = blockIdx.x;
  int r0 = b * rpb, r1 = min(r0 + rpb, M);
  float bi = bias[c];
  float s = 0.f, sq = 0.f;
  for (int r = r0; r < r1; ++r) {
    float v = X[(size_t)r * C + c] + bi;
    s += v; sq += v * v;
  }
  part[(size_t)b * 2 * C + c] = s;
  part[(size_t)b * 2 * C + C + c] = sq;
}

__global__ void k_colred(const float* __restrict__ part, int nblk, int C,
                         float* __restrict__ cs, float* __restrict__ csq) {
  int c = threadIdx.x;
  float s = 0.f, sq = 0.f;
  for (int b = 0; b < nblk; ++b) {
    s  += part[(size_t)b * 2 * C + c];
    sq += part[(size_t)b * 2 * C + C + c];
  }
  cs[c] = s; csq[c] = sq;
}

__global__ void k_bn_silu(const float* __restrict__ X, const float* __restrict__ bias,
                          const float* __restrict__ cs, const float* __restrict__ csq,
                          const float* __restrict__ g, const float* __restrict__ be,
                          const float* __restrict__ resid, float* __restrict__ out,
                          ushort* __restrict__ outb,
                          int tot, int cmask, float invM) {
  int i = blockIdx.x * blockDim.x + threadIdx.x;
  if (i >= tot) return;
  int c = i & cmask;
  float m = cs[c] * invM;
  float var = csq[c] * invM - m * m;
  float v = (X[i] + bias[c] - m) * rsqrtf(var + EPS_BN) * g[c] + be[c];
  float y = v / (1.f + expf(-v));
  if (resid) y += resid[i];
  out[i] = y;
  if (outb) outb[i] = f2bf(y);
}

// ---------------- softmax + entropy (block partials, no same-address atomics) ----------------
template <int C>
__global__ void k_softmax_ent3(float* __restrict__ X, ushort* __restrict__ outb,
                               float* __restrict__ part, int nrows) {
  constexpr int VPT = C / 64;
  __shared__ float went[4];
  int gt = blockIdx.x * blockDim.x + threadIdx.x;
  int row = gt >> 6;
  int l = gt & 63;
  int wid = threadIdx.x >> 6;
  bool active = row < nrows;
  size_t base = active ? (size_t)row * C : 0;
  float d[VPT];
  if (VPT == 4) {
    float4 v = *(const float4*)(X + base + l * 4);
    d[0] = v.x; d[1] = v.y; d[2] = v.z; d[3] = v.w;
  } else {
    d[0] = X[base + l];
  }
  float mx = d[0];
#pragma unroll
  for (int i = 1; i < VPT; ++i) mx = fmaxf(mx, d[i]);
  for (int o = 32; o > 0; o >>= 1) mx = fmaxf(mx, __shfl_xor(mx, o));
  float se = 0.f;
  float e[VPT];
#pragma unroll
  for (int i = 0; i < VPT; ++i) { d[i] -= mx; e[i] = expf(d[i]); se += e[i]; }
  for (int o = 32; o > 0; o >>= 1) se += __shfl_xor(se, o);
  float inv = 1.f / se;
  float pd = 0.f;
#pragma unroll
  for (int i = 0; i < VPT; ++i) { e[i] *= inv; pd += e[i] * d[i]; }
  if (active) {
    if (VPT == 4) {
      float4 v; v.x = e[0]; v.y = e[1]; v.z = e[2]; v.w = e[3];
      *(float4*)(X + base + l * 4) = v;
      if (outb) {
        ushort4 u; u.x = f2bf(e[0]); u.y = f2bf(e[1]); u.z = f2bf(e[2]); u.w = f2bf(e[3]);
        *(ushort4*)(outb + base + l * 4) = u;
      }
    } else {
      X[base + l] = e[0];
      if (outb) outb[base + l] = f2bf(e[0]);
    }
  }
  for (int o = 32; o > 0; o >>= 1) pd += __shfl_xor(pd, o);
  if (l == 0) went[wid] = active ? (logf(se) - pd) : 0.f;
  __syncthreads();
  if (threadIdx.x == 0) part[blockIdx.x] = went[0] + went[1] + went[2] + went[3];
}

__global__ void k_reduce_arr(const float* __restrict__ in, int n, float* __restrict__ out) {
  __shared__ float sh[256];
  int t = threadIdx.x;
  float s = 0.f;
  for (int i = t; i < n; i += 256) s += in[i];
  sh[t] = s; __syncthreads();
  for (int o = 128; o > 0; o >>= 1) { if (t < o) sh[t] += sh[t + o]; __syncthreads(); }
  if (t == 0) *out = sh[0];
}

__global__ void k_trace(const float* __restrict__ A, int K, float* __restrict__ out) {
  __shared__ float sh[256];
  int t = threadIdx.x;
  float s = 0.f;
  for (int i = t; i < K; i += 256) s += A[(size_t)i * K + i];
  sh[t] = s; __syncthreads();
  for (int o = 128; o > 0; o >>= 1) { if (t < o) sh[t] += sh[t + o]; __syncthreads(); }
  if (t == 0) *out = sh[0];
}

__global__ void k_sumsq(const float* __restrict__ A, int n, float* __restrict__ out) {
  __shared__ float sh[256];
  int t = threadIdx.x;
  float s = 0.f;
  for (int i = blockIdx.x * 256 + t; i < n; i += gridDim.x * 256) { float v = A[i]; s += v * v; }
  sh[t] = s; __syncthreads();
  for (int o = 128; o > 0; o >>= 1) { if (t < o) sh[t] += sh[t + o]; __syncthreads(); }
  if (t == 0) atomicAdd(out, sh[0]);
}

// ---------------- level-2 dense graph ----------------

__global__ void k_deg2(const float* __restrict__ Ap, float* __restrict__ dinv2, int Np) {
  int q = blockIdx.x * blockDim.x + threadIdx.x;
  if (q >= Np) return;
  float d = 1.0f;
  for (int p = 0; p < Np; ++p) d += Ap[(size_t)p * Np + q];
  dinv2[q] = d > 0.f ? rsqrtf(fmaxf(d, 1e-12f)) : 0.f;
}

__global__ void k_dense_agg(const float* __restrict__ Ap, const float* __restrict__ dinv2,
                            const float* __restrict__ H, float* __restrict__ out,
                            int Np, int C) {
  int q = blockIdx.x, c = threadIdx.x;
  float acc = 0.f;
  for (int p = 0; p < Np; ++p)
    acc += dinv2[p] * Ap[(size_t)p * Np + q] * H[(size_t)p * C + c];
  float dq = dinv2[q];
  out[(size_t)q * C + c] = dq * acc + dq * dq * H[(size_t)q * C + c];
}

// ---------------- final head ----------------
__global__ void k_final(const float* __restrict__ xp2, const float* __restrict__ Wlin,
                        const float* __restrict__ blin, const float* __restrict__ scal,
                        float* __restrict__ out, int N1, int E1, int K1, int K2, int OUT) {
  __shared__ float pooled[128];
  __shared__ float logits[32];
  int t = threadIdx.x;
  float s = 0.f;
  for (int r = 0; r < K2; ++r) s += xp2[(size_t)r * 128 + t];
  pooled[t] = s / (float)K2;
  __syncthreads();
  if (t < OUT) {
    float acc = blin[t];
    for (int k = 0; k < 128; ++k) acc += pooled[k] * Wlin[(size_t)k * OUT + t];
    logits[t] = acc;
  }
  __syncthreads();
  if (t == 0) {
    float mx = logits[0];
    for (int j = 1; j < OUT; ++j) mx = fmaxf(mx, logits[j]);
    float se = 0.f;
    for (int j = 0; j < OUT; ++j) se += expf(logits[j] - mx);
    float lse = mx + logf(se);
    for (int j = 0; j < OUT; ++j) out[j] = logits[j] - lse;
    float n1 = (float)N1;
    float ent1 = scal[0] / n1;
    float ent2 = scal[1] / (float)K1;
    float link1 = sqrtf(fmaxf((float)E1 - 2.f * scal[2] + scal[3], 0.f)) / (n1 * n1);
    float link2 = sqrtf(fmaxf(scal[4] - 2.f * scal[5] + scal[6], 0.f)) / ((float)K1 * (float)K1);
    out[OUT] = ent1 + ent2 + link1 + link2;
  }
}

// ---------------- host ----------------

extern "C" void kernel_launch(void* const* d_in, const int* in_sizes, int n_in,
                              void* d_out, int out_size, void* d_ws, size_t ws_size,
                              hipStream_t stream) {
  (void)n_in; (void)out_size; (void)ws_size;
  const float* x = (const float*)d_in[0];
  const int* ei  = (const int*)d_in[1];
  const int N = in_sizes[0] / 128;   // 20000
  const int E = in_sizes[1] / 2;     // 640000
  const int* src = ei;
  const int* dst = ei + E;
  const float *W1a=(const float*)d_in[4],  *b1a=(const float*)d_in[5],
              *g1a=(const float*)d_in[6],  *be1a=(const float*)d_in[7];
  const float *W1b=(const float*)d_in[8],  *b1b=(const float*)d_in[9],
              *g1b=(const float*)d_in[10], *be1b=(const float*)d_in[11];
  const float *Wp1=(const float*)d_in[12], *bp1=(const float*)d_in[13],
              *gp1=(const float*)d_in[14], *bep1=(const float*)d_in[15];
  const float *W2a=(const float*)d_in[16], *b2a=(const float*)d_in[17],
              *g2a=(const float*)d_in[18], *be2a=(const float*)d_in[19];
  const float *W2b=(const float*)d_in[20], *b2b=(const float*)d_in[21],
              *g2b=(const float*)d_in[22], *be2b=(const float*)d_in[23];
  const float *Wp2=(const float*)d_in[24], *bp2=(const float*)d_in[25],
              *gp2=(const float*)d_in[26], *bep2=(const float*)d_in[27];
  const float *Wlin=(const float*)d_in[28], *blin=(const float*)d_in[29];
  const int K1 = in_sizes[12] / 128;   // 256
  const int K2 = in_sizes[24] / 128;   // 64
  const int OUT = in_sizes[29];        // 10

  char* base = (char*)d_ws;
  size_t off = 0;
  auto allocb = [&](size_t bytes) -> void* {
    void* p = (void*)(base + off);
    off += ((bytes + 255) & ~(size_t)255);
    return p;
  };
  auto alloc = [&](size_t nf) -> float* { return (float*)allocb(nf * 4); };
  auto alloci = [&](size_t ni) -> int* { return (int*)allocb(ni * 4); };
  auto allocu = [&](size_t nu) -> ushort* { return (ushort*)allocb(nu * 2); };

  auto cdiv = [](long long a, long long b) { return (int)((a + b - 1) / b); };

  float* scal  = alloc(16);
  float* cs    = alloc(256);
  float* csq   = alloc(256);
  float* dinv  = alloc(N);
  float* dinv2 = alloc(K1);
  float* apool = alloc((size_t)K1 * K1);
  float* sts   = alloc((size_t)K1 * K1);
  float* xp    = alloc((size_t)K1 * 128);
  float* h2    = alloc((size_t)K1 * 128);
  float* y2    = alloc((size_t)K1 * 128);
  float* xa2   = alloc((size_t)K1 * 128);
  float* x2f   = alloc((size_t)K1 * 128);
  float* s2b   = alloc((size_t)K1 * K2);
  float* t2    = alloc((size_t)K1 * K2);
  float* a2    = alloc((size_t)K2 * K2);
  float* sts2  = alloc((size_t)K2 * K2);
  float* xp2   = alloc((size_t)K2 * 128);
  float* ent1p = alloc(cdiv(N, 4) + 8);
  float* ent2p = alloc(64 + 8);
  float* csp   = alloc((size_t)(cdiv(N, 64) + 2) * 512);
  float* R1 = alloc((size_t)N * 128);   // fp32; later St bf16 [K1,N] (exact fit)
  float* R2 = alloc((size_t)N * 128);   // fp32; later ASt bf16 [K1,N] (exact fit)
  float* R3 = alloc((size_t)N * K1);    // Hb bf16 / Sb bf16 [N,K1]
  float* R4 = alloc((size_t)N * K1);    // agg out / S fp32 / AS fp32
  ushort* B16A = allocu((size_t)N * 128);  // xb -> R1b -> R2b -> R2t
  ushort* W1at = allocu(128 * 128);
  ushort* W1bt = allocu(128 * 128);
  ushort* Wp1t = allocu((size_t)K1 * 128);
  // CSR structures
  int* cnt_d = alloci(N);
  int* rp_d  = alloci(N + 1);
  int* cur_d = alloci(N);
  int* col_s = alloci(E);
  int* cnt_s = alloci(N);
  int* rp_s  = alloci(N + 1);
  int* cur_s = alloci(N);
  int* col_d = alloci(E);

  ushort* Hb  = (ushort*)R3;   // [N, C<=256] bf16 GEMM output for gather
  ushort* Sb  = (ushort*)R3;   // [N, K1] bf16 row-major S (overwrites dead Hb; 10.24MB <= 20.48MB)
  ushort* St  = (ushort*)R1;   // [K1, N] bf16 (R1 dead by then; exact fit)
  ushort* ASt = (ushort*)R2;   // [K1, N] bf16 (R2 dead after R2t transpose; exact fit)
  ushort* R2t = B16A;          // [128, N] bf16 (after R2b dead)

  hipMemsetAsync(scal, 0, 16 * sizeof(float), stream);

  // ---- CSR by dst (+ dinv) ----
  hipMemsetAsync(cnt_d, 0, N * sizeof(int), stream);
  k_hist<<<cdiv(E, 256), 256, 0, stream>>>(dst, cnt_d, E);
  k_scan<<<1, 1024, 0, stream>>>(cnt_d, rp_d, cur_d, N, E);
  k_fill_csr<<<cdiv(E, 256), 256, 0, stream>>>(dst, src, cur_d, col_s, E);
  k_dinv_cnt<<<cdiv(N, 256), 256, 0, stream>>>(cnt_d, dinv, N);
  // ---- CSR by src ----
  hipMemsetAsync(cnt_s, 0, N * sizeof(int), stream);
  k_hist<<<cdiv(E, 256), 256, 0, stream>>>(src, cnt_s, E);
  k_scan<<<1, 1024, 0, stream>>>(cnt_s, rp_s, cur_s, N, E);
  k_fill_csr<<<cdiv(E, 256), 256, 0, stream>>>(src, dst, cur_s, col_d, E);

  // ---- weight transposes + x conversion ----
  {
    dim3 b32(32, 8);
    k_tconv<<<dim3(4, 4), b32, 0, stream>>>(W1a, W1at, 128, 128);
    k_tconv<<<dim3(4, 4), b32, 0, stream>>>(W1b, W1bt, 128, 128);
    k_tconv<<<dim3(8, 4), b32, 0, stream>>>(Wp1, Wp1t, 128, K1);
  }
  k_conv<<<cdiv((size_t)N * 128 / 4, 256), 256, 0, stream>>>(x, B16A, N * 128 / 4);

  auto mfma_nt = [&](const ushort* A, const ushort* B, float* C, ushort* Cb,
                     int I, int J, int K, int nz) {
    int chunk = K, z = 1;
    if (nz > 1) {
      chunk = ((cdiv(K, nz) + 31) & ~31);
      z = cdiv(K, chunk);
      hipMemsetAsync(C, 0, (size_t)I * J * sizeof(float), stream);
    }
    dim3 g(J / 64, cdiv(I, 64), z);
    k_mfma_nt<<<g, 256, 0, stream>>>(A, B, C, Cb, I, J, K, chunk, z > 1 ? 1 : 0);
  };
  auto gemm_nn = [&](const float* A, const float* B, float* C, int M, int Nn, int K) {
    dim3 g(Nn / 64, cdiv(M, 64));
    k_sgemm_nn<<<g, 256, 0, stream>>>(A, B, C, M, Nn, K);
  };
  auto gemm_tn = [&](const float* A, const float* B, float* C, int M, int I, int J, int nz) {
    hipMemsetAsync(C, 0, (size_t)I * J * sizeof(float), stream);
    int chunk = cdiv(M, nz);
    chunk = (chunk + 15) & ~15;
    int zz = cdiv(M, chunk);
    dim3 g(J / 64, I / 64, zz);
    k_sgemm_tn<<<g, 256, 0, stream>>>(A, B, C, M, I, J, chunk);
  };

  // level-1 ResidualBlock: GCN(W) -> BN -> SiLU (+resid); bf16 staging
  auto block1 = [&](const ushort* xin_b, const ushort* Wt, const float* b, const float* gg,
                    const float* be, const float* resid, float* outp, ushort* outb, int C) {
    mfma_nt(xin_b, Wt, nullptr, Hb, N, C, 128, 1);
    k_gather_agg_b2<<<N, C / 2, 0, stream>>>(rp_d, col_s, dinv, Hb, R4, C / 2);
    int nblk = cdiv(N, 64);
    k_col_stats2<<<nblk, C, 0, stream>>>(R4, b, csp, N, C, 64);
    k_colred<<<1, C, 0, stream>>>(csp, nblk, C, cs, csq);
    int tot = N * C;
    k_bn_silu<<<cdiv(tot, 256), 256, 0, stream>>>(R4, b, cs, csq, gg, be, resid, outp,
                                                  outb, tot, C - 1, 1.f / N);
  };

  block1(B16A, W1at, b1a, g1a, be1a, nullptr, R1, B16A, 128);  // R1 + R1b
  block1(B16A, W1bt, b1b, g1b, be1b, R1,      R2, B16A, 128);  // R2 + R2b
  block1(B16A, Wp1t, bp1, gp1, bep1, nullptr, R4, nullptr, K1); // pooling feats in R4
  // S = softmax(R4) fp32 in-place + bf16 copy in Sb (over dead Hb)
  k_softmax_ent3<256><<<cdiv(N, 4), 256, 0, stream>>>(R4, Sb, ent1p, N);
  k_reduce_arr<<<1, 256, 0, stream>>>(ent1p, cdiv(N, 4), &scal[0]);

  {
    dim3 b32(32, 8);
    // St = S^T bf16 (from fp32 S in R4) — BEFORE R4 is reused for AS
    k_tconv<<<dim3(K1 / 32, cdiv(N, 32)), b32, 0, stream>>>(R4, St, N, K1);
    // R2t = x^T bf16 (R2 becomes dead)
    k_tconv<<<dim3(128 / 32, cdiv(N, 32)), b32, 0, stream>>>(R2, R2t, N, 128);
  }
  // AS = A S (gather over bf16 Sb) -> R4 fp32 (S fp32 dead now)
  k_gather_T_b2<<<N, K1 / 2, 0, stream>>>(rp_s, col_d, Sb, R4, K1 / 2);
  {
    dim3 b32(32, 8);
    // ASt = (AS)^T bf16 into dead R2
    k_tconv<<<dim3(K1 / 32, cdiv(N, 32)), b32, 0, stream>>>(R4, ASt, N, K1);
  }

  mfma_nt(St, ASt, apool, nullptr, K1, K1, N, 16);   // a_pool = S^T (A S)
  mfma_nt(St, St,  sts,   nullptr, K1, K1, N, 16);   // sts = S^T S
  mfma_nt(St, R2t, xp,    nullptr, K1, 128, N, 16);  // xp = S^T x
  k_trace<<<1, 256, 0, stream>>>(apool, K1, &scal[2]);
  k_sumsq<<<64, 256, 0, stream>>>(sts, K1 * K1, &scal[3]);
  k_sumsq<<<64, 256, 0, stream>>>(apool, K1 * K1, &scal[4]);

  // ---------------- level 2 (dense 256-node graph) ----------------
  k_deg2<<<1, 256, 0, stream>>>(apool, dinv2, K1);

  auto block2 = [&](const float* xin, const float* W, const float* b, const float* gg,
                    const float* be, const float* resid, float* outp, int C) {
    gemm_nn(xin, W, h2, K1, C, 128);
    k_dense_agg<<<K1, C, 0, stream>>>(apool, dinv2, h2, y2, K1, C);
    int nblk = cdiv(K1, 64);
    k_col_stats2<<<nblk, C, 0, stream>>>(y2, b, csp, K1, C, 64);
    k_colred<<<1, C, 0, stream>>>(csp, nblk, C, cs, csq);
    k_bn_silu<<<cdiv(K1 * C, 256), 256, 0, stream>>>(y2, b, cs, csq, gg, be, resid, outp,
                                                     nullptr, K1 * C, C - 1, 1.f / K1);
  };

  block2(xp,  W2a, b2a, g2a, be2a, nullptr, xa2, 128);
  block2(xa2, W2b, b2b, g2b, be2b, xa2,     x2f, 128);
  block2(x2f, Wp2, bp2, gp2, bep2, nullptr, s2b, K2);
  k_softmax_ent3<64><<<cdiv(K1, 4), 256, 0, stream>>>(s2b, nullptr, ent2p, K1);
  k_reduce_arr<<<1, 256, 0, stream>>>(ent2p, cdiv(K1, 4), &scal[1]);

  gemm_nn(apool, s2b, t2, K1, K2, K1);
  gemm_tn(s2b, t2,  a2,   K1, K2, K2, 1);
  gemm_tn(s2b, s2b, sts2, K1, K2, K2, 1);
  gemm_tn(s2b, x2f, xp2,  K1, K2, 128, 1);
  k_trace<<<1, 256, 0, stream>>>(a2, K2, &scal[5]);
  k_sumsq<<<16, 256, 0, stream>>>(sts2, K2 * K2, &scal[6]);

  k_final<<<1, 128, 0, stream>>>(xp2, Wlin, blin, scal, (float*)d_out, N, E, K1, K2, OUT);
}

// Round 6
// 873.221 us; speedup vs baseline: 3.2948x; 1.5689x over previous
//
#include <hip/hip_runtime.h>

#define EPS_BN 1e-5f
typedef unsigned int uint;
typedef unsigned short ushort;
typedef __attribute__((ext_vector_type(8))) short bf16x8;
typedef __attribute__((ext_vector_type(4))) float f32x4;

__device__ inline ushort f2bf(float f) {
  uint u = __float_as_uint(f);
  uint r = (u + 0x7FFFu + ((u >> 16) & 1u)) >> 16;
  return (ushort)r;
}
__device__ inline float bflo(uint h) { return __uint_as_float(h << 16); }
__device__ inline float bfhi(uint h) { return __uint_as_float(h & 0xFFFF0000u); }

// ---------------- CSR build ----------------

__global__ void k_hist(const int* __restrict__ idx, int* __restrict__ cnt, int E) {
  int e = blockIdx.x * blockDim.x + threadIdx.x;
  if (e < E) atomicAdd(&cnt[idx[e]], 1);
}

__global__ __launch_bounds__(1024) void k_scan(
    const int* __restrict__ cnt, int* __restrict__ rowptr, int* __restrict__ cursor,
    int N, int E) {
  __shared__ int sh[1024];
  int t = threadIdx.x;
  int chunk = (N + 1023) / 1024;
  int i0 = t * chunk, i1 = min(i0 + chunk, N);
  int s = 0;
  for (int i = i0; i < i1; ++i) s += cnt[i];
  sh[t] = s; __syncthreads();
  for (int o = 1; o < 1024; o <<= 1) {
    int v = (t >= o) ? sh[t - o] : 0;
    __syncthreads();
    sh[t] += v;
    __syncthreads();
  }
  int run = (t == 0) ? 0 : sh[t - 1];
  for (int i = i0; i < i1; ++i) { rowptr[i] = run; cursor[i] = run; run += cnt[i]; }
  if (t == 1023) rowptr[N] = E;
}

__global__ void k_fill_csr(const int* __restrict__ key, const int* __restrict__ val,
                           int* __restrict__ cursor, int* __restrict__ col, int E) {
  int e = blockIdx.x * blockDim.x + threadIdx.x;
  if (e < E) {
    int pos = atomicAdd(&cursor[key[e]], 1);
    col[pos] = val[e];
  }
}

__global__ void k_dinv_cnt(const int* __restrict__ cnt, float* __restrict__ dinv, int n) {
  int i = blockIdx.x * blockDim.x + threadIdx.x;
  if (i < n) dinv[i] = rsqrtf(1.0f + (float)cnt[i]);
}

// ---------------- gather aggregation, bf16 input, 2 ch/thread ----------------

__global__ void k_gather_agg_b2(const int* __restrict__ rowptr, const int* __restrict__ col,
                                const float* __restrict__ dinv, const ushort* __restrict__ H,
                                float* __restrict__ out, int C2) {
  int d = blockIdx.x;
  int c2 = threadIdx.x;
  const uint* H2 = (const uint*)H;
  int b = rowptr[d], e = rowptr[d + 1];
  float a0 = 0.f, a1 = 0.f;
  for (int i = b; i < e; ++i) {
    int s = col[i];
    float dv = dinv[s];
    uint h = H2[(size_t)s * C2 + c2];
    a0 += dv * bflo(h);
    a1 += dv * bfhi(h);
  }
  float dd = dinv[d];
  uint hd = H2[(size_t)d * C2 + c2];
  float2 o;
  o.x = dd * a0 + dd * dd * bflo(hd);
  o.y = dd * a1 + dd * dd * bfhi(hd);
  *(float2*)(out + (size_t)d * (C2 * 2) + c2 * 2) = o;
}

__global__ void k_gather_T_b2(const int* __restrict__ rowptr, const int* __restrict__ col,
                              const ushort* __restrict__ S, float* __restrict__ T, int C2) {
  int s = blockIdx.x;
  int c2 = threadIdx.x;
  const uint* S2 = (const uint*)S;
  int b = rowptr[s], e = rowptr[s + 1];
  float a0 = 0.f, a1 = 0.f;
  for (int i = b; i < e; ++i) {
    int d = col[i];
    uint h = S2[(size_t)d * C2 + c2];
    a0 += bflo(h);
    a1 += bfhi(h);
  }
  float2 o; o.x = a0; o.y = a1;
  *(float2*)(T + (size_t)s * (C2 * 2) + c2 * 2) = o;
}

// ---------------- conversion / transpose ----------------

__global__ void k_conv(const float* __restrict__ in, ushort* __restrict__ out, int n4) {
  int i = blockIdx.x * blockDim.x + threadIdx.x;
  if (i < n4) {
    float4 v = ((const float4*)in)[i];
    ushort4 o;
    o.x = f2bf(v.x); o.y = f2bf(v.y); o.z = f2bf(v.z); o.w = f2bf(v.w);
    ((ushort4*)out)[i] = o;
  }
}

// out[c, r] = bf16(in[r, c])
__global__ void k_tconv(const float* __restrict__ in, ushort* __restrict__ out,
                        int R, int Cc) {
  __shared__ float tile[32][33];
  int c0 = blockIdx.x * 32, r0 = blockIdx.y * 32;
  int tx = threadIdx.x, ty = threadIdx.y;
  for (int i = 0; i < 32; i += 8) {
    int r = r0 + ty + i, c = c0 + tx;
    if (r < R && c < Cc) tile[ty + i][tx] = in[(size_t)r * Cc + c];
  }
  __syncthreads();
  for (int i = 0; i < 32; i += 8) {
    int oc = c0 + ty + i;
    int orr = r0 + tx;
    if (oc < Cc && orr < R) out[(size_t)oc * R + orr] = f2bf(tile[tx][ty + i]);
  }
}

// ---------------- bf16 MFMA NT GEMM ----------------
__global__ __launch_bounds__(256) void k_mfma_nt(
    const ushort* __restrict__ A, const ushort* __restrict__ B, float* __restrict__ C,
    ushort* __restrict__ Cb, int I, int J, int K, int kChunk, int atom) {
  __shared__ ushort As[64][40];
  __shared__ ushort Bs[64][40];
  int t = threadIdx.x;
  int w = t >> 6, l = t & 63;
  int i0 = blockIdx.y * 64, j0 = blockIdx.x * 64;
  int k0 = blockIdx.z * kChunk;
  int k1 = min(k0 + kChunk, K);
  f32x4 acc[4] = {};
  int lrow = t >> 2;
  int lk = (t & 3) * 8;
  for (int kk = k0; kk < k1; kk += 32) {
    uint4 av = make_uint4(0u, 0u, 0u, 0u);
    int ar = i0 + lrow;
    if (ar < I) av = *(const uint4*)(A + (size_t)ar * K + kk + lk);
    uint4 bv = *(const uint4*)(B + (size_t)(j0 + lrow) * K + kk + lk);
    *(uint4*)&As[lrow][lk] = av;
    *(uint4*)&Bs[lrow][lk] = bv;
    __syncthreads();
    bf16x8 af = *(const bf16x8*)&As[16 * w + (l & 15)][(l >> 4) * 8];
#pragma unroll
    for (int jt = 0; jt < 4; ++jt) {
      bf16x8 bf = *(const bf16x8*)&Bs[16 * jt + (l & 15)][(l >> 4) * 8];
      acc[jt] = __builtin_amdgcn_mfma_f32_16x16x32_bf16(af, bf, acc[jt], 0, 0, 0);
    }
    __syncthreads();
  }
  int rbase = i0 + 16 * w + ((l >> 4) * 4);
  int cbase = j0 + (l & 15);
#pragma unroll
  for (int jt = 0; jt < 4; ++jt) {
#pragma unroll
    for (int rr = 0; rr < 4; ++rr) {
      int r = rbase + rr;
      if (r < I) {
        size_t idx = (size_t)r * J + jt * 16 + cbase;
        if (Cb) Cb[idx] = f2bf(acc[jt][rr]);
        else if (atom) atomicAdd(&C[idx], acc[jt][rr]);
        else C[idx] = acc[jt][rr];
      }
    }
  }
}

// ---------------- fp32 GEMM (small, level-2) ----------------
__global__ __launch_bounds__(256) void k_sgemm_nn(
    const float* __restrict__ A, const float* __restrict__ B, float* __restrict__ C,
    int M, int N, int K) {
  __shared__ float As[16][64];
  __shared__ float Bs[16][68];
  int t = threadIdx.x;
  int tx = t & 15, ty = t >> 4;
  int row0 = blockIdx.y * 64, col0 = blockIdx.x * 64;
  float acc[4][4] = {};
  for (int k0 = 0; k0 < K; k0 += 16) {
    int ar = t >> 2;
    int ak = (t & 3) * 4;
    float4 av = make_float4(0.f, 0.f, 0.f, 0.f);
    if (row0 + ar < M) av = *(const float4*)(A + (size_t)(row0 + ar) * K + k0 + ak);
    As[ak + 0][ar] = av.x; As[ak + 1][ar] = av.y;
    As[ak + 2][ar] = av.z; As[ak + 3][ar] = av.w;
    int bk = t >> 4;
    int bc = (t & 15) * 4;
    float4 bv = *(const float4*)(B + (size_t)(k0 + bk) * N + col0 + bc);
    *(float4*)&Bs[bk][bc] = bv;
    __syncthreads();
#pragma unroll
    for (int k = 0; k < 16; ++k) {
      float a[4], b[4];
#pragma unroll
      for (int u = 0; u < 4; ++u) a[u] = As[k][ty * 4 + u];
#pragma unroll
      for (int v = 0; v < 4; ++v) b[v] = Bs[k][tx * 4 + v];
#pragma unroll
      for (int u = 0; u < 4; ++u)
#pragma unroll
        for (int v = 0; v < 4; ++v) acc[u][v] += a[u] * b[v];
    }
    __syncthreads();
  }
#pragma unroll
  for (int u = 0; u < 4; ++u) {
    int r = row0 + ty * 4 + u;
    if (r < M) {
#pragma unroll
      for (int v = 0; v < 4; ++v) C[(size_t)r * N + col0 + tx * 4 + v] = acc[u][v];
    }
  }
}

__global__ __launch_bounds__(256) void k_sgemm_tn(
    const float* __restrict__ A, const float* __restrict__ B, float* __restrict__ C,
    int M, int I, int J, int mChunk) {
  __shared__ float As[16][68];
  __shared__ float Bs[16][68];
  int t = threadIdx.x;
  int tx = t & 15, ty = t >> 4;
  int i0 = blockIdx.y * 64, j0 = blockIdx.x * 64;
  int m0 = blockIdx.z * mChunk;
  int m1 = min(m0 + mChunk, M);
  float acc[4][4] = {};
  for (int mb = m0; mb < m1; mb += 16) {
    int mr = t >> 4;
    int cc = (t & 15) * 4;
    int m = mb + mr;
    float4 av = make_float4(0.f, 0.f, 0.f, 0.f);
    float4 bv = make_float4(0.f, 0.f, 0.f, 0.f);
    if (m < m1) {
      av = *(const float4*)(A + (size_t)m * I + i0 + cc);
      bv = *(const float4*)(B + (size_t)m * J + j0 + cc);
    }
    *(float4*)&As[mr][cc] = av;
    *(float4*)&Bs[mr][cc] = bv;
    __syncthreads();
#pragma unroll
    for (int k = 0; k < 16; ++k) {
      float a[4], b[4];
#pragma unroll
      for (int u = 0; u < 4; ++u) a[u] = As[k][ty * 4 + u];
#pragma unroll
      for (int v = 0; v < 4; ++v) b[v] = Bs[k][tx * 4 + v];
#pragma unroll
      for (int u = 0; u < 4; ++u)
#pragma unroll
        for (int v = 0; v < 4; ++v) acc[u][v] += a[u] * b[v];
    }
    __syncthreads();
  }
#pragma unroll
  for (int u = 0; u < 4; ++u)
#pragma unroll
    for (int v = 0; v < 4; ++v)
      atomicAdd(&C[(size_t)(i0 + ty * 4 + u) * J + j0 + tx * 4 + v], acc[u][v]);
}

// ---------------- BN stats (no atomics, parallel reduce) ----------------

__global__ void k_col_stats2(const float* __restrict__ X, const float* __restrict__ bias,
                             float* __restrict__ part, int M, int C, int rpb) {
  int c = threadIdx.x;
  int b = blockIdx.x;
  int r0 = b * rpb, r1 = min(r0 + rpb, M);
  float bi = bias[c];
  float s = 0.f, sq = 0.f;
  for (int r = r0; r < r1; ++r) {
    float v = X[(size_t)r * C + c] + bi;
    s += v; sq += v * v;
  }
  part[(size_t)b * 2 * C + c] = s;
  part[(size_t)b * 2 * C + C + c] = sq;
}

// one block per column; 256 threads strided over partial-blocks
__global__ __launch_bounds__(256) void k_colred_par(
    const float* __restrict__ part, int nblk, int C,
    float* __restrict__ cs, float* __restrict__ csq) {
  __shared__ float sh[256];
  int c = blockIdx.x;
  int t = threadIdx.x;
  float s = 0.f, sq = 0.f;
  for (int b = t; b < nblk; b += 256) {
    s  += part[(size_t)b * 2 * C + c];
    sq += part[(size_t)b * 2 * C + C + c];
  }
  sh[t] = s; __syncthreads();
  for (int o = 128; o > 0; o >>= 1) { if (t < o) sh[t] += sh[t + o]; __syncthreads(); }
  if (t == 0) cs[c] = sh[0];
  __syncthreads();
  sh[t] = sq; __syncthreads();
  for (int o = 128; o > 0; o >>= 1) { if (t < o) sh[t] += sh[t + o]; __syncthreads(); }
  if (t == 0) csq[c] = sh[0];
}

__global__ void k_bn_silu(const float* __restrict__ X, const float* __restrict__ bias,
                          const float* __restrict__ cs, const float* __restrict__ csq,
                          const float* __restrict__ g, const float* __restrict__ be,
                          const float* __restrict__ resid, float* __restrict__ out,
                          ushort* __restrict__ outb,
                          int tot, int cmask, float invM) {
  int i = blockIdx.x * blockDim.x + threadIdx.x;
  if (i >= tot) return;
  int c = i & cmask;
  float m = cs[c] * invM;
  float var = csq[c] * invM - m * m;
  float v = (X[i] + bias[c] - m) * rsqrtf(var + EPS_BN) * g[c] + be[c];
  float y = v / (1.f + expf(-v));
  if (resid) y += resid[i];
  out[i] = y;
  if (outb) outb[i] = f2bf(y);
}

// ---------------- softmax + entropy (block partials) ----------------
template <int C>
__global__ void k_softmax_ent3(float* __restrict__ X, ushort* __restrict__ outb,
                               float* __restrict__ part, int nrows) {
  constexpr int VPT = C / 64;
  __shared__ float went[4];
  int gt = blockIdx.x * blockDim.x + threadIdx.x;
  int row = gt >> 6;
  int l = gt & 63;
  int wid = threadIdx.x >> 6;
  bool active = row < nrows;
  size_t base = active ? (size_t)row * C : 0;
  float d[VPT];
  if (VPT == 4) {
    float4 v = *(const float4*)(X + base + l * 4);
    d[0] = v.x; d[1] = v.y; d[2] = v.z; d[3] = v.w;
  } else {
    d[0] = X[base + l];
  }
  float mx = d[0];
#pragma unroll
  for (int i = 1; i < VPT; ++i) mx = fmaxf(mx, d[i]);
  for (int o = 32; o > 0; o >>= 1) mx = fmaxf(mx, __shfl_xor(mx, o));
  float se = 0.f;
  float e[VPT];
#pragma unroll
  for (int i = 0; i < VPT; ++i) { d[i] -= mx; e[i] = expf(d[i]); se += e[i]; }
  for (int o = 32; o > 0; o >>= 1) se += __shfl_xor(se, o);
  float inv = 1.f / se;
  float pd = 0.f;
#pragma unroll
  for (int i = 0; i < VPT; ++i) { e[i] *= inv; pd += e[i] * d[i]; }
  if (active) {
    if (VPT == 4) {
      float4 v; v.x = e[0]; v.y = e[1]; v.z = e[2]; v.w = e[3];
      *(float4*)(X + base + l * 4) = v;
      if (outb) {
        ushort4 u; u.x = f2bf(e[0]); u.y = f2bf(e[1]); u.z = f2bf(e[2]); u.w = f2bf(e[3]);
        *(ushort4*)(outb + base + l * 4) = u;
      }
    } else {
      X[base + l] = e[0];
      if (outb) outb[base + l] = f2bf(e[0]);
    }
  }
  for (int o = 32; o > 0; o >>= 1) pd += __shfl_xor(pd, o);
  if (l == 0) went[wid] = active ? (logf(se) - pd) : 0.f;
  __syncthreads();
  if (threadIdx.x == 0) part[blockIdx.x] = went[0] + went[1] + went[2] + went[3];
}

__global__ __launch_bounds__(1024) void k_reduce_arr(
    const float* __restrict__ in, int n, float* __restrict__ out) {
  __shared__ float sh[1024];
  int t = threadIdx.x;
  float s = 0.f;
  for (int i = t; i < n; i += 1024) s += in[i];
  sh[t] = s; __syncthreads();
  for (int o = 512; o > 0; o >>= 1) { if (t < o) sh[t] += sh[t + o]; __syncthreads(); }
  if (t == 0) *out = sh[0];
}

__global__ void k_trace(const float* __restrict__ A, int K, float* __restrict__ out) {
  __shared__ float sh[256];
  int t = threadIdx.x;
  float s = 0.f;
  for (int i = t; i < K; i += 256) s += A[(size_t)i * K + i];
  sh[t] = s; __syncthreads();
  for (int o = 128; o > 0; o >>= 1) { if (t < o) sh[t] += sh[t + o]; __syncthreads(); }
  if (t == 0) *out = sh[0];
}

__global__ void k_sumsq(const float* __restrict__ A, int n, float* __restrict__ out) {
  __shared__ float sh[256];
  int t = threadIdx.x;
  float s = 0.f;
  for (int i = blockIdx.x * 256 + t; i < n; i += gridDim.x * 256) { float v = A[i]; s += v * v; }
  sh[t] = s; __syncthreads();
  for (int o = 128; o > 0; o >>= 1) { if (t < o) sh[t] += sh[t + o]; __syncthreads(); }
  if (t == 0) atomicAdd(out, sh[0]);
}

// ---------------- level-2 dense graph ----------------

// one block per q; parallel column sum
__global__ __launch_bounds__(256) void k_deg2_par(
    const float* __restrict__ Ap, float* __restrict__ dinv2, int Np) {
  __shared__ float sh[256];
  int q = blockIdx.x;
  int t = threadIdx.x;
  float s = (t == 0) ? 1.0f : 0.f;
  for (int p = t; p < Np; p += 256) s += Ap[(size_t)p * Np + q];
  sh[t] = s; __syncthreads();
  for (int o = 128; o > 0; o >>= 1) { if (t < o) sh[t] += sh[t + o]; __syncthreads(); }
  if (t == 0) {
    float d = sh[0];
    dinv2[q] = d > 0.f ? rsqrtf(fmaxf(d, 1e-12f)) : 0.f;
  }
}

__global__ void k_dense_agg(const float* __restrict__ Ap, const float* __restrict__ dinv2,
                            const float* __restrict__ H, float* __restrict__ out,
                            int Np, int C) {
  int q = blockIdx.x, c = threadIdx.x;
  float acc = 0.f;
#pragma unroll 8
  for (int p = 0; p < Np; ++p)
    acc += dinv2[p] * Ap[(size_t)p * Np + q] * H[(size_t)p * C + c];
  float dq = dinv2[q];
  out[(size_t)q * C + c] = dq * acc + dq * dq * H[(size_t)q * C + c];
}

// ---------------- final head ----------------
__global__ void k_final(const float* __restrict__ xp2, const float* __restrict__ Wlin,
                        const float* __restrict__ blin, const float* __restrict__ scal,
                        float* __restrict__ out, int N1, int E1, int K1, int K2, int OUT) {
  __shared__ float pooled[128];
  __shared__ float logits[32];
  int t = threadIdx.x;
  float s = 0.f;
  for (int r = 0; r < K2; ++r) s += xp2[(size_t)r * 128 + t];
  pooled[t] = s / (float)K2;
  __syncthreads();
  if (t < OUT) {
    float acc = blin[t];
    for (int k = 0; k < 128; ++k) acc += pooled[k] * Wlin[(size_t)k * OUT + t];
    logits[t] = acc;
  }
  __syncthreads();
  if (t == 0) {
    float mx = logits[0];
    for (int j = 1; j < OUT; ++j) mx = fmaxf(mx, logits[j]);
    float se = 0.f;
    for (int j = 0; j < OUT; ++j) se += expf(logits[j] - mx);
    float lse = mx + logf(se);
    for (int j = 0; j < OUT; ++j) out[j] = logits[j] - lse;
    float n1 = (float)N1;
    float ent1 = scal[0] / n1;
    float ent2 = scal[1] / (float)K1;
    float link1 = sqrtf(fmaxf((float)E1 - 2.f * scal[2] + scal[3], 0.f)) / (n1 * n1);
    float link2 = sqrtf(fmaxf(scal[4] - 2.f * scal[5] + scal[6], 0.f)) / ((float)K1 * (float)K1);
    out[OUT] = ent1 + ent2 + link1 + link2;
  }
}

// ---------------- host ----------------

extern "C" void kernel_launch(void* const* d_in, const int* in_sizes, int n_in,
                              void* d_out, int out_size, void* d_ws, size_t ws_size,
                              hipStream_t stream) {
  (void)n_in; (void)out_size; (void)ws_size;
  const float* x = (const float*)d_in[0];
  const int* ei  = (const int*)d_in[1];
  const int N = in_sizes[0] / 128;   // 20000
  const int E = in_sizes[1] / 2;     // 640000
  const int* src = ei;
  const int* dst = ei + E;
  const float *W1a=(const float*)d_in[4],  *b1a=(const float*)d_in[5],
              *g1a=(const float*)d_in[6],  *be1a=(const float*)d_in[7];
  const float *W1b=(const float*)d_in[8],  *b1b=(const float*)d_in[9],
              *g1b=(const float*)d_in[10], *be1b=(const float*)d_in[11];
  const float *Wp1=(const float*)d_in[12], *bp1=(const float*)d_in[13],
              *gp1=(const float*)d_in[14], *bep1=(const float*)d_in[15];
  const float *W2a=(const float*)d_in[16], *b2a=(const float*)d_in[17],
              *g2a=(const float*)d_in[18], *be2a=(const float*)d_in[19];
  const float *W2b=(const float*)d_in[20], *b2b=(const float*)d_in[21],
              *g2b=(const float*)d_in[22], *be2b=(const float*)d_in[23];
  const float *Wp2=(const float*)d_in[24], *bp2=(const float*)d_in[25],
              *gp2=(const float*)d_in[26], *bep2=(const float*)d_in[27];
  const float *Wlin=(const float*)d_in[28], *blin=(const float*)d_in[29];
  const int K1 = in_sizes[12] / 128;   // 256
  const int K2 = in_sizes[24] / 128;   // 64
  const int OUT = in_sizes[29];        // 10

  char* base = (char*)d_ws;
  size_t off = 0;
  auto allocb = [&](size_t bytes) -> void* {
    void* p = (void*)(base + off);
    off += ((bytes + 255) & ~(size_t)255);
    return p;
  };
  auto alloc = [&](size_t nf) -> float* { return (float*)allocb(nf * 4); };
  auto alloci = [&](size_t ni) -> int* { return (int*)allocb(ni * 4); };
  auto allocu = [&](size_t nu) -> ushort* { return (ushort*)allocb(nu * 2); };

  auto cdiv = [](long long a, long long b) { return (int)((a + b - 1) / b); };

  const int RPB = 16;                      // rows per col-stat block
  const int NBLK1 = cdiv(N, RPB);          // 1250

  float* scal  = alloc(16);
  float* cs    = alloc(256);
  float* csq   = alloc(256);
  float* dinv  = alloc(N);
  float* dinv2 = alloc(K1);
  float* apool = alloc((size_t)K1 * K1);
  float* sts   = alloc((size_t)K1 * K1);
  float* xp    = alloc((size_t)K1 * 128);
  float* h2    = alloc((size_t)K1 * 128);
  float* y2    = alloc((size_t)K1 * 128);
  float* xa2   = alloc((size_t)K1 * 128);
  float* x2f   = alloc((size_t)K1 * 128);
  float* s2b   = alloc((size_t)K1 * K2);
  float* t2    = alloc((size_t)K1 * K2);
  float* a2    = alloc((size_t)K2 * K2);
  float* sts2  = alloc((size_t)K2 * K2);
  float* xp2   = alloc((size_t)K2 * 128);
  float* ent1p = alloc(cdiv(N, 4) + 8);
  float* ent2p = alloc(64 + 8);
  float* csp   = alloc((size_t)(NBLK1 + 2) * 512);
  float* R1 = alloc((size_t)N * 128);   // fp32; later St bf16 [K1,N] (exact fit)
  float* R2 = alloc((size_t)N * 128);   // fp32; later ASt bf16 [K1,N] (exact fit)
  float* R3 = alloc((size_t)N * K1);    // Hb bf16 / Sb bf16 [N,K1]
  float* R4 = alloc((size_t)N * K1);    // agg out / S fp32 / AS fp32
  ushort* B16A = allocu((size_t)N * 128);  // xb -> R1b -> R2b -> R2t
  ushort* W1at = allocu(128 * 128);
  ushort* W1bt = allocu(128 * 128);
  ushort* Wp1t = allocu((size_t)K1 * 128);
  // CSR structures
  int* cnt_d = alloci(N);
  int* rp_d  = alloci(N + 1);
  int* cur_d = alloci(N);
  int* col_s = alloci(E);
  int* cnt_s = alloci(N);
  int* rp_s  = alloci(N + 1);
  int* cur_s = alloci(N);
  int* col_d = alloci(E);

  ushort* Hb  = (ushort*)R3;   // [N, C<=256] bf16 GEMM output for gather
  ushort* Sb  = (ushort*)R3;   // [N, K1] bf16 row-major S (over dead Hb)
  ushort* St  = (ushort*)R1;   // [K1, N] bf16 (R1 dead by then)
  ushort* ASt = (ushort*)R2;   // [K1, N] bf16 (R2 dead after R2t)
  ushort* R2t = B16A;          // [128, N] bf16 (after R2b dead)

  hipMemsetAsync(scal, 0, 16 * sizeof(float), stream);

  // ---- CSR by dst (+ dinv) ----
  hipMemsetAsync(cnt_d, 0, N * sizeof(int), stream);
  k_hist<<<cdiv(E, 256), 256, 0, stream>>>(dst, cnt_d, E);
  k_scan<<<1, 1024, 0, stream>>>(cnt_d, rp_d, cur_d, N, E);
  k_fill_csr<<<cdiv(E, 256), 256, 0, stream>>>(dst, src, cur_d, col_s, E);
  k_dinv_cnt<<<cdiv(N, 256), 256, 0, stream>>>(cnt_d, dinv, N);
  // ---- CSR by src ----
  hipMemsetAsync(cnt_s, 0, N * sizeof(int), stream);
  k_hist<<<cdiv(E, 256), 256, 0, stream>>>(src, cnt_s, E);
  k_scan<<<1, 1024, 0, stream>>>(cnt_s, rp_s, cur_s, N, E);
  k_fill_csr<<<cdiv(E, 256), 256, 0, stream>>>(src, dst, cur_s, col_d, E);

  // ---- weight transposes + x conversion ----
  {
    dim3 b32(32, 8);
    k_tconv<<<dim3(4, 4), b32, 0, stream>>>(W1a, W1at, 128, 128);
    k_tconv<<<dim3(4, 4), b32, 0, stream>>>(W1b, W1bt, 128, 128);
    k_tconv<<<dim3(8, 4), b32, 0, stream>>>(Wp1, Wp1t, 128, K1);
  }
  k_conv<<<cdiv((size_t)N * 128 / 4, 256), 256, 0, stream>>>(x, B16A, N * 128 / 4);

  auto mfma_nt = [&](const ushort* A, const ushort* B, float* C, ushort* Cb,
                     int I, int J, int K, int nz) {
    int chunk = K, z = 1;
    if (nz > 1) {
      chunk = ((cdiv(K, nz) + 31) & ~31);
      z = cdiv(K, chunk);
      hipMemsetAsync(C, 0, (size_t)I * J * sizeof(float), stream);
    }
    dim3 g(J / 64, cdiv(I, 64), z);
    k_mfma_nt<<<g, 256, 0, stream>>>(A, B, C, Cb, I, J, K, chunk, z > 1 ? 1 : 0);
  };
  auto gemm_nn = [&](const float* A, const float* B, float* C, int M, int Nn, int K) {
    dim3 g(Nn / 64, cdiv(M, 64));
    k_sgemm_nn<<<g, 256, 0, stream>>>(A, B, C, M, Nn, K);
  };
  auto gemm_tn = [&](const float* A, const float* B, float* C, int M, int I, int J, int nz) {
    hipMemsetAsync(C, 0, (size_t)I * J * sizeof(float), stream);
    int chunk = cdiv(M, nz);
    chunk = (chunk + 15) & ~15;
    int zz = cdiv(M, chunk);
    dim3 g(J / 64, I / 64, zz);
    k_sgemm_tn<<<g, 256, 0, stream>>>(A, B, C, M, I, J, chunk);
  };

  // level-1 ResidualBlock: GCN(W) -> BN -> SiLU (+resid); bf16 staging
  auto block1 = [&](const ushort* xin_b, const ushort* Wt, const float* b, const float* gg,
                    const float* be, const float* resid, float* outp, ushort* outb, int C) {
    mfma_nt(xin_b, Wt, nullptr, Hb, N, C, 128, 1);
    k_gather_agg_b2<<<N, C / 2, 0, stream>>>(rp_d, col_s, dinv, Hb, R4, C / 2);
    int nblk = cdiv(N, RPB);
    k_col_stats2<<<nblk, C, 0, stream>>>(R4, b, csp, N, C, RPB);
    k_colred_par<<<C, 256, 0, stream>>>(csp, nblk, C, cs, csq);
    int tot = N * C;
    k_bn_silu<<<cdiv(tot, 256), 256, 0, stream>>>(R4, b, cs, csq, gg, be, resid, outp,
                                                  outb, tot, C - 1, 1.f / N);
  };

  block1(B16A, W1at, b1a, g1a, be1a, nullptr, R1, B16A, 128);  // R1 + R1b
  block1(B16A, W1bt, b1b, g1b, be1b, R1,      R2, B16A, 128);  // R2 + R2b
  block1(B16A, Wp1t, bp1, gp1, bep1, nullptr, R4, nullptr, K1); // pooling feats in R4
  // S = softmax(R4) fp32 in-place + bf16 copy in Sb (over dead Hb)
  k_softmax_ent3<256><<<cdiv(N, 4), 256, 0, stream>>>(R4, Sb, ent1p, N);
  k_reduce_arr<<<1, 1024, 0, stream>>>(ent1p, cdiv(N, 4), &scal[0]);

  {
    dim3 b32(32, 8);
    // St = S^T bf16 (from fp32 S in R4) — BEFORE R4 is reused for AS
    k_tconv<<<dim3(K1 / 32, cdiv(N, 32)), b32, 0, stream>>>(R4, St, N, K1);
    // R2t = x^T bf16 (R2 becomes dead)
    k_tconv<<<dim3(128 / 32, cdiv(N, 32)), b32, 0, stream>>>(R2, R2t, N, 128);
  }
  // AS = A S (gather over bf16 Sb) -> R4 fp32 (S fp32 dead now)
  k_gather_T_b2<<<N, K1 / 2, 0, stream>>>(rp_s, col_d, Sb, R4, K1 / 2);
  {
    dim3 b32(32, 8);
    // ASt = (AS)^T bf16 into dead R2
    k_tconv<<<dim3(K1 / 32, cdiv(N, 32)), b32, 0, stream>>>(R4, ASt, N, K1);
  }

  mfma_nt(St, ASt, apool, nullptr, K1, K1, N, 16);   // a_pool = S^T (A S)
  mfma_nt(St, St,  sts,   nullptr, K1, K1, N, 16);   // sts = S^T S
  mfma_nt(St, R2t, xp,    nullptr, K1, 128, N, 16);  // xp = S^T x
  k_trace<<<1, 256, 0, stream>>>(apool, K1, &scal[2]);
  k_sumsq<<<64, 256, 0, stream>>>(sts, K1 * K1, &scal[3]);
  k_sumsq<<<64, 256, 0, stream>>>(apool, K1 * K1, &scal[4]);

  // ---------------- level 2 (dense 256-node graph) ----------------
  k_deg2_par<<<K1, 256, 0, stream>>>(apool, dinv2, K1);

  auto block2 = [&](const float* xin, const float* W, const float* b, const float* gg,
                    const float* be, const float* resid, float* outp, int C) {
    gemm_nn(xin, W, h2, K1, C, 128);
    k_dense_agg<<<K1, C, 0, stream>>>(apool, dinv2, h2, y2, K1, C);
    int nblk = cdiv(K1, RPB);
    k_col_stats2<<<nblk, C, 0, stream>>>(y2, b, csp, K1, C, RPB);
    k_colred_par<<<C, 256, 0, stream>>>(csp, nblk, C, cs, csq);
    k_bn_silu<<<cdiv(K1 * C, 256), 256, 0, stream>>>(y2, b, cs, csq, gg, be, resid, outp,
                                                     nullptr, K1 * C, C - 1, 1.f / K1);
  };

  block2(xp,  W2a, b2a, g2a, be2a, nullptr, xa2, 128);
  block2(xa2, W2b, b2b, g2b, be2b, xa2,     x2f, 128);
  block2(x2f, Wp2, bp2, gp2, bep2, nullptr, s2b, K2);
  k_softmax_ent3<64><<<cdiv(K1, 4), 256, 0, stream>>>(s2b, nullptr, ent2p, K1);
  k_reduce_arr<<<1, 1024, 0, stream>>>(ent2p, cdiv(K1, 4), &scal[1]);

  gemm_nn(apool, s2b, t2, K1, K2, K1);
  gemm_tn(s2b, t2,  a2,   K1, K2, K2, 1);
  gemm_tn(s2b, s2b, sts2, K1, K2, K2, 1);
  gemm_tn(s2b, x2f, xp2,  K1, K2, 128, 1);
  k_trace<<<1, 256, 0, stream>>>(a2, K2, &scal[5]);
  k_sumsq<<<16, 256, 0, stream>>>(sts2, K2 * K2, &scal[6]);

  k_final<<<1, 128, 0, stream>>>(xp2, Wlin, blin, scal, (float*)d_out, N, E, K1, K2, OUT);
}

// Round 7
// 772.385 us; speedup vs baseline: 3.7250x; 1.1306x over previous
//
#include <hip/hip_runtime.h>

#define EPS_BN 1e-5f
typedef unsigned int uint;
typedef unsigned short ushort;
typedef __attribute__((ext_vector_type(8))) short bf16x8;
typedef __attribute__((ext_vector_type(4))) float f32x4;

__device__ inline ushort f2bf(float f) {
  uint u = __float_as_uint(f);
  uint r = (u + 0x7FFFu + ((u >> 16) & 1u)) >> 16;
  return (ushort)r;
}
__device__ inline float bflo(uint h) { return __uint_as_float(h << 16); }
__device__ inline float bfhi(uint h) { return __uint_as_float(h & 0xFFFF0000u); }

// ---------------- CSR build (combined src+dst) ----------------

__global__ void k_hist2(const int* __restrict__ ei, int* __restrict__ cnt_s,
                        int* __restrict__ cnt_d, int E) {
  int i = blockIdx.x * blockDim.x + threadIdx.x;
  if (i < 2 * E) {
    int v = ei[i];
    int* c = (i < E) ? cnt_s : cnt_d;
    atomicAdd(&c[v], 1);
  }
}

__global__ __launch_bounds__(1024) void k_scan2(
    const int* __restrict__ cnt_d, int* __restrict__ rp_d, int* __restrict__ cur_d,
    const int* __restrict__ cnt_s, int* __restrict__ rp_s, int* __restrict__ cur_s,
    int N, int E) {
  __shared__ int sh[1024];
  const int* cnt; int* rowptr; int* cursor;
  if (blockIdx.x == 0) { cnt = cnt_d; rowptr = rp_d; cursor = cur_d; }
  else                 { cnt = cnt_s; rowptr = rp_s; cursor = cur_s; }
  int t = threadIdx.x;
  int chunk = (N + 1023) / 1024;
  int i0 = t * chunk, i1 = min(i0 + chunk, N);
  int s = 0;
  for (int i = i0; i < i1; ++i) s += cnt[i];
  sh[t] = s; __syncthreads();
  for (int o = 1; o < 1024; o <<= 1) {
    int v = (t >= o) ? sh[t - o] : 0;
    __syncthreads();
    sh[t] += v;
    __syncthreads();
  }
  int run = (t == 0) ? 0 : sh[t - 1];
  for (int i = i0; i < i1; ++i) { rowptr[i] = run; cursor[i] = run; run += cnt[i]; }
  if (t == 1023) rowptr[N] = E;
}

// i<E: edge e=i, key=src -> cur_s, col_d[pos]=dst.  i>=E: key=dst -> cur_d, col_s[pos]=src
__global__ void k_fill2(const int* __restrict__ ei, int* __restrict__ cur_d,
                        int* __restrict__ col_s, int* __restrict__ cur_s,
                        int* __restrict__ col_d, int E) {
  int i = blockIdx.x * blockDim.x + threadIdx.x;
  if (i >= 2 * E) return;
  if (i < E) {
    int pos = atomicAdd(&cur_s[ei[i]], 1);
    col_d[pos] = ei[i + E];
  } else {
    int e = i - E;
    int pos = atomicAdd(&cur_d[ei[e + E]], 1);
    col_s[pos] = ei[e];
  }
}

__global__ void k_dinv_cnt(const int* __restrict__ cnt, float* __restrict__ dinv, int n) {
  int i = blockIdx.x * blockDim.x + threadIdx.x;
  if (i < n) dinv[i] = rsqrtf(1.0f + (float)cnt[i]);
}

// ---------------- gather aggregation, bf16 input, 2 ch/thread ----------------

__global__ void k_gather_agg_b2(const int* __restrict__ rowptr, const int* __restrict__ col,
                                const float* __restrict__ dinv, const ushort* __restrict__ H,
                                float* __restrict__ out, int C2) {
  int d = blockIdx.x;
  int c2 = threadIdx.x;
  const uint* H2 = (const uint*)H;
  int b = rowptr[d], e = rowptr[d + 1];
  float a0 = 0.f, a1 = 0.f;
#pragma unroll 4
  for (int i = b; i < e; ++i) {
    int s = col[i];
    float dv = dinv[s];
    uint h = H2[(size_t)s * C2 + c2];
    a0 += dv * bflo(h);
    a1 += dv * bfhi(h);
  }
  float dd = dinv[d];
  uint hd = H2[(size_t)d * C2 + c2];
  float2 o;
  o.x = dd * a0 + dd * dd * bflo(hd);
  o.y = dd * a1 + dd * dd * bfhi(hd);
  *(float2*)(out + (size_t)d * (C2 * 2) + c2 * 2) = o;
}

// bf16 output variant (for aggregate-then-GEMM pooling path)
__global__ void k_gather_agg_b2b(const int* __restrict__ rowptr, const int* __restrict__ col,
                                 const float* __restrict__ dinv, const ushort* __restrict__ H,
                                 ushort* __restrict__ out, int C2) {
  int d = blockIdx.x;
  int c2 = threadIdx.x;
  const uint* H2 = (const uint*)H;
  int b = rowptr[d], e = rowptr[d + 1];
  float a0 = 0.f, a1 = 0.f;
#pragma unroll 4
  for (int i = b; i < e; ++i) {
    int s = col[i];
    float dv = dinv[s];
    uint h = H2[(size_t)s * C2 + c2];
    a0 += dv * bflo(h);
    a1 += dv * bfhi(h);
  }
  float dd = dinv[d];
  uint hd = H2[(size_t)d * C2 + c2];
  ushort2 o;
  o.x = f2bf(dd * a0 + dd * dd * bflo(hd));
  o.y = f2bf(dd * a1 + dd * dd * bfhi(hd));
  *(ushort2*)(out + (size_t)d * (C2 * 2) + c2 * 2) = o;
}

__global__ void k_gather_T_b2(const int* __restrict__ rowptr, const int* __restrict__ col,
                              const ushort* __restrict__ S, float* __restrict__ T, int C2) {
  int s = blockIdx.x;
  int c2 = threadIdx.x;
  const uint* S2 = (const uint*)S;
  int b = rowptr[s], e = rowptr[s + 1];
  float a0 = 0.f, a1 = 0.f;
#pragma unroll 4
  for (int i = b; i < e; ++i) {
    int d = col[i];
    uint h = S2[(size_t)d * C2 + c2];
    a0 += bflo(h);
    a1 += bfhi(h);
  }
  float2 o; o.x = a0; o.y = a1;
  *(float2*)(T + (size_t)s * (C2 * 2) + c2 * 2) = o;
}

// ---------------- conversion / transpose ----------------

__global__ void k_conv(const float* __restrict__ in, ushort* __restrict__ out, int n4) {
  int i = blockIdx.x * blockDim.x + threadIdx.x;
  if (i < n4) {
    float4 v = ((const float4*)in)[i];
    ushort4 o;
    o.x = f2bf(v.x); o.y = f2bf(v.y); o.z = f2bf(v.z); o.w = f2bf(v.w);
    ((ushort4*)out)[i] = o;
  }
}

// out[c, r] = bf16(in[r, c])
__global__ void k_tconv(const float* __restrict__ in, ushort* __restrict__ out,
                        int R, int Cc) {
  __shared__ float tile[32][33];
  int c0 = blockIdx.x * 32, r0 = blockIdx.y * 32;
  int tx = threadIdx.x, ty = threadIdx.y;
  for (int i = 0; i < 32; i += 8) {
    int r = r0 + ty + i, c = c0 + tx;
    if (r < R && c < Cc) tile[ty + i][tx] = in[(size_t)r * Cc + c];
  }
  __syncthreads();
  for (int i = 0; i < 32; i += 8) {
    int oc = c0 + ty + i;
    int orr = r0 + tx;
    if (oc < Cc && orr < R) out[(size_t)oc * R + orr] = f2bf(tile[tx][ty + i]);
  }
}

// ---------------- bf16 MFMA NT GEMM ----------------
__global__ __launch_bounds__(256) void k_mfma_nt(
    const ushort* __restrict__ A, const ushort* __restrict__ B, float* __restrict__ C,
    ushort* __restrict__ Cb, int I, int J, int K, int kChunk, int atom) {
  __shared__ ushort As[64][40];
  __shared__ ushort Bs[64][40];
  int t = threadIdx.x;
  int w = t >> 6, l = t & 63;
  int i0 = blockIdx.y * 64, j0 = blockIdx.x * 64;
  int k0 = blockIdx.z * kChunk;
  int k1 = min(k0 + kChunk, K);
  f32x4 acc[4] = {};
  int lrow = t >> 2;
  int lk = (t & 3) * 8;
  for (int kk = k0; kk < k1; kk += 32) {
    uint4 av = make_uint4(0u, 0u, 0u, 0u);
    int ar = i0 + lrow;
    if (ar < I) av = *(const uint4*)(A + (size_t)ar * K + kk + lk);
    uint4 bv = *(const uint4*)(B + (size_t)(j0 + lrow) * K + kk + lk);
    *(uint4*)&As[lrow][lk] = av;
    *(uint4*)&Bs[lrow][lk] = bv;
    __syncthreads();
    bf16x8 af = *(const bf16x8*)&As[16 * w + (l & 15)][(l >> 4) * 8];
#pragma unroll
    for (int jt = 0; jt < 4; ++jt) {
      bf16x8 bf = *(const bf16x8*)&Bs[16 * jt + (l & 15)][(l >> 4) * 8];
      acc[jt] = __builtin_amdgcn_mfma_f32_16x16x32_bf16(af, bf, acc[jt], 0, 0, 0);
    }
    __syncthreads();
  }
  int rbase = i0 + 16 * w + ((l >> 4) * 4);
  int cbase = j0 + (l & 15);
#pragma unroll
  for (int jt = 0; jt < 4; ++jt) {
#pragma unroll
    for (int rr = 0; rr < 4; ++rr) {
      int r = rbase + rr;
      if (r < I) {
        size_t idx = (size_t)r * J + jt * 16 + cbase;
        if (Cb) Cb[idx] = f2bf(acc[jt][rr]);
        else if (atom) atomicAdd(&C[idx], acc[jt][rr]);
        else C[idx] = acc[jt][rr];
      }
    }
  }
}

// ---------------- fp32 GEMM (small, level-2) ----------------
__global__ __launch_bounds__(256) void k_sgemm_nn(
    const float* __restrict__ A, const float* __restrict__ B, float* __restrict__ C,
    int M, int N, int K) {
  __shared__ float As[16][64];
  __shared__ float Bs[16][68];
  int t = threadIdx.x;
  int tx = t & 15, ty = t >> 4;
  int row0 = blockIdx.y * 64, col0 = blockIdx.x * 64;
  float acc[4][4] = {};
  for (int k0 = 0; k0 < K; k0 += 16) {
    int ar = t >> 2;
    int ak = (t & 3) * 4;
    float4 av = make_float4(0.f, 0.f, 0.f, 0.f);
    if (row0 + ar < M) av = *(const float4*)(A + (size_t)(row0 + ar) * K + k0 + ak);
    As[ak + 0][ar] = av.x; As[ak + 1][ar] = av.y;
    As[ak + 2][ar] = av.z; As[ak + 3][ar] = av.w;
    int bk = t >> 4;
    int bc = (t & 15) * 4;
    float4 bv = *(const float4*)(B + (size_t)(k0 + bk) * N + col0 + bc);
    *(float4*)&Bs[bk][bc] = bv;
    __syncthreads();
#pragma unroll
    for (int k = 0; k < 16; ++k) {
      float a[4], b[4];
#pragma unroll
      for (int u = 0; u < 4; ++u) a[u] = As[k][ty * 4 + u];
#pragma unroll
      for (int v = 0; v < 4; ++v) b[v] = Bs[k][tx * 4 + v];
#pragma unroll
      for (int u = 0; u < 4; ++u)
#pragma unroll
        for (int v = 0; v < 4; ++v) acc[u][v] += a[u] * b[v];
    }
    __syncthreads();
  }
#pragma unroll
  for (int u = 0; u < 4; ++u) {
    int r = row0 + ty * 4 + u;
    if (r < M) {
#pragma unroll
      for (int v = 0; v < 4; ++v) C[(size_t)r * N + col0 + tx * 4 + v] = acc[u][v];
    }
  }
}

// ---------------- BN stats (level-1, two-stage, no atomics) ----------------

__global__ void k_col_stats2(const float* __restrict__ X, const float* __restrict__ bias,
                             float* __restrict__ part, int M, int C, int rpb) {
  int c = threadIdx.x;
  int b = blockIdx.x;
  int r0 = b * rpb, r1 = min(r0 + rpb, M);
  float bi = bias[c];
  float s = 0.f, sq = 0.f;
  for (int r = r0; r < r1; ++r) {
    float v = X[(size_t)r * C + c] + bi;
    s += v; sq += v * v;
  }
  part[(size_t)b * 2 * C + c] = s;
  part[(size_t)b * 2 * C + C + c] = sq;
}

__global__ __launch_bounds__(256) void k_colred_par(
    const float* __restrict__ part, int nblk, int C,
    float* __restrict__ cs, float* __restrict__ csq) {
  __shared__ float sh[256];
  int c = blockIdx.x;
  int t = threadIdx.x;
  float s = 0.f, sq = 0.f;
  for (int b = t; b < nblk; b += 256) {
    s  += part[(size_t)b * 2 * C + c];
    sq += part[(size_t)b * 2 * C + C + c];
  }
  sh[t] = s; __syncthreads();
  for (int o = 128; o > 0; o >>= 1) { if (t < o) sh[t] += sh[t + o]; __syncthreads(); }
  if (t == 0) cs[c] = sh[0];
  __syncthreads();
  sh[t] = sq; __syncthreads();
  for (int o = 128; o > 0; o >>= 1) { if (t < o) sh[t] += sh[t + o]; __syncthreads(); }
  if (t == 0) csq[c] = sh[0];
}

__global__ void k_bn_silu(const float* __restrict__ X, const float* __restrict__ bias,
                          const float* __restrict__ cs, const float* __restrict__ csq,
                          const float* __restrict__ g, const float* __restrict__ be,
                          const float* __restrict__ resid, float* __restrict__ out,
                          ushort* __restrict__ outb,
                          int tot, int cmask, float invM) {
  int i = blockIdx.x * blockDim.x + threadIdx.x;
  if (i >= tot) return;
  int c = i & cmask;
  float m = cs[c] * invM;
  float var = csq[c] * invM - m * m;
  float v = (X[i] + bias[c] - m) * rsqrtf(var + EPS_BN) * g[c] + be[c];
  float y = v / (1.f + expf(-v));
  if (resid) y += resid[i];
  out[i] = y;
  if (outb) outb[i] = f2bf(y);
}

// ---------------- fused small BN (level-2, M<=256): one block per column ----------------
__global__ __launch_bounds__(256) void k_bn_small(
    const float* __restrict__ X, const float* __restrict__ bias,
    const float* __restrict__ g, const float* __restrict__ be,
    const float* __restrict__ resid, float* __restrict__ out,
    int M, int C, float invM) {
  __shared__ float sh[256];
  int c = blockIdx.x;
  int t = threadIdx.x;
  bool act = t < M;
  float v = 0.f;
  if (act) v = X[(size_t)t * C + c] + bias[c];
  sh[t] = v; __syncthreads();
  for (int o = 128; o > 0; o >>= 1) { if (t < o) sh[t] += sh[t + o]; __syncthreads(); }
  float m = sh[0] * invM; __syncthreads();
  sh[t] = v * v; __syncthreads();
  for (int o = 128; o > 0; o >>= 1) { if (t < o) sh[t] += sh[t + o]; __syncthreads(); }
  float var = sh[0] * invM - m * m;
  if (act) {
    float y = (v - m) * rsqrtf(var + EPS_BN) * g[c] + be[c];
    y = y / (1.f + expf(-y));
    if (resid) y += resid[(size_t)t * C + c];
    out[(size_t)t * C + c] = y;
  }
}

// ---------------- softmax + entropy (block partials) ----------------
template <int C>
__global__ void k_softmax_ent3(float* __restrict__ X, ushort* __restrict__ outb,
                               float* __restrict__ part, int nrows) {
  constexpr int VPT = C / 64;
  __shared__ float went[4];
  int gt = blockIdx.x * blockDim.x + threadIdx.x;
  int row = gt >> 6;
  int l = gt & 63;
  int wid = threadIdx.x >> 6;
  bool active = row < nrows;
  size_t base = active ? (size_t)row * C : 0;
  float d[VPT];
  if (VPT == 4) {
    float4 v = *(const float4*)(X + base + l * 4);
    d[0] = v.x; d[1] = v.y; d[2] = v.z; d[3] = v.w;
  } else {
    d[0] = X[base + l];
  }
  float mx = d[0];
#pragma unroll
  for (int i = 1; i < VPT; ++i) mx = fmaxf(mx, d[i]);
  for (int o = 32; o > 0; o >>= 1) mx = fmaxf(mx, __shfl_xor(mx, o));
  float se = 0.f;
  float e[VPT];
#pragma unroll
  for (int i = 0; i < VPT; ++i) { d[i] -= mx; e[i] = expf(d[i]); se += e[i]; }
  for (int o = 32; o > 0; o >>= 1) se += __shfl_xor(se, o);
  float inv = 1.f / se;
  float pd = 0.f;
#pragma unroll
  for (int i = 0; i < VPT; ++i) { e[i] *= inv; pd += e[i] * d[i]; }
  if (active) {
    if (VPT == 4) {
      float4 v; v.x = e[0]; v.y = e[1]; v.z = e[2]; v.w = e[3];
      *(float4*)(X + base + l * 4) = v;
      if (outb) {
        ushort4 u; u.x = f2bf(e[0]); u.y = f2bf(e[1]); u.z = f2bf(e[2]); u.w = f2bf(e[3]);
        *(ushort4*)(outb + base + l * 4) = u;
      }
    } else {
      X[base + l] = e[0];
      if (outb) outb[base + l] = f2bf(e[0]);
    }
  }
  for (int o = 32; o > 0; o >>= 1) pd += __shfl_xor(pd, o);
  if (l == 0) went[wid] = active ? (logf(se) - pd) : 0.f;
  __syncthreads();
  if (threadIdx.x == 0) part[blockIdx.x] = went[0] + went[1] + went[2] + went[3];
}

__global__ __launch_bounds__(1024) void k_reduce_arr(
    const float* __restrict__ in, int n, float* __restrict__ out) {
  __shared__ float sh[1024];
  int t = threadIdx.x;
  float s = 0.f;
  for (int i = t; i < n; i += 1024) s += in[i];
  sh[t] = s; __syncthreads();
  for (int o = 512; o > 0; o >>= 1) { if (t < o) sh[t] += sh[t + o]; __syncthreads(); }
  if (t == 0) *out = sh[0];
}

// block0: trace(P0) -> out[0]; block1: sumsq(P1) -> out[1]; block2 (if present): sumsq(P0) -> out[2]
__global__ __launch_bounds__(256) void k_scalN(
    const float* __restrict__ P0, const float* __restrict__ P1, int K,
    float* __restrict__ outb) {
  __shared__ float sh[256];
  int b = blockIdx.x, t = threadIdx.x;
  float s = 0.f;
  if (b == 0) {
    for (int i = t; i < K; i += 256) s += P0[(size_t)i * K + i];
  } else {
    const float* P = (b == 1) ? P1 : P0;
    int n = K * K;
    for (int i = t; i < n; i += 256) { float v = P[i]; s += v * v; }
  }
  sh[t] = s; __syncthreads();
  for (int o = 128; o > 0; o >>= 1) { if (t < o) sh[t] += sh[t + o]; __syncthreads(); }
  if (t == 0) outb[b] = sh[0];
}

// ---------------- level-2 dense graph ----------------

__global__ __launch_bounds__(256) void k_deg2_par(
    const float* __restrict__ Ap, float* __restrict__ dinv2, int Np) {
  __shared__ float sh[256];
  int q = blockIdx.x;
  int t = threadIdx.x;
  float s = (t == 0) ? 1.0f : 0.f;
  for (int p = t; p < Np; p += 256) s += Ap[(size_t)p * Np + q];
  sh[t] = s; __syncthreads();
  for (int o = 128; o > 0; o >>= 1) { if (t < o) sh[t] += sh[t + o]; __syncthreads(); }
  if (t == 0) {
    float d = sh[0];
    dinv2[q] = d > 0.f ? rsqrtf(fmaxf(d, 1e-12f)) : 0.f;
  }
}

__global__ void k_dense_agg(const float* __restrict__ Ap, const float* __restrict__ dinv2,
                            const float* __restrict__ H, float* __restrict__ out,
                            int Np, int C) {
  int q = blockIdx.x, c = threadIdx.x;
  float acc = 0.f;
#pragma unroll 8
  for (int p = 0; p < Np; ++p)
    acc += dinv2[p] * Ap[(size_t)p * Np + q] * H[(size_t)p * C + c];
  float dq = dinv2[q];
  out[(size_t)q * C + c] = dq * acc + dq * dq * H[(size_t)q * C + c];
}

// ---------------- fused tail TN products (level 2) ----------------
// z0: a2 = S^T B0 [64x64]; z1: sts2 = S^T S; z2,z3: xp2 = S^T B2 [64x128] tiles
__global__ __launch_bounds__(256) void k_tn3(
    const float* __restrict__ S, const float* __restrict__ B0,
    const float* __restrict__ B2,
    float* __restrict__ a2, float* __restrict__ sts2, float* __restrict__ xp2, int M) {
  __shared__ float As[64][65];
  int z = blockIdx.x;
  const float* B; float* C; int J, j0;
  if (z == 0)      { B = B0; C = a2;   J = 64;  j0 = 0; }
  else if (z == 1) { B = S;  C = sts2; J = 64;  j0 = 0; }
  else             { B = B2; C = xp2;  J = 128; j0 = (z - 2) * 64; }
  int t = threadIdx.x;
  int tj = t & 63, ti = t >> 6;
  float acc[16] = {};
  for (int m0 = 0; m0 < M; m0 += 64) {
    for (int r = ti; r < 64; r += 4) As[r][tj] = S[(size_t)(m0 + r) * 64 + tj];
    __syncthreads();
    for (int mm = 0; mm < 64; ++mm) {
      float bv = B[(size_t)(m0 + mm) * J + j0 + tj];
#pragma unroll
      for (int ii = 0; ii < 16; ++ii) acc[ii] += As[mm][ti * 16 + ii] * bv;
    }
    __syncthreads();
  }
  for (int ii = 0; ii < 16; ++ii) C[(size_t)(ti * 16 + ii) * J + j0 + tj] = acc[ii];
}

// ---------------- final head ----------------
__global__ void k_final(const float* __restrict__ xp2, const float* __restrict__ Wlin,
                        const float* __restrict__ blin, const float* __restrict__ scal,
                        float* __restrict__ out, int N1, int E1, int K1, int K2, int OUT) {
  __shared__ float pooled[128];
  __shared__ float logits[32];
  int t = threadIdx.x;
  float s = 0.f;
  for (int r = 0; r < K2; ++r) s += xp2[(size_t)r * 128 + t];
  pooled[t] = s / (float)K2;
  __syncthreads();
  if (t < OUT) {
    float acc = blin[t];
    for (int k = 0; k < 128; ++k) acc += pooled[k] * Wlin[(size_t)k * OUT + t];
    logits[t] = acc;
  }
  __syncthreads();
  if (t == 0) {
    float mx = logits[0];
    for (int j = 1; j < OUT; ++j) mx = fmaxf(mx, logits[j]);
    float se = 0.f;
    for (int j = 0; j < OUT; ++j) se += expf(logits[j] - mx);
    float lse = mx + logf(se);
    for (int j = 0; j < OUT; ++j) out[j] = logits[j] - lse;
    float n1 = (float)N1;
    float ent1 = scal[0] / n1;
    float ent2 = scal[1] / (float)K1;
    float link1 = sqrtf(fmaxf((float)E1 - 2.f * scal[2] + scal[3], 0.f)) / (n1 * n1);
    float link2 = sqrtf(fmaxf(scal[4] - 2.f * scal[5] + scal[6], 0.f)) / ((float)K1 * (float)K1);
    out[OUT] = ent1 + ent2 + link1 + link2;
  }
}

// ---------------- host ----------------

extern "C" void kernel_launch(void* const* d_in, const int* in_sizes, int n_in,
                              void* d_out, int out_size, void* d_ws, size_t ws_size,
                              hipStream_t stream) {
  (void)n_in; (void)out_size; (void)ws_size;
  const float* x = (const float*)d_in[0];
  const int* ei  = (const int*)d_in[1];
  const int N = in_sizes[0] / 128;   // 20000
  const int E = in_sizes[1] / 2;     // 640000
  const float *W1a=(const float*)d_in[4],  *b1a=(const float*)d_in[5],
              *g1a=(const float*)d_in[6],  *be1a=(const float*)d_in[7];
  const float *W1b=(const float*)d_in[8],  *b1b=(const float*)d_in[9],
              *g1b=(const float*)d_in[10], *be1b=(const float*)d_in[11];
  const float *Wp1=(const float*)d_in[12], *bp1=(const float*)d_in[13],
              *gp1=(const float*)d_in[14], *bep1=(const float*)d_in[15];
  const float *W2a=(const float*)d_in[16], *b2a=(const float*)d_in[17],
              *g2a=(const float*)d_in[18], *be2a=(const float*)d_in[19];
  const float *W2b=(const float*)d_in[20], *b2b=(const float*)d_in[21],
              *g2b=(const float*)d_in[22], *be2b=(const float*)d_in[23];
  const float *Wp2=(const float*)d_in[24], *bp2=(const float*)d_in[25],
              *gp2=(const float*)d_in[26], *bep2=(const float*)d_in[27];
  const float *Wlin=(const float*)d_in[28], *blin=(const float*)d_in[29];
  const int K1 = in_sizes[12] / 128;   // 256
  const int K2 = in_sizes[24] / 128;   // 64
  const int OUT = in_sizes[29];        // 10

  char* base = (char*)d_ws;
  size_t off = 0;
  auto allocb = [&](size_t bytes) -> void* {
    void* p = (void*)(base + off);
    off += ((bytes + 255) & ~(size_t)255);
    return p;
  };
  auto alloc = [&](size_t nf) -> float* { return (float*)allocb(nf * 4); };
  auto alloci = [&](size_t ni) -> int* { return (int*)allocb(ni * 4); };
  auto allocu = [&](size_t nu) -> ushort* { return (ushort*)allocb(nu * 2); };

  auto cdiv = [](long long a, long long b) { return (int)((a + b - 1) / b); };

  const int RPB = 16;
  const int NBLK1 = cdiv(N, RPB);

  float* scal  = alloc(16);
  float* cs    = alloc(256);
  float* csq   = alloc(256);
  float* dinv  = alloc(N);
  float* dinv2 = alloc(K1);
  float* apool = alloc((size_t)K1 * K1);
  float* sts   = alloc((size_t)K1 * K1);
  float* xp    = alloc((size_t)K1 * 128);
  float* h2    = alloc((size_t)K1 * 128);
  float* y2    = alloc((size_t)K1 * 128);
  float* xa2   = alloc((size_t)K1 * 128);
  float* x2f   = alloc((size_t)K1 * 128);
  float* s2b   = alloc((size_t)K1 * K2);
  float* t2    = alloc((size_t)K1 * K2);
  float* a2    = alloc((size_t)K2 * K2);
  float* sts2  = alloc((size_t)K2 * K2);
  float* xp2   = alloc((size_t)K2 * 128);
  float* ent1p = alloc(cdiv(N, 4) + 8);
  float* ent2p = alloc(64 + 8);
  float* csp   = alloc((size_t)(NBLK1 + 2) * 512);
  float* R1 = alloc((size_t)N * 128);   // fp32; later St bf16 [K1,N]
  float* R2 = alloc((size_t)N * 128);   // fp32; later ASt bf16 [K1,N]
  float* R3 = alloc((size_t)N * K1);    // Hb/aggB bf16 / Sb bf16 [N,K1]
  float* R4 = alloc((size_t)N * K1);    // agg out / S fp32 / AS fp32
  ushort* B16A = allocu((size_t)N * 128);  // xb -> R1b -> R2b -> R2t
  ushort* W1at = allocu(128 * 128);
  ushort* W1bt = allocu(128 * 128);
  ushort* Wp1t = allocu((size_t)K1 * 128);
  // CSR structures (cnt_d, cnt_s contiguous for single memset)
  int* cnt2  = alloci(2 * (size_t)N);
  int* cnt_d = cnt2;
  int* cnt_s = cnt2 + N;
  int* rp_d  = alloci(N + 1);
  int* cur_d = alloci(N);
  int* col_s = alloci(E);
  int* rp_s  = alloci(N + 1);
  int* cur_s = alloci(N);
  int* col_d = alloci(E);

  ushort* Hb   = (ushort*)R3;  // [N, C] bf16 GEMM output for gather (blocks a,b)
  ushort* aggB = (ushort*)R3;  // [N, 128] bf16 aggregated input (pooling block)
  ushort* Sb   = (ushort*)R3;  // [N, K1] bf16 row-major S
  ushort* St   = (ushort*)R1;  // [K1, N] bf16
  ushort* ASt  = (ushort*)R2;  // [K1, N] bf16
  ushort* R2t  = B16A;         // [128, N] bf16

  hipMemsetAsync(scal, 0, 16 * sizeof(float), stream);

  // ---- combined CSR build ----
  hipMemsetAsync(cnt2, 0, 2 * (size_t)N * sizeof(int), stream);
  k_hist2<<<cdiv(2 * (long long)E, 256), 256, 0, stream>>>(ei, cnt_s, cnt_d, E);
  k_scan2<<<2, 1024, 0, stream>>>(cnt_d, rp_d, cur_d, cnt_s, rp_s, cur_s, N, E);
  k_fill2<<<cdiv(2 * (long long)E, 256), 256, 0, stream>>>(ei, cur_d, col_s, cur_s, col_d, E);
  k_dinv_cnt<<<cdiv(N, 256), 256, 0, stream>>>(cnt_d, dinv, N);

  // ---- weight transposes + x conversion ----
  {
    dim3 b32(32, 8);
    k_tconv<<<dim3(4, 4), b32, 0, stream>>>(W1a, W1at, 128, 128);
    k_tconv<<<dim3(4, 4), b32, 0, stream>>>(W1b, W1bt, 128, 128);
    k_tconv<<<dim3(8, 4), b32, 0, stream>>>(Wp1, Wp1t, 128, K1);
  }
  k_conv<<<cdiv((size_t)N * 128 / 4, 256), 256, 0, stream>>>(x, B16A, N * 128 / 4);

  auto mfma_nt = [&](const ushort* A, const ushort* B, float* C, ushort* Cb,
                     int I, int J, int K, int nz) {
    int chunk = K, z = 1;
    if (nz > 1) {
      chunk = ((cdiv(K, nz) + 31) & ~31);
      z = cdiv(K, chunk);
      hipMemsetAsync(C, 0, (size_t)I * J * sizeof(float), stream);
    }
    dim3 g(J / 64, cdiv(I, 64), z);
    k_mfma_nt<<<g, 256, 0, stream>>>(A, B, C, Cb, I, J, K, chunk, z > 1 ? 1 : 0);
  };
  auto gemm_nn = [&](const float* A, const float* B, float* C, int M, int Nn, int K) {
    dim3 g(Nn / 64, cdiv(M, 64));
    k_sgemm_nn<<<g, 256, 0, stream>>>(A, B, C, M, Nn, K);
  };

  // level-1 blocks a,b: GEMM -> gather -> BN/SiLU
  auto block1 = [&](const ushort* xin_b, const ushort* Wt, const float* b, const float* gg,
                    const float* be, const float* resid, float* outp, ushort* outb, int C) {
    mfma_nt(xin_b, Wt, nullptr, Hb, N, C, 128, 1);
    k_gather_agg_b2<<<N, C / 2, 0, stream>>>(rp_d, col_s, dinv, Hb, R4, C / 2);
    k_col_stats2<<<NBLK1, C, 0, stream>>>(R4, b, csp, N, C, RPB);
    k_colred_par<<<C, 256, 0, stream>>>(csp, NBLK1, C, cs, csq);
    int tot = N * C;
    k_bn_silu<<<cdiv(tot, 256), 256, 0, stream>>>(R4, b, cs, csq, gg, be, resid, outp,
                                                  outb, tot, C - 1, 1.f / N);
  };

  block1(B16A, W1at, b1a, g1a, be1a, nullptr, R1, B16A, 128);  // R1 + R1b
  block1(B16A, W1bt, b1b, g1b, be1b, R1,      R2, B16A, 128);  // R2 + R2b

  // pooling block, reordered: agg = A_hat * R2 (gather 128ch), then GEMM agg@Wp1 -> fp32 R4
  k_gather_agg_b2b<<<N, 64, 0, stream>>>(rp_d, col_s, dinv, B16A, aggB, 64);
  mfma_nt(aggB, Wp1t, R4, nullptr, N, K1, 128, 1);
  k_col_stats2<<<NBLK1, K1, 0, stream>>>(R4, bp1, csp, N, K1, RPB);
  k_colred_par<<<K1, 256, 0, stream>>>(csp, NBLK1, K1, cs, csq);
  k_bn_silu<<<cdiv(N * K1, 256), 256, 0, stream>>>(R4, bp1, cs, csq, gp1, bep1, nullptr,
                                                   R4, nullptr, N * K1, K1 - 1, 1.f / N);
  // S = softmax(R4) fp32 in-place + bf16 copy Sb (overwrites dead aggB region)
  k_softmax_ent3<256><<<cdiv(N, 4), 256, 0, stream>>>(R4, Sb, ent1p, N);
  k_reduce_arr<<<1, 1024, 0, stream>>>(ent1p, cdiv(N, 4), &scal[0]);

  {
    dim3 b32(32, 8);
    k_tconv<<<dim3(K1 / 32, cdiv(N, 32)), b32, 0, stream>>>(R4, St, N, K1);     // St = S^T
    k_tconv<<<dim3(128 / 32, cdiv(N, 32)), b32, 0, stream>>>(R2, R2t, N, 128);  // R2t = x^T
  }
  k_gather_T_b2<<<N, K1 / 2, 0, stream>>>(rp_s, col_d, Sb, R4, K1 / 2);         // R4 = A S
  {
    dim3 b32(32, 8);
    k_tconv<<<dim3(K1 / 32, cdiv(N, 32)), b32, 0, stream>>>(R4, ASt, N, K1);    // ASt
  }

  mfma_nt(St, ASt, apool, nullptr, K1, K1, N, 16);   // a_pool = S^T (A S)
  mfma_nt(St, St,  sts,   nullptr, K1, K1, N, 16);   // sts = S^T S
  mfma_nt(St, R2t, xp,    nullptr, K1, 128, N, 16);  // xp = S^T x
  k_scalN<<<3, 256, 0, stream>>>(apool, sts, K1, &scal[2]);  // trace, ||sts||^2, ||apool||^2

  // ---------------- level 2 (dense 256-node graph) ----------------
  k_deg2_par<<<K1, 256, 0, stream>>>(apool, dinv2, K1);

  auto block2 = [&](const float* xin, const float* W, const float* b, const float* gg,
                    const float* be, const float* resid, float* outp, int C) {
    gemm_nn(xin, W, h2, K1, C, 128);
    k_dense_agg<<<K1, C, 0, stream>>>(apool, dinv2, h2, y2, K1, C);
    k_bn_small<<<C, 256, 0, stream>>>(y2, b, gg, be, resid, outp, K1, C, 1.f / K1);
  };

  block2(xp,  W2a, b2a, g2a, be2a, nullptr, xa2, 128);
  block2(xa2, W2b, b2b, g2b, be2b, xa2,     x2f, 128);
  block2(x2f, Wp2, bp2, gp2, bep2, nullptr, s2b, K2);
  k_softmax_ent3<64><<<cdiv(K1, 4), 256, 0, stream>>>(s2b, nullptr, ent2p, K1);
  k_reduce_arr<<<1, 1024, 0, stream>>>(ent2p, cdiv(K1, 4), &scal[1]);

  gemm_nn(apool, s2b, t2, K1, K2, K1);                       // t2 = Apool @ s2
  k_tn3<<<4, 256, 0, stream>>>(s2b, t2, x2f, a2, sts2, xp2, K1);
  k_scalN<<<2, 256, 0, stream>>>(a2, sts2, K2, &scal[5]);    // trace(a2), ||sts2||^2

  k_final<<<1, 128, 0, stream>>>(xp2, Wlin, blin, scal, (float*)d_out, N, E, K1, K2, OUT);
}

// Round 8
// 661.197 us; speedup vs baseline: 4.3514x; 1.1682x over previous
//
#include <hip/hip_runtime.h>

#define EPS_BN 1e-5f
typedef unsigned int uint;
typedef unsigned short ushort;
typedef __attribute__((ext_vector_type(8))) short bf16x8;
typedef __attribute__((ext_vector_type(4))) float f32x4;

__device__ inline ushort f2bf(float f) {
  uint u = __float_as_uint(f);
  uint r = (u + 0x7FFFu + ((u >> 16) & 1u)) >> 16;
  return (ushort)r;
}
__device__ inline float bflo(uint h) { return __uint_as_float(h << 16); }
__device__ inline float bfhi(uint h) { return __uint_as_float(h & 0xFFFF0000u); }

// ---------------- CSR build (dst only) ----------------

__global__ void k_hist(const int* __restrict__ idx, int* __restrict__ cnt, int E) {
  int e = blockIdx.x * blockDim.x + threadIdx.x;
  if (e < E) atomicAdd(&cnt[idx[e]], 1);
}

__global__ __launch_bounds__(1024) void k_scan(
    const int* __restrict__ cnt, int* __restrict__ rowptr, int* __restrict__ cursor,
    int N, int E) {
  __shared__ int sh[1024];
  int t = threadIdx.x;
  int chunk = (N + 1023) / 1024;
  int i0 = t * chunk, i1 = min(i0 + chunk, N);
  int s = 0;
  for (int i = i0; i < i1; ++i) s += cnt[i];
  sh[t] = s; __syncthreads();
  for (int o = 1; o < 1024; o <<= 1) {
    int v = (t >= o) ? sh[t - o] : 0;
    __syncthreads();
    sh[t] += v;
    __syncthreads();
  }
  int run = (t == 0) ? 0 : sh[t - 1];
  for (int i = i0; i < i1; ++i) { rowptr[i] = run; cursor[i] = run; run += cnt[i]; }
  if (t == 1023) rowptr[N] = E;
}

__global__ void k_fill_csr(const int* __restrict__ key, const int* __restrict__ val,
                           int* __restrict__ cursor, int* __restrict__ col, int E) {
  int e = blockIdx.x * blockDim.x + threadIdx.x;
  if (e < E) {
    int pos = atomicAdd(&cursor[key[e]], 1);
    col[pos] = val[e];
  }
}

__global__ void k_dinv_cnt(const int* __restrict__ cnt, float* __restrict__ dinv, int n) {
  int i = blockIdx.x * blockDim.x + threadIdx.x;
  if (i < n) dinv[i] = rsqrtf(1.0f + (float)cnt[i]);
}

// ---------------- gather aggregation, bf16 input, 2 ch/thread ----------------

__global__ void k_gather_agg_b2(const int* __restrict__ rowptr, const int* __restrict__ col,
                                const float* __restrict__ dinv, const ushort* __restrict__ H,
                                float* __restrict__ out, int C2) {
  int d = blockIdx.x;
  int c2 = threadIdx.x;
  const uint* H2 = (const uint*)H;
  int b = rowptr[d], e = rowptr[d + 1];
  float a0 = 0.f, a1 = 0.f;
#pragma unroll 4
  for (int i = b; i < e; ++i) {
    int s = col[i];
    float dv = dinv[s];
    uint h = H2[(size_t)s * C2 + c2];
    a0 += dv * bflo(h);
    a1 += dv * bfhi(h);
  }
  float dd = dinv[d];
  uint hd = H2[(size_t)d * C2 + c2];
  float2 o;
  o.x = dd * a0 + dd * dd * bflo(hd);
  o.y = dd * a1 + dd * dd * bfhi(hd);
  *(float2*)(out + (size_t)d * (C2 * 2) + c2 * 2) = o;
}

// bf16 output variant (aggregate-then-GEMM pooling path)
__global__ void k_gather_agg_b2b(const int* __restrict__ rowptr, const int* __restrict__ col,
                                 const float* __restrict__ dinv, const ushort* __restrict__ H,
                                 ushort* __restrict__ out, int C2) {
  int d = blockIdx.x;
  int c2 = threadIdx.x;
  const uint* H2 = (const uint*)H;
  int b = rowptr[d], e = rowptr[d + 1];
  float a0 = 0.f, a1 = 0.f;
#pragma unroll 4
  for (int i = b; i < e; ++i) {
    int s = col[i];
    float dv = dinv[s];
    uint h = H2[(size_t)s * C2 + c2];
    a0 += dv * bflo(h);
    a1 += dv * bfhi(h);
  }
  float dd = dinv[d];
  uint hd = H2[(size_t)d * C2 + c2];
  ushort2 o;
  o.x = f2bf(dd * a0 + dd * dd * bflo(hd));
  o.y = f2bf(dd * a1 + dd * dd * bfhi(hd));
  *(ushort2*)(out + (size_t)d * (C2 * 2) + c2 * 2) = o;
}

// T[d] = sum_{e: dst=d} S[src_e]  (= A^T S with dst-CSR)
__global__ void k_gather_T_b2(const int* __restrict__ rowptr, const int* __restrict__ col,
                              const ushort* __restrict__ S, float* __restrict__ T, int C2) {
  int s = blockIdx.x;
  int c2 = threadIdx.x;
  const uint* S2 = (const uint*)S;
  int b = rowptr[s], e = rowptr[s + 1];
  float a0 = 0.f, a1 = 0.f;
#pragma unroll 4
  for (int i = b; i < e; ++i) {
    int d = col[i];
    uint h = S2[(size_t)d * C2 + c2];
    a0 += bflo(h);
    a1 += bfhi(h);
  }
  float2 o; o.x = a0; o.y = a1;
  *(float2*)(T + (size_t)s * (C2 * 2) + c2 * 2) = o;
}

// ---------------- conversion / transpose ----------------

__global__ void k_conv(const float* __restrict__ in, ushort* __restrict__ out, int n4) {
  int i = blockIdx.x * blockDim.x + threadIdx.x;
  if (i < n4) {
    float4 v = ((const float4*)in)[i];
    ushort4 o;
    o.x = f2bf(v.x); o.y = f2bf(v.y); o.z = f2bf(v.z); o.w = f2bf(v.w);
    ((ushort4*)out)[i] = o;
  }
}

// out[c, r] = bf16(in[r, c])
__global__ void k_tconv(const float* __restrict__ in, ushort* __restrict__ out,
                        int R, int Cc) {
  __shared__ float tile[32][33];
  int c0 = blockIdx.x * 32, r0 = blockIdx.y * 32;
  int tx = threadIdx.x, ty = threadIdx.y;
  for (int i = 0; i < 32; i += 8) {
    int r = r0 + ty + i, c = c0 + tx;
    if (r < R && c < Cc) tile[ty + i][tx] = in[(size_t)r * Cc + c];
  }
  __syncthreads();
  for (int i = 0; i < 32; i += 8) {
    int oc = c0 + ty + i;
    int orr = r0 + tx;
    if (oc < Cc && orr < R) out[(size_t)oc * R + orr] = f2bf(tile[tx][ty + i]);
  }
}

// ---------------- bf16 MFMA NT GEMM ----------------
__global__ __launch_bounds__(256) void k_mfma_nt(
    const ushort* __restrict__ A, const ushort* __restrict__ B, float* __restrict__ C,
    ushort* __restrict__ Cb, int I, int J, int K, int kChunk, int atom) {
  __shared__ ushort As[64][40];
  __shared__ ushort Bs[64][40];
  int t = threadIdx.x;
  int w = t >> 6, l = t & 63;
  int i0 = blockIdx.y * 64, j0 = blockIdx.x * 64;
  int k0 = blockIdx.z * kChunk;
  int k1 = min(k0 + kChunk, K);
  f32x4 acc[4] = {};
  int lrow = t >> 2;
  int lk = (t & 3) * 8;
  for (int kk = k0; kk < k1; kk += 32) {
    uint4 av = make_uint4(0u, 0u, 0u, 0u);
    int ar = i0 + lrow;
    if (ar < I) av = *(const uint4*)(A + (size_t)ar * K + kk + lk);
    uint4 bv = *(const uint4*)(B + (size_t)(j0 + lrow) * K + kk + lk);
    *(uint4*)&As[lrow][lk] = av;
    *(uint4*)&Bs[lrow][lk] = bv;
    __syncthreads();
    bf16x8 af = *(const bf16x8*)&As[16 * w + (l & 15)][(l >> 4) * 8];
#pragma unroll
    for (int jt = 0; jt < 4; ++jt) {
      bf16x8 bf = *(const bf16x8*)&Bs[16 * jt + (l & 15)][(l >> 4) * 8];
      acc[jt] = __builtin_amdgcn_mfma_f32_16x16x32_bf16(af, bf, acc[jt], 0, 0, 0);
    }
    __syncthreads();
  }
  int rbase = i0 + 16 * w + ((l >> 4) * 4);
  int cbase = j0 + (l & 15);
#pragma unroll
  for (int jt = 0; jt < 4; ++jt) {
#pragma unroll
    for (int rr = 0; rr < 4; ++rr) {
      int r = rbase + rr;
      if (r < I) {
        size_t idx = (size_t)r * J + jt * 16 + cbase;
        if (Cb) Cb[idx] = f2bf(acc[jt][rr]);
        else if (atom) atomicAdd(&C[idx], acc[jt][rr]);
        else C[idx] = acc[jt][rr];
      }
    }
  }
}

// ---------------- fp32 GEMM (small, level-2) ----------------
__global__ __launch_bounds__(256) void k_sgemm_nn(
    const float* __restrict__ A, const float* __restrict__ B, float* __restrict__ C,
    int M, int N, int K) {
  __shared__ float As[16][64];
  __shared__ float Bs[16][68];
  int t = threadIdx.x;
  int tx = t & 15, ty = t >> 4;
  int row0 = blockIdx.y * 64, col0 = blockIdx.x * 64;
  float acc[4][4] = {};
  for (int k0 = 0; k0 < K; k0 += 16) {
    int ar = t >> 2;
    int ak = (t & 3) * 4;
    float4 av = make_float4(0.f, 0.f, 0.f, 0.f);
    if (row0 + ar < M) av = *(const float4*)(A + (size_t)(row0 + ar) * K + k0 + ak);
    As[ak + 0][ar] = av.x; As[ak + 1][ar] = av.y;
    As[ak + 2][ar] = av.z; As[ak + 3][ar] = av.w;
    int bk = t >> 4;
    int bc = (t & 15) * 4;
    float4 bv = *(const float4*)(B + (size_t)(k0 + bk) * N + col0 + bc);
    *(float4*)&Bs[bk][bc] = bv;
    __syncthreads();
#pragma unroll
    for (int k = 0; k < 16; ++k) {
      float a[4], b[4];
#pragma unroll
      for (int u = 0; u < 4; ++u) a[u] = As[k][ty * 4 + u];
#pragma unroll
      for (int v = 0; v < 4; ++v) b[v] = Bs[k][tx * 4 + v];
#pragma unroll
      for (int u = 0; u < 4; ++u)
#pragma unroll
        for (int v = 0; v < 4; ++v) acc[u][v] += a[u] * b[v];
    }
    __syncthreads();
  }
#pragma unroll
  for (int u = 0; u < 4; ++u) {
    int r = row0 + ty * 4 + u;
    if (r < M) {
#pragma unroll
      for (int v = 0; v < 4; ++v) C[(size_t)r * N + col0 + tx * 4 + v] = acc[u][v];
    }
  }
}

// ---------------- BN stats (level-1, two-stage, no atomics) ----------------

__global__ void k_col_stats2(const float* __restrict__ X, const float* __restrict__ bias,
                             float* __restrict__ part, int M, int C, int rpb) {
  int c = threadIdx.x;
  int b = blockIdx.x;
  int r0 = b * rpb, r1 = min(r0 + rpb, M);
  float bi = bias[c];
  float s = 0.f, sq = 0.f;
  for (int r = r0; r < r1; ++r) {
    float v = X[(size_t)r * C + c] + bi;
    s += v; sq += v * v;
  }
  part[(size_t)b * 2 * C + c] = s;
  part[(size_t)b * 2 * C + C + c] = sq;
}

__global__ __launch_bounds__(256) void k_colred_par(
    const float* __restrict__ part, int nblk, int C,
    float* __restrict__ cs, float* __restrict__ csq) {
  __shared__ float sh[256];
  int c = blockIdx.x;
  int t = threadIdx.x;
  float s = 0.f, sq = 0.f;
  for (int b = t; b < nblk; b += 256) {
    s  += part[(size_t)b * 2 * C + c];
    sq += part[(size_t)b * 2 * C + C + c];
  }
  sh[t] = s; __syncthreads();
  for (int o = 128; o > 0; o >>= 1) { if (t < o) sh[t] += sh[t + o]; __syncthreads(); }
  if (t == 0) cs[c] = sh[0];
  __syncthreads();
  sh[t] = sq; __syncthreads();
  for (int o = 128; o > 0; o >>= 1) { if (t < o) sh[t] += sh[t + o]; __syncthreads(); }
  if (t == 0) csq[c] = sh[0];
}

__global__ void k_bn_silu(const float* __restrict__ X, const float* __restrict__ bias,
                          const float* __restrict__ cs, const float* __restrict__ csq,
                          const float* __restrict__ g, const float* __restrict__ be,
                          const float* __restrict__ resid, float* __restrict__ out,
                          ushort* __restrict__ outb,
                          int tot, int cmask, float invM) {
  int i = blockIdx.x * blockDim.x + threadIdx.x;
  if (i >= tot) return;
  int c = i & cmask;
  float m = cs[c] * invM;
  float var = csq[c] * invM - m * m;
  float v = (X[i] + bias[c] - m) * rsqrtf(var + EPS_BN) * g[c] + be[c];
  float y = v / (1.f + expf(-v));
  if (resid) y += resid[i];
  out[i] = y;
  if (outb) outb[i] = f2bf(y);
}

// ---------------- fused small BN (level-2, M<=256): one block per column ----------------
__global__ __launch_bounds__(256) void k_bn_small(
    const float* __restrict__ X, const float* __restrict__ bias,
    const float* __restrict__ g, const float* __restrict__ be,
    const float* __restrict__ resid, float* __restrict__ out,
    int M, int C, float invM) {
  __shared__ float sh[256];
  int c = blockIdx.x;
  int t = threadIdx.x;
  bool act = t < M;
  float v = 0.f;
  if (act) v = X[(size_t)t * C + c] + bias[c];
  sh[t] = v; __syncthreads();
  for (int o = 128; o > 0; o >>= 1) { if (t < o) sh[t] += sh[t + o]; __syncthreads(); }
  float m = sh[0] * invM; __syncthreads();
  sh[t] = v * v; __syncthreads();
  for (int o = 128; o > 0; o >>= 1) { if (t < o) sh[t] += sh[t + o]; __syncthreads(); }
  float var = sh[0] * invM - m * m;
  if (act) {
    float y = (v - m) * rsqrtf(var + EPS_BN) * g[c] + be[c];
    y = y / (1.f + expf(-y));
    if (resid) y += resid[(size_t)t * C + c];
    out[(size_t)t * C + c] = y;
  }
}

// ---------------- softmax + entropy (block partials) ----------------
template <int C>
__global__ void k_softmax_ent3(float* __restrict__ X, ushort* __restrict__ outb,
                               float* __restrict__ part, int nrows) {
  constexpr int VPT = C / 64;
  __shared__ float went[4];
  int gt = blockIdx.x * blockDim.x + threadIdx.x;
  int row = gt >> 6;
  int l = gt & 63;
  int wid = threadIdx.x >> 6;
  bool active = row < nrows;
  size_t base = active ? (size_t)row * C : 0;
  float d[VPT];
  if (VPT == 4) {
    float4 v = *(const float4*)(X + base + l * 4);
    d[0] = v.x; d[1] = v.y; d[2] = v.z; d[3] = v.w;
  } else {
    d[0] = X[base + l];
  }
  float mx = d[0];
#pragma unroll
  for (int i = 1; i < VPT; ++i) mx = fmaxf(mx, d[i]);
  for (int o = 32; o > 0; o >>= 1) mx = fmaxf(mx, __shfl_xor(mx, o));
  float se = 0.f;
  float e[VPT];
#pragma unroll
  for (int i = 0; i < VPT; ++i) { d[i] -= mx; e[i] = expf(d[i]); se += e[i]; }
  for (int o = 32; o > 0; o >>= 1) se += __shfl_xor(se, o);
  float inv = 1.f / se;
  float pd = 0.f;
#pragma unroll
  for (int i = 0; i < VPT; ++i) { e[i] *= inv; pd += e[i] * d[i]; }
  if (active) {
    if (VPT == 4) {
      float4 v; v.x = e[0]; v.y = e[1]; v.z = e[2]; v.w = e[3];
      *(float4*)(X + base + l * 4) = v;
      if (outb) {
        ushort4 u; u.x = f2bf(e[0]); u.y = f2bf(e[1]); u.z = f2bf(e[2]); u.w = f2bf(e[3]);
        *(ushort4*)(outb + base + l * 4) = u;
      }
    } else {
      X[base + l] = e[0];
      if (outb) outb[base + l] = f2bf(e[0]);
    }
  }
  for (int o = 32; o > 0; o >>= 1) pd += __shfl_xor(pd, o);
  if (l == 0) went[wid] = active ? (logf(se) - pd) : 0.f;
  __syncthreads();
  if (threadIdx.x == 0) part[blockIdx.x] = went[0] + went[1] + went[2] + went[3];
}

__global__ __launch_bounds__(1024) void k_reduce_arr(
    const float* __restrict__ in, int n, float* __restrict__ out) {
  __shared__ float sh[1024];
  int t = threadIdx.x;
  float s = 0.f;
  for (int i = t; i < n; i += 1024) s += in[i];
  sh[t] = s; __syncthreads();
  for (int o = 512; o > 0; o >>= 1) { if (t < o) sh[t] += sh[t + o]; __syncthreads(); }
  if (t == 0) *out = sh[0];
}

// block0: trace(P0); block1: sumsq(P1); block2: sumsq(P0)
__global__ __launch_bounds__(256) void k_scalN(
    const float* __restrict__ P0, const float* __restrict__ P1, int K,
    float* __restrict__ outb) {
  __shared__ float sh[256];
  int b = blockIdx.x, t = threadIdx.x;
  float s = 0.f;
  if (b == 0) {
    for (int i = t; i < K; i += 256) s += P0[(size_t)i * K + i];
  } else {
    const float* P = (b == 1) ? P1 : P0;
    int n = K * K;
    for (int i = t; i < n; i += 256) { float v = P[i]; s += v * v; }
  }
  sh[t] = s; __syncthreads();
  for (int o = 128; o > 0; o >>= 1) { if (t < o) sh[t] += sh[t + o]; __syncthreads(); }
  if (t == 0) outb[b] = sh[0];
}

// block0: dot(U, V) over n; block1: sumsq(P) over nP
__global__ __launch_bounds__(256) void k_scal2(
    const float* __restrict__ U, const float* __restrict__ V, int n,
    const float* __restrict__ P, int nP, float* __restrict__ outb) {
  __shared__ float sh[256];
  int b = blockIdx.x, t = threadIdx.x;
  float s = 0.f;
  if (b == 0) {
    for (int i = t; i < n; i += 256) s += U[i] * V[i];
  } else {
    for (int i = t; i < nP; i += 256) { float v = P[i]; s += v * v; }
  }
  sh[t] = s; __syncthreads();
  for (int o = 128; o > 0; o >>= 1) { if (t < o) sh[t] += sh[t + o]; __syncthreads(); }
  if (t == 0) outb[b] = sh[0];
}

// ---------------- level-2 dense graph (A2T = apool^T layout) ----------------

// deg[q] = 1 + sum_p A2[p,q] = 1 + row-sum of A2T[q,:]
__global__ __launch_bounds__(256) void k_deg2_par(
    const float* __restrict__ A2T, float* __restrict__ dinv2, int Np) {
  __shared__ float sh[256];
  int q = blockIdx.x;
  int t = threadIdx.x;
  float s = (t == 0) ? 1.0f : 0.f;
  for (int p = t; p < Np; p += 256) s += A2T[(size_t)q * Np + p];
  sh[t] = s; __syncthreads();
  for (int o = 128; o > 0; o >>= 1) { if (t < o) sh[t] += sh[t + o]; __syncthreads(); }
  if (t == 0) {
    float d = sh[0];
    dinv2[q] = d > 0.f ? rsqrtf(fmaxf(d, 1e-12f)) : 0.f;
  }
}

// out[q,c] = dq * sum_p dinv2[p]*A2T[q,p]*H[p,c] + dq^2 * H[q,c]
__global__ void k_dense_agg(const float* __restrict__ A2T, const float* __restrict__ dinv2,
                            const float* __restrict__ H, float* __restrict__ out,
                            int Np, int C) {
  int q = blockIdx.x, c = threadIdx.x;
  float acc = 0.f;
#pragma unroll 8
  for (int p = 0; p < Np; ++p)
    acc += dinv2[p] * A2T[(size_t)q * Np + p] * H[(size_t)p * C + c];
  float dq = dinv2[q];
  out[(size_t)q * C + c] = dq * acc + dq * dq * H[(size_t)q * C + c];
}

// ---------------- fused tail TN products (level 2), LDS-staged ----------------
// z0: sts2 = S^T S [64x64]; z1,z2: xp2 = S^T B2 [64x128] tiles
__global__ __launch_bounds__(256) void k_tn3(
    const float* __restrict__ S, const float* __restrict__ B2,
    float* __restrict__ sts2, float* __restrict__ xp2, int M) {
  __shared__ float As[64][65];
  __shared__ float Bs[64][65];
  int z = blockIdx.x;
  const float* B; float* C; int J, j0;
  if (z == 0) { B = S;  C = sts2; J = 64;  j0 = 0; }
  else        { B = B2; C = xp2;  J = 128; j0 = (z - 1) * 64; }
  int t = threadIdx.x;
  int tj = t & 63, ti = t >> 6;
  float acc[16] = {};
  for (int m0 = 0; m0 < M; m0 += 64) {
#pragma unroll
    for (int r = 0; r < 16; ++r) {
      As[ti * 16 + r][tj] = S[(size_t)(m0 + ti * 16 + r) * 64 + tj];
      Bs[ti * 16 + r][tj] = B[(size_t)(m0 + ti * 16 + r) * J + j0 + tj];
    }
    __syncthreads();
#pragma unroll 4
    for (int mm = 0; mm < 64; ++mm) {
      float bv = Bs[mm][tj];
#pragma unroll
      for (int ii = 0; ii < 16; ++ii) acc[ii] += As[mm][ti * 16 + ii] * bv;
    }
    __syncthreads();
  }
  for (int ii = 0; ii < 16; ++ii) C[(size_t)(ti * 16 + ii) * J + j0 + tj] = acc[ii];
}

// ---------------- final head ----------------
__global__ void k_final(const float* __restrict__ xp2, const float* __restrict__ Wlin,
                        const float* __restrict__ blin, const float* __restrict__ scal,
                        float* __restrict__ out, int N1, int E1, int K1, int K2, int OUT) {
  __shared__ float pooled[128];
  __shared__ float logits[32];
  int t = threadIdx.x;
  float s = 0.f;
  for (int r = 0; r < K2; ++r) s += xp2[(size_t)r * 128 + t];
  pooled[t] = s / (float)K2;
  __syncthreads();
  if (t < OUT) {
    float acc = blin[t];
    for (int k = 0; k < 128; ++k) acc += pooled[k] * Wlin[(size_t)k * OUT + t];
    logits[t] = acc;
  }
  __syncthreads();
  if (t == 0) {
    float mx = logits[0];
    for (int j = 1; j < OUT; ++j) mx = fmaxf(mx, logits[j]);
    float se = 0.f;
    for (int j = 0; j < OUT; ++j) se += expf(logits[j] - mx);
    float lse = mx + logf(se);
    for (int j = 0; j < OUT; ++j) out[j] = logits[j] - lse;
    float n1 = (float)N1;
    float ent1 = scal[0] / n1;
    float ent2 = scal[1] / (float)K1;
    float link1 = sqrtf(fmaxf((float)E1 - 2.f * scal[2] + scal[3], 0.f)) / (n1 * n1);
    float link2 = sqrtf(fmaxf(scal[4] - 2.f * scal[5] + scal[6], 0.f)) / ((float)K1 * (float)K1);
    out[OUT] = ent1 + ent2 + link1 + link2;
  }
}

// ---------------- host ----------------

extern "C" void kernel_launch(void* const* d_in, const int* in_sizes, int n_in,
                              void* d_out, int out_size, void* d_ws, size_t ws_size,
                              hipStream_t stream) {
  (void)n_in; (void)out_size; (void)ws_size;
  const float* x = (const float*)d_in[0];
  const int* ei  = (const int*)d_in[1];
  const int N = in_sizes[0] / 128;   // 20000
  const int E = in_sizes[1] / 2;     // 640000
  const int* src = ei;
  const int* dst = ei + E;
  const float *W1a=(const float*)d_in[4],  *b1a=(const float*)d_in[5],
              *g1a=(const float*)d_in[6],  *be1a=(const float*)d_in[7];
  const float *W1b=(const float*)d_in[8],  *b1b=(const float*)d_in[9],
              *g1b=(const float*)d_in[10], *be1b=(const float*)d_in[11];
  const float *Wp1=(const float*)d_in[12], *bp1=(const float*)d_in[13],
              *gp1=(const float*)d_in[14], *bep1=(const float*)d_in[15];
  const float *W2a=(const float*)d_in[16], *b2a=(const float*)d_in[17],
              *g2a=(const float*)d_in[18], *be2a=(const float*)d_in[19];
  const float *W2b=(const float*)d_in[20], *b2b=(const float*)d_in[21],
              *g2b=(const float*)d_in[22], *be2b=(const float*)d_in[23];
  const float *Wp2=(const float*)d_in[24], *bp2=(const float*)d_in[25],
              *gp2=(const float*)d_in[26], *bep2=(const float*)d_in[27];
  const float *Wlin=(const float*)d_in[28], *blin=(const float*)d_in[29];
  const int K1 = in_sizes[12] / 128;   // 256
  const int K2 = in_sizes[24] / 128;   // 64
  const int OUT = in_sizes[29];        // 10

  char* base = (char*)d_ws;
  size_t off = 0;
  auto allocb = [&](size_t bytes) -> void* {
    void* p = (void*)(base + off);
    off += ((bytes + 255) & ~(size_t)255);
    return p;
  };
  auto alloc = [&](size_t nf) -> float* { return (float*)allocb(nf * 4); };
  auto alloci = [&](size_t ni) -> int* { return (int*)allocb(ni * 4); };
  auto allocu = [&](size_t nu) -> ushort* { return (ushort*)allocb(nu * 2); };

  auto cdiv = [](long long a, long long b) { return (int)((a + b - 1) / b); };

  const int RPB = 16;
  const int NBLK1 = cdiv(N, RPB);

  float* scal  = alloc(16);
  float* cs    = alloc(256);
  float* csq   = alloc(256);
  float* dinv  = alloc(N);
  float* dinv2 = alloc(K1);
  float* apT   = alloc((size_t)K1 * K1);   // apool^T
  float* sts   = alloc((size_t)K1 * K1);
  float* xp    = alloc((size_t)K1 * 128);
  float* h2    = alloc((size_t)K1 * 128);
  float* y2    = alloc((size_t)K1 * 128);
  float* xa2   = alloc((size_t)K1 * 128);
  float* x2f   = alloc((size_t)K1 * 128);
  float* s2b   = alloc((size_t)K1 * K2);
  float* U     = alloc((size_t)K1 * K2);   // A2T @ s2
  float* sts2  = alloc((size_t)K2 * K2);
  float* xp2   = alloc((size_t)K2 * 128);
  float* ent1p = alloc(cdiv(N, 4) + 8);
  float* ent2p = alloc(64 + 8);
  float* csp   = alloc((size_t)(NBLK1 + 2) * 512);
  float* R1 = alloc((size_t)N * 128);   // fp32; later St bf16 [K1,N]
  float* R2 = alloc((size_t)N * 128);   // fp32; later ATSt bf16 [K1,N]
  float* R3 = alloc((size_t)N * K1);    // Hb/aggB bf16 / Sb bf16 [N,K1]
  float* R4 = alloc((size_t)N * K1);    // agg out / S fp32 / A^T S fp32
  ushort* B16A = allocu((size_t)N * 128);  // xb -> R1b -> R2b -> R2t
  ushort* W1at = allocu(128 * 128);
  ushort* W1bt = allocu(128 * 128);
  ushort* Wp1t = allocu((size_t)K1 * 128);
  // CSR (dst only)
  int* cnt_d = alloci(N);
  int* rp_d  = alloci(N + 1);
  int* cur_d = alloci(N);
  int* col_s = alloci(E);

  ushort* Hb   = (ushort*)R3;  // [N, C] bf16 GEMM output for gather (blocks a,b)
  ushort* aggB = (ushort*)R3;  // [N, 128] bf16 aggregated input (pooling block)
  ushort* Sb   = (ushort*)R3;  // [N, K1] bf16 row-major S
  ushort* St   = (ushort*)R1;  // [K1, N] bf16
  ushort* ATSt = (ushort*)R2;  // [K1, N] bf16 (A^T S)^T
  ushort* R2t  = B16A;         // [128, N] bf16

  hipMemsetAsync(scal, 0, 16 * sizeof(float), stream);

  // ---- CSR by dst ----
  hipMemsetAsync(cnt_d, 0, (size_t)N * sizeof(int), stream);
  k_hist<<<cdiv(E, 256), 256, 0, stream>>>(dst, cnt_d, E);
  k_scan<<<1, 1024, 0, stream>>>(cnt_d, rp_d, cur_d, N, E);
  k_fill_csr<<<cdiv(E, 256), 256, 0, stream>>>(dst, src, cur_d, col_s, E);
  k_dinv_cnt<<<cdiv(N, 256), 256, 0, stream>>>(cnt_d, dinv, N);

  // ---- weight transposes + x conversion ----
  {
    dim3 b32(32, 8);
    k_tconv<<<dim3(4, 4), b32, 0, stream>>>(W1a, W1at, 128, 128);
    k_tconv<<<dim3(4, 4), b32, 0, stream>>>(W1b, W1bt, 128, 128);
    k_tconv<<<dim3(8, 4), b32, 0, stream>>>(Wp1, Wp1t, 128, K1);
  }
  k_conv<<<cdiv((size_t)N * 128 / 4, 256), 256, 0, stream>>>(x, B16A, N * 128 / 4);

  auto mfma_nt = [&](const ushort* A, const ushort* B, float* C, ushort* Cb,
                     int I, int J, int K, int nz) {
    int chunk = K, z = 1;
    if (nz > 1) {
      chunk = ((cdiv(K, nz) + 31) & ~31);
      z = cdiv(K, chunk);
      hipMemsetAsync(C, 0, (size_t)I * J * sizeof(float), stream);
    }
    dim3 g(J / 64, cdiv(I, 64), z);
    k_mfma_nt<<<g, 256, 0, stream>>>(A, B, C, Cb, I, J, K, chunk, z > 1 ? 1 : 0);
  };
  auto gemm_nn = [&](const float* A, const float* B, float* C, int M, int Nn, int K) {
    dim3 g(Nn / 64, cdiv(M, 64));
    k_sgemm_nn<<<g, 256, 0, stream>>>(A, B, C, M, Nn, K);
  };

  // level-1 blocks a,b: GEMM -> gather -> BN/SiLU
  auto block1 = [&](const ushort* xin_b, const ushort* Wt, const float* b, const float* gg,
                    const float* be, const float* resid, float* outp, ushort* outb, int C) {
    mfma_nt(xin_b, Wt, nullptr, Hb, N, C, 128, 1);
    k_gather_agg_b2<<<N, C / 2, 0, stream>>>(rp_d, col_s, dinv, Hb, R4, C / 2);
    k_col_stats2<<<NBLK1, C, 0, stream>>>(R4, b, csp, N, C, RPB);
    k_colred_par<<<C, 256, 0, stream>>>(csp, NBLK1, C, cs, csq);
    int tot = N * C;
    k_bn_silu<<<cdiv(tot, 256), 256, 0, stream>>>(R4, b, cs, csq, gg, be, resid, outp,
                                                  outb, tot, C - 1, 1.f / N);
  };

  block1(B16A, W1at, b1a, g1a, be1a, nullptr, R1, B16A, 128);  // R1 + R1b
  block1(B16A, W1bt, b1b, g1b, be1b, R1,      R2, B16A, 128);  // R2 + R2b

  // pooling block: agg = A_hat * R2 in input space (128 ch), then GEMM agg@Wp1
  k_gather_agg_b2b<<<N, 64, 0, stream>>>(rp_d, col_s, dinv, B16A, aggB, 64);
  mfma_nt(aggB, Wp1t, R4, nullptr, N, K1, 128, 1);
  k_col_stats2<<<NBLK1, K1, 0, stream>>>(R4, bp1, csp, N, K1, RPB);
  k_colred_par<<<K1, 256, 0, stream>>>(csp, NBLK1, K1, cs, csq);
  k_bn_silu<<<cdiv(N * K1, 256), 256, 0, stream>>>(R4, bp1, cs, csq, gp1, bep1, nullptr,
                                                   R4, nullptr, N * K1, K1 - 1, 1.f / N);
  // S = softmax(R4) fp32 in-place + bf16 copy Sb
  k_softmax_ent3<256><<<cdiv(N, 4), 256, 0, stream>>>(R4, Sb, ent1p, N);
  k_reduce_arr<<<1, 1024, 0, stream>>>(ent1p, cdiv(N, 4), &scal[0]);

  {
    dim3 b32(32, 8);
    k_tconv<<<dim3(K1 / 32, cdiv(N, 32)), b32, 0, stream>>>(R4, St, N, K1);     // St = S^T
    k_tconv<<<dim3(128 / 32, cdiv(N, 32)), b32, 0, stream>>>(R2, R2t, N, 128);  // R2t = x^T
  }
  // A^T S via dst-CSR gather -> R4 fp32 (S fp32 dead now)
  k_gather_T_b2<<<N, K1 / 2, 0, stream>>>(rp_d, col_s, Sb, R4, K1 / 2);
  {
    dim3 b32(32, 8);
    k_tconv<<<dim3(K1 / 32, cdiv(N, 32)), b32, 0, stream>>>(R4, ATSt, N, K1);   // (A^T S)^T
  }

  mfma_nt(St, ATSt, apT, nullptr, K1, K1, N, 16);    // apT = S^T A^T S = apool^T
  mfma_nt(St, St,  sts,  nullptr, K1, K1, N, 16);    // sts = S^T S
  mfma_nt(St, R2t, xp,   nullptr, K1, 128, N, 16);   // xp = S^T x
  k_scalN<<<3, 256, 0, stream>>>(apT, sts, K1, &scal[2]);  // trace, ||sts||^2, ||apool||^2

  // ---------------- level 2 (dense 256-node graph, A2T layout) ----------------
  k_deg2_par<<<K1, 256, 0, stream>>>(apT, dinv2, K1);

  auto block2 = [&](const float* xin, const float* W, const float* b, const float* gg,
                    const float* be, const float* resid, float* outp, int C) {
    gemm_nn(xin, W, h2, K1, C, 128);
    k_dense_agg<<<K1, C, 0, stream>>>(apT, dinv2, h2, y2, K1, C);
    k_bn_small<<<C, 256, 0, stream>>>(y2, b, gg, be, resid, outp, K1, C, 1.f / K1);
  };

  block2(xp,  W2a, b2a, g2a, be2a, nullptr, xa2, 128);
  block2(xa2, W2b, b2b, g2b, be2b, xa2,     x2f, 128);
  block2(x2f, Wp2, bp2, gp2, bep2, nullptr, s2b, K2);
  k_softmax_ent3<64><<<cdiv(K1, 4), 256, 0, stream>>>(s2b, nullptr, ent2p, K1);
  k_reduce_arr<<<1, 1024, 0, stream>>>(ent2p, cdiv(K1, 4), &scal[1]);

  // cross2 = <A2 s2, s2> = <A2T^T ... > computed as dot(U, s2) with U = A2T @ s2
  gemm_nn(apT, s2b, U, K1, K2, K1);
  k_tn3<<<3, 256, 0, stream>>>(s2b, x2f, sts2, xp2, K1);
  k_scal2<<<2, 256, 0, stream>>>(U, s2b, K1 * K2, sts2, K2 * K2, &scal[5]);

  k_final<<<1, 128, 0, stream>>>(xp2, Wlin, blin, scal, (float*)d_out, N, E, K1, K2, OUT);
}

// Round 9
// 591.865 us; speedup vs baseline: 4.8611x; 1.1171x over previous
//
#include <hip/hip_runtime.h>

#define EPS_BN 1e-5f
typedef unsigned int uint;
typedef unsigned short ushort;
typedef __attribute__((ext_vector_type(8))) short bf16x8;
typedef __attribute__((ext_vector_type(4))) float f32x4;

__device__ inline ushort f2bf(float f) {
  uint u = __float_as_uint(f);
  uint r = (u + 0x7FFFu + ((u >> 16) & 1u)) >> 16;
  return (ushort)r;
}
__device__ inline float bflo(uint h) { return __uint_as_float(h << 16); }
__device__ inline float bfhi(uint h) { return __uint_as_float(h & 0xFFFF0000u); }

// ---------------- CSR build (dst only) ----------------

__global__ void k_hist(const int* __restrict__ idx, int* __restrict__ cnt, int E) {
  int e = blockIdx.x * blockDim.x + threadIdx.x;
  if (e < E) atomicAdd(&cnt[idx[e]], 1);
}

__global__ __launch_bounds__(1024) void k_scan(
    const int* __restrict__ cnt, int* __restrict__ rowptr, int* __restrict__ cursor,
    int N, int E) {
  __shared__ int sh[1024];
  int t = threadIdx.x;
  int chunk = (N + 1023) / 1024;
  int i0 = t * chunk, i1 = min(i0 + chunk, N);
  int s = 0;
  for (int i = i0; i < i1; ++i) s += cnt[i];
  sh[t] = s; __syncthreads();
  for (int o = 1; o < 1024; o <<= 1) {
    int v = (t >= o) ? sh[t - o] : 0;
    __syncthreads();
    sh[t] += v;
    __syncthreads();
  }
  int run = (t == 0) ? 0 : sh[t - 1];
  for (int i = i0; i < i1; ++i) { rowptr[i] = run; cursor[i] = run; run += cnt[i]; }
  if (t == 1023) rowptr[N] = E;
}

__global__ void k_fill_csr(const int* __restrict__ key, const int* __restrict__ val,
                           int* __restrict__ cursor, int* __restrict__ col, int E) {
  int e = blockIdx.x * blockDim.x + threadIdx.x;
  if (e < E) {
    int pos = atomicAdd(&cursor[key[e]], 1);
    col[pos] = val[e];
  }
}

__global__ void k_dinv_cnt(const int* __restrict__ cnt, float* __restrict__ dinv, int n) {
  int i = blockIdx.x * blockDim.x + threadIdx.x;
  if (i < n) dinv[i] = rsqrtf(1.0f + (float)cnt[i]);
}

// ---------------- gather aggregation, bf16 input, 2 ch/thread ----------------

__global__ void k_gather_agg_b2(const int* __restrict__ rowptr, const int* __restrict__ col,
                                const float* __restrict__ dinv, const ushort* __restrict__ H,
                                float* __restrict__ out, int C2) {
  int d = blockIdx.x;
  int c2 = threadIdx.x;
  const uint* H2 = (const uint*)H;
  int b = rowptr[d], e = rowptr[d + 1];
  float a0 = 0.f, a1 = 0.f;
#pragma unroll 4
  for (int i = b; i < e; ++i) {
    int s = col[i];
    float dv = dinv[s];
    uint h = H2[(size_t)s * C2 + c2];
    a0 += dv * bflo(h);
    a1 += dv * bfhi(h);
  }
  float dd = dinv[d];
  uint hd = H2[(size_t)d * C2 + c2];
  float2 o;
  o.x = dd * a0 + dd * dd * bflo(hd);
  o.y = dd * a1 + dd * dd * bfhi(hd);
  *(float2*)(out + (size_t)d * (C2 * 2) + c2 * 2) = o;
}

// bf16 output variant (aggregate-then-GEMM pooling path)
__global__ void k_gather_agg_b2b(const int* __restrict__ rowptr, const int* __restrict__ col,
                                 const float* __restrict__ dinv, const ushort* __restrict__ H,
                                 ushort* __restrict__ out, int C2) {
  int d = blockIdx.x;
  int c2 = threadIdx.x;
  const uint* H2 = (const uint*)H;
  int b = rowptr[d], e = rowptr[d + 1];
  float a0 = 0.f, a1 = 0.f;
#pragma unroll 4
  for (int i = b; i < e; ++i) {
    int s = col[i];
    float dv = dinv[s];
    uint h = H2[(size_t)s * C2 + c2];
    a0 += dv * bflo(h);
    a1 += dv * bfhi(h);
  }
  float dd = dinv[d];
  uint hd = H2[(size_t)d * C2 + c2];
  ushort2 o;
  o.x = f2bf(dd * a0 + dd * dd * bflo(hd));
  o.y = f2bf(dd * a1 + dd * dd * bfhi(hd));
  *(ushort2*)(out + (size_t)d * (C2 * 2) + c2 * 2) = o;
}

// T[d] = sum_{e: dst=d} S[src_e]  (= A^T S with dst-CSR)
__global__ void k_gather_T_b2(const int* __restrict__ rowptr, const int* __restrict__ col,
                              const ushort* __restrict__ S, float* __restrict__ T, int C2) {
  int s = blockIdx.x;
  int c2 = threadIdx.x;
  const uint* S2 = (const uint*)S;
  int b = rowptr[s], e = rowptr[s + 1];
  float a0 = 0.f, a1 = 0.f;
#pragma unroll 4
  for (int i = b; i < e; ++i) {
    int d = col[i];
    uint h = S2[(size_t)d * C2 + c2];
    a0 += bflo(h);
    a1 += bfhi(h);
  }
  float2 o; o.x = a0; o.y = a1;
  *(float2*)(T + (size_t)s * (C2 * 2) + c2 * 2) = o;
}

// ---------------- conversion / transpose ----------------

__global__ void k_conv(const float* __restrict__ in, ushort* __restrict__ out, int n4) {
  int i = blockIdx.x * blockDim.x + threadIdx.x;
  if (i < n4) {
    float4 v = ((const float4*)in)[i];
    ushort4 o;
    o.x = f2bf(v.x); o.y = f2bf(v.y); o.z = f2bf(v.z); o.w = f2bf(v.w);
    ((ushort4*)out)[i] = o;
  }
}

// out[c, r] = bf16(in[r, c])
__global__ void k_tconv(const float* __restrict__ in, ushort* __restrict__ out,
                        int R, int Cc) {
  __shared__ float tile[32][33];
  int c0 = blockIdx.x * 32, r0 = blockIdx.y * 32;
  int tx = threadIdx.x, ty = threadIdx.y;
  for (int i = 0; i < 32; i += 8) {
    int r = r0 + ty + i, c = c0 + tx;
    if (r < R && c < Cc) tile[ty + i][tx] = in[(size_t)r * Cc + c];
  }
  __syncthreads();
  for (int i = 0; i < 32; i += 8) {
    int oc = c0 + ty + i;
    int orr = r0 + tx;
    if (oc < Cc && orr < R) out[(size_t)oc * R + orr] = f2bf(tile[tx][ty + i]);
  }
}

// ---------------- bf16 MFMA NT GEMM ----------------
__global__ __launch_bounds__(256) void k_mfma_nt(
    const ushort* __restrict__ A, const ushort* __restrict__ B, float* __restrict__ C,
    ushort* __restrict__ Cb, int I, int J, int K, int kChunk, int atom) {
  __shared__ ushort As[64][40];
  __shared__ ushort Bs[64][40];
  int t = threadIdx.x;
  int w = t >> 6, l = t & 63;
  int i0 = blockIdx.y * 64, j0 = blockIdx.x * 64;
  int k0 = blockIdx.z * kChunk;
  int k1 = min(k0 + kChunk, K);
  f32x4 acc[4] = {};
  int lrow = t >> 2;
  int lk = (t & 3) * 8;
  for (int kk = k0; kk < k1; kk += 32) {
    uint4 av = make_uint4(0u, 0u, 0u, 0u);
    int ar = i0 + lrow;
    if (ar < I) av = *(const uint4*)(A + (size_t)ar * K + kk + lk);
    uint4 bv = *(const uint4*)(B + (size_t)(j0 + lrow) * K + kk + lk);
    *(uint4*)&As[lrow][lk] = av;
    *(uint4*)&Bs[lrow][lk] = bv;
    __syncthreads();
    bf16x8 af = *(const bf16x8*)&As[16 * w + (l & 15)][(l >> 4) * 8];
#pragma unroll
    for (int jt = 0; jt < 4; ++jt) {
      bf16x8 bf = *(const bf16x8*)&Bs[16 * jt + (l & 15)][(l >> 4) * 8];
      acc[jt] = __builtin_amdgcn_mfma_f32_16x16x32_bf16(af, bf, acc[jt], 0, 0, 0);
    }
    __syncthreads();
  }
  int rbase = i0 + 16 * w + ((l >> 4) * 4);
  int cbase = j0 + (l & 15);
#pragma unroll
  for (int jt = 0; jt < 4; ++jt) {
#pragma unroll
    for (int rr = 0; rr < 4; ++rr) {
      int r = rbase + rr;
      if (r < I) {
        size_t idx = (size_t)r * J + jt * 16 + cbase;
        if (Cb) Cb[idx] = f2bf(acc[jt][rr]);
        else if (atom) atomicAdd(&C[idx], acc[jt][rr]);
        else C[idx] = acc[jt][rr];
      }
    }
  }
}

// ---------------- fp32 GEMM (small, level-2) ----------------
__global__ __launch_bounds__(256) void k_sgemm_nn(
    const float* __restrict__ A, const float* __restrict__ B, float* __restrict__ C,
    int M, int N, int K) {
  __shared__ float As[16][64];
  __shared__ float Bs[16][68];
  int t = threadIdx.x;
  int tx = t & 15, ty = t >> 4;
  int row0 = blockIdx.y * 64, col0 = blockIdx.x * 64;
  float acc[4][4] = {};
  for (int k0 = 0; k0 < K; k0 += 16) {
    int ar = t >> 2;
    int ak = (t & 3) * 4;
    float4 av = make_float4(0.f, 0.f, 0.f, 0.f);
    if (row0 + ar < M) av = *(const float4*)(A + (size_t)(row0 + ar) * K + k0 + ak);
    As[ak + 0][ar] = av.x; As[ak + 1][ar] = av.y;
    As[ak + 2][ar] = av.z; As[ak + 3][ar] = av.w;
    int bk = t >> 4;
    int bc = (t & 15) * 4;
    float4 bv = *(const float4*)(B + (size_t)(k0 + bk) * N + col0 + bc);
    *(float4*)&Bs[bk][bc] = bv;
    __syncthreads();
#pragma unroll
    for (int k = 0; k < 16; ++k) {
      float a[4], b[4];
#pragma unroll
      for (int u = 0; u < 4; ++u) a[u] = As[k][ty * 4 + u];
#pragma unroll
      for (int v = 0; v < 4; ++v) b[v] = Bs[k][tx * 4 + v];
#pragma unroll
      for (int u = 0; u < 4; ++u)
#pragma unroll
        for (int v = 0; v < 4; ++v) acc[u][v] += a[u] * b[v];
    }
    __syncthreads();
  }
#pragma unroll
  for (int u = 0; u < 4; ++u) {
    int r = row0 + ty * 4 + u;
    if (r < M) {
#pragma unroll
      for (int v = 0; v < 4; ++v) C[(size_t)r * N + col0 + tx * 4 + v] = acc[u][v];
    }
  }
}

// ---------------- BN stats (level-1, two-stage, no atomics) ----------------

__global__ void k_col_stats2(const float* __restrict__ X, const float* __restrict__ bias,
                             float* __restrict__ part, int M, int C, int rpb) {
  int c = threadIdx.x;
  int b = blockIdx.x;
  int r0 = b * rpb, r1 = min(r0 + rpb, M);
  float bi = bias[c];
  float s = 0.f, sq = 0.f;
  for (int r = r0; r < r1; ++r) {
    float v = X[(size_t)r * C + c] + bi;
    s += v; sq += v * v;
  }
  part[(size_t)b * 2 * C + c] = s;
  part[(size_t)b * 2 * C + C + c] = sq;
}

__global__ __launch_bounds__(256) void k_colred_par(
    const float* __restrict__ part, int nblk, int C,
    float* __restrict__ cs, float* __restrict__ csq) {
  __shared__ float sh[256];
  int c = blockIdx.x;
  int t = threadIdx.x;
  float s = 0.f, sq = 0.f;
  for (int b = t; b < nblk; b += 256) {
    s  += part[(size_t)b * 2 * C + c];
    sq += part[(size_t)b * 2 * C + C + c];
  }
  sh[t] = s; __syncthreads();
  for (int o = 128; o > 0; o >>= 1) { if (t < o) sh[t] += sh[t + o]; __syncthreads(); }
  if (t == 0) cs[c] = sh[0];
  __syncthreads();
  sh[t] = sq; __syncthreads();
  for (int o = 128; o > 0; o >>= 1) { if (t < o) sh[t] += sh[t + o]; __syncthreads(); }
  if (t == 0) csq[c] = sh[0];
}

__global__ void k_bn_silu(const float* __restrict__ X, const float* __restrict__ bias,
                          const float* __restrict__ cs, const float* __restrict__ csq,
                          const float* __restrict__ g, const float* __restrict__ be,
                          const float* __restrict__ resid, float* __restrict__ out,
                          ushort* __restrict__ outb,
                          int tot, int cmask, float invM) {
  int i = blockIdx.x * blockDim.x + threadIdx.x;
  if (i >= tot) return;
  int c = i & cmask;
  float m = cs[c] * invM;
  float var = csq[c] * invM - m * m;
  float v = (X[i] + bias[c] - m) * rsqrtf(var + EPS_BN) * g[c] + be[c];
  float y = v / (1.f + expf(-v));
  if (resid) y += resid[i];
  out[i] = y;
  if (outb) outb[i] = f2bf(y);
}

// ---------------- fused small BN (level-2, M<=256): one block per column ----------------
__global__ __launch_bounds__(256) void k_bn_small(
    const float* __restrict__ X, const float* __restrict__ bias,
    const float* __restrict__ g, const float* __restrict__ be,
    const float* __restrict__ resid, float* __restrict__ out,
    int M, int C, float invM) {
  __shared__ float sh[256];
  int c = blockIdx.x;
  int t = threadIdx.x;
  bool act = t < M;
  float v = 0.f;
  if (act) v = X[(size_t)t * C + c] + bias[c];
  sh[t] = v; __syncthreads();
  for (int o = 128; o > 0; o >>= 1) { if (t < o) sh[t] += sh[t + o]; __syncthreads(); }
  float m = sh[0] * invM; __syncthreads();
  sh[t] = v * v; __syncthreads();
  for (int o = 128; o > 0; o >>= 1) { if (t < o) sh[t] += sh[t + o]; __syncthreads(); }
  float var = sh[0] * invM - m * m;
  if (act) {
    float y = (v - m) * rsqrtf(var + EPS_BN) * g[c] + be[c];
    y = y / (1.f + expf(-y));
    if (resid) y += resid[(size_t)t * C + c];
    out[(size_t)t * C + c] = y;
  }
}

// ---------------- softmax + entropy (block partials) ----------------
template <int C>
__global__ void k_softmax_ent3(float* __restrict__ X, ushort* __restrict__ outb,
                               float* __restrict__ part, int nrows) {
  constexpr int VPT = C / 64;
  __shared__ float went[4];
  int gt = blockIdx.x * blockDim.x + threadIdx.x;
  int row = gt >> 6;
  int l = gt & 63;
  int wid = threadIdx.x >> 6;
  bool active = row < nrows;
  size_t base = active ? (size_t)row * C : 0;
  float d[VPT];
  if (VPT == 4) {
    float4 v = *(const float4*)(X + base + l * 4);
    d[0] = v.x; d[1] = v.y; d[2] = v.z; d[3] = v.w;
  } else {
    d[0] = X[base + l];
  }
  float mx = d[0];
#pragma unroll
  for (int i = 1; i < VPT; ++i) mx = fmaxf(mx, d[i]);
  for (int o = 32; o > 0; o >>= 1) mx = fmaxf(mx, __shfl_xor(mx, o));
  float se = 0.f;
  float e[VPT];
#pragma unroll
  for (int i = 0; i < VPT; ++i) { d[i] -= mx; e[i] = expf(d[i]); se += e[i]; }
  for (int o = 32; o > 0; o >>= 1) se += __shfl_xor(se, o);
  float inv = 1.f / se;
  float pd = 0.f;
#pragma unroll
  for (int i = 0; i < VPT; ++i) { e[i] *= inv; pd += e[i] * d[i]; }
  if (active) {
    if (VPT == 4) {
      float4 v; v.x = e[0]; v.y = e[1]; v.z = e[2]; v.w = e[3];
      *(float4*)(X + base + l * 4) = v;
      if (outb) {
        ushort4 u; u.x = f2bf(e[0]); u.y = f2bf(e[1]); u.z = f2bf(e[2]); u.w = f2bf(e[3]);
        *(ushort4*)(outb + base + l * 4) = u;
      }
    } else {
      X[base + l] = e[0];
      if (outb) outb[base + l] = f2bf(e[0]);
    }
  }
  for (int o = 32; o > 0; o >>= 1) pd += __shfl_xor(pd, o);
  if (l == 0) went[wid] = active ? (logf(se) - pd) : 0.f;
  __syncthreads();
  if (threadIdx.x == 0) part[blockIdx.x] = went[0] + went[1] + went[2] + went[3];
}

// chunked parallel sum with one atomic per block
__global__ __launch_bounds__(256) void k_reduce_atom(
    const float* __restrict__ in, int n, float* __restrict__ out) {
  __shared__ float sh[256];
  int t = threadIdx.x;
  int per = (n + gridDim.x - 1) / gridDim.x;
  int i0 = blockIdx.x * per, i1 = min(i0 + per, n);
  float s = 0.f;
  for (int i = i0 + t; i < i1; i += 256) s += in[i];
  sh[t] = s; __syncthreads();
  for (int o = 128; o > 0; o >>= 1) { if (t < o) sh[t] += sh[t + o]; __syncthreads(); }
  if (t == 0) atomicAdd(out, sh[0]);
}

// grid = 1 + 2Z: b0 trace(P0); b 1..Z sumsq(P1) chunks; b Z+1..2Z sumsq(P0) chunks
__global__ __launch_bounds__(256) void k_scalN_par(
    const float* __restrict__ P0, const float* __restrict__ P1, int K,
    float* __restrict__ outb, int Z) {
  __shared__ float sh[256];
  int b = blockIdx.x, t = threadIdx.x;
  float s = 0.f;
  int slot;
  if (b == 0) {
    slot = 0;
    for (int i = t; i < K; i += 256) s += P0[(size_t)i * K + i];
  } else {
    int which = (b - 1) / Z;       // 0 -> P1, 1 -> P0
    int chunk = (b - 1) % Z;
    slot = 1 + which;
    const float4* P4 = (const float4*)(which ? P0 : P1);
    int n4 = (K * K) >> 2;
    int per = (n4 + Z - 1) / Z;
    int i0 = chunk * per, i1 = min(i0 + per, n4);
    for (int i = i0 + t; i < i1; i += 256) {
      float4 v = P4[i];
      s += v.x * v.x + v.y * v.y + v.z * v.z + v.w * v.w;
    }
  }
  sh[t] = s; __syncthreads();
  for (int o = 128; o > 0; o >>= 1) { if (t < o) sh[t] += sh[t + o]; __syncthreads(); }
  if (t == 0) atomicAdd(&outb[slot], sh[0]);
}

// grid = Z + 1: b<Z dot(U,V) chunks; b==Z sumsq(P)
__global__ __launch_bounds__(256) void k_scal2_par(
    const float* __restrict__ U, const float* __restrict__ V, int n,
    const float* __restrict__ P, int nP, float* __restrict__ outb, int Z) {
  __shared__ float sh[256];
  int b = blockIdx.x, t = threadIdx.x;
  float s = 0.f;
  int slot;
  if (b < Z) {
    slot = 0;
    const float4* U4 = (const float4*)U;
    const float4* V4 = (const float4*)V;
    int n4 = n >> 2;
    int per = (n4 + Z - 1) / Z;
    int i0 = b * per, i1 = min(i0 + per, n4);
    for (int i = i0 + t; i < i1; i += 256) {
      float4 u = U4[i], v = V4[i];
      s += u.x * v.x + u.y * v.y + u.z * v.z + u.w * v.w;
    }
  } else {
    slot = 1;
    const float4* P4 = (const float4*)P;
    int n4 = nP >> 2;
    for (int i = t; i < n4; i += 256) {
      float4 v = P4[i];
      s += v.x * v.x + v.y * v.y + v.z * v.z + v.w * v.w;
    }
  }
  sh[t] = s; __syncthreads();
  for (int o = 128; o > 0; o >>= 1) { if (t < o) sh[t] += sh[t + o]; __syncthreads(); }
  if (t == 0) atomicAdd(&outb[slot], sh[0]);
}

// ---------------- level-2 dense graph (A2T = apool^T layout) ----------------

__global__ __launch_bounds__(256) void k_deg2_par(
    const float* __restrict__ A2T, float* __restrict__ dinv2, int Np) {
  __shared__ float sh[256];
  int q = blockIdx.x;
  int t = threadIdx.x;
  float s = (t == 0) ? 1.0f : 0.f;
  for (int p = t; p < Np; p += 256) s += A2T[(size_t)q * Np + p];
  sh[t] = s; __syncthreads();
  for (int o = 128; o > 0; o >>= 1) { if (t < o) sh[t] += sh[t + o]; __syncthreads(); }
  if (t == 0) {
    float d = sh[0];
    dinv2[q] = d > 0.f ? rsqrtf(fmaxf(d, 1e-12f)) : 0.f;
  }
}

__global__ void k_dense_agg(const float* __restrict__ A2T, const float* __restrict__ dinv2,
                            const float* __restrict__ H, float* __restrict__ out,
                            int Np, int C) {
  int q = blockIdx.x, c = threadIdx.x;
  float acc = 0.f;
#pragma unroll 8
  for (int p = 0; p < Np; ++p)
    acc += dinv2[p] * A2T[(size_t)q * Np + p] * H[(size_t)p * C + c];
  float dq = dinv2[q];
  out[(size_t)q * C + c] = dq * acc + dq * dq * H[(size_t)q * C + c];
}

// ---------------- fused tail TN products (level 2), LDS-staged ----------------
__global__ __launch_bounds__(256) void k_tn3(
    const float* __restrict__ S, const float* __restrict__ B2,
    float* __restrict__ sts2, float* __restrict__ xp2, int M) {
  __shared__ float As[64][65];
  __shared__ float Bs[64][65];
  int z = blockIdx.x;
  const float* B; float* C; int J, j0;
  if (z == 0) { B = S;  C = sts2; J = 64;  j0 = 0; }
  else        { B = B2; C = xp2;  J = 128; j0 = (z - 1) * 64; }
  int t = threadIdx.x;
  int tj = t & 63, ti = t >> 6;
  float acc[16] = {};
  for (int m0 = 0; m0 < M; m0 += 64) {
#pragma unroll
    for (int r = 0; r < 16; ++r) {
      As[ti * 16 + r][tj] = S[(size_t)(m0 + ti * 16 + r) * 64 + tj];
      Bs[ti * 16 + r][tj] = B[(size_t)(m0 + ti * 16 + r) * J + j0 + tj];
    }
    __syncthreads();
#pragma unroll 4
    for (int mm = 0; mm < 64; ++mm) {
      float bv = Bs[mm][tj];
#pragma unroll
      for (int ii = 0; ii < 16; ++ii) acc[ii] += As[mm][ti * 16 + ii] * bv;
    }
    __syncthreads();
  }
  for (int ii = 0; ii < 16; ++ii) C[(size_t)(ti * 16 + ii) * J + j0 + tj] = acc[ii];
}

// ---------------- final head ----------------
__global__ void k_final(const float* __restrict__ xp2, const float* __restrict__ Wlin,
                        const float* __restrict__ blin, const float* __restrict__ scal,
                        float* __restrict__ out, int N1, int E1, int K1, int K2, int OUT) {
  __shared__ float pooled[128];
  __shared__ float logits[32];
  int t = threadIdx.x;
  float s = 0.f;
  for (int r = 0; r < K2; ++r) s += xp2[(size_t)r * 128 + t];
  pooled[t] = s / (float)K2;
  __syncthreads();
  if (t < OUT) {
    float acc = blin[t];
    for (int k = 0; k < 128; ++k) acc += pooled[k] * Wlin[(size_t)k * OUT + t];
    logits[t] = acc;
  }
  __syncthreads();
  if (t == 0) {
    float mx = logits[0];
    for (int j = 1; j < OUT; ++j) mx = fmaxf(mx, logits[j]);
    float se = 0.f;
    for (int j = 0; j < OUT; ++j) se += expf(logits[j] - mx);
    float lse = mx + logf(se);
    for (int j = 0; j < OUT; ++j) out[j] = logits[j] - lse;
    float n1 = (float)N1;
    float ent1 = scal[0] / n1;
    float ent2 = scal[1] / (float)K1;
    float link1 = sqrtf(fmaxf((float)E1 - 2.f * scal[2] + scal[3], 0.f)) / (n1 * n1);
    float link2 = sqrtf(fmaxf(scal[4] - 2.f * scal[5] + scal[6], 0.f)) / ((float)K1 * (float)K1);
    out[OUT] = ent1 + ent2 + link1 + link2;
  }
}

// ---------------- host ----------------

extern "C" void kernel_launch(void* const* d_in, const int* in_sizes, int n_in,
                              void* d_out, int out_size, void* d_ws, size_t ws_size,
                              hipStream_t stream) {
  (void)n_in; (void)out_size; (void)ws_size;
  const float* x = (const float*)d_in[0];
  const int* ei  = (const int*)d_in[1];
  const int N = in_sizes[0] / 128;   // 20000
  const int E = in_sizes[1] / 2;     // 640000
  const int* src = ei;
  const int* dst = ei + E;
  const float *W1a=(const float*)d_in[4],  *b1a=(const float*)d_in[5],
              *g1a=(const float*)d_in[6],  *be1a=(const float*)d_in[7];
  const float *W1b=(const float*)d_in[8],  *b1b=(const float*)d_in[9],
              *g1b=(const float*)d_in[10], *be1b=(const float*)d_in[11];
  const float *Wp1=(const float*)d_in[12], *bp1=(const float*)d_in[13],
              *gp1=(const float*)d_in[14], *bep1=(const float*)d_in[15];
  const float *W2a=(const float*)d_in[16], *b2a=(const float*)d_in[17],
              *g2a=(const float*)d_in[18], *be2a=(const float*)d_in[19];
  const float *W2b=(const float*)d_in[20], *b2b=(const float*)d_in[21],
              *g2b=(const float*)d_in[22], *be2b=(const float*)d_in[23];
  const float *Wp2=(const float*)d_in[24], *bp2=(const float*)d_in[25],
              *gp2=(const float*)d_in[26], *bep2=(const float*)d_in[27];
  const float *Wlin=(const float*)d_in[28], *blin=(const float*)d_in[29];
  const int K1 = in_sizes[12] / 128;   // 256
  const int K2 = in_sizes[24] / 128;   // 64
  const int OUT = in_sizes[29];        // 10

  char* base = (char*)d_ws;
  size_t off = 0;
  auto allocb = [&](size_t bytes) -> void* {
    void* p = (void*)(base + off);
    off += ((bytes + 255) & ~(size_t)255);
    return p;
  };
  auto alloc = [&](size_t nf) -> float* { return (float*)allocb(nf * 4); };
  auto alloci = [&](size_t ni) -> int* { return (int*)allocb(ni * 4); };
  auto allocu = [&](size_t nu) -> ushort* { return (ushort*)allocb(nu * 2); };

  auto cdiv = [](long long a, long long b) { return (int)((a + b - 1) / b); };

  const int RPB = 16;
  const int NBLK1 = cdiv(N, RPB);

  float* scal  = alloc(16);
  float* cs    = alloc(256);
  float* csq   = alloc(256);
  float* dinv  = alloc(N);
  float* dinv2 = alloc(K1);
  float* apT   = alloc((size_t)K1 * K1);   // apool^T
  float* sts   = alloc((size_t)K1 * K1);
  float* xp    = alloc((size_t)K1 * 128);
  float* h2    = alloc((size_t)K1 * 128);
  float* y2    = alloc((size_t)K1 * 128);
  float* xa2   = alloc((size_t)K1 * 128);
  float* x2f   = alloc((size_t)K1 * 128);
  float* s2b   = alloc((size_t)K1 * K2);
  float* U     = alloc((size_t)K1 * K2);   // A2T @ s2
  float* sts2  = alloc((size_t)K2 * K2);
  float* xp2   = alloc((size_t)K2 * 128);
  float* ent1p = alloc(cdiv(N, 4) + 8);
  float* ent2p = alloc(64 + 8);
  float* csp   = alloc((size_t)(NBLK1 + 2) * 512);
  float* R1 = alloc((size_t)N * 128);   // fp32; later St bf16 [K1,N]
  float* R2 = alloc((size_t)N * 128);   // fp32; later ATSt bf16 [K1,N]
  float* R3 = alloc((size_t)N * K1);    // Hb/aggB bf16 / Sb bf16 [N,K1]
  float* R4 = alloc((size_t)N * K1);    // agg out / S fp32 / A^T S fp32
  ushort* B16A = allocu((size_t)N * 128);  // xb -> R1b -> R2b -> R2t
  ushort* W1at = allocu(128 * 128);
  ushort* W1bt = allocu(128 * 128);
  ushort* Wp1t = allocu((size_t)K1 * 128);
  // CSR (dst only)
  int* cnt_d = alloci(N);
  int* rp_d  = alloci(N + 1);
  int* cur_d = alloci(N);
  int* col_s = alloci(E);

  ushort* Hb   = (ushort*)R3;  // [N, C] bf16 GEMM output for gather (blocks a,b)
  ushort* aggB = (ushort*)R3;  // [N, 128] bf16 aggregated input (pooling block)
  ushort* Sb   = (ushort*)R3;  // [N, K1] bf16 row-major S
  ushort* St   = (ushort*)R1;  // [K1, N] bf16
  ushort* ATSt = (ushort*)R2;  // [K1, N] bf16 (A^T S)^T
  ushort* R2t  = B16A;         // [128, N] bf16

  hipMemsetAsync(scal, 0, 16 * sizeof(float), stream);

  // ---- CSR by dst ----
  hipMemsetAsync(cnt_d, 0, (size_t)N * sizeof(int), stream);
  k_hist<<<cdiv(E, 256), 256, 0, stream>>>(dst, cnt_d, E);
  k_scan<<<1, 1024, 0, stream>>>(cnt_d, rp_d, cur_d, N, E);
  k_fill_csr<<<cdiv(E, 256), 256, 0, stream>>>(dst, src, cur_d, col_s, E);
  k_dinv_cnt<<<cdiv(N, 256), 256, 0, stream>>>(cnt_d, dinv, N);

  // ---- weight transposes + x conversion ----
  {
    dim3 b32(32, 8);
    k_tconv<<<dim3(4, 4), b32, 0, stream>>>(W1a, W1at, 128, 128);
    k_tconv<<<dim3(4, 4), b32, 0, stream>>>(W1b, W1bt, 128, 128);
    k_tconv<<<dim3(8, 4), b32, 0, stream>>>(Wp1, Wp1t, 128, K1);
  }
  k_conv<<<cdiv((size_t)N * 128 / 4, 256), 256, 0, stream>>>(x, B16A, N * 128 / 4);

  auto mfma_nt = [&](const ushort* A, const ushort* B, float* C, ushort* Cb,
                     int I, int J, int K, int nz) {
    int chunk = K, z = 1;
    if (nz > 1) {
      chunk = ((cdiv(K, nz) + 31) & ~31);
      z = cdiv(K, chunk);
      hipMemsetAsync(C, 0, (size_t)I * J * sizeof(float), stream);
    }
    dim3 g(J / 64, cdiv(I, 64), z);
    k_mfma_nt<<<g, 256, 0, stream>>>(A, B, C, Cb, I, J, K, chunk, z > 1 ? 1 : 0);
  };
  auto gemm_nn = [&](const float* A, const float* B, float* C, int M, int Nn, int K) {
    dim3 g(Nn / 64, cdiv(M, 64));
    k_sgemm_nn<<<g, 256, 0, stream>>>(A, B, C, M, Nn, K);
  };

  // level-1 blocks a,b: GEMM -> gather -> BN/SiLU
  auto block1 = [&](const ushort* xin_b, const ushort* Wt, const float* b, const float* gg,
                    const float* be, const float* resid, float* outp, ushort* outb, int C) {
    mfma_nt(xin_b, Wt, nullptr, Hb, N, C, 128, 1);
    k_gather_agg_b2<<<N, C / 2, 0, stream>>>(rp_d, col_s, dinv, Hb, R4, C / 2);
    k_col_stats2<<<NBLK1, C, 0, stream>>>(R4, b, csp, N, C, RPB);
    k_colred_par<<<C, 256, 0, stream>>>(csp, NBLK1, C, cs, csq);
    int tot = N * C;
    k_bn_silu<<<cdiv(tot, 256), 256, 0, stream>>>(R4, b, cs, csq, gg, be, resid, outp,
                                                  outb, tot, C - 1, 1.f / N);
  };

  block1(B16A, W1at, b1a, g1a, be1a, nullptr, R1, B16A, 128);  // R1 + R1b
  block1(B16A, W1bt, b1b, g1b, be1b, R1,      R2, B16A, 128);  // R2 + R2b

  // pooling block: agg = A_hat * R2 in input space (128 ch), then GEMM agg@Wp1
  k_gather_agg_b2b<<<N, 64, 0, stream>>>(rp_d, col_s, dinv, B16A, aggB, 64);
  mfma_nt(aggB, Wp1t, R4, nullptr, N, K1, 128, 1);
  k_col_stats2<<<NBLK1, K1, 0, stream>>>(R4, bp1, csp, N, K1, RPB);
  k_colred_par<<<K1, 256, 0, stream>>>(csp, NBLK1, K1, cs, csq);
  k_bn_silu<<<cdiv(N * K1, 256), 256, 0, stream>>>(R4, bp1, cs, csq, gp1, bep1, nullptr,
                                                   R4, nullptr, N * K1, K1 - 1, 1.f / N);
  // S = softmax(R4) fp32 in-place + bf16 copy Sb
  k_softmax_ent3<256><<<cdiv(N, 4), 256, 0, stream>>>(R4, Sb, ent1p, N);
  k_reduce_atom<<<8, 256, 0, stream>>>(ent1p, cdiv(N, 4), &scal[0]);

  {
    dim3 b32(32, 8);
    k_tconv<<<dim3(K1 / 32, cdiv(N, 32)), b32, 0, stream>>>(R4, St, N, K1);     // St = S^T
    k_tconv<<<dim3(128 / 32, cdiv(N, 32)), b32, 0, stream>>>(R2, R2t, N, 128);  // R2t = x^T
  }
  // A^T S via dst-CSR gather -> R4 fp32 (S fp32 dead now)
  k_gather_T_b2<<<N, K1 / 2, 0, stream>>>(rp_d, col_s, Sb, R4, K1 / 2);
  {
    dim3 b32(32, 8);
    k_tconv<<<dim3(K1 / 32, cdiv(N, 32)), b32, 0, stream>>>(R4, ATSt, N, K1);   // (A^T S)^T
  }

  mfma_nt(St, ATSt, apT, nullptr, K1, K1, N, 16);    // apT = S^T A^T S = apool^T
  mfma_nt(St, St,  sts,  nullptr, K1, K1, N, 16);    // sts = S^T S
  mfma_nt(St, R2t, xp,   nullptr, K1, 128, N, 16);   // xp = S^T x
  // scal[2]=trace(apT), scal[3]=||sts||^2, scal[4]=||apool||^2  (atomic accumulate, zeroed)
  k_scalN_par<<<1 + 2 * 16, 256, 0, stream>>>(apT, sts, K1, &scal[2], 16);

  // ---------------- level 2 (dense 256-node graph, A2T layout) ----------------
  k_deg2_par<<<K1, 256, 0, stream>>>(apT, dinv2, K1);

  auto block2 = [&](const float* xin, const float* W, const float* b, const float* gg,
                    const float* be, const float* resid, float* outp, int C) {
    gemm_nn(xin, W, h2, K1, C, 128);
    k_dense_agg<<<K1, C, 0, stream>>>(apT, dinv2, h2, y2, K1, C);
    k_bn_small<<<C, 256, 0, stream>>>(y2, b, gg, be, resid, outp, K1, C, 1.f / K1);
  };

  block2(xp,  W2a, b2a, g2a, be2a, nullptr, xa2, 128);
  block2(xa2, W2b, b2b, g2b, be2b, xa2,     x2f, 128);
  block2(x2f, Wp2, bp2, gp2, bep2, nullptr, s2b, K2);
  k_softmax_ent3<64><<<cdiv(K1, 4), 256, 0, stream>>>(s2b, nullptr, ent2p, K1);
  k_reduce_atom<<<2, 256, 0, stream>>>(ent2p, cdiv(K1, 4), &scal[1]);

  // cross2 = dot(U, s2) with U = A2T @ s2;  sumsq(sts2)
  gemm_nn(apT, s2b, U, K1, K2, K1);
  k_tn3<<<3, 256, 0, stream>>>(s2b, x2f, sts2, xp2, K1);
  k_scal2_par<<<8 + 1, 256, 0, stream>>>(U, s2b, K1 * K2, sts2, K2 * K2, &scal[5], 8);

  k_final<<<1, 128, 0, stream>>>(xp2, Wlin, blin, scal, (float*)d_out, N, E, K1, K2, OUT);
}

// Round 10
// 544.709 us; speedup vs baseline: 5.2819x; 1.0866x over previous
//
#include <hip/hip_runtime.h>

#define EPS_BN 1e-5f
typedef unsigned int uint;
typedef unsigned short ushort;
typedef __attribute__((ext_vector_type(8))) short bf16x8;
typedef __attribute__((ext_vector_type(4))) float f32x4;

__device__ inline ushort f2bf(float f) {
  uint u = __float_as_uint(f);
  uint r = (u + 0x7FFFu + ((u >> 16) & 1u)) >> 16;
  return (ushort)r;
}
__device__ inline float bflo(uint h) { return __uint_as_float(h << 16); }
__device__ inline float bfhi(uint h) { return __uint_as_float(h & 0xFFFF0000u); }

// ---------------- fused prologue: dst-histogram + x -> bf16 ----------------

__global__ void k_pre(const int* __restrict__ dst, int* __restrict__ cnt, int E,
                      const float* __restrict__ x, ushort* __restrict__ xb, int n4, int HB) {
  int b = blockIdx.x;
  if (b < HB) {
    int e = b * 256 + threadIdx.x;
    if (e < E) atomicAdd(&cnt[dst[e]], 1);
  } else {
    int i = (b - HB) * 256 + threadIdx.x;
    if (i < n4) {
      float4 v = ((const float4*)x)[i];
      ushort4 o;
      o.x = f2bf(v.x); o.y = f2bf(v.y); o.z = f2bf(v.z); o.w = f2bf(v.w);
      ((ushort4*)xb)[i] = o;
    }
  }
}

// scan over cnt -> rowptr/cursor, plus dinv = rsqrt(1+cnt)
__global__ __launch_bounds__(1024) void k_scan(
    const int* __restrict__ cnt, int* __restrict__ rowptr, int* __restrict__ cursor,
    float* __restrict__ dinv, int N, int E) {
  __shared__ int sh[1024];
  int t = threadIdx.x;
  int chunk = (N + 1023) / 1024;
  int i0 = t * chunk, i1 = min(i0 + chunk, N);
  int s = 0;
  for (int i = i0; i < i1; ++i) s += cnt[i];
  sh[t] = s; __syncthreads();
  for (int o = 1; o < 1024; o <<= 1) {
    int v = (t >= o) ? sh[t - o] : 0;
    __syncthreads();
    sh[t] += v;
    __syncthreads();
  }
  int run = (t == 0) ? 0 : sh[t - 1];
  for (int i = i0; i < i1; ++i) {
    rowptr[i] = run; cursor[i] = run; run += cnt[i];
    dinv[i] = rsqrtf(1.0f + (float)cnt[i]);
  }
  if (t == 1023) rowptr[N] = E;
}

__global__ void k_fill_csr(const int* __restrict__ key, const int* __restrict__ val,
                           int* __restrict__ cursor, int* __restrict__ col, int E) {
  int e = blockIdx.x * blockDim.x + threadIdx.x;
  if (e < E) {
    int pos = atomicAdd(&cursor[key[e]], 1);
    col[pos] = val[e];
  }
}

// ---------------- gather aggregation, bf16 input, 2 ch/thread ----------------

__global__ void k_gather_agg_b2(const int* __restrict__ rowptr, const int* __restrict__ col,
                                const float* __restrict__ dinv, const ushort* __restrict__ H,
                                float* __restrict__ out, int C2) {
  int d = blockIdx.x;
  int c2 = threadIdx.x;
  const uint* H2 = (const uint*)H;
  int b = rowptr[d], e = rowptr[d + 1];
  float a0 = 0.f, a1 = 0.f;
#pragma unroll 4
  for (int i = b; i < e; ++i) {
    int s = col[i];
    float dv = dinv[s];
    uint h = H2[(size_t)s * C2 + c2];
    a0 += dv * bflo(h);
    a1 += dv * bfhi(h);
  }
  float dd = dinv[d];
  uint hd = H2[(size_t)d * C2 + c2];
  float2 o;
  o.x = dd * a0 + dd * dd * bflo(hd);
  o.y = dd * a1 + dd * dd * bfhi(hd);
  *(float2*)(out + (size_t)d * (C2 * 2) + c2 * 2) = o;
}

// bf16 output variant (aggregate-then-GEMM pooling path)
__global__ void k_gather_agg_b2b(const int* __restrict__ rowptr, const int* __restrict__ col,
                                 const float* __restrict__ dinv, const ushort* __restrict__ H,
                                 ushort* __restrict__ out, int C2) {
  int d = blockIdx.x;
  int c2 = threadIdx.x;
  const uint* H2 = (const uint*)H;
  int b = rowptr[d], e = rowptr[d + 1];
  float a0 = 0.f, a1 = 0.f;
#pragma unroll 4
  for (int i = b; i < e; ++i) {
    int s = col[i];
    float dv = dinv[s];
    uint h = H2[(size_t)s * C2 + c2];
    a0 += dv * bflo(h);
    a1 += dv * bfhi(h);
  }
  float dd = dinv[d];
  uint hd = H2[(size_t)d * C2 + c2];
  ushort2 o;
  o.x = f2bf(dd * a0 + dd * dd * bflo(hd));
  o.y = f2bf(dd * a1 + dd * dd * bfhi(hd));
  *(ushort2*)(out + (size_t)d * (C2 * 2) + c2 * 2) = o;
}

// T[d] = sum_{e: dst=d} S[src_e]  (= A^T S with dst-CSR), bf16 out
__global__ void k_gather_T_b2b(const int* __restrict__ rowptr, const int* __restrict__ col,
                               const ushort* __restrict__ S, ushort* __restrict__ T, int C2) {
  int s = blockIdx.x;
  int c2 = threadIdx.x;
  const uint* S2 = (const uint*)S;
  int b = rowptr[s], e = rowptr[s + 1];
  float a0 = 0.f, a1 = 0.f;
#pragma unroll 4
  for (int i = b; i < e; ++i) {
    int d = col[i];
    uint h = S2[(size_t)d * C2 + c2];
    a0 += bflo(h);
    a1 += bfhi(h);
  }
  ushort2 o; o.x = f2bf(a0); o.y = f2bf(a1);
  *(ushort2*)(T + (size_t)s * (C2 * 2) + c2 * 2) = o;
}

// ---------------- transposes ----------------

// fp32 in -> bf16 out, out[c, r] = bf16(in[r, c])
__global__ void k_tconv(const float* __restrict__ in, ushort* __restrict__ out,
                        int R, int Cc) {
  __shared__ float tile[32][33];
  int c0 = blockIdx.x * 32, r0 = blockIdx.y * 32;
  int tx = threadIdx.x, ty = threadIdx.y;
  for (int i = 0; i < 32; i += 8) {
    int r = r0 + ty + i, c = c0 + tx;
    if (r < R && c < Cc) tile[ty + i][tx] = in[(size_t)r * Cc + c];
  }
  __syncthreads();
  for (int i = 0; i < 32; i += 8) {
    int oc = c0 + ty + i;
    int orr = r0 + tx;
    if (oc < Cc && orr < R) out[(size_t)oc * R + orr] = f2bf(tile[tx][ty + i]);
  }
}

// bf16 in -> bf16 out transpose
__global__ void k_tconv_b(const ushort* __restrict__ in, ushort* __restrict__ out,
                          int R, int Cc) {
  __shared__ ushort tile[32][33];
  int c0 = blockIdx.x * 32, r0 = blockIdx.y * 32;
  int tx = threadIdx.x, ty = threadIdx.y;
  for (int i = 0; i < 32; i += 8) {
    int r = r0 + ty + i, c = c0 + tx;
    if (r < R && c < Cc) tile[ty + i][tx] = in[(size_t)r * Cc + c];
  }
  __syncthreads();
  for (int i = 0; i < 32; i += 8) {
    int oc = c0 + ty + i;
    int orr = r0 + tx;
    if (oc < Cc && orr < R) out[(size_t)oc * R + orr] = tile[tx][ty + i];
  }
}

// three weight transposes in one launch (z = 0,1,2), R=128
__global__ void k_tconv3(const float* __restrict__ W0, const float* __restrict__ W1,
                         const float* __restrict__ W2,
                         ushort* __restrict__ O0, ushort* __restrict__ O1,
                         ushort* __restrict__ O2, int K1) {
  __shared__ float tile[32][33];
  int z = blockIdx.z;
  const float* in = (z == 0) ? W0 : (z == 1) ? W1 : W2;
  ushort* out = (z == 0) ? O0 : (z == 1) ? O1 : O2;
  int Cc = (z == 2) ? K1 : 128;
  int R = 128;
  int c0 = blockIdx.x * 32, r0 = blockIdx.y * 32;
  if (c0 >= Cc) return;
  int tx = threadIdx.x, ty = threadIdx.y;
  for (int i = 0; i < 32; i += 8) {
    int r = r0 + ty + i, c = c0 + tx;
    if (r < R && c < Cc) tile[ty + i][tx] = in[(size_t)r * Cc + c];
  }
  __syncthreads();
  for (int i = 0; i < 32; i += 8) {
    int oc = c0 + ty + i;
    int orr = r0 + tx;
    if (oc < Cc && orr < R) out[(size_t)oc * R + orr] = f2bf(tile[tx][ty + i]);
  }
}

// ---------------- bf16 MFMA NT GEMM (level-1 feature GEMMs) ----------------
__global__ __launch_bounds__(256) void k_mfma_nt(
    const ushort* __restrict__ A, const ushort* __restrict__ B, float* __restrict__ C,
    ushort* __restrict__ Cb, int I, int J, int K, int kChunk, int atom) {
  __shared__ ushort As[64][40];
  __shared__ ushort Bs[64][40];
  int t = threadIdx.x;
  int w = t >> 6, l = t & 63;
  int i0 = blockIdx.y * 64, j0 = blockIdx.x * 64;
  int k0 = blockIdx.z * kChunk;
  int k1 = min(k0 + kChunk, K);
  f32x4 acc[4] = {};
  int lrow = t >> 2;
  int lk = (t & 3) * 8;
  for (int kk = k0; kk < k1; kk += 32) {
    uint4 av = make_uint4(0u, 0u, 0u, 0u);
    int ar = i0 + lrow;
    if (ar < I) av = *(const uint4*)(A + (size_t)ar * K + kk + lk);
    uint4 bv = *(const uint4*)(B + (size_t)(j0 + lrow) * K + kk + lk);
    *(uint4*)&As[lrow][lk] = av;
    *(uint4*)&Bs[lrow][lk] = bv;
    __syncthreads();
    bf16x8 af = *(const bf16x8*)&As[16 * w + (l & 15)][(l >> 4) * 8];
#pragma unroll
    for (int jt = 0; jt < 4; ++jt) {
      bf16x8 bf = *(const bf16x8*)&Bs[16 * jt + (l & 15)][(l >> 4) * 8];
      acc[jt] = __builtin_amdgcn_mfma_f32_16x16x32_bf16(af, bf, acc[jt], 0, 0, 0);
    }
    __syncthreads();
  }
  int rbase = i0 + 16 * w + ((l >> 4) * 4);
  int cbase = j0 + (l & 15);
#pragma unroll
  for (int jt = 0; jt < 4; ++jt) {
#pragma unroll
    for (int rr = 0; rr < 4; ++rr) {
      int r = rbase + rr;
      if (r < I) {
        size_t idx = (size_t)r * J + jt * 16 + cbase;
        if (Cb) Cb[idx] = f2bf(acc[jt][rr]);
        else if (atom) atomicAdd(&C[idx], acc[jt][rr]);
        else C[idx] = acc[jt][rr];
      }
    }
  }
}

// merged 3-in-1 TN products: apT = St@ATSt^T, sts = St@St^T, xp = St@R2t^T
// (all NT form: C[i,j] = sum_k A[i,k]*B[j,k]); grid.x in [0,10): 4+4+2 output tiles
__global__ __launch_bounds__(256) void k_mfma3(
    const ushort* __restrict__ St, const ushort* __restrict__ ATSt,
    const ushort* __restrict__ R2t,
    float* __restrict__ apT, float* __restrict__ sts, float* __restrict__ xp,
    int K, int kChunk) {
  __shared__ ushort As[64][40];
  __shared__ ushort Bs[64][40];
  int xb_ = blockIdx.x;
  const ushort* B; float* C; int J, j0;
  if (xb_ < 4)      { B = ATSt; C = apT; J = 256; j0 = xb_ * 64; }
  else if (xb_ < 8) { B = St;   C = sts; J = 256; j0 = (xb_ - 4) * 64; }
  else              { B = R2t;  C = xp;  J = 128; j0 = (xb_ - 8) * 64; }
  int t = threadIdx.x;
  int w = t >> 6, l = t & 63;
  int i0 = blockIdx.y * 64;
  int k0 = blockIdx.z * kChunk;
  int k1 = min(k0 + kChunk, K);
  f32x4 acc[4] = {};
  int lrow = t >> 2;
  int lk = (t & 3) * 8;
  for (int kk = k0; kk < k1; kk += 32) {
    uint4 av = *(const uint4*)(St + (size_t)(i0 + lrow) * K + kk + lk);
    uint4 bv = *(const uint4*)(B + (size_t)(j0 + lrow) * K + kk + lk);
    *(uint4*)&As[lrow][lk] = av;
    *(uint4*)&Bs[lrow][lk] = bv;
    __syncthreads();
    bf16x8 af = *(const bf16x8*)&As[16 * w + (l & 15)][(l >> 4) * 8];
#pragma unroll
    for (int jt = 0; jt < 4; ++jt) {
      bf16x8 bf = *(const bf16x8*)&Bs[16 * jt + (l & 15)][(l >> 4) * 8];
      acc[jt] = __builtin_amdgcn_mfma_f32_16x16x32_bf16(af, bf, acc[jt], 0, 0, 0);
    }
    __syncthreads();
  }
  int rbase = i0 + 16 * w + ((l >> 4) * 4);
  int cbase = j0 + (l & 15);
#pragma unroll
  for (int jt = 0; jt < 4; ++jt) {
#pragma unroll
    for (int rr = 0; rr < 4; ++rr) {
      atomicAdd(&C[(size_t)(rbase + rr) * J + jt * 16 + cbase], acc[jt][rr]);
    }
  }
}

// ---------------- fp32 GEMM (small, level-2) ----------------
__global__ __launch_bounds__(256) void k_sgemm_nn(
    const float* __restrict__ A, const float* __restrict__ B, float* __restrict__ C,
    int M, int N, int K) {
  __shared__ float As[16][64];
  __shared__ float Bs[16][68];
  int t = threadIdx.x;
  int tx = t & 15, ty = t >> 4;
  int row0 = blockIdx.y * 64, col0 = blockIdx.x * 64;
  float acc[4][4] = {};
  for (int k0 = 0; k0 < K; k0 += 16) {
    int ar = t >> 2;
    int ak = (t & 3) * 4;
    float4 av = make_float4(0.f, 0.f, 0.f, 0.f);
    if (row0 + ar < M) av = *(const float4*)(A + (size_t)(row0 + ar) * K + k0 + ak);
    As[ak + 0][ar] = av.x; As[ak + 1][ar] = av.y;
    As[ak + 2][ar] = av.z; As[ak + 3][ar] = av.w;
    int bk = t >> 4;
    int bc = (t & 15) * 4;
    float4 bv = *(const float4*)(B + (size_t)(k0 + bk) * N + col0 + bc);
    *(float4*)&Bs[bk][bc] = bv;
    __syncthreads();
#pragma unroll
    for (int k = 0; k < 16; ++k) {
      float a[4], b[4];
#pragma unroll
      for (int u = 0; u < 4; ++u) a[u] = As[k][ty * 4 + u];
#pragma unroll
      for (int v = 0; v < 4; ++v) b[v] = Bs[k][tx * 4 + v];
#pragma unroll
      for (int u = 0; u < 4; ++u)
#pragma unroll
        for (int v = 0; v < 4; ++v) acc[u][v] += a[u] * b[v];
    }
    __syncthreads();
  }
#pragma unroll
  for (int u = 0; u < 4; ++u) {
    int r = row0 + ty * 4 + u;
    if (r < M) {
#pragma unroll
      for (int v = 0; v < 4; ++v) C[(size_t)r * N + col0 + tx * 4 + v] = acc[u][v];
    }
  }
}

// ---------------- BN stats (level-1, two-stage, no atomics) ----------------

__global__ void k_col_stats2(const float* __restrict__ X, const float* __restrict__ bias,
                             float* __restrict__ part, int M, int C, int rpb) {
  int c = threadIdx.x;
  int b = blockIdx.x;
  int r0 = b * rpb, r1 = min(r0 + rpb, M);
  float bi = bias[c];
  float s = 0.f, sq = 0.f;
  for (int r = r0; r < r1; ++r) {
    float v = X[(size_t)r * C + c] + bi;
    s += v; sq += v * v;
  }
  part[(size_t)b * 2 * C + c] = s;
  part[(size_t)b * 2 * C + C + c] = sq;
}

__global__ __launch_bounds__(256) void k_colred_par(
    const float* __restrict__ part, int nblk, int C,
    float* __restrict__ cs, float* __restrict__ csq) {
  __shared__ float sh[256];
  int c = blockIdx.x;
  int t = threadIdx.x;
  float s = 0.f, sq = 0.f;
  for (int b = t; b < nblk; b += 256) {
    s  += part[(size_t)b * 2 * C + c];
    sq += part[(size_t)b * 2 * C + C + c];
  }
  sh[t] = s; __syncthreads();
  for (int o = 128; o > 0; o >>= 1) { if (t < o) sh[t] += sh[t + o]; __syncthreads(); }
  if (t == 0) cs[c] = sh[0];
  __syncthreads();
  sh[t] = sq; __syncthreads();
  for (int o = 128; o > 0; o >>= 1) { if (t < o) sh[t] += sh[t + o]; __syncthreads(); }
  if (t == 0) csq[c] = sh[0];
}

__global__ void k_bn_silu(const float* __restrict__ X, const float* __restrict__ bias,
                          const float* __restrict__ cs, const float* __restrict__ csq,
                          const float* __restrict__ g, const float* __restrict__ be,
                          const float* __restrict__ resid, float* __restrict__ out,
                          ushort* __restrict__ outb,
                          int tot, int cmask, float invM) {
  int i = blockIdx.x * blockDim.x + threadIdx.x;
  if (i >= tot) return;
  int c = i & cmask;
  float m = cs[c] * invM;
  float var = csq[c] * invM - m * m;
  float v = (X[i] + bias[c] - m) * rsqrtf(var + EPS_BN) * g[c] + be[c];
  float y = v / (1.f + expf(-v));
  if (resid) y += resid[i];
  out[i] = y;
  if (outb) outb[i] = f2bf(y);
}

// ---------------- fused small BN (level-2, M<=256) ----------------
__global__ __launch_bounds__(256) void k_bn_small(
    const float* __restrict__ X, const float* __restrict__ bias,
    const float* __restrict__ g, const float* __restrict__ be,
    const float* __restrict__ resid, float* __restrict__ out,
    int M, int C, float invM) {
  __shared__ float sh[256];
  int c = blockIdx.x;
  int t = threadIdx.x;
  bool act = t < M;
  float v = 0.f;
  if (act) v = X[(size_t)t * C + c] + bias[c];
  sh[t] = v; __syncthreads();
  for (int o = 128; o > 0; o >>= 1) { if (t < o) sh[t] += sh[t + o]; __syncthreads(); }
  float m = sh[0] * invM; __syncthreads();
  sh[t] = v * v; __syncthreads();
  for (int o = 128; o > 0; o >>= 1) { if (t < o) sh[t] += sh[t + o]; __syncthreads(); }
  float var = sh[0] * invM - m * m;
  if (act) {
    float y = (v - m) * rsqrtf(var + EPS_BN) * g[c] + be[c];
    y = y / (1.f + expf(-y));
    if (resid) y += resid[(size_t)t * C + c];
    out[(size_t)t * C + c] = y;
  }
}

// ---------------- softmax + entropy (block partials) ----------------
template <int C>
__global__ void k_softmax_ent3(float* __restrict__ X, ushort* __restrict__ outb,
                               float* __restrict__ part, int nrows, int writeX) {
  constexpr int VPT = C / 64;
  __shared__ float went[4];
  int gt = blockIdx.x * blockDim.x + threadIdx.x;
  int row = gt >> 6;
  int l = gt & 63;
  int wid = threadIdx.x >> 6;
  bool active = row < nrows;
  size_t base = active ? (size_t)row * C : 0;
  float d[VPT];
  if (VPT == 4) {
    float4 v = *(const float4*)(X + base + l * 4);
    d[0] = v.x; d[1] = v.y; d[2] = v.z; d[3] = v.w;
  } else {
    d[0] = X[base + l];
  }
  float mx = d[0];
#pragma unroll
  for (int i = 1; i < VPT; ++i) mx = fmaxf(mx, d[i]);
  for (int o = 32; o > 0; o >>= 1) mx = fmaxf(mx, __shfl_xor(mx, o));
  float se = 0.f;
  float e[VPT];
#pragma unroll
  for (int i = 0; i < VPT; ++i) { d[i] -= mx; e[i] = expf(d[i]); se += e[i]; }
  for (int o = 32; o > 0; o >>= 1) se += __shfl_xor(se, o);
  float inv = 1.f / se;
  float pd = 0.f;
#pragma unroll
  for (int i = 0; i < VPT; ++i) { e[i] *= inv; pd += e[i] * d[i]; }
  if (active) {
    if (VPT == 4) {
      if (writeX) {
        float4 v; v.x = e[0]; v.y = e[1]; v.z = e[2]; v.w = e[3];
        *(float4*)(X + base + l * 4) = v;
      }
      if (outb) {
        ushort4 u; u.x = f2bf(e[0]); u.y = f2bf(e[1]); u.z = f2bf(e[2]); u.w = f2bf(e[3]);
        *(ushort4*)(outb + base + l * 4) = u;
      }
    } else {
      if (writeX) X[base + l] = e[0];
      if (outb) outb[base + l] = f2bf(e[0]);
    }
  }
  for (int o = 32; o > 0; o >>= 1) pd += __shfl_xor(pd, o);
  if (l == 0) went[wid] = active ? (logf(se) - pd) : 0.f;
  __syncthreads();
  if (threadIdx.x == 0) part[blockIdx.x] = went[0] + went[1] + went[2] + went[3];
}

__global__ __launch_bounds__(256) void k_reduce_atom(
    const float* __restrict__ in, int n, float* __restrict__ out) {
  __shared__ float sh[256];
  int t = threadIdx.x;
  int per = (n + gridDim.x - 1) / gridDim.x;
  int i0 = blockIdx.x * per, i1 = min(i0 + per, n);
  float s = 0.f;
  for (int i = i0 + t; i < i1; i += 256) s += in[i];
  sh[t] = s; __syncthreads();
  for (int o = 128; o > 0; o >>= 1) { if (t < o) sh[t] += sh[t + o]; __syncthreads(); }
  if (t == 0) atomicAdd(out, sh[0]);
}

// grid = 1 + 2Z: b0 trace(P0); b 1..Z sumsq(P1) chunks; b Z+1..2Z sumsq(P0) chunks
__global__ __launch_bounds__(256) void k_scalN_par(
    const float* __restrict__ P0, const float* __restrict__ P1, int K,
    float* __restrict__ outb, int Z) {
  __shared__ float sh[256];
  int b = blockIdx.x, t = threadIdx.x;
  float s = 0.f;
  int slot;
  if (b == 0) {
    slot = 0;
    for (int i = t; i < K; i += 256) s += P0[(size_t)i * K + i];
  } else {
    int which = (b - 1) / Z;
    int chunk = (b - 1) % Z;
    slot = 1 + which;
    const float4* P4 = (const float4*)(which ? P0 : P1);
    int n4 = (K * K) >> 2;
    int per = (n4 + Z - 1) / Z;
    int i0 = chunk * per, i1 = min(i0 + per, n4);
    for (int i = i0 + t; i < i1; i += 256) {
      float4 v = P4[i];
      s += v.x * v.x + v.y * v.y + v.z * v.z + v.w * v.w;
    }
  }
  sh[t] = s; __syncthreads();
  for (int o = 128; o > 0; o >>= 1) { if (t < o) sh[t] += sh[t + o]; __syncthreads(); }
  if (t == 0) atomicAdd(&outb[slot], sh[0]);
}

// grid = Z + 1: b<Z dot(U,V) chunks; b==Z sumsq(P)
__global__ __launch_bounds__(256) void k_scal2_par(
    const float* __restrict__ U, const float* __restrict__ V, int n,
    const float* __restrict__ P, int nP, float* __restrict__ outb, int Z) {
  __shared__ float sh[256];
  int b = blockIdx.x, t = threadIdx.x;
  float s = 0.f;
  int slot;
  if (b < Z) {
    slot = 0;
    const float4* U4 = (const float4*)U;
    const float4* V4 = (const float4*)V;
    int n4 = n >> 2;
    int per = (n4 + Z - 1) / Z;
    int i0 = b * per, i1 = min(i0 + per, n4);
    for (int i = i0 + t; i < i1; i += 256) {
      float4 u = U4[i], v = V4[i];
      s += u.x * v.x + u.y * v.y + u.z * v.z + u.w * v.w;
    }
  } else {
    slot = 1;
    const float4* P4 = (const float4*)P;
    int n4 = nP >> 2;
    for (int i = t; i < n4; i += 256) {
      float4 v = P4[i];
      s += v.x * v.x + v.y * v.y + v.z * v.z + v.w * v.w;
    }
  }
  sh[t] = s; __syncthreads();
  for (int o = 128; o > 0; o >>= 1) { if (t < o) sh[t] += sh[t + o]; __syncthreads(); }
  if (t == 0) atomicAdd(&outb[slot], sh[0]);
}

// ---------------- level-2 dense graph (A2T = apool^T layout) ----------------

__global__ __launch_bounds__(256) void k_deg2_par(
    const float* __restrict__ A2T, float* __restrict__ dinv2, int Np) {
  __shared__ float sh[256];
  int q = blockIdx.x;
  int t = threadIdx.x;
  float s = (t == 0) ? 1.0f : 0.f;
  for (int p = t; p < Np; p += 256) s += A2T[(size_t)q * Np + p];
  sh[t] = s; __syncthreads();
  for (int o = 128; o > 0; o >>= 1) { if (t < o) sh[t] += sh[t + o]; __syncthreads(); }
  if (t == 0) {
    float d = sh[0];
    dinv2[q] = d > 0.f ? rsqrtf(fmaxf(d, 1e-12f)) : 0.f;
  }
}

__global__ void k_dense_agg(const float* __restrict__ A2T, const float* __restrict__ dinv2,
                            const float* __restrict__ H, float* __restrict__ out,
                            int Np, int C) {
  int q = blockIdx.x, c = threadIdx.x;
  float acc = 0.f;
#pragma unroll 8
  for (int p = 0; p < Np; ++p)
    acc += dinv2[p] * A2T[(size_t)q * Np + p] * H[(size_t)p * C + c];
  float dq = dinv2[q];
  out[(size_t)q * C + c] = dq * acc + dq * dq * H[(size_t)q * C + c];
}

// ---------------- fused tail TN products (level 2), LDS-staged ----------------
__global__ __launch_bounds__(256) void k_tn3(
    const float* __restrict__ S, const float* __restrict__ B2,
    float* __restrict__ sts2, float* __restrict__ xp2, int M) {
  __shared__ float As[64][65];
  __shared__ float Bs[64][65];
  int z = blockIdx.x;
  const float* B; float* C; int J, j0;
  if (z == 0) { B = S;  C = sts2; J = 64;  j0 = 0; }
  else        { B = B2; C = xp2;  J = 128; j0 = (z - 1) * 64; }
  int t = threadIdx.x;
  int tj = t & 63, ti = t >> 6;
  float acc[16] = {};
  for (int m0 = 0; m0 < M; m0 += 64) {
#pragma unroll
    for (int r = 0; r < 16; ++r) {
      As[ti * 16 + r][tj] = S[(size_t)(m0 + ti * 16 + r) * 64 + tj];
      Bs[ti * 16 + r][tj] = B[(size_t)(m0 + ti * 16 + r) * J + j0 + tj];
    }
    __syncthreads();
#pragma unroll 4
    for (int mm = 0; mm < 64; ++mm) {
      float bv = Bs[mm][tj];
#pragma unroll
      for (int ii = 0; ii < 16; ++ii) acc[ii] += As[mm][ti * 16 + ii] * bv;
    }
    __syncthreads();
  }
  for (int ii = 0; ii < 16; ++ii) C[(size_t)(ti * 16 + ii) * J + j0 + tj] = acc[ii];
}

// ---------------- final head ----------------
__global__ void k_final(const float* __restrict__ xp2, const float* __restrict__ Wlin,
                        const float* __restrict__ blin, const float* __restrict__ scal,
                        float* __restrict__ out, int N1, int E1, int K1, int K2, int OUT) {
  __shared__ float pooled[128];
  __shared__ float logits[32];
  int t = threadIdx.x;
  float s = 0.f;
  for (int r = 0; r < K2; ++r) s += xp2[(size_t)r * 128 + t];
  pooled[t] = s / (float)K2;
  __syncthreads();
  if (t < OUT) {
    float acc = blin[t];
    for (int k = 0; k < 128; ++k) acc += pooled[k] * Wlin[(size_t)k * OUT + t];
    logits[t] = acc;
  }
  __syncthreads();
  if (t == 0) {
    float mx = logits[0];
    for (int j = 1; j < OUT; ++j) mx = fmaxf(mx, logits[j]);
    float se = 0.f;
    for (int j = 0; j < OUT; ++j) se += expf(logits[j] - mx);
    float lse = mx + logf(se);
    for (int j = 0; j < OUT; ++j) out[j] = logits[j] - lse;
    float n1 = (float)N1;
    float ent1 = scal[0] / n1;
    float ent2 = scal[1] / (float)K1;
    float link1 = sqrtf(fmaxf((float)E1 - 2.f * scal[2] + scal[3], 0.f)) / (n1 * n1);
    float link2 = sqrtf(fmaxf(scal[4] - 2.f * scal[5] + scal[6], 0.f)) / ((float)K1 * (float)K1);
    out[OUT] = ent1 + ent2 + link1 + link2;
  }
}

// ---------------- host ----------------

extern "C" void kernel_launch(void* const* d_in, const int* in_sizes, int n_in,
                              void* d_out, int out_size, void* d_ws, size_t ws_size,
                              hipStream_t stream) {
  (void)n_in; (void)out_size; (void)ws_size;
  const float* x = (const float*)d_in[0];
  const int* ei  = (const int*)d_in[1];
  const int N = in_sizes[0] / 128;   // 20000
  const int E = in_sizes[1] / 2;     // 640000
  const int* src = ei;
  const int* dst = ei + E;
  const float *W1a=(const float*)d_in[4],  *b1a=(const float*)d_in[5],
              *g1a=(const float*)d_in[6],  *be1a=(const float*)d_in[7];
  const float *W1b=(const float*)d_in[8],  *b1b=(const float*)d_in[9],
              *g1b=(const float*)d_in[10], *be1b=(const float*)d_in[11];
  const float *Wp1=(const float*)d_in[12], *bp1=(const float*)d_in[13],
              *gp1=(const float*)d_in[14], *bep1=(const float*)d_in[15];
  const float *W2a=(const float*)d_in[16], *b2a=(const float*)d_in[17],
              *g2a=(const float*)d_in[18], *be2a=(const float*)d_in[19];
  const float *W2b=(const float*)d_in[20], *b2b=(const float*)d_in[21],
              *g2b=(const float*)d_in[22], *be2b=(const float*)d_in[23];
  const float *Wp2=(const float*)d_in[24], *bp2=(const float*)d_in[25],
              *gp2=(const float*)d_in[26], *bep2=(const float*)d_in[27];
  const float *Wlin=(const float*)d_in[28], *blin=(const float*)d_in[29];
  const int K1 = in_sizes[12] / 128;   // 256
  const int K2 = in_sizes[24] / 128;   // 64
  const int OUT = in_sizes[29];        // 10

  char* base = (char*)d_ws;
  size_t off = 0;
  auto allocb = [&](size_t bytes) -> void* {
    void* p = (void*)(base + off);
    off += ((bytes + 255) & ~(size_t)255);
    return p;
  };
  auto alloc = [&](size_t nf) -> float* { return (float*)allocb(nf * 4); };
  auto alloci = [&](size_t ni) -> int* { return (int*)allocb(ni * 4); };
  auto allocu = [&](size_t nu) -> ushort* { return (ushort*)allocb(nu * 2); };

  auto cdiv = [](long long a, long long b) { return (int)((a + b - 1) / b); };

  const int RPB = 16;
  const int NBLK1 = cdiv(N, RPB);

  float* scal  = alloc(16);
  float* cs    = alloc(256);
  float* csq   = alloc(256);
  float* dinv  = alloc(N);
  float* dinv2 = alloc(K1);
  float* apT   = alloc((size_t)K1 * K1);   // contiguous with sts, xp (sizes 256B-mult)
  float* sts   = alloc((size_t)K1 * K1);
  float* xp    = alloc((size_t)K1 * 128);
  float* h2    = alloc((size_t)K1 * 128);
  float* y2    = alloc((size_t)K1 * 128);
  float* xa2   = alloc((size_t)K1 * 128);
  float* x2f   = alloc((size_t)K1 * 128);
  float* s2b   = alloc((size_t)K1 * K2);
  float* U     = alloc((size_t)K1 * K2);
  float* sts2  = alloc((size_t)K2 * K2);
  float* xp2   = alloc((size_t)K2 * 128);
  float* ent1p = alloc(cdiv(N, 4) + 8);
  float* ent2p = alloc(64 + 8);
  float* csp   = alloc((size_t)(NBLK1 + 2) * 512);
  float* R1 = alloc((size_t)N * 128);   // fp32; later St bf16 [K1,N]
  float* R2 = alloc((size_t)N * 128);   // fp32; later ATSt bf16 [K1,N]
  float* R3 = alloc((size_t)N * K1);    // Hb/aggB bf16 / Sb bf16 [N,K1]
  float* R4 = alloc((size_t)N * K1);    // agg out fp32 / ATSb bf16 [N,K1]
  ushort* B16A = allocu((size_t)N * 128);  // xb -> R1b -> R2b -> R2t
  ushort* W1at = allocu(128 * 128);
  ushort* W1bt = allocu(128 * 128);
  ushort* Wp1t = allocu((size_t)K1 * 128);
  // CSR (dst only)
  int* cnt_d = alloci(N);
  int* rp_d  = alloci(N + 1);
  int* cur_d = alloci(N);
  int* col_s = alloci(E);

  ushort* Hb   = (ushort*)R3;  // [N, C] bf16 GEMM output for gather (blocks a,b)
  ushort* aggB = (ushort*)R3;  // [N, 128] bf16 aggregated input (pooling block)
  ushort* Sb   = (ushort*)R3;  // [N, K1] bf16 row-major S
  ushort* ATSb = (ushort*)R4;  // [N, K1] bf16 row-major A^T S
  ushort* St   = (ushort*)R1;  // [K1, N] bf16
  ushort* ATSt = (ushort*)R2;  // [K1, N] bf16 (A^T S)^T
  ushort* R2t  = B16A;         // [128, N] bf16

  hipMemsetAsync(scal, 0, 16 * sizeof(float), stream);

  // ---- prologue: histogram + x->bf16 in one launch; scan(+dinv); fill ----
  hipMemsetAsync(cnt_d, 0, (size_t)N * sizeof(int), stream);
  {
    int HB = cdiv(E, 256);
    int CB = cdiv((size_t)N * 128 / 4, 256);
    k_pre<<<HB + CB, 256, 0, stream>>>(dst, cnt_d, E, x, B16A, N * 128 / 4, HB);
  }
  k_scan<<<1, 1024, 0, stream>>>(cnt_d, rp_d, cur_d, dinv, N, E);
  k_fill_csr<<<cdiv(E, 256), 256, 0, stream>>>(dst, src, cur_d, col_s, E);

  // ---- weight transposes (one launch) ----
  {
    dim3 b32(32, 8);
    k_tconv3<<<dim3(8, 4, 3), b32, 0, stream>>>(W1a, W1b, Wp1, W1at, W1bt, Wp1t, K1);
  }

  auto mfma_nt = [&](const ushort* A, const ushort* B, float* C, ushort* Cb,
                     int I, int J, int K) {
    dim3 g(J / 64, cdiv(I, 64), 1);
    k_mfma_nt<<<g, 256, 0, stream>>>(A, B, C, Cb, I, J, K, K, 0);
  };
  auto gemm_nn = [&](const float* A, const float* B, float* C, int M, int Nn, int K) {
    dim3 g(Nn / 64, cdiv(M, 64));
    k_sgemm_nn<<<g, 256, 0, stream>>>(A, B, C, M, Nn, K);
  };

  // level-1 blocks a,b: GEMM -> gather -> BN/SiLU
  auto block1 = [&](const ushort* xin_b, const ushort* Wt, const float* b, const float* gg,
                    const float* be, const float* resid, float* outp, ushort* outb, int C) {
    mfma_nt(xin_b, Wt, nullptr, Hb, N, C, 128);
    k_gather_agg_b2<<<N, C / 2, 0, stream>>>(rp_d, col_s, dinv, Hb, R4, C / 2);
    k_col_stats2<<<NBLK1, C, 0, stream>>>(R4, b, csp, N, C, RPB);
    k_colred_par<<<C, 256, 0, stream>>>(csp, NBLK1, C, cs, csq);
    int tot = N * C;
    k_bn_silu<<<cdiv(tot, 256), 256, 0, stream>>>(R4, b, cs, csq, gg, be, resid, outp,
                                                  outb, tot, C - 1, 1.f / N);
  };

  block1(B16A, W1at, b1a, g1a, be1a, nullptr, R1, B16A, 128);  // R1 + R1b
  block1(B16A, W1bt, b1b, g1b, be1b, R1,      R2, B16A, 128);  // R2 + R2b

  // pooling block: agg = A_hat * R2 in input space (128 ch), then GEMM agg@Wp1
  k_gather_agg_b2b<<<N, 64, 0, stream>>>(rp_d, col_s, dinv, B16A, aggB, 64);
  mfma_nt(aggB, Wp1t, R4, nullptr, N, K1, 128);
  k_col_stats2<<<NBLK1, K1, 0, stream>>>(R4, bp1, csp, N, K1, RPB);
  k_colred_par<<<K1, 256, 0, stream>>>(csp, NBLK1, K1, cs, csq);
  k_bn_silu<<<cdiv(N * K1, 256), 256, 0, stream>>>(R4, bp1, cs, csq, gp1, bep1, nullptr,
                                                   R4, nullptr, N * K1, K1 - 1, 1.f / N);
  // S = softmax: bf16 only (Sb), entropy partials
  k_softmax_ent3<256><<<cdiv(N, 4), 256, 0, stream>>>(R4, Sb, ent1p, N, 0);
  k_reduce_atom<<<8, 256, 0, stream>>>(ent1p, cdiv(N, 4), &scal[0]);

  {
    dim3 b32(32, 8);
    k_tconv_b<<<dim3(K1 / 32, cdiv(N, 32)), b32, 0, stream>>>(Sb, St, N, K1);   // St = S^T
    k_tconv<<<dim3(128 / 32, cdiv(N, 32)), b32, 0, stream>>>(R2, R2t, N, 128);  // R2t = x^T
  }
  // A^T S via dst-CSR gather, bf16 out -> ATSb (over R4; fp32 feats dead)
  k_gather_T_b2b<<<N, K1 / 2, 0, stream>>>(rp_d, col_s, Sb, ATSb, K1 / 2);
  {
    dim3 b32(32, 8);
    k_tconv_b<<<dim3(K1 / 32, cdiv(N, 32)), b32, 0, stream>>>(ATSb, ATSt, N, K1);
  }

  // merged TN products: apT | sts | xp in one launch (atomic accumulate; one memset)
  {
    hipMemsetAsync(apT, 0, (size_t)(2 * K1 * K1 + K1 * 128) * sizeof(float), stream);
    int chunk = ((cdiv(N, 16) + 31) & ~31);
    int z = cdiv(N, chunk);
    k_mfma3<<<dim3(10, 4, z), 256, 0, stream>>>(St, ATSt, R2t, apT, sts, xp, N, chunk);
  }
  k_scalN_par<<<1 + 2 * 16, 256, 0, stream>>>(apT, sts, K1, &scal[2], 16);

  // ---------------- level 2 (dense 256-node graph, A2T layout) ----------------
  k_deg2_par<<<K1, 256, 0, stream>>>(apT, dinv2, K1);

  auto block2 = [&](const float* xin, const float* W, const float* b, const float* gg,
                    const float* be, const float* resid, float* outp, int C) {
    gemm_nn(xin, W, h2, K1, C, 128);
    k_dense_agg<<<K1, C, 0, stream>>>(apT, dinv2, h2, y2, K1, C);
    k_bn_small<<<C, 256, 0, stream>>>(y2, b, gg, be, resid, outp, K1, C, 1.f / K1);
  };

  block2(xp,  W2a, b2a, g2a, be2a, nullptr, xa2, 128);
  block2(xa2, W2b, b2b, g2b, be2b, xa2,     x2f, 128);
  block2(x2f, Wp2, bp2, gp2, bep2, nullptr, s2b, K2);
  k_softmax_ent3<64><<<cdiv(K1, 4), 256, 0, stream>>>(s2b, nullptr, ent2p, K1, 1);
  k_reduce_atom<<<2, 256, 0, stream>>>(ent2p, cdiv(K1, 4), &scal[1]);

  // cross2 = dot(U, s2) with U = A2T @ s2;  sumsq(sts2)
  gemm_nn(apT, s2b, U, K1, K2, K1);
  k_tn3<<<3, 256, 0, stream>>>(s2b, x2f, sts2, xp2, K1);
  k_scal2_par<<<8 + 1, 256, 0, stream>>>(U, s2b, K1 * K2, sts2, K2 * K2, &scal[5], 8);

  k_final<<<1, 128, 0, stream>>>(xp2, Wlin, blin, scal, (float*)d_out, N, E, K1, K2, OUT);
}

// Round 11
// 519.731 us; speedup vs baseline: 5.5358x; 1.0481x over previous
//
#include <hip/hip_runtime.h>

#define EPS_BN 1e-5f
typedef unsigned int uint;
typedef unsigned short ushort;
typedef __attribute__((ext_vector_type(8))) short bf16x8;
typedef __attribute__((ext_vector_type(4))) float f32x4;

__device__ inline ushort f2bf(float f) {
  uint u = __float_as_uint(f);
  uint r = (u + 0x7FFFu + ((u >> 16) & 1u)) >> 16;
  return (ushort)r;
}
__device__ inline float bflo(uint h) { return __uint_as_float(h << 16); }
__device__ inline float bfhi(uint h) { return __uint_as_float(h & 0xFFFF0000u); }

// ---------------- fused prologue: dst-histogram + x -> bf16 ----------------

__global__ void k_pre(const int* __restrict__ dst, int* __restrict__ cnt, int E,
                      const float* __restrict__ x, ushort* __restrict__ xb, int n4, int HB) {
  int b = blockIdx.x;
  if (b < HB) {
    int e = b * 256 + threadIdx.x;
    if (e < E) atomicAdd(&cnt[dst[e]], 1);
  } else {
    int i = (b - HB) * 256 + threadIdx.x;
    if (i < n4) {
      float4 v = ((const float4*)x)[i];
      ushort4 o;
      o.x = f2bf(v.x); o.y = f2bf(v.y); o.z = f2bf(v.z); o.w = f2bf(v.w);
      ((ushort4*)xb)[i] = o;
    }
  }
}

// ---------------- parallel chained scan: cnt -> rowptr/cursor/dinv ----------------
// 1024 elements per block; chained inter-block prefix via flags/partials (zeroed).
__global__ __launch_bounds__(256) void k_scan_par(
    const int* __restrict__ cnt, int* __restrict__ rowptr, int* __restrict__ cursor,
    float* __restrict__ dinv, int* __restrict__ flags, int* __restrict__ partials,
    int N, int E) {
  __shared__ int wsum[4];
  __shared__ int sbase;
  int tile = blockIdx.x;
  int t = threadIdx.x;
  int lane = t & 63, w = t >> 6;
  int i0 = tile * 1024 + t * 4;
  int c[4];
#pragma unroll
  for (int j = 0; j < 4; ++j) {
    int i = i0 + j;
    c[j] = (i < N) ? cnt[i] : 0;
  }
  int p1 = c[0], p2 = p1 + c[1], p3 = p2 + c[2];
  int tsum = p3 + c[3];
  int incl = tsum;
  for (int o = 1; o < 64; o <<= 1) {
    int v = __shfl_up(incl, o);
    if (lane >= o) incl += v;
  }
  int excl = incl - tsum;
  if (lane == 63) wsum[w] = incl;
  __syncthreads();
  if (t == 0) {
    int tot = wsum[0] + wsum[1] + wsum[2] + wsum[3];
    int basev = 0;
    if (tile > 0) {
      while (atomicAdd(&flags[tile - 1], 0) == 0) {}
      basev = atomicAdd(&partials[tile - 1], 0);
    }
    atomicExch(&partials[tile], basev + tot);
    __threadfence();
    atomicExch(&flags[tile], 1);
    sbase = basev;
  }
  __syncthreads();
  int base = sbase;
  for (int ww = 0; ww < w; ++ww) base += wsum[ww];
  base += excl;
  int pre[4] = {0, p1, p2, p3};
#pragma unroll
  for (int j = 0; j < 4; ++j) {
    int i = i0 + j;
    if (i < N) {
      int run = base + pre[j];
      rowptr[i] = run; cursor[i] = run;
      dinv[i] = rsqrtf(1.0f + (float)c[j]);
    }
  }
  if (tile == 0 && t == 0) rowptr[N] = E;
}

__global__ void k_fill_csr(const int* __restrict__ key, const int* __restrict__ val,
                           int* __restrict__ cursor, int* __restrict__ col, int E) {
  int e = blockIdx.x * blockDim.x + threadIdx.x;
  if (e < E) {
    int pos = atomicAdd(&cursor[key[e]], 1);
    col[pos] = val[e];
  }
}

// ---------------- gather aggregation, bf16 input, 2 ch/thread ----------------

__global__ void k_gather_agg_b2(const int* __restrict__ rowptr, const int* __restrict__ col,
                                const float* __restrict__ dinv, const ushort* __restrict__ H,
                                float* __restrict__ out, int C2) {
  int d = blockIdx.x;
  int c2 = threadIdx.x;
  const uint* H2 = (const uint*)H;
  int b = rowptr[d], e = rowptr[d + 1];
  float a0 = 0.f, a1 = 0.f;
#pragma unroll 4
  for (int i = b; i < e; ++i) {
    int s = col[i];
    float dv = dinv[s];
    uint h = H2[(size_t)s * C2 + c2];
    a0 += dv * bflo(h);
    a1 += dv * bfhi(h);
  }
  float dd = dinv[d];
  uint hd = H2[(size_t)d * C2 + c2];
  float2 o;
  o.x = dd * a0 + dd * dd * bflo(hd);
  o.y = dd * a1 + dd * dd * bfhi(hd);
  *(float2*)(out + (size_t)d * (C2 * 2) + c2 * 2) = o;
}

__global__ void k_gather_agg_b2b(const int* __restrict__ rowptr, const int* __restrict__ col,
                                 const float* __restrict__ dinv, const ushort* __restrict__ H,
                                 ushort* __restrict__ out, int C2) {
  int d = blockIdx.x;
  int c2 = threadIdx.x;
  const uint* H2 = (const uint*)H;
  int b = rowptr[d], e = rowptr[d + 1];
  float a0 = 0.f, a1 = 0.f;
#pragma unroll 4
  for (int i = b; i < e; ++i) {
    int s = col[i];
    float dv = dinv[s];
    uint h = H2[(size_t)s * C2 + c2];
    a0 += dv * bflo(h);
    a1 += dv * bfhi(h);
  }
  float dd = dinv[d];
  uint hd = H2[(size_t)d * C2 + c2];
  ushort2 o;
  o.x = f2bf(dd * a0 + dd * dd * bflo(hd));
  o.y = f2bf(dd * a1 + dd * dd * bfhi(hd));
  *(ushort2*)(out + (size_t)d * (C2 * 2) + c2 * 2) = o;
}

// T[d] = sum_{e: dst=d} S[src_e]  (= A^T S with dst-CSR), bf16 out
__global__ void k_gather_T_b2b(const int* __restrict__ rowptr, const int* __restrict__ col,
                               const ushort* __restrict__ S, ushort* __restrict__ T, int C2) {
  int s = blockIdx.x;
  int c2 = threadIdx.x;
  const uint* S2 = (const uint*)S;
  int b = rowptr[s], e = rowptr[s + 1];
  float a0 = 0.f, a1 = 0.f;
#pragma unroll 4
  for (int i = b; i < e; ++i) {
    int d = col[i];
    uint h = S2[(size_t)d * C2 + c2];
    a0 += bflo(h);
    a1 += bfhi(h);
  }
  ushort2 o; o.x = f2bf(a0); o.y = f2bf(a1);
  *(ushort2*)(T + (size_t)s * (C2 * 2) + c2 * 2) = o;
}

// ---------------- transposes ----------------

__global__ void k_tconv(const float* __restrict__ in, ushort* __restrict__ out,
                        int R, int Cc) {
  __shared__ float tile[32][33];
  int c0 = blockIdx.x * 32, r0 = blockIdx.y * 32;
  int tx = threadIdx.x, ty = threadIdx.y;
  for (int i = 0; i < 32; i += 8) {
    int r = r0 + ty + i, c = c0 + tx;
    if (r < R && c < Cc) tile[ty + i][tx] = in[(size_t)r * Cc + c];
  }
  __syncthreads();
  for (int i = 0; i < 32; i += 8) {
    int oc = c0 + ty + i;
    int orr = r0 + tx;
    if (oc < Cc && orr < R) out[(size_t)oc * R + orr] = f2bf(tile[tx][ty + i]);
  }
}

__global__ void k_tconv_b(const ushort* __restrict__ in, ushort* __restrict__ out,
                          int R, int Cc) {
  __shared__ ushort tile[32][33];
  int c0 = blockIdx.x * 32, r0 = blockIdx.y * 32;
  int tx = threadIdx.x, ty = threadIdx.y;
  for (int i = 0; i < 32; i += 8) {
    int r = r0 + ty + i, c = c0 + tx;
    if (r < R && c < Cc) tile[ty + i][tx] = in[(size_t)r * Cc + c];
  }
  __syncthreads();
  for (int i = 0; i < 32; i += 8) {
    int oc = c0 + ty + i;
    int orr = r0 + tx;
    if (oc < Cc && orr < R) out[(size_t)oc * R + orr] = tile[tx][ty + i];
  }
}

__global__ void k_tconv3(const float* __restrict__ W0, const float* __restrict__ W1,
                         const float* __restrict__ W2,
                         ushort* __restrict__ O0, ushort* __restrict__ O1,
                         ushort* __restrict__ O2, int K1) {
  __shared__ float tile[32][33];
  int z = blockIdx.z;
  const float* in = (z == 0) ? W0 : (z == 1) ? W1 : W2;
  ushort* out = (z == 0) ? O0 : (z == 1) ? O1 : O2;
  int Cc = (z == 2) ? K1 : 128;
  int R = 128;
  int c0 = blockIdx.x * 32, r0 = blockIdx.y * 32;
  if (c0 >= Cc) return;
  int tx = threadIdx.x, ty = threadIdx.y;
  for (int i = 0; i < 32; i += 8) {
    int r = r0 + ty + i, c = c0 + tx;
    if (r < R && c < Cc) tile[ty + i][tx] = in[(size_t)r * Cc + c];
  }
  __syncthreads();
  for (int i = 0; i < 32; i += 8) {
    int oc = c0 + ty + i;
    int orr = r0 + tx;
    if (oc < Cc && orr < R) out[(size_t)oc * R + orr] = f2bf(tile[tx][ty + i]);
  }
}

// ---------------- bf16 MFMA NT GEMM (level-1 feature GEMMs) ----------------
__global__ __launch_bounds__(256) void k_mfma_nt(
    const ushort* __restrict__ A, const ushort* __restrict__ B, float* __restrict__ C,
    ushort* __restrict__ Cb, int I, int J, int K, int kChunk, int atom) {
  __shared__ ushort As[64][40];
  __shared__ ushort Bs[64][40];
  int t = threadIdx.x;
  int w = t >> 6, l = t & 63;
  int i0 = blockIdx.y * 64, j0 = blockIdx.x * 64;
  int k0 = blockIdx.z * kChunk;
  int k1 = min(k0 + kChunk, K);
  f32x4 acc[4] = {};
  int lrow = t >> 2;
  int lk = (t & 3) * 8;
  for (int kk = k0; kk < k1; kk += 32) {
    uint4 av = make_uint4(0u, 0u, 0u, 0u);
    int ar = i0 + lrow;
    if (ar < I) av = *(const uint4*)(A + (size_t)ar * K + kk + lk);
    uint4 bv = *(const uint4*)(B + (size_t)(j0 + lrow) * K + kk + lk);
    *(uint4*)&As[lrow][lk] = av;
    *(uint4*)&Bs[lrow][lk] = bv;
    __syncthreads();
    bf16x8 af = *(const bf16x8*)&As[16 * w + (l & 15)][(l >> 4) * 8];
#pragma unroll
    for (int jt = 0; jt < 4; ++jt) {
      bf16x8 bf = *(const bf16x8*)&Bs[16 * jt + (l & 15)][(l >> 4) * 8];
      acc[jt] = __builtin_amdgcn_mfma_f32_16x16x32_bf16(af, bf, acc[jt], 0, 0, 0);
    }
    __syncthreads();
  }
  int rbase = i0 + 16 * w + ((l >> 4) * 4);
  int cbase = j0 + (l & 15);
#pragma unroll
  for (int jt = 0; jt < 4; ++jt) {
#pragma unroll
    for (int rr = 0; rr < 4; ++rr) {
      int r = rbase + rr;
      if (r < I) {
        size_t idx = (size_t)r * J + jt * 16 + cbase;
        if (Cb) Cb[idx] = f2bf(acc[jt][rr]);
        else if (atom) atomicAdd(&C[idx], acc[jt][rr]);
        else C[idx] = acc[jt][rr];
      }
    }
  }
}

// merged 3-in-1 TN products: apT = St@ATSt^T, sts = St@St^T, xp = St@R2t^T
__global__ __launch_bounds__(256) void k_mfma3(
    const ushort* __restrict__ St, const ushort* __restrict__ ATSt,
    const ushort* __restrict__ R2t,
    float* __restrict__ apT, float* __restrict__ sts, float* __restrict__ xp,
    int K, int kChunk) {
  __shared__ ushort As[64][40];
  __shared__ ushort Bs[64][40];
  int xb_ = blockIdx.x;
  const ushort* B; float* C; int J, j0;
  if (xb_ < 4)      { B = ATSt; C = apT; J = 256; j0 = xb_ * 64; }
  else if (xb_ < 8) { B = St;   C = sts; J = 256; j0 = (xb_ - 4) * 64; }
  else              { B = R2t;  C = xp;  J = 128; j0 = (xb_ - 8) * 64; }
  int t = threadIdx.x;
  int w = t >> 6, l = t & 63;
  int i0 = blockIdx.y * 64;
  int k0 = blockIdx.z * kChunk;
  int k1 = min(k0 + kChunk, K);
  f32x4 acc[4] = {};
  int lrow = t >> 2;
  int lk = (t & 3) * 8;
  for (int kk = k0; kk < k1; kk += 32) {
    uint4 av = *(const uint4*)(St + (size_t)(i0 + lrow) * K + kk + lk);
    uint4 bv = *(const uint4*)(B + (size_t)(j0 + lrow) * K + kk + lk);
    *(uint4*)&As[lrow][lk] = av;
    *(uint4*)&Bs[lrow][lk] = bv;
    __syncthreads();
    bf16x8 af = *(const bf16x8*)&As[16 * w + (l & 15)][(l >> 4) * 8];
#pragma unroll
    for (int jt = 0; jt < 4; ++jt) {
      bf16x8 bf = *(const bf16x8*)&Bs[16 * jt + (l & 15)][(l >> 4) * 8];
      acc[jt] = __builtin_amdgcn_mfma_f32_16x16x32_bf16(af, bf, acc[jt], 0, 0, 0);
    }
    __syncthreads();
  }
  int rbase = i0 + 16 * w + ((l >> 4) * 4);
  int cbase = j0 + (l & 15);
#pragma unroll
  for (int jt = 0; jt < 4; ++jt) {
#pragma unroll
    for (int rr = 0; rr < 4; ++rr) {
      atomicAdd(&C[(size_t)(rbase + rr) * J + jt * 16 + cbase], acc[jt][rr]);
    }
  }
}

// ---------------- fp32 GEMM (small, level-2) ----------------
__global__ __launch_bounds__(256) void k_sgemm_nn(
    const float* __restrict__ A, const float* __restrict__ B, float* __restrict__ C,
    int M, int N, int K) {
  __shared__ float As[16][64];
  __shared__ float Bs[16][68];
  int t = threadIdx.x;
  int tx = t & 15, ty = t >> 4;
  int row0 = blockIdx.y * 64, col0 = blockIdx.x * 64;
  float acc[4][4] = {};
  for (int k0 = 0; k0 < K; k0 += 16) {
    int ar = t >> 2;
    int ak = (t & 3) * 4;
    float4 av = make_float4(0.f, 0.f, 0.f, 0.f);
    if (row0 + ar < M) av = *(const float4*)(A + (size_t)(row0 + ar) * K + k0 + ak);
    As[ak + 0][ar] = av.x; As[ak + 1][ar] = av.y;
    As[ak + 2][ar] = av.z; As[ak + 3][ar] = av.w;
    int bk = t >> 4;
    int bc = (t & 15) * 4;
    float4 bv = *(const float4*)(B + (size_t)(k0 + bk) * N + col0 + bc);
    *(float4*)&Bs[bk][bc] = bv;
    __syncthreads();
#pragma unroll
    for (int k = 0; k < 16; ++k) {
      float a[4], b[4];
#pragma unroll
      for (int u = 0; u < 4; ++u) a[u] = As[k][ty * 4 + u];
#pragma unroll
      for (int v = 0; v < 4; ++v) b[v] = Bs[k][tx * 4 + v];
#pragma unroll
      for (int u = 0; u < 4; ++u)
#pragma unroll
        for (int v = 0; v < 4; ++v) acc[u][v] += a[u] * b[v];
    }
    __syncthreads();
  }
#pragma unroll
  for (int u = 0; u < 4; ++u) {
    int r = row0 + ty * 4 + u;
    if (r < M) {
#pragma unroll
      for (int v = 0; v < 4; ++v) C[(size_t)r * N + col0 + tx * 4 + v] = acc[u][v];
    }
  }
}

// ---------------- BN stats (level-1, two-stage, no atomics) ----------------

__global__ void k_col_stats2(const float* __restrict__ X, const float* __restrict__ bias,
                             float* __restrict__ part, int M, int C, int rpb) {
  int c = threadIdx.x;
  int b = blockIdx.x;
  int r0 = b * rpb, r1 = min(r0 + rpb, M);
  float bi = bias[c];
  float s = 0.f, sq = 0.f;
  for (int r = r0; r < r1; ++r) {
    float v = X[(size_t)r * C + c] + bi;
    s += v; sq += v * v;
  }
  part[(size_t)b * 2 * C + c] = s;
  part[(size_t)b * 2 * C + C + c] = sq;
}

__global__ __launch_bounds__(256) void k_colred_par(
    const float* __restrict__ part, int nblk, int C,
    float* __restrict__ cs, float* __restrict__ csq) {
  __shared__ float sh[256];
  int c = blockIdx.x;
  int t = threadIdx.x;
  float s = 0.f, sq = 0.f;
  for (int b = t; b < nblk; b += 256) {
    s  += part[(size_t)b * 2 * C + c];
    sq += part[(size_t)b * 2 * C + C + c];
  }
  sh[t] = s; __syncthreads();
  for (int o = 128; o > 0; o >>= 1) { if (t < o) sh[t] += sh[t + o]; __syncthreads(); }
  if (t == 0) cs[c] = sh[0];
  __syncthreads();
  sh[t] = sq; __syncthreads();
  for (int o = 128; o > 0; o >>= 1) { if (t < o) sh[t] += sh[t + o]; __syncthreads(); }
  if (t == 0) csq[c] = sh[0];
}

__global__ void k_bn_silu(const float* __restrict__ X, const float* __restrict__ bias,
                          const float* __restrict__ cs, const float* __restrict__ csq,
                          const float* __restrict__ g, const float* __restrict__ be,
                          const float* __restrict__ resid, float* __restrict__ out,
                          ushort* __restrict__ outb,
                          int tot, int cmask, float invM) {
  int i = blockIdx.x * blockDim.x + threadIdx.x;
  if (i >= tot) return;
  int c = i & cmask;
  float m = cs[c] * invM;
  float var = csq[c] * invM - m * m;
  float v = (X[i] + bias[c] - m) * rsqrtf(var + EPS_BN) * g[c] + be[c];
  float y = v / (1.f + expf(-v));
  if (resid) y += resid[i];
  out[i] = y;
  if (outb) outb[i] = f2bf(y);
}

// ---------------- fused small BN (level-2, M<=256) ----------------
__global__ __launch_bounds__(256) void k_bn_small(
    const float* __restrict__ X, const float* __restrict__ bias,
    const float* __restrict__ g, const float* __restrict__ be,
    const float* __restrict__ resid, float* __restrict__ out,
    int M, int C, float invM) {
  __shared__ float sh[256];
  int c = blockIdx.x;
  int t = threadIdx.x;
  bool act = t < M;
  float v = 0.f;
  if (act) v = X[(size_t)t * C + c] + bias[c];
  sh[t] = v; __syncthreads();
  for (int o = 128; o > 0; o >>= 1) { if (t < o) sh[t] += sh[t + o]; __syncthreads(); }
  float m = sh[0] * invM; __syncthreads();
  sh[t] = v * v; __syncthreads();
  for (int o = 128; o > 0; o >>= 1) { if (t < o) sh[t] += sh[t + o]; __syncthreads(); }
  float var = sh[0] * invM - m * m;
  if (act) {
    float y = (v - m) * rsqrtf(var + EPS_BN) * g[c] + be[c];
    y = y / (1.f + expf(-y));
    if (resid) y += resid[(size_t)t * C + c];
    out[(size_t)t * C + c] = y;
  }
}

// ---------------- softmax + entropy (block partials) ----------------
template <int C>
__global__ void k_softmax_ent3(float* __restrict__ X, ushort* __restrict__ outb,
                               float* __restrict__ part, int nrows, int writeX) {
  constexpr int VPT = C / 64;
  __shared__ float went[4];
  int gt = blockIdx.x * blockDim.x + threadIdx.x;
  int row = gt >> 6;
  int l = gt & 63;
  int wid = threadIdx.x >> 6;
  bool active = row < nrows;
  size_t base = active ? (size_t)row * C : 0;
  float d[VPT];
  if (VPT == 4) {
    float4 v = *(const float4*)(X + base + l * 4);
    d[0] = v.x; d[1] = v.y; d[2] = v.z; d[3] = v.w;
  } else {
    d[0] = X[base + l];
  }
  float mx = d[0];
#pragma unroll
  for (int i = 1; i < VPT; ++i) mx = fmaxf(mx, d[i]);
  for (int o = 32; o > 0; o >>= 1) mx = fmaxf(mx, __shfl_xor(mx, o));
  float se = 0.f;
  float e[VPT];
#pragma unroll
  for (int i = 0; i < VPT; ++i) { d[i] -= mx; e[i] = expf(d[i]); se += e[i]; }
  for (int o = 32; o > 0; o >>= 1) se += __shfl_xor(se, o);
  float inv = 1.f / se;
  float pd = 0.f;
#pragma unroll
  for (int i = 0; i < VPT; ++i) { e[i] *= inv; pd += e[i] * d[i]; }
  if (active) {
    if (VPT == 4) {
      if (writeX) {
        float4 v; v.x = e[0]; v.y = e[1]; v.z = e[2]; v.w = e[3];
        *(float4*)(X + base + l * 4) = v;
      }
      if (outb) {
        ushort4 u; u.x = f2bf(e[0]); u.y = f2bf(e[1]); u.z = f2bf(e[2]); u.w = f2bf(e[3]);
        *(ushort4*)(outb + base + l * 4) = u;
      }
    } else {
      if (writeX) X[base + l] = e[0];
      if (outb) outb[base + l] = f2bf(e[0]);
    }
  }
  for (int o = 32; o > 0; o >>= 1) pd += __shfl_xor(pd, o);
  if (l == 0) went[wid] = active ? (logf(se) - pd) : 0.f;
  __syncthreads();
  if (threadIdx.x == 0) part[blockIdx.x] = went[0] + went[1] + went[2] + went[3];
}

__global__ __launch_bounds__(256) void k_reduce_atom(
    const float* __restrict__ in, int n, float* __restrict__ out) {
  __shared__ float sh[256];
  int t = threadIdx.x;
  int per = (n + gridDim.x - 1) / gridDim.x;
  int i0 = blockIdx.x * per, i1 = min(i0 + per, n);
  float s = 0.f;
  for (int i = i0 + t; i < i1; i += 256) s += in[i];
  sh[t] = s; __syncthreads();
  for (int o = 128; o > 0; o >>= 1) { if (t < o) sh[t] += sh[t + o]; __syncthreads(); }
  if (t == 0) atomicAdd(out, sh[0]);
}

// grid = 1 + 2Z: b0 trace(P0); b 1..Z sumsq(P1) chunks; b Z+1..2Z sumsq(P0) chunks
__global__ __launch_bounds__(256) void k_scalN_par(
    const float* __restrict__ P0, const float* __restrict__ P1, int K,
    float* __restrict__ outb, int Z) {
  __shared__ float sh[256];
  int b = blockIdx.x, t = threadIdx.x;
  float s = 0.f;
  int slot;
  if (b == 0) {
    slot = 0;
    for (int i = t; i < K; i += 256) s += P0[(size_t)i * K + i];
  } else {
    int which = (b - 1) / Z;
    int chunk = (b - 1) % Z;
    slot = 1 + which;
    const float4* P4 = (const float4*)(which ? P0 : P1);
    int n4 = (K * K) >> 2;
    int per = (n4 + Z - 1) / Z;
    int i0 = chunk * per, i1 = min(i0 + per, n4);
    for (int i = i0 + t; i < i1; i += 256) {
      float4 v = P4[i];
      s += v.x * v.x + v.y * v.y + v.z * v.z + v.w * v.w;
    }
  }
  sh[t] = s; __syncthreads();
  for (int o = 128; o > 0; o >>= 1) { if (t < o) sh[t] += sh[t + o]; __syncthreads(); }
  if (t == 0) atomicAdd(&outb[slot], sh[0]);
}

// grid = Z + 1: b<Z dot(U,V) chunks; b==Z sumsq(P)
__global__ __launch_bounds__(256) void k_scal2_par(
    const float* __restrict__ U, const float* __restrict__ V, int n,
    const float* __restrict__ P, int nP, float* __restrict__ outb, int Z) {
  __shared__ float sh[256];
  int b = blockIdx.x, t = threadIdx.x;
  float s = 0.f;
  int slot;
  if (b < Z) {
    slot = 0;
    const float4* U4 = (const float4*)U;
    const float4* V4 = (const float4*)V;
    int n4 = n >> 2;
    int per = (n4 + Z - 1) / Z;
    int i0 = b * per, i1 = min(i0 + per, n4);
    for (int i = i0 + t; i < i1; i += 256) {
      float4 u = U4[i], v = V4[i];
      s += u.x * v.x + u.y * v.y + u.z * v.z + u.w * v.w;
    }
  } else {
    slot = 1;
    const float4* P4 = (const float4*)P;
    int n4 = nP >> 2;
    for (int i = t; i < n4; i += 256) {
      float4 v = P4[i];
      s += v.x * v.x + v.y * v.y + v.z * v.z + v.w * v.w;
    }
  }
  sh[t] = s; __syncthreads();
  for (int o = 128; o > 0; o >>= 1) { if (t < o) sh[t] += sh[t + o]; __syncthreads(); }
  if (t == 0) atomicAdd(&outb[slot], sh[0]);
}

// ---------------- level-2 dense graph (A2T = apool^T layout) ----------------

__global__ __launch_bounds__(256) void k_deg2_par(
    const float* __restrict__ A2T, float* __restrict__ dinv2, int Np) {
  __shared__ float sh[256];
  int q = blockIdx.x;
  int t = threadIdx.x;
  float s = (t == 0) ? 1.0f : 0.f;
  for (int p = t; p < Np; p += 256) s += A2T[(size_t)q * Np + p];
  sh[t] = s; __syncthreads();
  for (int o = 128; o > 0; o >>= 1) { if (t < o) sh[t] += sh[t + o]; __syncthreads(); }
  if (t == 0) {
    float d = sh[0];
    dinv2[q] = d > 0.f ? rsqrtf(fmaxf(d, 1e-12f)) : 0.f;
  }
}

__global__ void k_dense_agg(const float* __restrict__ A2T, const float* __restrict__ dinv2,
                            const float* __restrict__ H, float* __restrict__ out,
                            int Np, int C) {
  int q = blockIdx.x, c = threadIdx.x;
  float acc = 0.f;
#pragma unroll 8
  for (int p = 0; p < Np; ++p)
    acc += dinv2[p] * A2T[(size_t)q * Np + p] * H[(size_t)p * C + c];
  float dq = dinv2[q];
  out[(size_t)q * C + c] = dq * acc + dq * dq * H[(size_t)q * C + c];
}

// ---------------- fused tail TN products (level 2), LDS-staged ----------------
__global__ __launch_bounds__(256) void k_tn3(
    const float* __restrict__ S, const float* __restrict__ B2,
    float* __restrict__ sts2, float* __restrict__ xp2, int M) {
  __shared__ float As[64][65];
  __shared__ float Bs[64][65];
  int z = blockIdx.x;
  const float* B; float* C; int J, j0;
  if (z == 0) { B = S;  C = sts2; J = 64;  j0 = 0; }
  else        { B = B2; C = xp2;  J = 128; j0 = (z - 1) * 64; }
  int t = threadIdx.x;
  int tj = t & 63, ti = t >> 6;
  float acc[16] = {};
  for (int m0 = 0; m0 < M; m0 += 64) {
#pragma unroll
    for (int r = 0; r < 16; ++r) {
      As[ti * 16 + r][tj] = S[(size_t)(m0 + ti * 16 + r) * 64 + tj];
      Bs[ti * 16 + r][tj] = B[(size_t)(m0 + ti * 16 + r) * J + j0 + tj];
    }
    __syncthreads();
#pragma unroll 4
    for (int mm = 0; mm < 64; ++mm) {
      float bv = Bs[mm][tj];
#pragma unroll
      for (int ii = 0; ii < 16; ++ii) acc[ii] += As[mm][ti * 16 + ii] * bv;
    }
    __syncthreads();
  }
  for (int ii = 0; ii < 16; ++ii) C[(size_t)(ti * 16 + ii) * J + j0 + tj] = acc[ii];
}

// ---------------- final head ----------------
__global__ void k_final(const float* __restrict__ xp2, const float* __restrict__ Wlin,
                        const float* __restrict__ blin, const float* __restrict__ scal,
                        float* __restrict__ out, int N1, int E1, int K1, int K2, int OUT) {
  __shared__ float pooled[128];
  __shared__ float logits[32];
  int t = threadIdx.x;
  float s = 0.f;
  for (int r = 0; r < K2; ++r) s += xp2[(size_t)r * 128 + t];
  pooled[t] = s / (float)K2;
  __syncthreads();
  if (t < OUT) {
    float acc = blin[t];
    for (int k = 0; k < 128; ++k) acc += pooled[k] * Wlin[(size_t)k * OUT + t];
    logits[t] = acc;
  }
  __syncthreads();
  if (t == 0) {
    float mx = logits[0];
    for (int j = 1; j < OUT; ++j) mx = fmaxf(mx, logits[j]);
    float se = 0.f;
    for (int j = 0; j < OUT; ++j) se += expf(logits[j] - mx);
    float lse = mx + logf(se);
    for (int j = 0; j < OUT; ++j) out[j] = logits[j] - lse;
    float n1 = (float)N1;
    float ent1 = scal[0] / n1;
    float ent2 = scal[1] / (float)K1;
    float link1 = sqrtf(fmaxf((float)E1 - 2.f * scal[2] + scal[3], 0.f)) / (n1 * n1);
    float link2 = sqrtf(fmaxf(scal[4] - 2.f * scal[5] + scal[6], 0.f)) / ((float)K1 * (float)K1);
    out[OUT] = ent1 + ent2 + link1 + link2;
  }
}

// ---------------- host ----------------

extern "C" void kernel_launch(void* const* d_in, const int* in_sizes, int n_in,
                              void* d_out, int out_size, void* d_ws, size_t ws_size,
                              hipStream_t stream) {
  (void)n_in; (void)out_size; (void)ws_size;
  const float* x = (const float*)d_in[0];
  const int* ei  = (const int*)d_in[1];
  const int N = in_sizes[0] / 128;   // 20000
  const int E = in_sizes[1] / 2;     // 640000
  const int* src = ei;
  const int* dst = ei + E;
  const float *W1a=(const float*)d_in[4],  *b1a=(const float*)d_in[5],
              *g1a=(const float*)d_in[6],  *be1a=(const float*)d_in[7];
  const float *W1b=(const float*)d_in[8],  *b1b=(const float*)d_in[9],
              *g1b=(const float*)d_in[10], *be1b=(const float*)d_in[11];
  const float *Wp1=(const float*)d_in[12], *bp1=(const float*)d_in[13],
              *gp1=(const float*)d_in[14], *bep1=(const float*)d_in[15];
  const float *W2a=(const float*)d_in[16], *b2a=(const float*)d_in[17],
              *g2a=(const float*)d_in[18], *be2a=(const float*)d_in[19];
  const float *W2b=(const float*)d_in[20], *b2b=(const float*)d_in[21],
              *g2b=(const float*)d_in[22], *be2b=(const float*)d_in[23];
  const float *Wp2=(const float*)d_in[24], *bp2=(const float*)d_in[25],
              *gp2=(const float*)d_in[26], *bep2=(const float*)d_in[27];
  const float *Wlin=(const float*)d_in[28], *blin=(const float*)d_in[29];
  const int K1 = in_sizes[12] / 128;   // 256
  const int K2 = in_sizes[24] / 128;   // 64
  const int OUT = in_sizes[29];        // 10

  char* base = (char*)d_ws;
  size_t off = 0;
  auto allocb = [&](size_t bytes) -> void* {
    void* p = (void*)(base + off);
    off += ((bytes + 255) & ~(size_t)255);
    return p;
  };
  auto alloc = [&](size_t nf) -> float* { return (float*)allocb(nf * 4); };
  auto alloci = [&](size_t ni) -> int* { return (int*)allocb(ni * 4); };
  auto allocu = [&](size_t nu) -> ushort* { return (ushort*)allocb(nu * 2); };

  auto cdiv = [](long long a, long long b) { return (int)((a + b - 1) / b); };

  const int RPB = 16;
  const int NBLK1 = cdiv(N, RPB);
  const int NTILES = cdiv(N, 1024);

  float* scal  = alloc(16);
  float* cs    = alloc(256);
  float* csq   = alloc(256);
  float* dinv  = alloc(N);
  float* dinv2 = alloc(K1);
  float* apT   = alloc((size_t)K1 * K1);
  float* sts   = alloc((size_t)K1 * K1);
  float* xp    = alloc((size_t)K1 * 128);
  float* h2    = alloc((size_t)K1 * 128);
  float* y2    = alloc((size_t)K1 * 128);
  float* xa2   = alloc((size_t)K1 * 128);
  float* x2f   = alloc((size_t)K1 * 128);
  float* s2b   = alloc((size_t)K1 * K2);
  float* U     = alloc((size_t)K1 * K2);
  float* sts2  = alloc((size_t)K2 * K2);
  float* xp2   = alloc((size_t)K2 * 128);
  float* ent1p = alloc(cdiv(N, 4) + 8);
  float* ent2p = alloc(64 + 8);
  float* csp   = alloc((size_t)(NBLK1 + 2) * 512);
  float* R1 = alloc((size_t)N * 128);
  float* R2 = alloc((size_t)N * 128);
  float* R3 = alloc((size_t)N * K1);
  float* R4 = alloc((size_t)N * K1);
  ushort* B16A = allocu((size_t)N * 128);
  ushort* W1at = allocu(128 * 128);
  ushort* W1bt = allocu(128 * 128);
  ushort* Wp1t = allocu((size_t)K1 * 128);
  // CSR (dst only) + scan handshake (flags/partials) appended to cnt for one memset
  int* cnt_d = alloci((size_t)N + 64);
  int* flags = cnt_d + N;
  int* parts = cnt_d + N + 32;
  int* rp_d  = alloci(N + 1);
  int* cur_d = alloci(N);
  int* col_s = alloci(E);

  ushort* Hb   = (ushort*)R3;
  ushort* aggB = (ushort*)R3;
  ushort* Sb   = (ushort*)R3;
  ushort* ATSb = (ushort*)R4;
  ushort* St   = (ushort*)R1;
  ushort* ATSt = (ushort*)R2;
  ushort* R2t  = B16A;

  hipMemsetAsync(scal, 0, 16 * sizeof(float), stream);

  // ---- prologue: histogram + x->bf16; parallel scan (+dinv); fill ----
  hipMemsetAsync(cnt_d, 0, ((size_t)N + 64) * sizeof(int), stream);
  {
    int HB = cdiv(E, 256);
    int CB = cdiv((size_t)N * 128 / 4, 256);
    k_pre<<<HB + CB, 256, 0, stream>>>(dst, cnt_d, E, x, B16A, N * 128 / 4, HB);
  }
  k_scan_par<<<NTILES, 256, 0, stream>>>(cnt_d, rp_d, cur_d, dinv, flags, parts, N, E);
  k_fill_csr<<<cdiv(E, 256), 256, 0, stream>>>(dst, src, cur_d, col_s, E);

  // ---- weight transposes (one launch) ----
  {
    dim3 b32(32, 8);
    k_tconv3<<<dim3(8, 4, 3), b32, 0, stream>>>(W1a, W1b, Wp1, W1at, W1bt, Wp1t, K1);
  }

  auto mfma_nt = [&](const ushort* A, const ushort* B, float* C, ushort* Cb,
                     int I, int J, int K) {
    dim3 g(J / 64, cdiv(I, 64), 1);
    k_mfma_nt<<<g, 256, 0, stream>>>(A, B, C, Cb, I, J, K, K, 0);
  };
  auto gemm_nn = [&](const float* A, const float* B, float* C, int M, int Nn, int K) {
    dim3 g(Nn / 64, cdiv(M, 64));
    k_sgemm_nn<<<g, 256, 0, stream>>>(A, B, C, M, Nn, K);
  };

  // level-1 blocks a,b: GEMM -> gather -> BN/SiLU
  auto block1 = [&](const ushort* xin_b, const ushort* Wt, const float* b, const float* gg,
                    const float* be, const float* resid, float* outp, ushort* outb, int C) {
    mfma_nt(xin_b, Wt, nullptr, Hb, N, C, 128);
    k_gather_agg_b2<<<N, C / 2, 0, stream>>>(rp_d, col_s, dinv, Hb, R4, C / 2);
    k_col_stats2<<<NBLK1, C, 0, stream>>>(R4, b, csp, N, C, RPB);
    k_colred_par<<<C, 256, 0, stream>>>(csp, NBLK1, C, cs, csq);
    int tot = N * C;
    k_bn_silu<<<cdiv(tot, 256), 256, 0, stream>>>(R4, b, cs, csq, gg, be, resid, outp,
                                                  outb, tot, C - 1, 1.f / N);
  };

  block1(B16A, W1at, b1a, g1a, be1a, nullptr, R1, B16A, 128);  // R1 + R1b
  block1(B16A, W1bt, b1b, g1b, be1b, R1,      R2, B16A, 128);  // R2 + R2b

  // pooling block: agg = A_hat * R2 in input space (128 ch), then GEMM agg@Wp1
  k_gather_agg_b2b<<<N, 64, 0, stream>>>(rp_d, col_s, dinv, B16A, aggB, 64);
  mfma_nt(aggB, Wp1t, R4, nullptr, N, K1, 128);
  k_col_stats2<<<NBLK1, K1, 0, stream>>>(R4, bp1, csp, N, K1, RPB);
  k_colred_par<<<K1, 256, 0, stream>>>(csp, NBLK1, K1, cs, csq);
  k_bn_silu<<<cdiv(N * K1, 256), 256, 0, stream>>>(R4, bp1, cs, csq, gp1, bep1, nullptr,
                                                   R4, nullptr, N * K1, K1 - 1, 1.f / N);
  // S = softmax: bf16 only (Sb), entropy partials
  k_softmax_ent3<256><<<cdiv(N, 4), 256, 0, stream>>>(R4, Sb, ent1p, N, 0);
  k_reduce_atom<<<8, 256, 0, stream>>>(ent1p, cdiv(N, 4), &scal[0]);

  {
    dim3 b32(32, 8);
    k_tconv_b<<<dim3(K1 / 32, cdiv(N, 32)), b32, 0, stream>>>(Sb, St, N, K1);
    k_tconv<<<dim3(128 / 32, cdiv(N, 32)), b32, 0, stream>>>(R2, R2t, N, 128);
  }
  k_gather_T_b2b<<<N, K1 / 2, 0, stream>>>(rp_d, col_s, Sb, ATSb, K1 / 2);
  {
    dim3 b32(32, 8);
    k_tconv_b<<<dim3(K1 / 32, cdiv(N, 32)), b32, 0, stream>>>(ATSb, ATSt, N, K1);
  }

  // merged TN products: apT | sts | xp in one launch
  {
    hipMemsetAsync(apT, 0, (size_t)(2 * K1 * K1 + K1 * 128) * sizeof(float), stream);
    int chunk = ((cdiv(N, 16) + 31) & ~31);
    int z = cdiv(N, chunk);
    k_mfma3<<<dim3(10, 4, z), 256, 0, stream>>>(St, ATSt, R2t, apT, sts, xp, N, chunk);
  }
  k_scalN_par<<<1 + 2 * 16, 256, 0, stream>>>(apT, sts, K1, &scal[2], 16);

  // ---------------- level 2 (dense 256-node graph, A2T layout) ----------------
  k_deg2_par<<<K1, 256, 0, stream>>>(apT, dinv2, K1);

  auto block2 = [&](const float* xin, const float* W, const float* b, const float* gg,
                    const float* be, const float* resid, float* outp, int C) {
    gemm_nn(xin, W, h2, K1, C, 128);
    k_dense_agg<<<K1, C, 0, stream>>>(apT, dinv2, h2, y2, K1, C);
    k_bn_small<<<C, 256, 0, stream>>>(y2, b, gg, be, resid, outp, K1, C, 1.f / K1);
  };

  block2(xp,  W2a, b2a, g2a, be2a, nullptr, xa2, 128);
  block2(xa2, W2b, b2b, g2b, be2b, xa2,     x2f, 128);
  block2(x2f, Wp2, bp2, gp2, bep2, nullptr, s2b, K2);
  k_softmax_ent3<64><<<cdiv(K1, 4), 256, 0, stream>>>(s2b, nullptr, ent2p, K1, 1);
  k_reduce_atom<<<2, 256, 0, stream>>>(ent2p, cdiv(K1, 4), &scal[1]);

  // cross2 = dot(U, s2) with U = A2T @ s2;  sumsq(sts2)
  gemm_nn(apT, s2b, U, K1, K2, K1);
  k_tn3<<<3, 256, 0, stream>>>(s2b, x2f, sts2, xp2, K1);
  k_scal2_par<<<8 + 1, 256, 0, stream>>>(U, s2b, K1 * K2, sts2, K2 * K2, &scal[5], 8);

  k_final<<<1, 128, 0, stream>>>(xp2, Wlin, blin, scal, (float*)d_out, N, E, K1, K2, OUT);
}

// Round 12
// 515.410 us; speedup vs baseline: 5.5822x; 1.0084x over previous
//
#include <hip/hip_runtime.h>

#define EPS_BN 1e-5f
typedef unsigned int uint;
typedef unsigned short ushort;
typedef __attribute__((ext_vector_type(8))) short bf16x8;
typedef __attribute__((ext_vector_type(4))) float f32x4;

__device__ inline ushort f2bf(float f) {
  uint u = __float_as_uint(f);
  uint r = (u + 0x7FFFu + ((u >> 16) & 1u)) >> 16;
  return (ushort)r;
}
__device__ inline float bflo(uint h) { return __uint_as_float(h << 16); }
__device__ inline float bfhi(uint h) { return __uint_as_float(h & 0xFFFF0000u); }
__device__ inline float bf2f(ushort h) { return __uint_as_float(((uint)h) << 16); }

// ---------------- fused prologue: dst-histogram + x -> bf16 ----------------

__global__ void k_pre(const int* __restrict__ dst, int* __restrict__ cnt, int E,
                      const float* __restrict__ x, ushort* __restrict__ xb, int n4, int HB) {
  int b = blockIdx.x;
  if (b < HB) {
    int e = b * 256 + threadIdx.x;
    if (e < E) atomicAdd(&cnt[dst[e]], 1);
  } else {
    int i = (b - HB) * 256 + threadIdx.x;
    if (i < n4) {
      float4 v = ((const float4*)x)[i];
      ushort4 o;
      o.x = f2bf(v.x); o.y = f2bf(v.y); o.z = f2bf(v.z); o.w = f2bf(v.w);
      ((ushort4*)xb)[i] = o;
    }
  }
}

// ---------------- parallel chained scan: cnt -> rowptr/cursor/dinv ----------------
__global__ __launch_bounds__(256) void k_scan_par(
    const int* __restrict__ cnt, int* __restrict__ rowptr, int* __restrict__ cursor,
    float* __restrict__ dinv, int* __restrict__ flags, int* __restrict__ partials,
    int N, int E) {
  __shared__ int wsum[4];
  __shared__ int sbase;
  int tile = blockIdx.x;
  int t = threadIdx.x;
  int lane = t & 63, w = t >> 6;
  int i0 = tile * 1024 + t * 4;
  int c[4];
#pragma unroll
  for (int j = 0; j < 4; ++j) {
    int i = i0 + j;
    c[j] = (i < N) ? cnt[i] : 0;
  }
  int p1 = c[0], p2 = p1 + c[1], p3 = p2 + c[2];
  int tsum = p3 + c[3];
  int incl = tsum;
  for (int o = 1; o < 64; o <<= 1) {
    int v = __shfl_up(incl, o);
    if (lane >= o) incl += v;
  }
  int excl = incl - tsum;
  if (lane == 63) wsum[w] = incl;
  __syncthreads();
  if (t == 0) {
    int tot = wsum[0] + wsum[1] + wsum[2] + wsum[3];
    int basev = 0;
    if (tile > 0) {
      while (atomicAdd(&flags[tile - 1], 0) == 0) {}
      basev = atomicAdd(&partials[tile - 1], 0);
    }
    atomicExch(&partials[tile], basev + tot);
    __threadfence();
    atomicExch(&flags[tile], 1);
    sbase = basev;
  }
  __syncthreads();
  int base = sbase;
  for (int ww = 0; ww < w; ++ww) base += wsum[ww];
  base += excl;
  int pre[4] = {0, p1, p2, p3};
#pragma unroll
  for (int j = 0; j < 4; ++j) {
    int i = i0 + j;
    if (i < N) {
      int run = base + pre[j];
      rowptr[i] = run; cursor[i] = run;
      dinv[i] = rsqrtf(1.0f + (float)c[j]);
    }
  }
  if (tile == 0 && t == 0) rowptr[N] = E;
}

__global__ void k_fill_csr(const int* __restrict__ key, const int* __restrict__ val,
                           int* __restrict__ cursor, int* __restrict__ col, int E) {
  int e = blockIdx.x * blockDim.x + threadIdx.x;
  if (e < E) {
    int pos = atomicAdd(&cursor[key[e]], 1);
    col[pos] = val[e];
  }
}

// ---------------- gather aggregation, bf16 input, 2 ch/thread ----------------

__global__ void k_gather_agg_b2(const int* __restrict__ rowptr, const int* __restrict__ col,
                                const float* __restrict__ dinv, const ushort* __restrict__ H,
                                float* __restrict__ out, int C2) {
  int d = blockIdx.x;
  int c2 = threadIdx.x;
  const uint* H2 = (const uint*)H;
  int b = rowptr[d], e = rowptr[d + 1];
  float a0 = 0.f, a1 = 0.f;
#pragma unroll 4
  for (int i = b; i < e; ++i) {
    int s = col[i];
    float dv = dinv[s];
    uint h = H2[(size_t)s * C2 + c2];
    a0 += dv * bflo(h);
    a1 += dv * bfhi(h);
  }
  float dd = dinv[d];
  uint hd = H2[(size_t)d * C2 + c2];
  float2 o;
  o.x = dd * a0 + dd * dd * bflo(hd);
  o.y = dd * a1 + dd * dd * bfhi(hd);
  *(float2*)(out + (size_t)d * (C2 * 2) + c2 * 2) = o;
}

__global__ void k_gather_agg_b2b(const int* __restrict__ rowptr, const int* __restrict__ col,
                                 const float* __restrict__ dinv, const ushort* __restrict__ H,
                                 ushort* __restrict__ out, int C2) {
  int d = blockIdx.x;
  int c2 = threadIdx.x;
  const uint* H2 = (const uint*)H;
  int b = rowptr[d], e = rowptr[d + 1];
  float a0 = 0.f, a1 = 0.f;
#pragma unroll 4
  for (int i = b; i < e; ++i) {
    int s = col[i];
    float dv = dinv[s];
    uint h = H2[(size_t)s * C2 + c2];
    a0 += dv * bflo(h);
    a1 += dv * bfhi(h);
  }
  float dd = dinv[d];
  uint hd = H2[(size_t)d * C2 + c2];
  ushort2 o;
  o.x = f2bf(dd * a0 + dd * dd * bflo(hd));
  o.y = f2bf(dd * a1 + dd * dd * bfhi(hd));
  *(ushort2*)(out + (size_t)d * (C2 * 2) + c2 * 2) = o;
}

// T[d] = sum_{e: dst=d} S[src_e]  (= A^T S with dst-CSR), bf16 out
__global__ void k_gather_T_b2b(const int* __restrict__ rowptr, const int* __restrict__ col,
                               const ushort* __restrict__ S, ushort* __restrict__ T, int C2) {
  int s = blockIdx.x;
  int c2 = threadIdx.x;
  const uint* S2 = (const uint*)S;
  int b = rowptr[s], e = rowptr[s + 1];
  float a0 = 0.f, a1 = 0.f;
#pragma unroll 4
  for (int i = b; i < e; ++i) {
    int d = col[i];
    uint h = S2[(size_t)d * C2 + c2];
    a0 += bflo(h);
    a1 += bfhi(h);
  }
  ushort2 o; o.x = f2bf(a0); o.y = f2bf(a1);
  *(ushort2*)(T + (size_t)s * (C2 * 2) + c2 * 2) = o;
}

// ---------------- transposes ----------------

__global__ void k_tconv_b(const ushort* __restrict__ in, ushort* __restrict__ out,
                          int R, int Cc) {
  __shared__ ushort tile[32][33];
  int c0 = blockIdx.x * 32, r0 = blockIdx.y * 32;
  int tx = threadIdx.x, ty = threadIdx.y;
  for (int i = 0; i < 32; i += 8) {
    int r = r0 + ty + i, c = c0 + tx;
    if (r < R && c < Cc) tile[ty + i][tx] = in[(size_t)r * Cc + c];
  }
  __syncthreads();
  for (int i = 0; i < 32; i += 8) {
    int oc = c0 + ty + i;
    int orr = r0 + tx;
    if (oc < Cc && orr < R) out[(size_t)oc * R + orr] = tile[tx][ty + i];
  }
}

__global__ void k_tconv3(const float* __restrict__ W0, const float* __restrict__ W1,
                         const float* __restrict__ W2,
                         ushort* __restrict__ O0, ushort* __restrict__ O1,
                         ushort* __restrict__ O2, int K1) {
  __shared__ float tile[32][33];
  int z = blockIdx.z;
  const float* in = (z == 0) ? W0 : (z == 1) ? W1 : W2;
  ushort* out = (z == 0) ? O0 : (z == 1) ? O1 : O2;
  int Cc = (z == 2) ? K1 : 128;
  int R = 128;
  int c0 = blockIdx.x * 32, r0 = blockIdx.y * 32;
  if (c0 >= Cc) return;
  int tx = threadIdx.x, ty = threadIdx.y;
  for (int i = 0; i < 32; i += 8) {
    int r = r0 + ty + i, c = c0 + tx;
    if (r < R && c < Cc) tile[ty + i][tx] = in[(size_t)r * Cc + c];
  }
  __syncthreads();
  for (int i = 0; i < 32; i += 8) {
    int oc = c0 + ty + i;
    int orr = r0 + tx;
    if (oc < Cc && orr < R) out[(size_t)oc * R + orr] = f2bf(tile[tx][ty + i]);
  }
}

// ---------------- bf16 MFMA NT GEMM (level-1 feature GEMMs) ----------------
__global__ __launch_bounds__(256) void k_mfma_nt(
    const ushort* __restrict__ A, const ushort* __restrict__ B, float* __restrict__ C,
    ushort* __restrict__ Cb, int I, int J, int K, int kChunk, int atom) {
  __shared__ ushort As[64][40];
  __shared__ ushort Bs[64][40];
  int t = threadIdx.x;
  int w = t >> 6, l = t & 63;
  int i0 = blockIdx.y * 64, j0 = blockIdx.x * 64;
  int k0 = blockIdx.z * kChunk;
  int k1 = min(k0 + kChunk, K);
  f32x4 acc[4] = {};
  int lrow = t >> 2;
  int lk = (t & 3) * 8;
  for (int kk = k0; kk < k1; kk += 32) {
    uint4 av = make_uint4(0u, 0u, 0u, 0u);
    int ar = i0 + lrow;
    if (ar < I) av = *(const uint4*)(A + (size_t)ar * K + kk + lk);
    uint4 bv = *(const uint4*)(B + (size_t)(j0 + lrow) * K + kk + lk);
    *(uint4*)&As[lrow][lk] = av;
    *(uint4*)&Bs[lrow][lk] = bv;
    __syncthreads();
    bf16x8 af = *(const bf16x8*)&As[16 * w + (l & 15)][(l >> 4) * 8];
#pragma unroll
    for (int jt = 0; jt < 4; ++jt) {
      bf16x8 bf = *(const bf16x8*)&Bs[16 * jt + (l & 15)][(l >> 4) * 8];
      acc[jt] = __builtin_amdgcn_mfma_f32_16x16x32_bf16(af, bf, acc[jt], 0, 0, 0);
    }
    __syncthreads();
  }
  int rbase = i0 + 16 * w + ((l >> 4) * 4);
  int cbase = j0 + (l & 15);
#pragma unroll
  for (int jt = 0; jt < 4; ++jt) {
#pragma unroll
    for (int rr = 0; rr < 4; ++rr) {
      int r = rbase + rr;
      if (r < I) {
        size_t idx = (size_t)r * J + jt * 16 + cbase;
        if (Cb) Cb[idx] = f2bf(acc[jt][rr]);
        else if (atom) atomicAdd(&C[idx], acc[jt][rr]);
        else C[idx] = acc[jt][rr];
      }
    }
  }
}

// merged 3-in-1 TN products
__global__ __launch_bounds__(256) void k_mfma3(
    const ushort* __restrict__ St, const ushort* __restrict__ ATSt,
    const ushort* __restrict__ R2t,
    float* __restrict__ apT, float* __restrict__ sts, float* __restrict__ xp,
    int K, int kChunk) {
  __shared__ ushort As[64][40];
  __shared__ ushort Bs[64][40];
  int xb_ = blockIdx.x;
  const ushort* B; float* C; int J, j0;
  if (xb_ < 4)      { B = ATSt; C = apT; J = 256; j0 = xb_ * 64; }
  else if (xb_ < 8) { B = St;   C = sts; J = 256; j0 = (xb_ - 4) * 64; }
  else              { B = R2t;  C = xp;  J = 128; j0 = (xb_ - 8) * 64; }
  int t = threadIdx.x;
  int w = t >> 6, l = t & 63;
  int i0 = blockIdx.y * 64;
  int k0 = blockIdx.z * kChunk;
  int k1 = min(k0 + kChunk, K);
  f32x4 acc[4] = {};
  int lrow = t >> 2;
  int lk = (t & 3) * 8;
  for (int kk = k0; kk < k1; kk += 32) {
    uint4 av = *(const uint4*)(St + (size_t)(i0 + lrow) * K + kk + lk);
    uint4 bv = *(const uint4*)(B + (size_t)(j0 + lrow) * K + kk + lk);
    *(uint4*)&As[lrow][lk] = av;
    *(uint4*)&Bs[lrow][lk] = bv;
    __syncthreads();
    bf16x8 af = *(const bf16x8*)&As[16 * w + (l & 15)][(l >> 4) * 8];
#pragma unroll
    for (int jt = 0; jt < 4; ++jt) {
      bf16x8 bf = *(const bf16x8*)&Bs[16 * jt + (l & 15)][(l >> 4) * 8];
      acc[jt] = __builtin_amdgcn_mfma_f32_16x16x32_bf16(af, bf, acc[jt], 0, 0, 0);
    }
    __syncthreads();
  }
  int rbase = i0 + 16 * w + ((l >> 4) * 4);
  int cbase = j0 + (l & 15);
#pragma unroll
  for (int jt = 0; jt < 4; ++jt) {
#pragma unroll
    for (int rr = 0; rr < 4; ++rr) {
      atomicAdd(&C[(size_t)(rbase + rr) * J + jt * 16 + cbase], acc[jt][rr]);
    }
  }
}

// ---------------- fp32 GEMM (small, level-2) ----------------
__global__ __launch_bounds__(256) void k_sgemm_nn(
    const float* __restrict__ A, const float* __restrict__ B, float* __restrict__ C,
    int M, int N, int K) {
  __shared__ float As[16][64];
  __shared__ float Bs[16][68];
  int t = threadIdx.x;
  int tx = t & 15, ty = t >> 4;
  int row0 = blockIdx.y * 64, col0 = blockIdx.x * 64;
  float acc[4][4] = {};
  for (int k0 = 0; k0 < K; k0 += 16) {
    int ar = t >> 2;
    int ak = (t & 3) * 4;
    float4 av = make_float4(0.f, 0.f, 0.f, 0.f);
    if (row0 + ar < M) av = *(const float4*)(A + (size_t)(row0 + ar) * K + k0 + ak);
    As[ak + 0][ar] = av.x; As[ak + 1][ar] = av.y;
    As[ak + 2][ar] = av.z; As[ak + 3][ar] = av.w;
    int bk = t >> 4;
    int bc = (t & 15) * 4;
    float4 bv = *(const float4*)(B + (size_t)(k0 + bk) * N + col0 + bc);
    *(float4*)&Bs[bk][bc] = bv;
    __syncthreads();
#pragma unroll
    for (int k = 0; k < 16; ++k) {
      float a[4], b[4];
#pragma unroll
      for (int u = 0; u < 4; ++u) a[u] = As[k][ty * 4 + u];
#pragma unroll
      for (int v = 0; v < 4; ++v) b[v] = Bs[k][tx * 4 + v];
#pragma unroll
      for (int u = 0; u < 4; ++u)
#pragma unroll
        for (int v = 0; v < 4; ++v) acc[u][v] += a[u] * b[v];
    }
    __syncthreads();
  }
#pragma unroll
  for (int u = 0; u < 4; ++u) {
    int r = row0 + ty * 4 + u;
    if (r < M) {
#pragma unroll
      for (int v = 0; v < 4; ++v) C[(size_t)r * N + col0 + tx * 4 + v] = acc[u][v];
    }
  }
}

// ---------------- BN stats ----------------

__global__ void k_col_stats2(const float* __restrict__ X, const float* __restrict__ bias,
                             float* __restrict__ part, int M, int C, int rpb) {
  int c = threadIdx.x;
  int b = blockIdx.x;
  int r0 = b * rpb, r1 = min(r0 + rpb, M);
  float bi = bias[c];
  float s = 0.f, sq = 0.f;
  for (int r = r0; r < r1; ++r) {
    float v = X[(size_t)r * C + c] + bi;
    s += v; sq += v * v;
  }
  part[(size_t)b * 2 * C + c] = s;
  part[(size_t)b * 2 * C + C + c] = sq;
}

// bf16 input variant
__global__ void k_col_stats2b(const ushort* __restrict__ X, const float* __restrict__ bias,
                              float* __restrict__ part, int M, int C, int rpb) {
  int c = threadIdx.x;
  int b = blockIdx.x;
  int r0 = b * rpb, r1 = min(r0 + rpb, M);
  float bi = bias[c];
  float s = 0.f, sq = 0.f;
  for (int r = r0; r < r1; ++r) {
    float v = bf2f(X[(size_t)r * C + c]) + bi;
    s += v; sq += v * v;
  }
  part[(size_t)b * 2 * C + c] = s;
  part[(size_t)b * 2 * C + C + c] = sq;
}

__global__ __launch_bounds__(256) void k_colred_par(
    const float* __restrict__ part, int nblk, int C,
    float* __restrict__ cs, float* __restrict__ csq) {
  __shared__ float sh[256];
  int c = blockIdx.x;
  int t = threadIdx.x;
  float s = 0.f, sq = 0.f;
  for (int b = t; b < nblk; b += 256) {
    s  += part[(size_t)b * 2 * C + c];
    sq += part[(size_t)b * 2 * C + C + c];
  }
  sh[t] = s; __syncthreads();
  for (int o = 128; o > 0; o >>= 1) { if (t < o) sh[t] += sh[t + o]; __syncthreads(); }
  if (t == 0) cs[c] = sh[0];
  __syncthreads();
  sh[t] = sq; __syncthreads();
  for (int o = 128; o > 0; o >>= 1) { if (t < o) sh[t] += sh[t + o]; __syncthreads(); }
  if (t == 0) csq[c] = sh[0];
}

// BN + SiLU (+ bf16 residual), bf16 output only
__global__ void k_bn_silu(const float* __restrict__ X, const float* __restrict__ bias,
                          const float* __restrict__ cs, const float* __restrict__ csq,
                          const float* __restrict__ g, const float* __restrict__ be,
                          const ushort* __restrict__ residb, ushort* __restrict__ outb,
                          int tot, int cmask, float invM) {
  int i = blockIdx.x * blockDim.x + threadIdx.x;
  if (i >= tot) return;
  int c = i & cmask;
  float m = cs[c] * invM;
  float var = csq[c] * invM - m * m;
  float v = (X[i] + bias[c] - m) * rsqrtf(var + EPS_BN) * g[c] + be[c];
  float y = v / (1.f + expf(-v));
  if (residb) y += bf2f(residb[i]);
  outb[i] = f2bf(y);
}

// ---------------- fused small BN (level-2, M<=256) ----------------
__global__ __launch_bounds__(256) void k_bn_small(
    const float* __restrict__ X, const float* __restrict__ bias,
    const float* __restrict__ g, const float* __restrict__ be,
    const float* __restrict__ resid, float* __restrict__ out,
    int M, int C, float invM) {
  __shared__ float sh[256];
  int c = blockIdx.x;
  int t = threadIdx.x;
  bool act = t < M;
  float v = 0.f;
  if (act) v = X[(size_t)t * C + c] + bias[c];
  sh[t] = v; __syncthreads();
  for (int o = 128; o > 0; o >>= 1) { if (t < o) sh[t] += sh[t + o]; __syncthreads(); }
  float m = sh[0] * invM; __syncthreads();
  sh[t] = v * v; __syncthreads();
  for (int o = 128; o > 0; o >>= 1) { if (t < o) sh[t] += sh[t + o]; __syncthreads(); }
  float var = sh[0] * invM - m * m;
  if (act) {
    float y = (v - m) * rsqrtf(var + EPS_BN) * g[c] + be[c];
    y = y / (1.f + expf(-y));
    if (resid) y += resid[(size_t)t * C + c];
    out[(size_t)t * C + c] = y;
  }
}

// ---------------- fused BN + SiLU + softmax + entropy (pooling block, C=256) ----------------
// bf16 input rows (GEMM output), bf16 softmax output, entropy block-partials.
template <int C>
__global__ void k_bn_softmax(const ushort* __restrict__ H, const float* __restrict__ bias,
                             const float* __restrict__ cs, const float* __restrict__ csq,
                             const float* __restrict__ g, const float* __restrict__ be,
                             ushort* __restrict__ outb, float* __restrict__ part,
                             int nrows, float invM) {
  constexpr int VPT = C / 64;   // 4
  __shared__ float went[4];
  int gt = blockIdx.x * blockDim.x + threadIdx.x;
  int row = gt >> 6;
  int l = gt & 63;
  int wid = threadIdx.x >> 6;
  bool active = row < nrows;
  size_t base = active ? (size_t)row * C : 0;
  ushort4 hv = *(const ushort4*)(H + base + l * 4);
  ushort hs[4] = {hv.x, hv.y, hv.z, hv.w};
  float d[VPT];
#pragma unroll
  for (int i = 0; i < VPT; ++i) {
    int c = l * 4 + i;
    float m = cs[c] * invM;
    float var = csq[c] * invM - m * m;
    float v = (bf2f(hs[i]) + bias[c] - m) * rsqrtf(var + EPS_BN) * g[c] + be[c];
    d[i] = v / (1.f + expf(-v));   // SiLU
  }
  float mx = d[0];
#pragma unroll
  for (int i = 1; i < VPT; ++i) mx = fmaxf(mx, d[i]);
  for (int o = 32; o > 0; o >>= 1) mx = fmaxf(mx, __shfl_xor(mx, o));
  float se = 0.f;
  float e[VPT];
#pragma unroll
  for (int i = 0; i < VPT; ++i) { d[i] -= mx; e[i] = expf(d[i]); se += e[i]; }
  for (int o = 32; o > 0; o >>= 1) se += __shfl_xor(se, o);
  float inv = 1.f / se;
  float pd = 0.f;
#pragma unroll
  for (int i = 0; i < VPT; ++i) { e[i] *= inv; pd += e[i] * d[i]; }
  if (active) {
    ushort4 u; u.x = f2bf(e[0]); u.y = f2bf(e[1]); u.z = f2bf(e[2]); u.w = f2bf(e[3]);
    *(ushort4*)(outb + base + l * 4) = u;
  }
  for (int o = 32; o > 0; o >>= 1) pd += __shfl_xor(pd, o);
  if (l == 0) went[wid] = active ? (logf(se) - pd) : 0.f;
  __syncthreads();
  if (threadIdx.x == 0) part[blockIdx.x] = went[0] + went[1] + went[2] + went[3];
}

// ---------------- softmax + entropy (level-2, fp32 in/out) ----------------
template <int C>
__global__ void k_softmax_ent3(float* __restrict__ X, float* __restrict__ part, int nrows) {
  constexpr int VPT = C / 64;
  __shared__ float went[4];
  int gt = blockIdx.x * blockDim.x + threadIdx.x;
  int row = gt >> 6;
  int l = gt & 63;
  int wid = threadIdx.x >> 6;
  bool active = row < nrows;
  size_t base = active ? (size_t)row * C : 0;
  float d[VPT];
  d[0] = X[base + l];
  float mx = d[0];
  for (int o = 32; o > 0; o >>= 1) mx = fmaxf(mx, __shfl_xor(mx, o));
  float se = 0.f;
  float e[VPT];
#pragma unroll
  for (int i = 0; i < VPT; ++i) { d[i] -= mx; e[i] = expf(d[i]); se += e[i]; }
  for (int o = 32; o > 0; o >>= 1) se += __shfl_xor(se, o);
  float inv = 1.f / se;
  float pd = 0.f;
#pragma unroll
  for (int i = 0; i < VPT; ++i) { e[i] *= inv; pd += e[i] * d[i]; }
  if (active) X[base + l] = e[0];
  for (int o = 32; o > 0; o >>= 1) pd += __shfl_xor(pd, o);
  if (l == 0) went[wid] = active ? (logf(se) - pd) : 0.f;
  __syncthreads();
  if (threadIdx.x == 0) part[blockIdx.x] = went[0] + went[1] + went[2] + went[3];
}

__global__ __launch_bounds__(256) void k_reduce_atom(
    const float* __restrict__ in, int n, float* __restrict__ out) {
  __shared__ float sh[256];
  int t = threadIdx.x;
  int per = (n + gridDim.x - 1) / gridDim.x;
  int i0 = blockIdx.x * per, i1 = min(i0 + per, n);
  float s = 0.f;
  for (int i = i0 + t; i < i1; i += 256) s += in[i];
  sh[t] = s; __syncthreads();
  for (int o = 128; o > 0; o >>= 1) { if (t < o) sh[t] += sh[t + o]; __syncthreads(); }
  if (t == 0) atomicAdd(out, sh[0]);
}

__global__ __launch_bounds__(256) void k_scalN_par(
    const float* __restrict__ P0, const float* __restrict__ P1, int K,
    float* __restrict__ outb, int Z) {
  __shared__ float sh[256];
  int b = blockIdx.x, t = threadIdx.x;
  float s = 0.f;
  int slot;
  if (b == 0) {
    slot = 0;
    for (int i = t; i < K; i += 256) s += P0[(size_t)i * K + i];
  } else {
    int which = (b - 1) / Z;
    int chunk = (b - 1) % Z;
    slot = 1 + which;
    const float4* P4 = (const float4*)(which ? P0 : P1);
    int n4 = (K * K) >> 2;
    int per = (n4 + Z - 1) / Z;
    int i0 = chunk * per, i1 = min(i0 + per, n4);
    for (int i = i0 + t; i < i1; i += 256) {
      float4 v = P4[i];
      s += v.x * v.x + v.y * v.y + v.z * v.z + v.w * v.w;
    }
  }
  sh[t] = s; __syncthreads();
  for (int o = 128; o > 0; o >>= 1) { if (t < o) sh[t] += sh[t + o]; __syncthreads(); }
  if (t == 0) atomicAdd(&outb[slot], sh[0]);
}

__global__ __launch_bounds__(256) void k_scal2_par(
    const float* __restrict__ U, const float* __restrict__ V, int n,
    const float* __restrict__ P, int nP, float* __restrict__ outb, int Z) {
  __shared__ float sh[256];
  int b = blockIdx.x, t = threadIdx.x;
  float s = 0.f;
  int slot;
  if (b < Z) {
    slot = 0;
    const float4* U4 = (const float4*)U;
    const float4* V4 = (const float4*)V;
    int n4 = n >> 2;
    int per = (n4 + Z - 1) / Z;
    int i0 = b * per, i1 = min(i0 + per, n4);
    for (int i = i0 + t; i < i1; i += 256) {
      float4 u = U4[i], v = V4[i];
      s += u.x * v.x + u.y * v.y + u.z * v.z + u.w * v.w;
    }
  } else {
    slot = 1;
    const float4* P4 = (const float4*)P;
    int n4 = nP >> 2;
    for (int i = t; i < n4; i += 256) {
      float4 v = P4[i];
      s += v.x * v.x + v.y * v.y + v.z * v.z + v.w * v.w;
    }
  }
  sh[t] = s; __syncthreads();
  for (int o = 128; o > 0; o >>= 1) { if (t < o) sh[t] += sh[t + o]; __syncthreads(); }
  if (t == 0) atomicAdd(&outb[slot], sh[0]);
}

// ---------------- level-2 dense graph (A2T = apool^T layout) ----------------

__global__ __launch_bounds__(256) void k_deg2_par(
    const float* __restrict__ A2T, float* __restrict__ dinv2, int Np) {
  __shared__ float sh[256];
  int q = blockIdx.x;
  int t = threadIdx.x;
  float s = (t == 0) ? 1.0f : 0.f;
  for (int p = t; p < Np; p += 256) s += A2T[(size_t)q * Np + p];
  sh[t] = s; __syncthreads();
  for (int o = 128; o > 0; o >>= 1) { if (t < o) sh[t] += sh[t + o]; __syncthreads(); }
  if (t == 0) {
    float d = sh[0];
    dinv2[q] = d > 0.f ? rsqrtf(fmaxf(d, 1e-12f)) : 0.f;
  }
}

__global__ void k_dense_agg(const float* __restrict__ A2T, const float* __restrict__ dinv2,
                            const float* __restrict__ H, float* __restrict__ out,
                            int Np, int C) {
  int q = blockIdx.x, c = threadIdx.x;
  float acc = 0.f;
#pragma unroll 8
  for (int p = 0; p < Np; ++p)
    acc += dinv2[p] * A2T[(size_t)q * Np + p] * H[(size_t)p * C + c];
  float dq = dinv2[q];
  out[(size_t)q * C + c] = dq * acc + dq * dq * H[(size_t)q * C + c];
}

// ---------------- fused tail TN products (level 2), LDS-staged ----------------
__global__ __launch_bounds__(256) void k_tn3(
    const float* __restrict__ S, const float* __restrict__ B2,
    float* __restrict__ sts2, float* __restrict__ xp2, int M) {
  __shared__ float As[64][65];
  __shared__ float Bs[64][65];
  int z = blockIdx.x;
  const float* B; float* C; int J, j0;
  if (z == 0) { B = S;  C = sts2; J = 64;  j0 = 0; }
  else        { B = B2; C = xp2;  J = 128; j0 = (z - 1) * 64; }
  int t = threadIdx.x;
  int tj = t & 63, ti = t >> 6;
  float acc[16] = {};
  for (int m0 = 0; m0 < M; m0 += 64) {
#pragma unroll
    for (int r = 0; r < 16; ++r) {
      As[ti * 16 + r][tj] = S[(size_t)(m0 + ti * 16 + r) * 64 + tj];
      Bs[ti * 16 + r][tj] = B[(size_t)(m0 + ti * 16 + r) * J + j0 + tj];
    }
    __syncthreads();
#pragma unroll 4
    for (int mm = 0; mm < 64; ++mm) {
      float bv = Bs[mm][tj];
#pragma unroll
      for (int ii = 0; ii < 16; ++ii) acc[ii] += As[mm][ti * 16 + ii] * bv;
    }
    __syncthreads();
  }
  for (int ii = 0; ii < 16; ++ii) C[(size_t)(ti * 16 + ii) * J + j0 + tj] = acc[ii];
}

// ---------------- final head ----------------
__global__ void k_final(const float* __restrict__ xp2, const float* __restrict__ Wlin,
                        const float* __restrict__ blin, const float* __restrict__ scal,
                        float* __restrict__ out, int N1, int E1, int K1, int K2, int OUT) {
  __shared__ float pooled[128];
  __shared__ float logits[32];
  int t = threadIdx.x;
  float s = 0.f;
  for (int r = 0; r < K2; ++r) s += xp2[(size_t)r * 128 + t];
  pooled[t] = s / (float)K2;
  __syncthreads();
  if (t < OUT) {
    float acc = blin[t];
    for (int k = 0; k < 128; ++k) acc += pooled[k] * Wlin[(size_t)k * OUT + t];
    logits[t] = acc;
  }
  __syncthreads();
  if (t == 0) {
    float mx = logits[0];
    for (int j = 1; j < OUT; ++j) mx = fmaxf(mx, logits[j]);
    float se = 0.f;
    for (int j = 0; j < OUT; ++j) se += expf(logits[j] - mx);
    float lse = mx + logf(se);
    for (int j = 0; j < OUT; ++j) out[j] = logits[j] - lse;
    float n1 = (float)N1;
    float ent1 = scal[0] / n1;
    float ent2 = scal[1] / (float)K1;
    float link1 = sqrtf(fmaxf((float)E1 - 2.f * scal[2] + scal[3], 0.f)) / (n1 * n1);
    float link2 = sqrtf(fmaxf(scal[4] - 2.f * scal[5] + scal[6], 0.f)) / ((float)K1 * (float)K1);
    out[OUT] = ent1 + ent2 + link1 + link2;
  }
}

// ---------------- host ----------------

extern "C" void kernel_launch(void* const* d_in, const int* in_sizes, int n_in,
                              void* d_out, int out_size, void* d_ws, size_t ws_size,
                              hipStream_t stream) {
  (void)n_in; (void)out_size; (void)ws_size;
  const float* x = (const float*)d_in[0];
  const int* ei  = (const int*)d_in[1];
  const int N = in_sizes[0] / 128;   // 20000
  const int E = in_sizes[1] / 2;     // 640000
  const int* src = ei;
  const int* dst = ei + E;
  const float *W1a=(const float*)d_in[4],  *b1a=(const float*)d_in[5],
              *g1a=(const float*)d_in[6],  *be1a=(const float*)d_in[7];
  const float *W1b=(const float*)d_in[8],  *b1b=(const float*)d_in[9],
              *g1b=(const float*)d_in[10], *be1b=(const float*)d_in[11];
  const float *Wp1=(const float*)d_in[12], *bp1=(const float*)d_in[13],
              *gp1=(const float*)d_in[14], *bep1=(const float*)d_in[15];
  const float *W2a=(const float*)d_in[16], *b2a=(const float*)d_in[17],
              *g2a=(const float*)d_in[18], *be2a=(const float*)d_in[19];
  const float *W2b=(const float*)d_in[20], *b2b=(const float*)d_in[21],
              *g2b=(const float*)d_in[22], *be2b=(const float*)d_in[23];
  const float *Wp2=(const float*)d_in[24], *bp2=(const float*)d_in[25],
              *gp2=(const float*)d_in[26], *bep2=(const float*)d_in[27];
  const float *Wlin=(const float*)d_in[28], *blin=(const float*)d_in[29];
  const int K1 = in_sizes[12] / 128;   // 256
  const int K2 = in_sizes[24] / 128;   // 64
  const int OUT = in_sizes[29];        // 10

  char* base = (char*)d_ws;
  size_t off = 0;
  auto allocb = [&](size_t bytes) -> void* {
    void* p = (void*)(base + off);
    off += ((bytes + 255) & ~(size_t)255);
    return p;
  };
  auto alloc = [&](size_t nf) -> float* { return (float*)allocb(nf * 4); };
  auto alloci = [&](size_t ni) -> int* { return (int*)allocb(ni * 4); };
  auto allocu = [&](size_t nu) -> ushort* { return (ushort*)allocb(nu * 2); };

  auto cdiv = [](long long a, long long b) { return (int)((a + b - 1) / b); };

  const int RPB = 16;
  const int NBLK1 = cdiv(N, RPB);
  const int NTILES = cdiv(N, 1024);

  float* scal  = alloc(16);
  float* cs    = alloc(256);
  float* csq   = alloc(256);
  float* dinv  = alloc(N);
  float* dinv2 = alloc(K1);
  float* apT   = alloc((size_t)K1 * K1);
  float* sts   = alloc((size_t)K1 * K1);
  float* xp    = alloc((size_t)K1 * 128);
  float* h2    = alloc((size_t)K1 * 128);
  float* y2    = alloc((size_t)K1 * 128);
  float* xa2   = alloc((size_t)K1 * 128);
  float* x2f   = alloc((size_t)K1 * 128);
  float* s2b   = alloc((size_t)K1 * K2);
  float* U     = alloc((size_t)K1 * K2);
  float* sts2  = alloc((size_t)K2 * K2);
  float* xp2   = alloc((size_t)K2 * 128);
  float* ent1p = alloc(cdiv(N, 4) + 8);
  float* ent2p = alloc(64 + 8);
  float* csp   = alloc((size_t)(NBLK1 + 2) * 512);
  float* R1 = alloc((size_t)N * 128);   // St bf16 [K1,N]
  float* R2 = alloc((size_t)N * 128);   // ATSt bf16 [K1,N]
  float* R3 = alloc((size_t)N * K1);    // Hb/aggB/Sb bf16 [N,K1]
  float* R4 = alloc((size_t)N * K1);    // gather out fp32 / Pb bf16 / ATSb bf16
  ushort* B16A = allocu((size_t)N * 128);  // xb -> R1b -> R2b
  ushort* R2tb = allocu((size_t)N * 128);  // x^T bf16 [128,N]
  ushort* W1at = allocu(128 * 128);
  ushort* W1bt = allocu(128 * 128);
  ushort* Wp1t = allocu((size_t)K1 * 128);
  int* cnt_d = alloci((size_t)N + 64);
  int* flags = cnt_d + N;
  int* parts = cnt_d + N + 32;
  int* rp_d  = alloci(N + 1);
  int* cur_d = alloci(N);
  int* col_s = alloci(E);

  ushort* Hb   = (ushort*)R3;   // [N,128] bf16 GEMM out (blocks a,b)
  ushort* aggB = (ushort*)R3;   // [N,128] bf16 aggregated input (pooling)
  ushort* Sb   = (ushort*)R3;   // [N,K1] bf16 S
  ushort* Pb   = (ushort*)R4;   // [N,K1] bf16 pooling GEMM out
  ushort* ATSb = (ushort*)R4;   // [N,K1] bf16 A^T S (after Pb dead)
  ushort* St   = (ushort*)R1;   // [K1,N] bf16
  ushort* ATSt = (ushort*)R2;   // [K1,N] bf16

  hipMemsetAsync(scal, 0, 16 * sizeof(float), stream);

  // ---- prologue ----
  hipMemsetAsync(cnt_d, 0, ((size_t)N + 64) * sizeof(int), stream);
  {
    int HB = cdiv(E, 256);
    int CB = cdiv((size_t)N * 128 / 4, 256);
    k_pre<<<HB + CB, 256, 0, stream>>>(dst, cnt_d, E, x, B16A, N * 128 / 4, HB);
  }
  k_scan_par<<<NTILES, 256, 0, stream>>>(cnt_d, rp_d, cur_d, dinv, flags, parts, N, E);
  k_fill_csr<<<cdiv(E, 256), 256, 0, stream>>>(dst, src, cur_d, col_s, E);

  {
    dim3 b32(32, 8);
    k_tconv3<<<dim3(8, 4, 3), b32, 0, stream>>>(W1a, W1b, Wp1, W1at, W1bt, Wp1t, K1);
  }

  auto mfma_nt = [&](const ushort* A, const ushort* B, float* C, ushort* Cb,
                     int I, int J, int K) {
    dim3 g(J / 64, cdiv(I, 64), 1);
    k_mfma_nt<<<g, 256, 0, stream>>>(A, B, C, Cb, I, J, K, K, 0);
  };
  auto gemm_nn = [&](const float* A, const float* B, float* C, int M, int Nn, int K) {
    dim3 g(Nn / 64, cdiv(M, 64));
    k_sgemm_nn<<<g, 256, 0, stream>>>(A, B, C, M, Nn, K);
  };

  // level-1 blocks a,b: GEMM(bf16) -> gather(fp32) -> BN/SiLU(+bf16 resid) -> bf16
  auto block1 = [&](const float* b, const float* gg, const float* be,
                    const ushort* Wt, const ushort* residb) {
    mfma_nt(B16A, Wt, nullptr, Hb, N, 128, 128);
    k_gather_agg_b2<<<N, 64, 0, stream>>>(rp_d, col_s, dinv, Hb, R4, 64);
    k_col_stats2<<<NBLK1, 128, 0, stream>>>(R4, b, csp, N, 128, RPB);
    k_colred_par<<<128, 256, 0, stream>>>(csp, NBLK1, 128, cs, csq);
    int tot = N * 128;
    k_bn_silu<<<cdiv(tot, 256), 256, 0, stream>>>(R4, b, cs, csq, gg, be, residb, B16A,
                                                  tot, 127, 1.f / N);
  };

  block1(b1a, g1a, be1a, W1at, nullptr);   // B16A <- R1b
  block1(b1b, g1b, be1b, W1bt, B16A);      // B16A <- R2b (resid = R1b in-place)

  // pooling: agg in input space (bf16), GEMM -> Pb bf16, stats, fused BN+softmax -> Sb
  k_gather_agg_b2b<<<N, 64, 0, stream>>>(rp_d, col_s, dinv, B16A, aggB, 64);
  mfma_nt(aggB, Wp1t, nullptr, Pb, N, K1, 128);
  k_col_stats2b<<<NBLK1, K1, 0, stream>>>(Pb, bp1, csp, N, K1, RPB);
  k_colred_par<<<K1, 256, 0, stream>>>(csp, NBLK1, K1, cs, csq);
  k_bn_softmax<256><<<cdiv(N, 4), 256, 0, stream>>>(Pb, bp1, cs, csq, gp1, bep1,
                                                    Sb, ent1p, N, 1.f / N);
  k_reduce_atom<<<8, 256, 0, stream>>>(ent1p, cdiv(N, 4), &scal[0]);

  {
    dim3 b32(32, 8);
    k_tconv_b<<<dim3(K1 / 32, cdiv(N, 32)), b32, 0, stream>>>(Sb, St, N, K1);     // St
    k_tconv_b<<<dim3(128 / 32, cdiv(N, 32)), b32, 0, stream>>>(B16A, R2tb, N, 128); // x^T
  }
  k_gather_T_b2b<<<N, K1 / 2, 0, stream>>>(rp_d, col_s, Sb, ATSb, K1 / 2);
  {
    dim3 b32(32, 8);
    k_tconv_b<<<dim3(K1 / 32, cdiv(N, 32)), b32, 0, stream>>>(ATSb, ATSt, N, K1);
  }

  {
    hipMemsetAsync(apT, 0, (size_t)(2 * K1 * K1 + K1 * 128) * sizeof(float), stream);
    int chunk = ((cdiv(N, 16) + 31) & ~31);
    int z = cdiv(N, chunk);
    k_mfma3<<<dim3(10, 4, z), 256, 0, stream>>>(St, ATSt, R2tb, apT, sts, xp, N, chunk);
  }
  k_scalN_par<<<1 + 2 * 16, 256, 0, stream>>>(apT, sts, K1, &scal[2], 16);

  // ---------------- level 2 ----------------
  k_deg2_par<<<K1, 256, 0, stream>>>(apT, dinv2, K1);

  auto block2 = [&](const float* xin, const float* W, const float* b, const float* gg,
                    const float* be, const float* resid, float* outp, int C) {
    gemm_nn(xin, W, h2, K1, C, 128);
    k_dense_agg<<<K1, C, 0, stream>>>(apT, dinv2, h2, y2, K1, C);
    k_bn_small<<<C, 256, 0, stream>>>(y2, b, gg, be, resid, outp, K1, C, 1.f / K1);
  };

  block2(xp,  W2a, b2a, g2a, be2a, nullptr, xa2, 128);
  block2(xa2, W2b, b2b, g2b, be2b, xa2,     x2f, 128);
  block2(x2f, Wp2, bp2, gp2, bep2, nullptr, s2b, K2);
  k_softmax_ent3<64><<<cdiv(K1, 4), 256, 0, stream>>>(s2b, ent2p, K1);
  k_reduce_atom<<<2, 256, 0, stream>>>(ent2p, cdiv(K1, 4), &scal[1]);

  gemm_nn(apT, s2b, U, K1, K2, K1);
  k_tn3<<<3, 256, 0, stream>>>(s2b, x2f, sts2, xp2, K1);
  k_scal2_par<<<8 + 1, 256, 0, stream>>>(U, s2b, K1 * K2, sts2, K2 * K2, &scal[5], 8);

  k_final<<<1, 128, 0, stream>>>(xp2, Wlin, blin, scal, (float*)d_out, N, E, K1, K2, OUT);
}

// Round 13
// 508.946 us; speedup vs baseline: 5.6531x; 1.0127x over previous
//
#include <hip/hip_runtime.h>

#define EPS_BN 1e-5f
typedef unsigned int uint;
typedef unsigned short ushort;
typedef __attribute__((ext_vector_type(8))) short bf16x8;
typedef __attribute__((ext_vector_type(4))) float f32x4;

__device__ inline ushort f2bf(float f) {
  uint u = __float_as_uint(f);
  uint r = (u + 0x7FFFu + ((u >> 16) & 1u)) >> 16;
  return (ushort)r;
}
__device__ inline float bflo(uint h) { return __uint_as_float(h << 16); }
__device__ inline float bfhi(uint h) { return __uint_as_float(h & 0xFFFF0000u); }
__device__ inline float bf2f(ushort h) { return __uint_as_float(((uint)h) << 16); }

// ---------------- fused prologue: dst-histogram + x -> bf16 ----------------

__global__ void k_pre(const int* __restrict__ dst, int* __restrict__ cnt, int E,
                      const float* __restrict__ x, ushort* __restrict__ xb, int n4, int HB) {
  int b = blockIdx.x;
  if (b < HB) {
    int e = b * 256 + threadIdx.x;
    if (e < E) atomicAdd(&cnt[dst[e]], 1);
  } else {
    int i = (b - HB) * 256 + threadIdx.x;
    if (i < n4) {
      float4 v = ((const float4*)x)[i];
      ushort4 o;
      o.x = f2bf(v.x); o.y = f2bf(v.y); o.z = f2bf(v.z); o.w = f2bf(v.w);
      ((ushort4*)xb)[i] = o;
    }
  }
}

// ---------------- parallel chained scan ----------------
__global__ __launch_bounds__(256) void k_scan_par(
    const int* __restrict__ cnt, int* __restrict__ rowptr, int* __restrict__ cursor,
    float* __restrict__ dinv, int* __restrict__ flags, int* __restrict__ partials,
    int N, int E) {
  __shared__ int wsum[4];
  __shared__ int sbase;
  int tile = blockIdx.x;
  int t = threadIdx.x;
  int lane = t & 63, w = t >> 6;
  int i0 = tile * 1024 + t * 4;
  int c[4];
#pragma unroll
  for (int j = 0; j < 4; ++j) {
    int i = i0 + j;
    c[j] = (i < N) ? cnt[i] : 0;
  }
  int p1 = c[0], p2 = p1 + c[1], p3 = p2 + c[2];
  int tsum = p3 + c[3];
  int incl = tsum;
  for (int o = 1; o < 64; o <<= 1) {
    int v = __shfl_up(incl, o);
    if (lane >= o) incl += v;
  }
  int excl = incl - tsum;
  if (lane == 63) wsum[w] = incl;
  __syncthreads();
  if (t == 0) {
    int tot = wsum[0] + wsum[1] + wsum[2] + wsum[3];
    int basev = 0;
    if (tile > 0) {
      while (atomicAdd(&flags[tile - 1], 0) == 0) {}
      basev = atomicAdd(&partials[tile - 1], 0);
    }
    atomicExch(&partials[tile], basev + tot);
    __threadfence();
    atomicExch(&flags[tile], 1);
    sbase = basev;
  }
  __syncthreads();
  int base = sbase;
  for (int ww = 0; ww < w; ++ww) base += wsum[ww];
  base += excl;
  int pre[4] = {0, p1, p2, p3};
#pragma unroll
  for (int j = 0; j < 4; ++j) {
    int i = i0 + j;
    if (i < N) {
      int run = base + pre[j];
      rowptr[i] = run; cursor[i] = run;
      dinv[i] = rsqrtf(1.0f + (float)c[j]);
    }
  }
  if (tile == 0 && t == 0) rowptr[N] = E;
}

__global__ void k_fill_csr(const int* __restrict__ key, const int* __restrict__ val,
                           int* __restrict__ cursor, int* __restrict__ col, int E) {
  int e = blockIdx.x * blockDim.x + threadIdx.x;
  if (e < E) {
    int pos = atomicAdd(&cursor[key[e]], 1);
    col[pos] = val[e];
  }
}

// ---------------- gather aggregation ----------------

__global__ void k_gather_agg_b2(const int* __restrict__ rowptr, const int* __restrict__ col,
                                const float* __restrict__ dinv, const ushort* __restrict__ H,
                                float* __restrict__ out, int C2) {
  int d = blockIdx.x;
  int c2 = threadIdx.x;
  const uint* H2 = (const uint*)H;
  int b = rowptr[d], e = rowptr[d + 1];
  float a0 = 0.f, a1 = 0.f;
#pragma unroll 4
  for (int i = b; i < e; ++i) {
    int s = col[i];
    float dv = dinv[s];
    uint h = H2[(size_t)s * C2 + c2];
    a0 += dv * bflo(h);
    a1 += dv * bfhi(h);
  }
  float dd = dinv[d];
  uint hd = H2[(size_t)d * C2 + c2];
  float2 o;
  o.x = dd * a0 + dd * dd * bflo(hd);
  o.y = dd * a1 + dd * dd * bfhi(hd);
  *(float2*)(out + (size_t)d * (C2 * 2) + c2 * 2) = o;
}

__global__ void k_gather_agg_b2b(const int* __restrict__ rowptr, const int* __restrict__ col,
                                 const float* __restrict__ dinv, const ushort* __restrict__ H,
                                 ushort* __restrict__ out, int C2) {
  int d = blockIdx.x;
  int c2 = threadIdx.x;
  const uint* H2 = (const uint*)H;
  int b = rowptr[d], e = rowptr[d + 1];
  float a0 = 0.f, a1 = 0.f;
#pragma unroll 4
  for (int i = b; i < e; ++i) {
    int s = col[i];
    float dv = dinv[s];
    uint h = H2[(size_t)s * C2 + c2];
    a0 += dv * bflo(h);
    a1 += dv * bfhi(h);
  }
  float dd = dinv[d];
  uint hd = H2[(size_t)d * C2 + c2];
  ushort2 o;
  o.x = f2bf(dd * a0 + dd * dd * bflo(hd));
  o.y = f2bf(dd * a1 + dd * dd * bfhi(hd));
  *(ushort2*)(out + (size_t)d * (C2 * 2) + c2 * 2) = o;
}

__global__ void k_gather_T_b2b(const int* __restrict__ rowptr, const int* __restrict__ col,
                               const ushort* __restrict__ S, ushort* __restrict__ T, int C2) {
  int s = blockIdx.x;
  int c2 = threadIdx.x;
  const uint* S2 = (const uint*)S;
  int b = rowptr[s], e = rowptr[s + 1];
  float a0 = 0.f, a1 = 0.f;
#pragma unroll 4
  for (int i = b; i < e; ++i) {
    int d = col[i];
    uint h = S2[(size_t)d * C2 + c2];
    a0 += bflo(h);
    a1 += bfhi(h);
  }
  ushort2 o; o.x = f2bf(a0); o.y = f2bf(a1);
  *(ushort2*)(T + (size_t)s * (C2 * 2) + c2 * 2) = o;
}

// ---------------- transposes ----------------

__global__ void k_tconv_b(const ushort* __restrict__ in, ushort* __restrict__ out,
                          int R, int Cc) {
  __shared__ ushort tile[32][33];
  int c0 = blockIdx.x * 32, r0 = blockIdx.y * 32;
  int tx = threadIdx.x, ty = threadIdx.y;
  for (int i = 0; i < 32; i += 8) {
    int r = r0 + ty + i, c = c0 + tx;
    if (r < R && c < Cc) tile[ty + i][tx] = in[(size_t)r * Cc + c];
  }
  __syncthreads();
  for (int i = 0; i < 32; i += 8) {
    int oc = c0 + ty + i;
    int orr = r0 + tx;
    if (oc < Cc && orr < R) out[(size_t)oc * R + orr] = tile[tx][ty + i];
  }
}

// merged: z=0 Sb[N,K1]->St; z=1 B16A[N,128]->R2tb (x<4)
__global__ void k_tconv_b2(const ushort* __restrict__ Sb, ushort* __restrict__ St,
                           const ushort* __restrict__ Xb, ushort* __restrict__ Xt,
                           int N, int K1) {
  __shared__ ushort tile[32][33];
  int z = blockIdx.z;
  const ushort* in; ushort* out; int Cc;
  if (z == 0) { in = Sb; out = St; Cc = K1; }
  else        { in = Xb; out = Xt; Cc = 128; }
  int c0 = blockIdx.x * 32, r0 = blockIdx.y * 32;
  if (c0 >= Cc) return;
  int tx = threadIdx.x, ty = threadIdx.y;
  for (int i = 0; i < 32; i += 8) {
    int r = r0 + ty + i, c = c0 + tx;
    if (r < N && c < Cc) tile[ty + i][tx] = in[(size_t)r * Cc + c];
  }
  __syncthreads();
  for (int i = 0; i < 32; i += 8) {
    int oc = c0 + ty + i;
    int orr = r0 + tx;
    if (oc < Cc && orr < N) out[(size_t)oc * N + orr] = tile[tx][ty + i];
  }
}

__global__ void k_tconv3(const float* __restrict__ W0, const float* __restrict__ W1,
                         const float* __restrict__ W2,
                         ushort* __restrict__ O0, ushort* __restrict__ O1,
                         ushort* __restrict__ O2, int K1) {
  __shared__ float tile[32][33];
  int z = blockIdx.z;
  const float* in = (z == 0) ? W0 : (z == 1) ? W1 : W2;
  ushort* out = (z == 0) ? O0 : (z == 1) ? O1 : O2;
  int Cc = (z == 2) ? K1 : 128;
  int R = 128;
  int c0 = blockIdx.x * 32, r0 = blockIdx.y * 32;
  if (c0 >= Cc) return;
  int tx = threadIdx.x, ty = threadIdx.y;
  for (int i = 0; i < 32; i += 8) {
    int r = r0 + ty + i, c = c0 + tx;
    if (r < R && c < Cc) tile[ty + i][tx] = in[(size_t)r * Cc + c];
  }
  __syncthreads();
  for (int i = 0; i < 32; i += 8) {
    int oc = c0 + ty + i;
    int orr = r0 + tx;
    if (oc < Cc && orr < R) out[(size_t)oc * R + orr] = f2bf(tile[tx][ty + i]);
  }
}

// ---------------- bf16 MFMA NT GEMM ----------------
__global__ __launch_bounds__(256) void k_mfma_nt(
    const ushort* __restrict__ A, const ushort* __restrict__ B, float* __restrict__ C,
    ushort* __restrict__ Cb, int I, int J, int K, int kChunk, int atom) {
  __shared__ ushort As[64][40];
  __shared__ ushort Bs[64][40];
  int t = threadIdx.x;
  int w = t >> 6, l = t & 63;
  int i0 = blockIdx.y * 64, j0 = blockIdx.x * 64;
  int k0 = blockIdx.z * kChunk;
  int k1 = min(k0 + kChunk, K);
  f32x4 acc[4] = {};
  int lrow = t >> 2;
  int lk = (t & 3) * 8;
  for (int kk = k0; kk < k1; kk += 32) {
    uint4 av = make_uint4(0u, 0u, 0u, 0u);
    int ar = i0 + lrow;
    if (ar < I) av = *(const uint4*)(A + (size_t)ar * K + kk + lk);
    uint4 bv = *(const uint4*)(B + (size_t)(j0 + lrow) * K + kk + lk);
    *(uint4*)&As[lrow][lk] = av;
    *(uint4*)&Bs[lrow][lk] = bv;
    __syncthreads();
    bf16x8 af = *(const bf16x8*)&As[16 * w + (l & 15)][(l >> 4) * 8];
#pragma unroll
    for (int jt = 0; jt < 4; ++jt) {
      bf16x8 bf = *(const bf16x8*)&Bs[16 * jt + (l & 15)][(l >> 4) * 8];
      acc[jt] = __builtin_amdgcn_mfma_f32_16x16x32_bf16(af, bf, acc[jt], 0, 0, 0);
    }
    __syncthreads();
  }
  int rbase = i0 + 16 * w + ((l >> 4) * 4);
  int cbase = j0 + (l & 15);
#pragma unroll
  for (int jt = 0; jt < 4; ++jt) {
#pragma unroll
    for (int rr = 0; rr < 4; ++rr) {
      int r = rbase + rr;
      if (r < I) {
        size_t idx = (size_t)r * J + jt * 16 + cbase;
        if (Cb) Cb[idx] = f2bf(acc[jt][rr]);
        else if (atom) atomicAdd(&C[idx], acc[jt][rr]);
        else C[idx] = acc[jt][rr];
      }
    }
  }
}

// merged 3-in-1 TN products
__global__ __launch_bounds__(256) void k_mfma3(
    const ushort* __restrict__ St, const ushort* __restrict__ ATSt,
    const ushort* __restrict__ R2t,
    float* __restrict__ apT, float* __restrict__ sts, float* __restrict__ xp,
    int K, int kChunk) {
  __shared__ ushort As[64][40];
  __shared__ ushort Bs[64][40];
  int xb_ = blockIdx.x;
  const ushort* B; float* C; int J, j0;
  if (xb_ < 4)      { B = ATSt; C = apT; J = 256; j0 = xb_ * 64; }
  else if (xb_ < 8) { B = St;   C = sts; J = 256; j0 = (xb_ - 4) * 64; }
  else              { B = R2t;  C = xp;  J = 128; j0 = (xb_ - 8) * 64; }
  int t = threadIdx.x;
  int w = t >> 6, l = t & 63;
  int i0 = blockIdx.y * 64;
  int k0 = blockIdx.z * kChunk;
  int k1 = min(k0 + kChunk, K);
  f32x4 acc[4] = {};
  int lrow = t >> 2;
  int lk = (t & 3) * 8;
  for (int kk = k0; kk < k1; kk += 32) {
    uint4 av = *(const uint4*)(St + (size_t)(i0 + lrow) * K + kk + lk);
    uint4 bv = *(const uint4*)(B + (size_t)(j0 + lrow) * K + kk + lk);
    *(uint4*)&As[lrow][lk] = av;
    *(uint4*)&Bs[lrow][lk] = bv;
    __syncthreads();
    bf16x8 af = *(const bf16x8*)&As[16 * w + (l & 15)][(l >> 4) * 8];
#pragma unroll
    for (int jt = 0; jt < 4; ++jt) {
      bf16x8 bf = *(const bf16x8*)&Bs[16 * jt + (l & 15)][(l >> 4) * 8];
      acc[jt] = __builtin_amdgcn_mfma_f32_16x16x32_bf16(af, bf, acc[jt], 0, 0, 0);
    }
    __syncthreads();
  }
  int rbase = i0 + 16 * w + ((l >> 4) * 4);
  int cbase = j0 + (l & 15);
#pragma unroll
  for (int jt = 0; jt < 4; ++jt) {
#pragma unroll
    for (int rr = 0; rr < 4; ++rr) {
      atomicAdd(&C[(size_t)(rbase + rr) * J + jt * 16 + cbase], acc[jt][rr]);
    }
  }
}

// ---------------- fp32 GEMM (small, level-2) ----------------
__global__ __launch_bounds__(256) void k_sgemm_nn(
    const float* __restrict__ A, const float* __restrict__ B, float* __restrict__ C,
    int M, int N, int K) {
  __shared__ float As[16][64];
  __shared__ float Bs[16][68];
  int t = threadIdx.x;
  int tx = t & 15, ty = t >> 4;
  int row0 = blockIdx.y * 64, col0 = blockIdx.x * 64;
  float acc[4][4] = {};
  for (int k0 = 0; k0 < K; k0 += 16) {
    int ar = t >> 2;
    int ak = (t & 3) * 4;
    float4 av = make_float4(0.f, 0.f, 0.f, 0.f);
    if (row0 + ar < M) av = *(const float4*)(A + (size_t)(row0 + ar) * K + k0 + ak);
    As[ak + 0][ar] = av.x; As[ak + 1][ar] = av.y;
    As[ak + 2][ar] = av.z; As[ak + 3][ar] = av.w;
    int bk = t >> 4;
    int bc = (t & 15) * 4;
    float4 bv = *(const float4*)(B + (size_t)(k0 + bk) * N + col0 + bc);
    *(float4*)&Bs[bk][bc] = bv;
    __syncthreads();
#pragma unroll
    for (int k = 0; k < 16; ++k) {
      float a[4], b[4];
#pragma unroll
      for (int u = 0; u < 4; ++u) a[u] = As[k][ty * 4 + u];
#pragma unroll
      for (int v = 0; v < 4; ++v) b[v] = Bs[k][tx * 4 + v];
#pragma unroll
      for (int u = 0; u < 4; ++u)
#pragma unroll
        for (int v = 0; v < 4; ++v) acc[u][v] += a[u] * b[v];
    }
    __syncthreads();
  }
#pragma unroll
  for (int u = 0; u < 4; ++u) {
    int r = row0 + ty * 4 + u;
    if (r < M) {
#pragma unroll
      for (int v = 0; v < 4; ++v) C[(size_t)r * N + col0 + tx * 4 + v] = acc[u][v];
    }
  }
}

// GEMM whose result is only needed for dot(C, V): accumulate atomically, no C write.
// dotOut += sum_{r,c} (A@B)[r,c] * V[r,c]
__global__ __launch_bounds__(256) void k_sgemm_dot(
    const float* __restrict__ A, const float* __restrict__ B, const float* __restrict__ V,
    float* __restrict__ dotOut, int M, int N, int K) {
  __shared__ float As[16][64];
  __shared__ float Bs[16][68];
  __shared__ float red[256];
  int t = threadIdx.x;
  int tx = t & 15, ty = t >> 4;
  int row0 = blockIdx.y * 64, col0 = blockIdx.x * 64;
  float acc[4][4] = {};
  for (int k0 = 0; k0 < K; k0 += 16) {
    int ar = t >> 2;
    int ak = (t & 3) * 4;
    float4 av = make_float4(0.f, 0.f, 0.f, 0.f);
    if (row0 + ar < M) av = *(const float4*)(A + (size_t)(row0 + ar) * K + k0 + ak);
    As[ak + 0][ar] = av.x; As[ak + 1][ar] = av.y;
    As[ak + 2][ar] = av.z; As[ak + 3][ar] = av.w;
    int bk = t >> 4;
    int bc = (t & 15) * 4;
    float4 bv = *(const float4*)(B + (size_t)(k0 + bk) * N + col0 + bc);
    *(float4*)&Bs[bk][bc] = bv;
    __syncthreads();
#pragma unroll
    for (int k = 0; k < 16; ++k) {
      float a[4], b[4];
#pragma unroll
      for (int u = 0; u < 4; ++u) a[u] = As[k][ty * 4 + u];
#pragma unroll
      for (int v = 0; v < 4; ++v) b[v] = Bs[k][tx * 4 + v];
#pragma unroll
      for (int u = 0; u < 4; ++u)
#pragma unroll
        for (int v = 0; v < 4; ++v) acc[u][v] += a[u] * b[v];
    }
    __syncthreads();
  }
  float s = 0.f;
#pragma unroll
  for (int u = 0; u < 4; ++u) {
    int r = row0 + ty * 4 + u;
    if (r < M) {
#pragma unroll
      for (int v = 0; v < 4; ++v)
        s += acc[u][v] * V[(size_t)r * N + col0 + tx * 4 + v];
    }
  }
  red[t] = s; __syncthreads();
  for (int o = 128; o > 0; o >>= 1) { if (t < o) red[t] += red[t + o]; __syncthreads(); }
  if (t == 0) atomicAdd(dotOut, red[0]);
}

// ---------------- BN stats ----------------

__global__ void k_col_stats2(const float* __restrict__ X, const float* __restrict__ bias,
                             float* __restrict__ part, int M, int C, int rpb) {
  int c = threadIdx.x;
  int b = blockIdx.x;
  int r0 = b * rpb, r1 = min(r0 + rpb, M);
  float bi = bias[c];
  float s = 0.f, sq = 0.f;
  for (int r = r0; r < r1; ++r) {
    float v = X[(size_t)r * C + c] + bi;
    s += v; sq += v * v;
  }
  part[(size_t)b * 2 * C + c] = s;
  part[(size_t)b * 2 * C + C + c] = sq;
}

__global__ void k_col_stats2b(const ushort* __restrict__ X, const float* __restrict__ bias,
                              float* __restrict__ part, int M, int C, int rpb) {
  int c = threadIdx.x;
  int b = blockIdx.x;
  int r0 = b * rpb, r1 = min(r0 + rpb, M);
  float bi = bias[c];
  float s = 0.f, sq = 0.f;
  for (int r = r0; r < r1; ++r) {
    float v = bf2f(X[(size_t)r * C + c]) + bi;
    s += v; sq += v * v;
  }
  part[(size_t)b * 2 * C + c] = s;
  part[(size_t)b * 2 * C + C + c] = sq;
}

__global__ __launch_bounds__(256) void k_colred_par(
    const float* __restrict__ part, int nblk, int C,
    float* __restrict__ cs, float* __restrict__ csq) {
  __shared__ float sh[256];
  int c = blockIdx.x;
  int t = threadIdx.x;
  float s = 0.f, sq = 0.f;
  for (int b = t; b < nblk; b += 256) {
    s  += part[(size_t)b * 2 * C + c];
    sq += part[(size_t)b * 2 * C + C + c];
  }
  sh[t] = s; __syncthreads();
  for (int o = 128; o > 0; o >>= 1) { if (t < o) sh[t] += sh[t + o]; __syncthreads(); }
  if (t == 0) cs[c] = sh[0];
  __syncthreads();
  sh[t] = sq; __syncthreads();
  for (int o = 128; o > 0; o >>= 1) { if (t < o) sh[t] += sh[t + o]; __syncthreads(); }
  if (t == 0) csq[c] = sh[0];
}

__global__ void k_bn_silu(const float* __restrict__ X, const float* __restrict__ bias,
                          const float* __restrict__ cs, const float* __restrict__ csq,
                          const float* __restrict__ g, const float* __restrict__ be,
                          const ushort* __restrict__ residb, ushort* __restrict__ outb,
                          int tot, int cmask, float invM) {
  int i = blockIdx.x * blockDim.x + threadIdx.x;
  if (i >= tot) return;
  int c = i & cmask;
  float m = cs[c] * invM;
  float var = csq[c] * invM - m * m;
  float v = (X[i] + bias[c] - m) * rsqrtf(var + EPS_BN) * g[c] + be[c];
  float y = v / (1.f + expf(-v));
  if (residb) y += bf2f(residb[i]);
  outb[i] = f2bf(y);
}

// ---------------- fused small BN (level-2, M<=256) ----------------
__global__ __launch_bounds__(256) void k_bn_small(
    const float* __restrict__ X, const float* __restrict__ bias,
    const float* __restrict__ g, const float* __restrict__ be,
    const float* __restrict__ resid, float* __restrict__ out,
    int M, int C, float invM) {
  __shared__ float sh[256];
  int c = blockIdx.x;
  int t = threadIdx.x;
  bool act = t < M;
  float v = 0.f;
  if (act) v = X[(size_t)t * C + c] + bias[c];
  sh[t] = v; __syncthreads();
  for (int o = 128; o > 0; o >>= 1) { if (t < o) sh[t] += sh[t + o]; __syncthreads(); }
  float m = sh[0] * invM; __syncthreads();
  sh[t] = v * v; __syncthreads();
  for (int o = 128; o > 0; o >>= 1) { if (t < o) sh[t] += sh[t + o]; __syncthreads(); }
  float var = sh[0] * invM - m * m;
  if (act) {
    float y = (v - m) * rsqrtf(var + EPS_BN) * g[c] + be[c];
    y = y / (1.f + expf(-y));
    if (resid) y += resid[(size_t)t * C + c];
    out[(size_t)t * C + c] = y;
  }
}

// ---------------- fused BN + SiLU + softmax + entropy (pooling, C=256) ----------------
template <int C>
__global__ void k_bn_softmax(const ushort* __restrict__ H, const float* __restrict__ bias,
                             const float* __restrict__ cs, const float* __restrict__ csq,
                             const float* __restrict__ g, const float* __restrict__ be,
                             ushort* __restrict__ outb, float* __restrict__ part,
                             int nrows, float invM) {
  constexpr int VPT = C / 64;
  __shared__ float went[4];
  int gt = blockIdx.x * blockDim.x + threadIdx.x;
  int row = gt >> 6;
  int l = gt & 63;
  int wid = threadIdx.x >> 6;
  bool active = row < nrows;
  size_t base = active ? (size_t)row * C : 0;
  ushort4 hv = *(const ushort4*)(H + base + l * 4);
  ushort hs[4] = {hv.x, hv.y, hv.z, hv.w};
  float d[VPT];
#pragma unroll
  for (int i = 0; i < VPT; ++i) {
    int c = l * 4 + i;
    float m = cs[c] * invM;
    float var = csq[c] * invM - m * m;
    float v = (bf2f(hs[i]) + bias[c] - m) * rsqrtf(var + EPS_BN) * g[c] + be[c];
    d[i] = v / (1.f + expf(-v));
  }
  float mx = d[0];
#pragma unroll
  for (int i = 1; i < VPT; ++i) mx = fmaxf(mx, d[i]);
  for (int o = 32; o > 0; o >>= 1) mx = fmaxf(mx, __shfl_xor(mx, o));
  float se = 0.f;
  float e[VPT];
#pragma unroll
  for (int i = 0; i < VPT; ++i) { d[i] -= mx; e[i] = expf(d[i]); se += e[i]; }
  for (int o = 32; o > 0; o >>= 1) se += __shfl_xor(se, o);
  float inv = 1.f / se;
  float pd = 0.f;
#pragma unroll
  for (int i = 0; i < VPT; ++i) { e[i] *= inv; pd += e[i] * d[i]; }
  if (active) {
    ushort4 u; u.x = f2bf(e[0]); u.y = f2bf(e[1]); u.z = f2bf(e[2]); u.w = f2bf(e[3]);
    *(ushort4*)(outb + base + l * 4) = u;
  }
  for (int o = 32; o > 0; o >>= 1) pd += __shfl_xor(pd, o);
  if (l == 0) went[wid] = active ? (logf(se) - pd) : 0.f;
  __syncthreads();
  if (threadIdx.x == 0) part[blockIdx.x] = went[0] + went[1] + went[2] + went[3];
}

// ---------------- softmax + entropy (level-2, direct atomic) ----------------
template <int C>
__global__ void k_softmax_ent3(float* __restrict__ X, float* __restrict__ entOut, int nrows) {
  constexpr int VPT = C / 64;
  __shared__ float went[4];
  int gt = blockIdx.x * blockDim.x + threadIdx.x;
  int row = gt >> 6;
  int l = gt & 63;
  int wid = threadIdx.x >> 6;
  bool active = row < nrows;
  size_t base = active ? (size_t)row * C : 0;
  float d[VPT];
  d[0] = X[base + l];
  float mx = d[0];
  for (int o = 32; o > 0; o >>= 1) mx = fmaxf(mx, __shfl_xor(mx, o));
  float se = 0.f;
  float e[VPT];
#pragma unroll
  for (int i = 0; i < VPT; ++i) { d[i] -= mx; e[i] = expf(d[i]); se += e[i]; }
  for (int o = 32; o > 0; o >>= 1) se += __shfl_xor(se, o);
  float inv = 1.f / se;
  float pd = 0.f;
#pragma unroll
  for (int i = 0; i < VPT; ++i) { e[i] *= inv; pd += e[i] * d[i]; }
  if (active) X[base + l] = e[0];
  for (int o = 32; o > 0; o >>= 1) pd += __shfl_xor(pd, o);
  if (l == 0) went[wid] = active ? (logf(se) - pd) : 0.f;
  __syncthreads();
  if (threadIdx.x == 0)
    atomicAdd(entOut, went[0] + went[1] + went[2] + went[3]);
}

__global__ __launch_bounds__(256) void k_reduce_atom(
    const float* __restrict__ in, int n, float* __restrict__ out) {
  __shared__ float sh[256];
  int t = threadIdx.x;
  int per = (n + gridDim.x - 1) / gridDim.x;
  int i0 = blockIdx.x * per, i1 = min(i0 + per, n);
  float s = 0.f;
  for (int i = i0 + t; i < i1; i += 256) s += in[i];
  sh[t] = s; __syncthreads();
  for (int o = 128; o > 0; o >>= 1) { if (t < o) sh[t] += sh[t + o]; __syncthreads(); }
  if (t == 0) atomicAdd(out, sh[0]);
}

// merged: scalars from mfma3 outputs + level-2 degree.
// b==0: trace(apT) -> outb[0]; b in [1,Z]: sumsq(sts) chunks -> outb[1];
// b in (Z,2Z]: sumsq(apT) chunks -> outb[2]; b >= 1+2Z: deg2 row q = b-(1+2Z).
__global__ __launch_bounds__(256) void k_post1(
    const float* __restrict__ apT, const float* __restrict__ sts, int K,
    float* __restrict__ outb, int Z, float* __restrict__ dinv2) {
  __shared__ float sh[256];
  int b = blockIdx.x, t = threadIdx.x;
  int nsc = 1 + 2 * Z;
  float s = 0.f;
  if (b >= nsc) {
    int q = b - nsc;
    s = (t == 0) ? 1.0f : 0.f;
    for (int p = t; p < K; p += 256) s += apT[(size_t)q * K + p];
    sh[t] = s; __syncthreads();
    for (int o = 128; o > 0; o >>= 1) { if (t < o) sh[t] += sh[t + o]; __syncthreads(); }
    if (t == 0) {
      float d = sh[0];
      dinv2[q] = d > 0.f ? rsqrtf(fmaxf(d, 1e-12f)) : 0.f;
    }
    return;
  }
  int slot;
  if (b == 0) {
    slot = 0;
    for (int i = t; i < K; i += 256) s += apT[(size_t)i * K + i];
  } else {
    int which = (b - 1) / Z;       // 0 -> sts, 1 -> apT
    int chunk = (b - 1) % Z;
    slot = 1 + which;
    const float4* P4 = (const float4*)(which ? apT : sts);
    int n4 = (K * K) >> 2;
    int per = (n4 + Z - 1) / Z;
    int i0 = chunk * per, i1 = min(i0 + per, n4);
    for (int i = i0 + t; i < i1; i += 256) {
      float4 v = P4[i];
      s += v.x * v.x + v.y * v.y + v.z * v.z + v.w * v.w;
    }
  }
  sh[t] = s; __syncthreads();
  for (int o = 128; o > 0; o >>= 1) { if (t < o) sh[t] += sh[t + o]; __syncthreads(); }
  if (t == 0) atomicAdd(&outb[slot], sh[0]);
}

__global__ void k_dense_agg(const float* __restrict__ A2T, const float* __restrict__ dinv2,
                            const float* __restrict__ H, float* __restrict__ out,
                            int Np, int C) {
  int q = blockIdx.x, c = threadIdx.x;
  float acc = 0.f;
#pragma unroll 8
  for (int p = 0; p < Np; ++p)
    acc += dinv2[p] * A2T[(size_t)q * Np + p] * H[(size_t)p * C + c];
  float dq = dinv2[q];
  out[(size_t)q * C + c] = dq * acc + dq * dq * H[(size_t)q * C + c];
}

// ---------------- fused tail TN products; z=0 computes sumsq(S^T S) only ----------------
__global__ __launch_bounds__(256) void k_tn3(
    const float* __restrict__ S, const float* __restrict__ B2,
    float* __restrict__ stsq, float* __restrict__ xp2, int M) {
  __shared__ float As[64][65];
  __shared__ float Bs[64][65];
  int z = blockIdx.x;
  const float* B; int J, j0;
  if (z == 0) { B = S;  J = 64;  j0 = 0; }
  else        { B = B2; J = 128; j0 = (z - 1) * 64; }
  int t = threadIdx.x;
  int tj = t & 63, ti = t >> 6;
  float acc[16] = {};
  for (int m0 = 0; m0 < M; m0 += 64) {
#pragma unroll
    for (int r = 0; r < 16; ++r) {
      As[ti * 16 + r][tj] = S[(size_t)(m0 + ti * 16 + r) * 64 + tj];
      Bs[ti * 16 + r][tj] = B[(size_t)(m0 + ti * 16 + r) * J + j0 + tj];
    }
    __syncthreads();
#pragma unroll 4
    for (int mm = 0; mm < 64; ++mm) {
      float bv = Bs[mm][tj];
#pragma unroll
      for (int ii = 0; ii < 16; ++ii) acc[ii] += As[mm][ti * 16 + ii] * bv;
    }
    __syncthreads();
  }
  if (z == 0) {
    // sumsq of the 64x64 S^T S tile (entirely in this block)
    float s = 0.f;
#pragma unroll
    for (int ii = 0; ii < 16; ++ii) s += acc[ii] * acc[ii];
    __syncthreads();
    As[0][t < 64 ? t : 64] = 0.f;  // reuse LDS safely via separate array below
    __shared__ float red[256];
    red[t] = s; __syncthreads();
    for (int o = 128; o > 0; o >>= 1) { if (t < o) red[t] += red[t + o]; __syncthreads(); }
    if (t == 0) *stsq = red[0];
  } else {
    for (int ii = 0; ii < 16; ++ii) xp2[(size_t)(ti * 16 + ii) * J + j0 + tj] = acc[ii];
  }
}

// ---------------- final head ----------------
__global__ void k_final(const float* __restrict__ xp2, const float* __restrict__ Wlin,
                        const float* __restrict__ blin, const float* __restrict__ scal,
                        float* __restrict__ out, int N1, int E1, int K1, int K2, int OUT) {
  __shared__ float pooled[128];
  __shared__ float logits[32];
  int t = threadIdx.x;
  float s = 0.f;
  for (int r = 0; r < K2; ++r) s += xp2[(size_t)r * 128 + t];
  pooled[t] = s / (float)K2;
  __syncthreads();
  if (t < OUT) {
    float acc = blin[t];
    for (int k = 0; k < 128; ++k) acc += pooled[k] * Wlin[(size_t)k * OUT + t];
    logits[t] = acc;
  }
  __syncthreads();
  if (t == 0) {
    float mx = logits[0];
    for (int j = 1; j < OUT; ++j) mx = fmaxf(mx, logits[j]);
    float se = 0.f;
    for (int j = 0; j < OUT; ++j) se += expf(logits[j] - mx);
    float lse = mx + logf(se);
    for (int j = 0; j < OUT; ++j) out[j] = logits[j] - lse;
    float n1 = (float)N1;
    float ent1 = scal[0] / n1;
    float ent2 = scal[1] / (float)K1;
    float link1 = sqrtf(fmaxf((float)E1 - 2.f * scal[2] + scal[3], 0.f)) / (n1 * n1);
    float link2 = sqrtf(fmaxf(scal[4] - 2.f * scal[5] + scal[6], 0.f)) / ((float)K1 * (float)K1);
    out[OUT] = ent1 + ent2 + link1 + link2;
  }
}

// ---------------- host ----------------

extern "C" void kernel_launch(void* const* d_in, const int* in_sizes, int n_in,
                              void* d_out, int out_size, void* d_ws, size_t ws_size,
                              hipStream_t stream) {
  (void)n_in; (void)out_size; (void)ws_size;
  const float* x = (const float*)d_in[0];
  const int* ei  = (const int*)d_in[1];
  const int N = in_sizes[0] / 128;   // 20000
  const int E = in_sizes[1] / 2;     // 640000
  const int* src = ei;
  const int* dst = ei + E;
  const float *W1a=(const float*)d_in[4],  *b1a=(const float*)d_in[5],
              *g1a=(const float*)d_in[6],  *be1a=(const float*)d_in[7];
  const float *W1b=(const float*)d_in[8],  *b1b=(const float*)d_in[9],
              *g1b=(const float*)d_in[10], *be1b=(const float*)d_in[11];
  const float *Wp1=(const float*)d_in[12], *bp1=(const float*)d_in[13],
              *gp1=(const float*)d_in[14], *bep1=(const float*)d_in[15];
  const float *W2a=(const float*)d_in[16], *b2a=(const float*)d_in[17],
              *g2a=(const float*)d_in[18], *be2a=(const float*)d_in[19];
  const float *W2b=(const float*)d_in[20], *b2b=(const float*)d_in[21],
              *g2b=(const float*)d_in[22], *be2b=(const float*)d_in[23];
  const float *Wp2=(const float*)d_in[24], *bp2=(const float*)d_in[25],
              *gp2=(const float*)d_in[26], *bep2=(const float*)d_in[27];
  const float *Wlin=(const float*)d_in[28], *blin=(const float*)d_in[29];
  const int K1 = in_sizes[12] / 128;   // 256
  const int K2 = in_sizes[24] / 128;   // 64
  const int OUT = in_sizes[29];        // 10

  char* base = (char*)d_ws;
  size_t off = 0;
  auto allocb = [&](size_t bytes) -> void* {
    void* p = (void*)(base + off);
    off += ((bytes + 255) & ~(size_t)255);
    return p;
  };
  auto alloc = [&](size_t nf) -> float* { return (float*)allocb(nf * 4); };
  auto alloci = [&](size_t ni) -> int* { return (int*)allocb(ni * 4); };
  auto allocu = [&](size_t nu) -> ushort* { return (ushort*)allocb(nu * 2); };

  auto cdiv = [](long long a, long long b) { return (int)((a + b - 1) / b); };

  const int RPB = 16;
  const int NBLK1 = cdiv(N, RPB);
  const int NTILES = cdiv(N, 1024);

  float* scal  = alloc(16);
  float* cs    = alloc(256);
  float* csq   = alloc(256);
  float* dinv  = alloc(N);
  float* dinv2 = alloc(K1);
  float* apT   = alloc((size_t)K1 * K1);
  float* sts   = alloc((size_t)K1 * K1);
  float* xp    = alloc((size_t)K1 * 128);
  float* h2    = alloc((size_t)K1 * 128);
  float* y2    = alloc((size_t)K1 * 128);
  float* xa2   = alloc((size_t)K1 * 128);
  float* x2f   = alloc((size_t)K1 * 128);
  float* s2b   = alloc((size_t)K1 * K2);
  float* xp2   = alloc((size_t)K2 * 128);
  float* ent1p = alloc(cdiv(N, 4) + 8);
  float* csp   = alloc((size_t)(NBLK1 + 2) * 512);
  float* R1 = alloc((size_t)N * 128);
  float* R2 = alloc((size_t)N * 128);
  float* R3 = alloc((size_t)N * K1);
  float* R4 = alloc((size_t)N * K1);
  ushort* B16A = allocu((size_t)N * 128);
  ushort* R2tb = allocu((size_t)N * 128);
  ushort* W1at = allocu(128 * 128);
  ushort* W1bt = allocu(128 * 128);
  ushort* Wp1t = allocu((size_t)K1 * 128);
  int* cnt_d = alloci((size_t)N + 64);
  int* flags = cnt_d + N;
  int* parts = cnt_d + N + 32;
  int* rp_d  = alloci(N + 1);
  int* cur_d = alloci(N);
  int* col_s = alloci(E);

  ushort* Hb   = (ushort*)R3;
  ushort* aggB = (ushort*)R3;
  ushort* Sb   = (ushort*)R3;
  ushort* Pb   = (ushort*)R4;
  ushort* ATSb = (ushort*)R4;
  ushort* St   = (ushort*)R1;
  ushort* ATSt = (ushort*)R2;

  hipMemsetAsync(scal, 0, 16 * sizeof(float), stream);

  // ---- prologue ----
  hipMemsetAsync(cnt_d, 0, ((size_t)N + 64) * sizeof(int), stream);
  {
    int HB = cdiv(E, 256);
    int CB = cdiv((size_t)N * 128 / 4, 256);
    k_pre<<<HB + CB, 256, 0, stream>>>(dst, cnt_d, E, x, B16A, N * 128 / 4, HB);
  }
  k_scan_par<<<NTILES, 256, 0, stream>>>(cnt_d, rp_d, cur_d, dinv, flags, parts, N, E);
  k_fill_csr<<<cdiv(E, 256), 256, 0, stream>>>(dst, src, cur_d, col_s, E);

  {
    dim3 b32(32, 8);
    k_tconv3<<<dim3(8, 4, 3), b32, 0, stream>>>(W1a, W1b, Wp1, W1at, W1bt, Wp1t, K1);
  }

  auto mfma_nt = [&](const ushort* A, const ushort* B, float* C, ushort* Cb,
                     int I, int J, int K) {
    dim3 g(J / 64, cdiv(I, 64), 1);
    k_mfma_nt<<<g, 256, 0, stream>>>(A, B, C, Cb, I, J, K, K, 0);
  };
  auto gemm_nn = [&](const float* A, const float* B, float* C, int M, int Nn, int K) {
    dim3 g(Nn / 64, cdiv(M, 64));
    k_sgemm_nn<<<g, 256, 0, stream>>>(A, B, C, M, Nn, K);
  };

  // level-1 blocks a,b
  auto block1 = [&](const float* b, const float* gg, const float* be,
                    const ushort* Wt, const ushort* residb) {
    mfma_nt(B16A, Wt, nullptr, Hb, N, 128, 128);
    k_gather_agg_b2<<<N, 64, 0, stream>>>(rp_d, col_s, dinv, Hb, R4, 64);
    k_col_stats2<<<NBLK1, 128, 0, stream>>>(R4, b, csp, N, 128, RPB);
    k_colred_par<<<128, 256, 0, stream>>>(csp, NBLK1, 128, cs, csq);
    int tot = N * 128;
    k_bn_silu<<<cdiv(tot, 256), 256, 0, stream>>>(R4, b, cs, csq, gg, be, residb, B16A,
                                                  tot, 127, 1.f / N);
  };

  block1(b1a, g1a, be1a, W1at, nullptr);
  block1(b1b, g1b, be1b, W1bt, B16A);

  // pooling block
  k_gather_agg_b2b<<<N, 64, 0, stream>>>(rp_d, col_s, dinv, B16A, aggB, 64);
  mfma_nt(aggB, Wp1t, nullptr, Pb, N, K1, 128);
  k_col_stats2b<<<NBLK1, K1, 0, stream>>>(Pb, bp1, csp, N, K1, RPB);
  k_colred_par<<<K1, 256, 0, stream>>>(csp, NBLK1, K1, cs, csq);
  k_bn_softmax<256><<<cdiv(N, 4), 256, 0, stream>>>(Pb, bp1, cs, csq, gp1, bep1,
                                                    Sb, ent1p, N, 1.f / N);
  k_reduce_atom<<<8, 256, 0, stream>>>(ent1p, cdiv(N, 4), &scal[0]);

  // merged transposes: St = S^T, R2tb = x^T
  {
    dim3 b32(32, 8);
    k_tconv_b2<<<dim3(K1 / 32, cdiv(N, 32), 2), b32, 0, stream>>>(Sb, St, B16A, R2tb, N, K1);
  }
  k_gather_T_b2b<<<N, K1 / 2, 0, stream>>>(rp_d, col_s, Sb, ATSb, K1 / 2);
  {
    dim3 b32(32, 8);
    k_tconv_b<<<dim3(K1 / 32, cdiv(N, 32)), b32, 0, stream>>>(ATSb, ATSt, N, K1);
  }

  {
    hipMemsetAsync(apT, 0, (size_t)(2 * K1 * K1 + K1 * 128) * sizeof(float), stream);
    int chunk = ((cdiv(N, 16) + 31) & ~31);
    int z = cdiv(N, chunk);
    k_mfma3<<<dim3(10, 4, z), 256, 0, stream>>>(St, ATSt, R2tb, apT, sts, xp, N, chunk);
  }
  // merged: trace/sumsq scalars + level-2 degree
  k_post1<<<1 + 2 * 16 + K1, 256, 0, stream>>>(apT, sts, K1, &scal[2], 16, dinv2);

  // ---------------- level 2 ----------------
  auto block2 = [&](const float* xin, const float* W, const float* b, const float* gg,
                    const float* be, const float* resid, float* outp, int C) {
    gemm_nn(xin, W, h2, K1, C, 128);
    k_dense_agg<<<K1, C, 0, stream>>>(apT, dinv2, h2, y2, K1, C);
    k_bn_small<<<C, 256, 0, stream>>>(y2, b, gg, be, resid, outp, K1, C, 1.f / K1);
  };

  block2(xp,  W2a, b2a, g2a, be2a, nullptr, xa2, 128);
  block2(xa2, W2b, b2b, g2b, be2b, xa2,     x2f, 128);
  block2(x2f, Wp2, bp2, gp2, bep2, nullptr, s2b, K2);
  k_softmax_ent3<64><<<cdiv(K1, 4), 256, 0, stream>>>(s2b, &scal[1], K1);

  // cross2 = dot(apT@s2, s2) fused into GEMM epilogue (U never materialized)
  {
    dim3 g(K2 / 64, cdiv(K1, 64));
    k_sgemm_dot<<<g, 256, 0, stream>>>(apT, s2b, s2b, &scal[5], K1, K2, K1);
  }
  // sts2 sumsq fused into tn3 z=0 (sts2 never materialized); xp2 in z=1,2
  k_tn3<<<3, 256, 0, stream>>>(s2b, x2f, &scal[6], xp2, K1);

  k_final<<<1, 128, 0, stream>>>(xp2, Wlin, blin, scal, (float*)d_out, N, E, K1, K2, OUT);
}